// Round 1
// baseline (925.030 us; speedup 1.0000x reference)
//
#include <hip/hip_runtime.h>
#include <math.h>

#define NN 4096
#define FF 128
#define HH 32
#define CC 205
#define DD 269
#define LL 512
#define TT 12
#define RR 4
#define KSC 16   // k-split for conv adj passes
#define KSN 4    // k-split for norm pass

// ---------------- reduction helpers ----------------
__device__ __forceinline__ float wave_sum(float v) {
#pragma unroll
  for (int o = 32; o > 0; o >>= 1) v += __shfl_xor(v, o, 64);
  return v;
}
__device__ __forceinline__ float wave_max(float v) {
#pragma unroll
  for (int o = 32; o > 0; o >>= 1) v = fmaxf(v, __shfl_xor(v, o, 64));
  return v;
}
__device__ __forceinline__ float blk_sum(float v, float* red) {
  v = wave_sum(v);
  __syncthreads();
  if ((threadIdx.x & 63) == 0) red[threadIdx.x >> 6] = v;
  __syncthreads();
  return red[0] + red[1] + red[2] + red[3];
}
__device__ __forceinline__ float blk_max(float v, float* red) {
  v = wave_max(v);
  __syncthreads();
  if ((threadIdx.x & 63) == 0) red[threadIdx.x >> 6] = v;
  __syncthreads();
  return fmaxf(fmaxf(red[0], red[1]), fmaxf(red[2], red[3]));
}

// ---------------- small dual projection: o1 = A@W1, o2 = A@W2 (N x 32 outputs) ----------------
__global__ __launch_bounds__(256) void k_proj(const float* __restrict__ A,
                                              const float* __restrict__ W1,
                                              const float* __restrict__ W2,
                                              float* __restrict__ o1,
                                              float* __restrict__ o2, int K) {
  const int idx = blockIdx.x * 256 + threadIdx.x;  // N*32
  const int row = idx >> 5;
  const int c = idx & 31;
  float a1 = 0.f, a2 = 0.f;
  for (int k = 0; k < K; ++k) {
    float av = A[(size_t)row * K + k];
    a1 = fmaf(av, W1[k * HH + c], a1);
    a2 = fmaf(av, W2[k * HH + c], a2);
  }
  o1[idx] = a1;
  o2[idx] = a2;
}

// ---------------- row-normalize x -> xn ----------------
__global__ __launch_bounds__(256) void k_xn(const float* __restrict__ x, float* __restrict__ xn) {
  const int lane = threadIdx.x & 63;
  const int row = blockIdx.x * 4 + (threadIdx.x >> 6);
  float v0 = x[(size_t)row * FF + lane];
  float v1 = x[(size_t)row * FF + 64 + lane];
  float ss = wave_sum(v0 * v0 + v1 * v1);
  float n = fmaxf(sqrtf(ss), 1e-8f);
  xn[(size_t)row * FF + lane] = v0 / n;
  xn[(size_t)row * FF + 64 + lane] = v1 / n;
}

// ---------------- adj @ M (M: N x 32), k-split partials ----------------
// grid: (NN/256, KSC); part layout [split][NN][32]
__global__ __launch_bounds__(256) void k_adjpass(const float* __restrict__ adj,
                                                 const float* __restrict__ M,
                                                 float* __restrict__ part) {
  __shared__ float sA[256][33];
  __shared__ float sB[32][33];
  const int i0 = blockIdx.x * 256;
  const int split = blockIdx.y;
  const int kbase = split * (NN / KSC);
  const int tid = threadIdx.x;
  const int r0 = (tid >> 3) << 3;   // 0..248
  const int c0 = (tid & 7) << 2;    // 0..28
  const int lr = tid >> 3;          // 0..31
  const int lk = (tid & 7) << 2;
  float acc[8][4];
#pragma unroll
  for (int a = 0; a < 8; ++a)
#pragma unroll
    for (int b = 0; b < 4; ++b) acc[a][b] = 0.f;

  for (int kb = 0; kb < NN / KSC; kb += 32) {
#pragma unroll
    for (int rr = 0; rr < 8; ++rr) {
      const float4 v = *reinterpret_cast<const float4*>(
          &adj[(size_t)(i0 + lr + (rr << 5)) * NN + (kbase + kb + lk)]);
      float* dst = &sA[lr + (rr << 5)][lk];
      dst[0] = v.x; dst[1] = v.y; dst[2] = v.z; dst[3] = v.w;
    }
    {
      const float4 v = *reinterpret_cast<const float4*>(
          &M[(size_t)(kbase + kb + (tid >> 3)) * HH + ((tid & 7) << 2)]);
      float* dst = &sB[tid >> 3][(tid & 7) << 2];
      dst[0] = v.x; dst[1] = v.y; dst[2] = v.z; dst[3] = v.w;
    }
    __syncthreads();
#pragma unroll 4
    for (int k = 0; k < 32; ++k) {
      const float b0 = sB[k][c0], b1 = sB[k][c0 + 1], b2 = sB[k][c0 + 2], b3 = sB[k][c0 + 3];
#pragma unroll
      for (int rr = 0; rr < 8; ++rr) {
        const float a = sA[r0 + rr][k];
        acc[rr][0] = fmaf(a, b0, acc[rr][0]);
        acc[rr][1] = fmaf(a, b1, acc[rr][1]);
        acc[rr][2] = fmaf(a, b2, acc[rr][2]);
        acc[rr][3] = fmaf(a, b3, acc[rr][3]);
      }
    }
    __syncthreads();
  }
  float* pp = part + (size_t)split * (NN * HH);
#pragma unroll
  for (int rr = 0; rr < 8; ++rr) {
    float4 o;
    o.x = acc[rr][0]; o.y = acc[rr][1]; o.z = acc[rr][2]; o.w = acc[rr][3];
    *reinterpret_cast<float4*>(&pp[(size_t)(i0 + r0 + rr) * HH + c0]) = o;
  }
}

// ---------------- conv epilogue (32-wide): sum partials + bias + root, relu, BN stats ----------------
__global__ __launch_bounds__(256) void k_epi32(const float* __restrict__ part,
                                               const float* __restrict__ bias,
                                               const float* __restrict__ root,
                                               float* __restrict__ t,
                                               float* __restrict__ colsum,
                                               float* __restrict__ colsq) {
  __shared__ float ls[HH], lq[HH];
  const int tid = threadIdx.x;
  const int idx = blockIdx.x * 256 + tid;
  const int c = idx & (HH - 1);
  if (tid < HH) { ls[tid] = 0.f; lq[tid] = 0.f; }
  __syncthreads();
  float s = bias[c] + root[idx];
#pragma unroll
  for (int sp = 0; sp < KSC; ++sp) s += part[(size_t)sp * (NN * HH) + idx];
  s = fmaxf(s, 0.f);
  t[idx] = s;
  atomicAdd(&ls[c], s);
  atomicAdd(&lq[c], s * s);
  __syncthreads();
  if (tid < HH) {
    atomicAdd(&colsum[tid], ls[tid]);
    atomicAdd(&colsq[tid], lq[tid]);
  }
}

// ---------------- BN finalize: per-col scale/shift ----------------
__global__ void k_bnfinal(const float* __restrict__ colsum, const float* __restrict__ colsq,
                          const float* __restrict__ g, const float* __restrict__ be,
                          float* __restrict__ A, float* __restrict__ B, int Ccols) {
  const int c = threadIdx.x;
  if (c >= Ccols) return;
  const float m = colsum[c] * (1.f / NN);
  const float var = fmaxf(colsq[c] * (1.f / NN) - m * m, 0.f);
  const float a = g[c] / sqrtf(var + 1e-5f);
  A[c] = a;
  B[c] = be[c] - m * a;
}

__global__ __launch_bounds__(256) void k_bnapply32(const float* __restrict__ t,
                                                   const float* __restrict__ A,
                                                   const float* __restrict__ B,
                                                   float* __restrict__ xo,
                                                   float* __restrict__ emb, int embOff) {
  const int idx = blockIdx.x * 256 + threadIdx.x;
  const int c = idx & (HH - 1);
  const int row = idx >> 5;
  const float v = fmaf(A[c], t[idx], B[c]);
  xo[idx] = v;
  emb[(size_t)row * DD + embOff + c] = v;
}

// ---------------- conv3 epilogue: y = (adj@x2)@W3r + b3 + x2@W3root, relu, stats ----------------
// grid: NN/16
__global__ __launch_bounds__(256) void k_epi3(const float* __restrict__ part,
                                              const float* __restrict__ W3r,
                                              const float* __restrict__ b3,
                                              const float* __restrict__ x2,
                                              const float* __restrict__ W3root,
                                              float* __restrict__ t3,
                                              float* __restrict__ colsum,
                                              float* __restrict__ colsq) {
  __shared__ float z[16][33];
  __shared__ float xr[16][33];
  const int row0 = blockIdx.x * 16;
  for (int s = threadIdx.x; s < 16 * 32; s += 256) {
    const int r = s >> 5, k = s & 31;
    float a = 0.f;
#pragma unroll
    for (int sp = 0; sp < KSC; ++sp)
      a += part[(size_t)sp * (NN * HH) + (size_t)(row0 + r) * HH + k];
    z[r][k] = a;
    xr[r][k] = x2[(size_t)(row0 + r) * HH + k];
  }
  __syncthreads();
  const int c = threadIdx.x;
  if (c >= CC) return;
  float acc[16];
  const float bb = b3[c];
#pragma unroll
  for (int r = 0; r < 16; ++r) acc[r] = bb;
  for (int k = 0; k < 32; ++k) {
    const float w1 = W3r[k * CC + c];
    const float w2 = W3root[k * CC + c];
#pragma unroll
    for (int r = 0; r < 16; ++r) acc[r] += z[r][k] * w1 + xr[r][k] * w2;
  }
  float lsm = 0.f, lqm = 0.f;
#pragma unroll
  for (int r = 0; r < 16; ++r) {
    const float v = fmaxf(acc[r], 0.f);
    t3[(size_t)(row0 + r) * CC + c] = v;
    lsm += v;
    lqm += v * v;
  }
  atomicAdd(&colsum[c], lsm);
  atomicAdd(&colsq[c], lqm);
}

__global__ void k_bnapply205(const float* __restrict__ t3, const float* __restrict__ A,
                             const float* __restrict__ B, float* __restrict__ x3,
                             float* __restrict__ emb) {
  const int row = blockIdx.x;
  const int c = threadIdx.x;
  if (c >= CC) return;
  const float v = fmaf(A[c], t3[(size_t)row * CC + c], B[c]);
  x3[(size_t)row * CC + c] = v;
  emb[(size_t)row * DD + 2 * HH + c] = v;
}

// ---------------- layer4: logits -> relu -> softmax (s1) + sn + entropy(e1) ----------------
// grid: NN/16
__global__ __launch_bounds__(256) void k_layer4(const float* __restrict__ x1,
                                                const float* __restrict__ x2,
                                                const float* __restrict__ x3,
                                                const float* __restrict__ Wl1,
                                                const float* __restrict__ bl1,
                                                float* __restrict__ s1,
                                                float* __restrict__ sn,
                                                float* __restrict__ scalars) {
  __shared__ float xr[16][DD + 3];
  __shared__ float red[4];
  const int row0 = blockIdx.x * 16;
  const int tid = threadIdx.x;
  for (int s = tid; s < 16 * DD; s += 256) {
    const int r = s / DD, d = s - r * DD;
    const int row = row0 + r;
    float v;
    if (d < HH) v = x1[(size_t)row * HH + d];
    else if (d < 2 * HH) v = x2[(size_t)row * HH + (d - HH)];
    else v = x3[(size_t)row * CC + (d - 2 * HH)];
    xr[r][d] = v;
  }
  __syncthreads();
  const int c = tid;
  float acc[16];
#pragma unroll
  for (int r = 0; r < 16; ++r) acc[r] = 0.f;
  if (c < CC) {
    const float bias = bl1[c];
#pragma unroll
    for (int r = 0; r < 16; ++r) acc[r] = bias;
    for (int k = 0; k < DD; ++k) {
      const float w = Wl1[(size_t)k * CC + c];
#pragma unroll
      for (int r = 0; r < 16; ++r) acc[r] = fmaf(xr[r][k], w, acc[r]);
    }
  }
  float ent_acc = 0.f;
#pragma unroll
  for (int r = 0; r < 16; ++r) {
    const float v = (c < CC) ? fmaxf(acc[r], 0.f) : -1e30f;
    const float m = blk_max(v, red);
    const float e = (c < CC) ? __expf(v - m) : 0.f;
    const float S = blk_sum(e, red);
    const float p = (c < CC) ? e / S : 0.f;
    const float q = blk_sum(p * p, red);
    const float inv = 1.f / fmaxf(sqrtf(q), 1e-8f);
    if (c < CC) {
      s1[(size_t)(row0 + r) * CC + c] = p;
      sn[(size_t)(row0 + r) * CC + c] = p * inv;
    }
    const float m2 = blk_max((c < CC) ? p : -1e30f, red);
    const float e2 = (c < CC) ? __expf(p - m2) : 0.f;
    const float S2 = blk_sum(e2, red);
    const float s2 = e2 / S2;
    const float term = (c < CC) ? -s2 * logf(s2 + 1e-15f) : 0.f;
    ent_acc += blk_sum(term, red);
  }
  if (tid == 0) atomicAdd(&scalars[2], ent_acc);
}

// ---------------- norm pass: contraction sum(s1 .* (adj@s1)) and sum(adj^2) ----------------
// grid: (NN/64, KSN); 64 rows x 256 cols per block, 8x8 per thread
__global__ __launch_bounds__(256) void k_normpass(const float* __restrict__ adj,
                                                  const float* __restrict__ s1,
                                                  float* __restrict__ scalars) {
  __shared__ float sA[64][33];
  __shared__ float sB[32][8][33];  // [k][c&7][c>>3] layout: conflict-free b-reads
  const int i0 = blockIdx.x * 64;
  const int kbase = blockIdx.y * (NN / KSN);
  const int tid = threadIdx.x;
  const int r0 = (tid >> 5) << 3;  // 8 row-groups of 8
  const int cg = tid & 31;         // col group; c = cg*8 + cc
  float acc[8][8];
#pragma unroll
  for (int a = 0; a < 8; ++a)
#pragma unroll
    for (int b = 0; b < 8; ++b) acc[a][b] = 0.f;
  float adjsq = 0.f;

  for (int kb = 0; kb < NN / KSN; kb += 32) {
#pragma unroll
    for (int rr = 0; rr < 2; ++rr) {
      const int r = (tid >> 3) + (rr << 5);
      const float4 v = *reinterpret_cast<const float4*>(
          &adj[(size_t)(i0 + r) * NN + (kbase + kb + ((tid & 7) << 2))]);
      adjsq += v.x * v.x + v.y * v.y + v.z * v.z + v.w * v.w;
      float* dst = &sA[r][(tid & 7) << 2];
      dst[0] = v.x; dst[1] = v.y; dst[2] = v.z; dst[3] = v.w;
    }
    for (int k = 0; k < 32; ++k) {
      const float v = (tid < CC) ? s1[(size_t)(kbase + kb + k) * CC + tid] : 0.f;
      sB[k][tid & 7][tid >> 3] = v;
    }
    __syncthreads();
#pragma unroll 2
    for (int k = 0; k < 32; ++k) {
      float a[8], b[8];
#pragma unroll
      for (int r = 0; r < 8; ++r) a[r] = sA[r0 + r][k];
#pragma unroll
      for (int cc = 0; cc < 8; ++cc) b[cc] = sB[k][cc][cg];
#pragma unroll
      for (int r = 0; r < 8; ++r)
#pragma unroll
        for (int cc = 0; cc < 8; ++cc) acc[r][cc] = fmaf(a[r], b[cc], acc[r][cc]);
    }
    __syncthreads();
  }
  // contract partial (adj@S) tile against s1 tile
  float part = 0.f;
#pragma unroll
  for (int r = 0; r < 8; ++r) {
#pragma unroll
    for (int cc = 0; cc < 8; ++cc) {
      const int c = cg * 8 + cc;
      if (c < CC) part = fmaf(acc[r][cc], s1[(size_t)(i0 + r0 + r) * CC + c], part);
    }
  }
  part = wave_sum(part);
  adjsq = wave_sum(adjsq);
  if ((tid & 63) == 0) {
    atomicAdd(&scalars[0], part);
    atomicAdd(&scalars[1], adjsq);
  }
}

// ---------------- four Gram matrices in one launch: G=xn'xn, Gxs=xn'sn, Gs=sn'sn, Gs0=s1's1 ----------------
// grid: (4,4,4*8): z = gram_id*8 + split
__global__ __launch_bounds__(256) void k_gram4(const float* __restrict__ xn,
                                               const float* __restrict__ sn,
                                               const float* __restrict__ s1f,
                                               float* __restrict__ G, float* __restrict__ Gxs,
                                               float* __restrict__ Gs, float* __restrict__ Gs0) {
  const int gid = blockIdx.z >> 3;
  const int split = blockIdx.z & 7;
  const float *A, *B;
  float* Cp;
  int Wa, Wb;
  if (gid == 0)      { A = xn;  B = xn;  Cp = G;   Wa = FF; Wb = FF; }
  else if (gid == 1) { A = xn;  B = sn;  Cp = Gxs; Wa = FF; Wb = CC; }
  else if (gid == 2) { A = sn;  B = sn;  Cp = Gs;  Wa = CC; Wb = CC; }
  else               { A = s1f; B = s1f; Cp = Gs0; Wa = CC; Wb = CC; }
  const int tx = blockIdx.x, ty = blockIdx.y;
  if (tx * 64 >= Wa || ty * 64 >= Wb) return;
  __shared__ float sA[32][68];
  __shared__ float sB[32][68];
  const int tid = threadIdx.x;
  const int a0 = (tid >> 4) << 2;
  const int b0 = (tid & 15) << 2;
  const int kb0 = split * (NN / 8);
  float acc[4][4];
#pragma unroll
  for (int i = 0; i < 4; ++i)
#pragma unroll
    for (int j = 0; j < 4; ++j) acc[i][j] = 0.f;

  for (int kb = 0; kb < NN / 8; kb += 32) {
    for (int s = tid; s < 2048; s += 256) {
      const int k = s >> 6, cl = s & 63;
      const int ca = tx * 64 + cl, cb = ty * 64 + cl;
      sA[k][cl] = (ca < Wa) ? A[(size_t)(kb0 + kb + k) * Wa + ca] : 0.f;
      sB[k][cl] = (cb < Wb) ? B[(size_t)(kb0 + kb + k) * Wb + cb] : 0.f;
    }
    __syncthreads();
#pragma unroll 8
    for (int k = 0; k < 32; ++k) {
      const float4 av = *reinterpret_cast<const float4*>(&sA[k][a0]);
      const float4 bv = *reinterpret_cast<const float4*>(&sB[k][b0]);
      acc[0][0] = fmaf(av.x, bv.x, acc[0][0]); acc[0][1] = fmaf(av.x, bv.y, acc[0][1]);
      acc[0][2] = fmaf(av.x, bv.z, acc[0][2]); acc[0][3] = fmaf(av.x, bv.w, acc[0][3]);
      acc[1][0] = fmaf(av.y, bv.x, acc[1][0]); acc[1][1] = fmaf(av.y, bv.y, acc[1][1]);
      acc[1][2] = fmaf(av.y, bv.z, acc[1][2]); acc[1][3] = fmaf(av.y, bv.w, acc[1][3]);
      acc[2][0] = fmaf(av.z, bv.x, acc[2][0]); acc[2][1] = fmaf(av.z, bv.y, acc[2][1]);
      acc[2][2] = fmaf(av.z, bv.z, acc[2][2]); acc[2][3] = fmaf(av.z, bv.w, acc[2][3]);
      acc[3][0] = fmaf(av.w, bv.x, acc[3][0]); acc[3][1] = fmaf(av.w, bv.y, acc[3][1]);
      acc[3][2] = fmaf(av.w, bv.z, acc[3][2]); acc[3][3] = fmaf(av.w, bv.w, acc[3][3]);
    }
    __syncthreads();
  }
#pragma unroll
  for (int r = 0; r < 4; ++r) {
#pragma unroll
    for (int cc = 0; cc < 4; ++cc) {
      const int ca = tx * 64 + a0 + r, cb = ty * 64 + b0 + cc;
      if (ca < Wa && cb < Wb) atomicAdd(&Cp[(size_t)ca * Wb + cb], acc[r][cc]);
    }
  }
}

// ---------------- thin GEMM: C[N x Nc] = A[N x K] @ B[K x Nc], 16 rows per block ----------------
__global__ __launch_bounds__(256) void k_rowmm(const float* __restrict__ A,
                                               const float* __restrict__ B,
                                               float* __restrict__ Cm, int K, int Nc) {
  __shared__ float sA[16][208];
  const int row0 = blockIdx.x * 16;
  for (int s = threadIdx.x; s < 16 * K; s += 256) {
    const int r = s / K, k = s - r * K;
    sA[r][k] = A[(size_t)(row0 + r) * K + k];
  }
  __syncthreads();
  const int c = threadIdx.x;
  if (c >= Nc) return;
  float acc[16];
#pragma unroll
  for (int r = 0; r < 16; ++r) acc[r] = 0.f;
  for (int k = 0; k < K; ++k) {
    const float w = B[(size_t)k * Nc + c];
#pragma unroll
    for (int r = 0; r < 16; ++r) acc[r] = fmaf(sA[r][k], w, acc[r]);
  }
#pragma unroll
  for (int r = 0; r < 16; ++r) Cm[(size_t)(row0 + r) * Nc + c] = acc[r];
}

// ---------------- per-row sim contribution ----------------
__global__ __launch_bounds__(256) void k_simrow(const float* __restrict__ H1,
                                                const float* __restrict__ Uu,
                                                const float* __restrict__ H2,
                                                const float* __restrict__ xn,
                                                const float* __restrict__ sn,
                                                float* __restrict__ scalars) {
  const int lane = threadIdx.x & 63;
  const int row = blockIdx.x * 4 + (threadIdx.x >> 6);
  float suu = 0.f, suv = 0.f, svv = 0.f;
#pragma unroll
  for (int c0 = 0; c0 < FF; c0 += 64) {
    const float xv = xn[(size_t)row * FF + c0 + lane];
    suu = fmaf(H1[(size_t)row * FF + c0 + lane], xv, suu);
  }
  for (int cb = lane; cb < CC; cb += 64) {
    const float sv = sn[(size_t)row * CC + cb];
    suv = fmaf(Uu[(size_t)row * CC + cb], sv, suv);
    svv = fmaf(H2[(size_t)row * CC + cb], sv, svv);
  }
  suu = wave_sum(suu);
  suv = wave_sum(suv);
  svv = wave_sum(svv);
  if (lane == 0) atomicAdd(&scalars[3], suv / sqrtf(suu * svv));
}

// ---------------- team embedding loss ----------------
__global__ __launch_bounds__(256) void k_embloss(const float* __restrict__ emb,
                                                 const int* __restrict__ teams,
                                                 const int* __restrict__ reps,
                                                 float* __restrict__ scalars) {
  const int team = blockIdx.x;
  float part = 0.f;
  for (int d = threadIdx.x; d < DD; d += 256) {
    float a = 0.f, b = 0.f;
#pragma unroll
    for (int m = 0; m < RR; ++m) a += emb[(size_t)reps[team * RR + m] * DD + d];
#pragma unroll
    for (int m = RR; m < TT; ++m) b += emb[(size_t)teams[team * TT + m] * DD + d];
    part += fabsf(a * (1.f / RR) - b * (1.f / (TT - RR)));
  }
  part = wave_sum(part);
  if ((threadIdx.x & 63) == 0) atomicAdd(&scalars[4], part);
}

// ---------------- finalize scalars ----------------
__global__ void k_final(const float* __restrict__ Gs0, const float* __restrict__ scalars,
                        float* __restrict__ outsc) {
  __shared__ float red[4];
  float p = 0.f;
  for (int i = threadIdx.x; i < CC * CC; i += 256) {
    const float v = Gs0[i];
    p = fmaf(v, v, p);
  }
  p = wave_sum(p);
  if ((threadIdx.x & 63) == 0) red[threadIdx.x >> 6] = p;
  __syncthreads();
  if (threadIdx.x == 0) {
    const float sumP2 = red[0] + red[1] + red[2] + red[3];
    const float normsq = fmaxf(sumP2 - 2.f * scalars[0] + scalars[1], 0.f);
    const float norm = sqrtf(normsq);
    const float e1 = scalars[2] * (1.f / NN);
    const float sim = -scalars[3] * (1.f / NN);
    const float embl = scalars[4] * (1.f / LL);
    outsc[0] = norm;
    outsc[1] = e1;
    outsc[2] = sim;
    outsc[3] = 100.f * norm + 10.f * e1 + 100.f * sim + embl;
    outsc[4] = embl;
  }
}

// ================= launch =================
extern "C" void kernel_launch(void* const* d_in, const int* in_sizes, int n_in,
                              void* d_out, int out_size, void* d_ws, size_t ws_size,
                              hipStream_t stream) {
  const float* x      = (const float*)d_in[0];
  const float* adj    = (const float*)d_in[1];
  const int*   teams  = (const int*)d_in[2];
  const int*   reps   = (const int*)d_in[3];
  const float* W1r    = (const float*)d_in[4];
  const float* b1     = (const float*)d_in[5];
  const float* W1root = (const float*)d_in[6];
  const float* g1     = (const float*)d_in[7];
  const float* be1    = (const float*)d_in[8];
  const float* W2r    = (const float*)d_in[9];
  const float* b2     = (const float*)d_in[10];
  const float* W2root = (const float*)d_in[11];
  const float* g2     = (const float*)d_in[12];
  const float* be2    = (const float*)d_in[13];
  const float* W3r    = (const float*)d_in[14];
  const float* b3     = (const float*)d_in[15];
  const float* W3root = (const float*)d_in[16];
  const float* g3     = (const float*)d_in[17];
  const float* be3    = (const float*)d_in[18];
  const float* Wl1    = (const float*)d_in[19];
  const float* bl1    = (const float*)d_in[20];

  float* w = (float*)d_ws;
  auto alloc = [&](size_t n) { float* p = w; w += n; return p; };
  float* xr1    = alloc((size_t)NN * HH);
  float* xroot1 = alloc((size_t)NN * HH);
  float* xr2    = alloc((size_t)NN * HH);
  float* xroot2 = alloc((size_t)NN * HH);
  float* t      = alloc((size_t)NN * HH);
  float* x1     = alloc((size_t)NN * HH);
  float* x2     = alloc((size_t)NN * HH);
  float* part   = alloc((size_t)KSC * NN * HH);
  float* t3     = alloc((size_t)NN * CC);
  float* x3     = alloc((size_t)NN * CC);
  float* sn     = alloc((size_t)NN * CC);
  float* xn     = alloc((size_t)NN * FF);
  float* H1     = alloc((size_t)NN * FF);
  float* Uu     = alloc((size_t)NN * CC);
  float* H2     = alloc((size_t)NN * CC);
  float* G      = alloc((size_t)FF * FF);
  float* Gxs    = alloc((size_t)FF * CC);
  float* Gs     = alloc((size_t)CC * CC);
  float* Gs0    = alloc((size_t)CC * CC);
  float* scalars = alloc(16);
  float* colsum = alloc(256);
  float* colsq  = alloc(256);
  float* bnA    = alloc(256);
  float* bnB    = alloc(256);
  (void)ws_size; (void)in_sizes; (void)n_in; (void)out_size;

  float* out   = (float*)d_out;
  float* s1    = out;                          // N*C
  float* outsc = out + (size_t)NN * CC;        // 5 scalars
  float* emb   = out + (size_t)NN * CC + 5;    // N*D

  // zero accumulators (G..Gs0+scalars contiguous; stats separately)
  const size_t gram_bytes = ((size_t)FF * FF + (size_t)FF * CC + 2 * (size_t)CC * CC + 16) * 4;
  hipMemsetAsync(G, 0, gram_bytes, stream);
  hipMemsetAsync(colsum, 0, 512 * 4, stream);

  // conv1
  k_proj<<<512, 256, 0, stream>>>(x, W1r, W1root, xr1, xroot1, FF);
  k_xn<<<NN / 4, 256, 0, stream>>>(x, xn);
  k_adjpass<<<dim3(NN / 256, KSC), 256, 0, stream>>>(adj, xr1, part);
  k_epi32<<<NN * HH / 256, 256, 0, stream>>>(part, b1, xroot1, t, colsum, colsq);
  k_bnfinal<<<1, 256, 0, stream>>>(colsum, colsq, g1, be1, bnA, bnB, HH);
  k_bnapply32<<<NN * HH / 256, 256, 0, stream>>>(t, bnA, bnB, x1, emb, 0);

  // conv2
  hipMemsetAsync(colsum, 0, 512 * 4, stream);
  k_proj<<<512, 256, 0, stream>>>(x1, W2r, W2root, xr2, xroot2, HH);
  k_adjpass<<<dim3(NN / 256, KSC), 256, 0, stream>>>(adj, xr2, part);
  k_epi32<<<NN * HH / 256, 256, 0, stream>>>(part, b2, xroot2, t, colsum, colsq);
  k_bnfinal<<<1, 256, 0, stream>>>(colsum, colsq, g2, be2, bnA, bnB, HH);
  k_bnapply32<<<NN * HH / 256, 256, 0, stream>>>(t, bnA, bnB, x2, emb, HH);

  // conv3
  hipMemsetAsync(colsum, 0, 512 * 4, stream);
  k_adjpass<<<dim3(NN / 256, KSC), 256, 0, stream>>>(adj, x2, part);
  k_epi3<<<NN / 16, 256, 0, stream>>>(part, W3r, b3, x2, W3root, t3, colsum, colsq);
  k_bnfinal<<<1, 256, 0, stream>>>(colsum, colsq, g3, be3, bnA, bnB, CC);
  k_bnapply205<<<NN, 256, 0, stream>>>(t3, bnA, bnB, x3, emb);

  // head: s1 softmax + sn + entropy
  k_layer4<<<NN / 16, 256, 0, stream>>>(x1, x2, x3, Wl1, bl1, s1, sn, scalars);

  // link-pred norm pieces: tr(S' A S) and sum(adj^2)
  k_normpass<<<dim3(NN / 64, KSN), 256, 0, stream>>>(adj, s1, scalars);

  // Gram matrices
  k_gram4<<<dim3(4, 4, 32), 256, 0, stream>>>(xn, sn, s1, G, Gxs, Gs, Gs0);

  // bilinear-form GEMMs
  k_rowmm<<<NN / 16, 256, 0, stream>>>(xn, G, H1, FF, FF);
  k_rowmm<<<NN / 16, 256, 0, stream>>>(xn, Gxs, Uu, FF, CC);
  k_rowmm<<<NN / 16, 256, 0, stream>>>(sn, Gs, H2, CC, CC);

  // per-row sim, team loss, finalize
  k_simrow<<<NN / 4, 256, 0, stream>>>(H1, Uu, H2, xn, sn, scalars);
  k_embloss<<<LL, 256, 0, stream>>>(emb, teams, reps, scalars);
  k_final<<<1, 256, 0, stream>>>(Gs0, scalars, outsc);
}

// Round 2
// 765.938 us; speedup vs baseline: 1.2077x; 1.2077x over previous
//
#include <hip/hip_runtime.h>
#include <math.h>

#define NN 4096
#define FF 128
#define HH 32
#define CC 205
#define DD 269
#define LL 512
#define TT 12
#define RR 4
#define KS 16    // k-split for all adj MFMA passes

typedef __attribute__((ext_vector_type(8))) short bf16x8;
typedef __attribute__((ext_vector_type(4))) float f32x4;

// ---------------- helpers ----------------
__device__ __forceinline__ float wave_sum(float v) {
#pragma unroll
  for (int o = 32; o > 0; o >>= 1) v += __shfl_xor(v, o, 64);
  return v;
}
__device__ __forceinline__ float wave_max(float v) {
#pragma unroll
  for (int o = 32; o > 0; o >>= 1) v = fmaxf(v, __shfl_xor(v, o, 64));
  return v;
}
__device__ __forceinline__ float blk_sum(float v, float* red) {
  v = wave_sum(v);
  __syncthreads();
  if ((threadIdx.x & 63) == 0) red[threadIdx.x >> 6] = v;
  __syncthreads();
  return red[0] + red[1] + red[2] + red[3];
}
__device__ __forceinline__ float blk_max(float v, float* red) {
  v = wave_max(v);
  __syncthreads();
  if ((threadIdx.x & 63) == 0) red[threadIdx.x >> 6] = v;
  __syncthreads();
  return fmaxf(fmaxf(red[0], red[1]), fmaxf(red[2], red[3]));
}
__device__ __forceinline__ unsigned short f2bf(float x) {  // RNE
  union { float f; unsigned u; } v; v.f = x;
  unsigned r = v.u + 0x7FFFu + ((v.u >> 16) & 1u);
  return (unsigned short)(r >> 16);
}

// ---------------- adj fp32 -> bf16 + sum(adj^2) ----------------
__global__ __launch_bounds__(256) void k_cvt_adj(const float* __restrict__ adj,
                                                 unsigned short* __restrict__ adj_h,
                                                 float* __restrict__ scalars) {
  const size_t nvec = (size_t)NN * NN / 4;
  float acc = 0.f;
  for (size_t i = (size_t)blockIdx.x * 256 + threadIdx.x; i < nvec; i += (size_t)gridDim.x * 256) {
    const float4 v = reinterpret_cast<const float4*>(adj)[i];
    acc += v.x * v.x + v.y * v.y + v.z * v.z + v.w * v.w;
    ushort4 h;
    h.x = f2bf(v.x); h.y = f2bf(v.y); h.z = f2bf(v.z); h.w = f2bf(v.w);
    reinterpret_cast<ushort4*>(adj_h)[i] = h;
  }
  acc = wave_sum(acc);
  if ((threadIdx.x & 63) == 0) atomicAdd(&scalars[1], acc);
}

// ---------------- dual projection: o1T(bf16,[32][N]) = (A@W1)^T, o2(f32,[N][32]) = A@W2 ----------------
__global__ __launch_bounds__(256) void k_proj_t(const float* __restrict__ A,
                                                const float* __restrict__ W1,
                                                const float* __restrict__ W2,
                                                unsigned short* __restrict__ o1T,
                                                float* __restrict__ o2, int K) {
  const int idx = blockIdx.x * 256 + threadIdx.x;  // N*32
  const int row = idx >> 5;
  const int c = idx & 31;
  float a1 = 0.f, a2 = 0.f;
  for (int k = 0; k < K; ++k) {
    const float av = A[(size_t)row * K + k];
    a1 = fmaf(av, W1[k * HH + c], a1);
    a2 = fmaf(av, W2[k * HH + c], a2);
  }
  o1T[(size_t)c * NN + row] = f2bf(a1);
  o2[idx] = a2;
}

// ---------------- row-normalize x -> xn ----------------
__global__ __launch_bounds__(256) void k_xn(const float* __restrict__ x, float* __restrict__ xn) {
  const int lane = threadIdx.x & 63;
  const int row = blockIdx.x * 4 + (threadIdx.x >> 6);
  float v0 = x[(size_t)row * FF + lane];
  float v1 = x[(size_t)row * FF + 64 + lane];
  float ss = wave_sum(v0 * v0 + v1 * v1);
  float n = fmaxf(sqrtf(ss), 1e-8f);
  xn[(size_t)row * FF + lane] = v0 / n;
  xn[(size_t)row * FF + 64 + lane] = v1 / n;
}

// ---------------- MFMA adj pass: part[split] = adj_h[rows] @ M  (M via BT bf16 [32][N]) ----------------
// grid (NN/64, KS), 4 waves/block; wave w owns 16 rows; 2 col-tiles of 16 (32 cols)
__global__ __launch_bounds__(256) void k_adjmm(const unsigned short* __restrict__ adj_h,
                                               const unsigned short* __restrict__ BT,
                                               float* __restrict__ part) {
  const int tid = threadIdx.x;
  const int lane = tid & 63;
  const int w = tid >> 6;
  const int rbase = blockIdx.x * 64 + w * 16;
  const int k0base = blockIdx.y * (NN / KS);
  const int l15 = lane & 15;
  const int kgrp = (lane >> 4) * 8;
  const size_t arow_off = (size_t)(rbase + l15) * NN;
  f32x4 acc0 = {0.f, 0.f, 0.f, 0.f}, acc1 = {0.f, 0.f, 0.f, 0.f};
#pragma unroll
  for (int k0 = 0; k0 < NN / KS; k0 += 32) {
    const int kk = k0base + k0 + kgrp;
    const bf16x8 a = *reinterpret_cast<const bf16x8*>(&adj_h[arow_off + kk]);
    const bf16x8 b0 = *reinterpret_cast<const bf16x8*>(&BT[(size_t)l15 * NN + kk]);
    const bf16x8 b1 = *reinterpret_cast<const bf16x8*>(&BT[(size_t)(16 + l15) * NN + kk]);
    acc0 = __builtin_amdgcn_mfma_f32_16x16x32_bf16(a, b0, acc0, 0, 0, 0);
    acc1 = __builtin_amdgcn_mfma_f32_16x16x32_bf16(a, b1, acc1, 0, 0, 0);
  }
  float* pp = part + (size_t)blockIdx.y * (NN * HH);
  const int rout = rbase + (lane >> 4) * 4;
#pragma unroll
  for (int r = 0; r < 4; ++r) {
    pp[(size_t)(rout + r) * HH + l15] = acc0[r];
    pp[(size_t)(rout + r) * HH + 16 + l15] = acc1[r];
  }
}

// ---------------- MFMA norm pass: scalars[0] += sum( (adj@S1)_partial .* s1 ) ----------------
// grid (NN/64, KS); S1 via s1T bf16 [208][N] (rows 205..207 zero)
__global__ __launch_bounds__(256) void k_normmfma(const unsigned short* __restrict__ adj_h,
                                                  const unsigned short* __restrict__ s1T,
                                                  const float* __restrict__ s1,
                                                  float* __restrict__ scalars) {
  const int tid = threadIdx.x;
  const int lane = tid & 63;
  const int w = tid >> 6;
  const int rbase = blockIdx.x * 64 + w * 16;
  const int k0base = blockIdx.y * (NN / KS);
  const int l15 = lane & 15;
  const int kgrp = (lane >> 4) * 8;
  const size_t arow_off = (size_t)(rbase + l15) * NN;
  f32x4 acc[13];
#pragma unroll
  for (int ct = 0; ct < 13; ++ct) acc[ct] = (f32x4){0.f, 0.f, 0.f, 0.f};
  for (int k0 = 0; k0 < NN / KS; k0 += 32) {
    const int kk = k0base + k0 + kgrp;
    const bf16x8 a = *reinterpret_cast<const bf16x8*>(&adj_h[arow_off + kk]);
#pragma unroll
    for (int ct = 0; ct < 13; ++ct) {
      const bf16x8 b = *reinterpret_cast<const bf16x8*>(&s1T[(size_t)(ct * 16 + l15) * NN + kk]);
      acc[ct] = __builtin_amdgcn_mfma_f32_16x16x32_bf16(a, b, acc[ct], 0, 0, 0);
    }
  }
  const int rout = rbase + (lane >> 4) * 4;
  float sc = 0.f;
#pragma unroll
  for (int ct = 0; ct < 13; ++ct) {
    const int col = ct * 16 + l15;
    if (col < CC) {
#pragma unroll
      for (int r = 0; r < 4; ++r)
        sc = fmaf(acc[ct][r], s1[(size_t)(rout + r) * CC + col], sc);
    }
  }
  sc = wave_sum(sc);
  if (lane == 0) atomicAdd(&scalars[0], sc);
}

// ---------------- conv epilogue (32-wide): sum partials + bias + root, relu, BN stats ----------------
__global__ __launch_bounds__(256) void k_epi32(const float* __restrict__ part,
                                               const float* __restrict__ bias,
                                               const float* __restrict__ root,
                                               float* __restrict__ t,
                                               float* __restrict__ colsum,
                                               float* __restrict__ colsq) {
  __shared__ float ls[HH], lq[HH];
  const int tid = threadIdx.x;
  const int idx = blockIdx.x * 256 + tid;
  const int c = idx & (HH - 1);
  if (tid < HH) { ls[tid] = 0.f; lq[tid] = 0.f; }
  __syncthreads();
  float s = bias[c] + root[idx];
#pragma unroll
  for (int sp = 0; sp < KS; ++sp) s += part[(size_t)sp * (NN * HH) + idx];
  s = fmaxf(s, 0.f);
  t[idx] = s;
  atomicAdd(&ls[c], s);
  atomicAdd(&lq[c], s * s);
  __syncthreads();
  if (tid < HH) {
    atomicAdd(&colsum[tid], ls[tid]);
    atomicAdd(&colsq[tid], lq[tid]);
  }
}

// ---------------- BN finalize ----------------
__global__ void k_bnfinal(const float* __restrict__ colsum, const float* __restrict__ colsq,
                          const float* __restrict__ g, const float* __restrict__ be,
                          float* __restrict__ A, float* __restrict__ B, int Ccols) {
  const int c = threadIdx.x;
  if (c >= Ccols) return;
  const float m = colsum[c] * (1.f / NN);
  const float var = fmaxf(colsq[c] * (1.f / NN) - m * m, 0.f);
  const float a = g[c] / sqrtf(var + 1e-5f);
  A[c] = a;
  B[c] = be[c] - m * a;
}

// xT (optional): bf16 transposed copy [32][N] for the next adj pass
__global__ __launch_bounds__(256) void k_bnapply32(const float* __restrict__ t,
                                                   const float* __restrict__ A,
                                                   const float* __restrict__ B,
                                                   float* __restrict__ xo,
                                                   float* __restrict__ emb, int embOff,
                                                   unsigned short* __restrict__ xT) {
  const int idx = blockIdx.x * 256 + threadIdx.x;
  const int c = idx & (HH - 1);
  const int row = idx >> 5;
  const float v = fmaf(A[c], t[idx], B[c]);
  xo[idx] = v;
  emb[(size_t)row * DD + embOff + c] = v;
  if (xT) xT[(size_t)c * NN + row] = f2bf(v);
}

// ---------------- conv3 epilogue ----------------
__global__ __launch_bounds__(256) void k_epi3(const float* __restrict__ part,
                                              const float* __restrict__ W3r,
                                              const float* __restrict__ b3,
                                              const float* __restrict__ x2,
                                              const float* __restrict__ W3root,
                                              float* __restrict__ t3,
                                              float* __restrict__ colsum,
                                              float* __restrict__ colsq) {
  __shared__ float z[16][33];
  __shared__ float xr[16][33];
  const int row0 = blockIdx.x * 16;
  for (int s = threadIdx.x; s < 16 * 32; s += 256) {
    const int r = s >> 5, k = s & 31;
    float a = 0.f;
#pragma unroll
    for (int sp = 0; sp < KS; ++sp)
      a += part[(size_t)sp * (NN * HH) + (size_t)(row0 + r) * HH + k];
    z[r][k] = a;
    xr[r][k] = x2[(size_t)(row0 + r) * HH + k];
  }
  __syncthreads();
  const int c = threadIdx.x;
  if (c >= CC) return;
  float acc[16];
  const float bb = b3[c];
#pragma unroll
  for (int r = 0; r < 16; ++r) acc[r] = bb;
  for (int k = 0; k < 32; ++k) {
    const float w1 = W3r[k * CC + c];
    const float w2 = W3root[k * CC + c];
#pragma unroll
    for (int r = 0; r < 16; ++r) acc[r] += z[r][k] * w1 + xr[r][k] * w2;
  }
  float lsm = 0.f, lqm = 0.f;
#pragma unroll
  for (int r = 0; r < 16; ++r) {
    const float v = fmaxf(acc[r], 0.f);
    t3[(size_t)(row0 + r) * CC + c] = v;
    lsm += v;
    lqm += v * v;
  }
  atomicAdd(&colsum[c], lsm);
  atomicAdd(&colsq[c], lqm);
}

__global__ void k_bnapply205(const float* __restrict__ t3, const float* __restrict__ A,
                             const float* __restrict__ B, float* __restrict__ x3,
                             float* __restrict__ emb) {
  const int row = blockIdx.x;
  const int c = threadIdx.x;
  if (c >= CC) return;
  const float v = fmaf(A[c], t3[(size_t)row * CC + c], B[c]);
  x3[(size_t)row * CC + c] = v;
  emb[(size_t)row * DD + 2 * HH + c] = v;
}

// ---------------- layer4: logits -> relu -> softmax (s1) + sn + s1T + entropy ----------------
__global__ __launch_bounds__(256) void k_layer4(const float* __restrict__ x1,
                                                const float* __restrict__ x2,
                                                const float* __restrict__ x3,
                                                const float* __restrict__ Wl1,
                                                const float* __restrict__ bl1,
                                                float* __restrict__ s1,
                                                float* __restrict__ sn,
                                                unsigned short* __restrict__ s1T,
                                                float* __restrict__ scalars) {
  __shared__ float xr[16][DD + 3];
  __shared__ float red[4];
  const int row0 = blockIdx.x * 16;
  const int tid = threadIdx.x;
  for (int s = tid; s < 16 * DD; s += 256) {
    const int r = s / DD, d = s - r * DD;
    const int row = row0 + r;
    float v;
    if (d < HH) v = x1[(size_t)row * HH + d];
    else if (d < 2 * HH) v = x2[(size_t)row * HH + (d - HH)];
    else v = x3[(size_t)row * CC + (d - 2 * HH)];
    xr[r][d] = v;
  }
  __syncthreads();
  const int c = tid;
  float acc[16];
#pragma unroll
  for (int r = 0; r < 16; ++r) acc[r] = 0.f;
  if (c < CC) {
    const float bias = bl1[c];
#pragma unroll
    for (int r = 0; r < 16; ++r) acc[r] = bias;
    for (int k = 0; k < DD; ++k) {
      const float w = Wl1[(size_t)k * CC + c];
#pragma unroll
      for (int r = 0; r < 16; ++r) acc[r] = fmaf(xr[r][k], w, acc[r]);
    }
  }
  float ent_acc = 0.f;
#pragma unroll
  for (int r = 0; r < 16; ++r) {
    const float v = (c < CC) ? fmaxf(acc[r], 0.f) : -1e30f;
    const float m = blk_max(v, red);
    const float e = (c < CC) ? __expf(v - m) : 0.f;
    const float S = blk_sum(e, red);
    const float p = (c < CC) ? e / S : 0.f;
    const float q = blk_sum(p * p, red);
    const float inv = 1.f / fmaxf(sqrtf(q), 1e-8f);
    if (c < CC) {
      s1[(size_t)(row0 + r) * CC + c] = p;
      sn[(size_t)(row0 + r) * CC + c] = p * inv;
      s1T[(size_t)c * NN + row0 + r] = f2bf(p);
    }
    const float m2 = blk_max((c < CC) ? p : -1e30f, red);
    const float e2 = (c < CC) ? __expf(p - m2) : 0.f;
    const float S2 = blk_sum(e2, red);
    const float s2 = e2 / S2;
    const float term = (c < CC) ? -s2 * logf(s2 + 1e-15f) : 0.f;
    ent_acc += blk_sum(term, red);
  }
  if (tid == 0) atomicAdd(&scalars[2], ent_acc);
}

// ---------------- four Gram matrices ----------------
__global__ __launch_bounds__(256) void k_gram4(const float* __restrict__ xn,
                                               const float* __restrict__ sn,
                                               const float* __restrict__ s1f,
                                               float* __restrict__ G, float* __restrict__ Gxs,
                                               float* __restrict__ Gs, float* __restrict__ Gs0) {
  const int gid = blockIdx.z >> 3;
  const int split = blockIdx.z & 7;
  const float *A, *B;
  float* Cp;
  int Wa, Wb;
  if (gid == 0)      { A = xn;  B = xn;  Cp = G;   Wa = FF; Wb = FF; }
  else if (gid == 1) { A = xn;  B = sn;  Cp = Gxs; Wa = FF; Wb = CC; }
  else if (gid == 2) { A = sn;  B = sn;  Cp = Gs;  Wa = CC; Wb = CC; }
  else               { A = s1f; B = s1f; Cp = Gs0; Wa = CC; Wb = CC; }
  const int tx = blockIdx.x, ty = blockIdx.y;
  if (tx * 64 >= Wa || ty * 64 >= Wb) return;
  __shared__ float sA[32][68];
  __shared__ float sB[32][68];
  const int tid = threadIdx.x;
  const int a0 = (tid >> 4) << 2;
  const int b0 = (tid & 15) << 2;
  const int kb0 = split * (NN / 8);
  float acc[4][4];
#pragma unroll
  for (int i = 0; i < 4; ++i)
#pragma unroll
    for (int j = 0; j < 4; ++j) acc[i][j] = 0.f;

  for (int kb = 0; kb < NN / 8; kb += 32) {
    for (int s = tid; s < 2048; s += 256) {
      const int k = s >> 6, cl = s & 63;
      const int ca = tx * 64 + cl, cb = ty * 64 + cl;
      sA[k][cl] = (ca < Wa) ? A[(size_t)(kb0 + kb + k) * Wa + ca] : 0.f;
      sB[k][cl] = (cb < Wb) ? B[(size_t)(kb0 + kb + k) * Wb + cb] : 0.f;
    }
    __syncthreads();
#pragma unroll 8
    for (int k = 0; k < 32; ++k) {
      const float4 av = *reinterpret_cast<const float4*>(&sA[k][a0]);
      const float4 bv = *reinterpret_cast<const float4*>(&sB[k][b0]);
      acc[0][0] = fmaf(av.x, bv.x, acc[0][0]); acc[0][1] = fmaf(av.x, bv.y, acc[0][1]);
      acc[0][2] = fmaf(av.x, bv.z, acc[0][2]); acc[0][3] = fmaf(av.x, bv.w, acc[0][3]);
      acc[1][0] = fmaf(av.y, bv.x, acc[1][0]); acc[1][1] = fmaf(av.y, bv.y, acc[1][1]);
      acc[1][2] = fmaf(av.y, bv.z, acc[1][2]); acc[1][3] = fmaf(av.y, bv.w, acc[1][3]);
      acc[2][0] = fmaf(av.z, bv.x, acc[2][0]); acc[2][1] = fmaf(av.z, bv.y, acc[2][1]);
      acc[2][2] = fmaf(av.z, bv.z, acc[2][2]); acc[2][3] = fmaf(av.z, bv.w, acc[2][3]);
      acc[3][0] = fmaf(av.w, bv.x, acc[3][0]); acc[3][1] = fmaf(av.w, bv.y, acc[3][1]);
      acc[3][2] = fmaf(av.w, bv.z, acc[3][2]); acc[3][3] = fmaf(av.w, bv.w, acc[3][3]);
    }
    __syncthreads();
  }
#pragma unroll
  for (int r = 0; r < 4; ++r) {
#pragma unroll
    for (int cc = 0; cc < 4; ++cc) {
      const int ca = tx * 64 + a0 + r, cb = ty * 64 + b0 + cc;
      if (ca < Wa && cb < Wb) atomicAdd(&Cp[(size_t)ca * Wb + cb], acc[r][cc]);
    }
  }
}

// ---------------- thin GEMM ----------------
__global__ __launch_bounds__(256) void k_rowmm(const float* __restrict__ A,
                                               const float* __restrict__ B,
                                               float* __restrict__ Cm, int K, int Nc) {
  __shared__ float sA[16][208];
  const int row0 = blockIdx.x * 16;
  for (int s = threadIdx.x; s < 16 * K; s += 256) {
    const int r = s / K, k = s - r * K;
    sA[r][k] = A[(size_t)(row0 + r) * K + k];
  }
  __syncthreads();
  const int c = threadIdx.x;
  if (c >= Nc) return;
  float acc[16];
#pragma unroll
  for (int r = 0; r < 16; ++r) acc[r] = 0.f;
  for (int k = 0; k < K; ++k) {
    const float w = B[(size_t)k * Nc + c];
#pragma unroll
    for (int r = 0; r < 16; ++r) acc[r] = fmaf(sA[r][k], w, acc[r]);
  }
#pragma unroll
  for (int r = 0; r < 16; ++r) Cm[(size_t)(row0 + r) * Nc + c] = acc[r];
}

// ---------------- per-row sim contribution ----------------
__global__ __launch_bounds__(256) void k_simrow(const float* __restrict__ H1,
                                                const float* __restrict__ Uu,
                                                const float* __restrict__ H2,
                                                const float* __restrict__ xn,
                                                const float* __restrict__ sn,
                                                float* __restrict__ scalars) {
  const int lane = threadIdx.x & 63;
  const int row = blockIdx.x * 4 + (threadIdx.x >> 6);
  float suu = 0.f, suv = 0.f, svv = 0.f;
#pragma unroll
  for (int c0 = 0; c0 < FF; c0 += 64) {
    const float xv = xn[(size_t)row * FF + c0 + lane];
    suu = fmaf(H1[(size_t)row * FF + c0 + lane], xv, suu);
  }
  for (int cb = lane; cb < CC; cb += 64) {
    const float sv = sn[(size_t)row * CC + cb];
    suv = fmaf(Uu[(size_t)row * CC + cb], sv, suv);
    svv = fmaf(H2[(size_t)row * CC + cb], sv, svv);
  }
  suu = wave_sum(suu);
  suv = wave_sum(suv);
  svv = wave_sum(svv);
  if (lane == 0) atomicAdd(&scalars[3], suv / sqrtf(suu * svv));
}

// ---------------- team embedding loss ----------------
__global__ __launch_bounds__(256) void k_embloss(const float* __restrict__ emb,
                                                 const int* __restrict__ teams,
                                                 const int* __restrict__ reps,
                                                 float* __restrict__ scalars) {
  const int team = blockIdx.x;
  float part = 0.f;
  for (int d = threadIdx.x; d < DD; d += 256) {
    float a = 0.f, b = 0.f;
#pragma unroll
    for (int m = 0; m < RR; ++m) a += emb[(size_t)reps[team * RR + m] * DD + d];
#pragma unroll
    for (int m = RR; m < TT; ++m) b += emb[(size_t)teams[team * TT + m] * DD + d];
    part += fabsf(a * (1.f / RR) - b * (1.f / (TT - RR)));
  }
  part = wave_sum(part);
  if ((threadIdx.x & 63) == 0) atomicAdd(&scalars[4], part);
}

// ---------------- finalize ----------------
__global__ void k_final(const float* __restrict__ Gs0, const float* __restrict__ scalars,
                        float* __restrict__ outsc) {
  __shared__ float red[4];
  float p = 0.f;
  for (int i = threadIdx.x; i < CC * CC; i += 256) {
    const float v = Gs0[i];
    p = fmaf(v, v, p);
  }
  p = wave_sum(p);
  if ((threadIdx.x & 63) == 0) red[threadIdx.x >> 6] = p;
  __syncthreads();
  if (threadIdx.x == 0) {
    const float sumP2 = red[0] + red[1] + red[2] + red[3];
    const float normsq = fmaxf(sumP2 - 2.f * scalars[0] + scalars[1], 0.f);
    const float norm = sqrtf(normsq);
    const float e1 = scalars[2] * (1.f / NN);
    const float sim = -scalars[3] * (1.f / NN);
    const float embl = scalars[4] * (1.f / LL);
    outsc[0] = norm;
    outsc[1] = e1;
    outsc[2] = sim;
    outsc[3] = 100.f * norm + 10.f * e1 + 100.f * sim + embl;
    outsc[4] = embl;
  }
}

// ================= launch =================
extern "C" void kernel_launch(void* const* d_in, const int* in_sizes, int n_in,
                              void* d_out, int out_size, void* d_ws, size_t ws_size,
                              hipStream_t stream) {
  const float* x      = (const float*)d_in[0];
  const float* adj    = (const float*)d_in[1];
  const int*   teams  = (const int*)d_in[2];
  const int*   reps   = (const int*)d_in[3];
  const float* W1r    = (const float*)d_in[4];
  const float* b1     = (const float*)d_in[5];
  const float* W1root = (const float*)d_in[6];
  const float* g1     = (const float*)d_in[7];
  const float* be1    = (const float*)d_in[8];
  const float* W2r    = (const float*)d_in[9];
  const float* b2     = (const float*)d_in[10];
  const float* W2root = (const float*)d_in[11];
  const float* g2     = (const float*)d_in[12];
  const float* be2    = (const float*)d_in[13];
  const float* W3r    = (const float*)d_in[14];
  const float* b3     = (const float*)d_in[15];
  const float* W3root = (const float*)d_in[16];
  const float* g3     = (const float*)d_in[17];
  const float* be3    = (const float*)d_in[18];
  const float* Wl1    = (const float*)d_in[19];
  const float* bl1    = (const float*)d_in[20];

  char* wp = (char*)d_ws;
  auto alloc = [&](size_t bytes) { char* p = wp; wp += (bytes + 255) & ~(size_t)255; return p; };
  unsigned short* adj_h = (unsigned short*)alloc((size_t)NN * NN * 2);
  unsigned short* mT    = (unsigned short*)alloc((size_t)HH * NN * 2);
  unsigned short* x2T   = (unsigned short*)alloc((size_t)HH * NN * 2);
  unsigned short* s1T   = (unsigned short*)alloc((size_t)208 * NN * 2);
  float* rootb  = (float*)alloc((size_t)NN * HH * 4);
  float* t      = (float*)alloc((size_t)NN * HH * 4);
  float* x1     = (float*)alloc((size_t)NN * HH * 4);
  float* x2     = (float*)alloc((size_t)NN * HH * 4);
  float* part   = (float*)alloc((size_t)KS * NN * HH * 4);
  float* t3     = (float*)alloc((size_t)NN * CC * 4);
  float* x3     = (float*)alloc((size_t)NN * CC * 4);
  float* sn     = (float*)alloc((size_t)NN * CC * 4);
  float* xn     = (float*)alloc((size_t)NN * FF * 4);
  float* H1     = (float*)alloc((size_t)NN * FF * 4);
  float* Uu     = (float*)alloc((size_t)NN * CC * 4);
  float* H2     = (float*)alloc((size_t)NN * CC * 4);
  float* G      = (float*)alloc((size_t)FF * FF * 4);
  float* Gxs    = (float*)alloc((size_t)FF * CC * 4);
  float* Gs     = (float*)alloc((size_t)CC * CC * 4);
  float* Gs0    = (float*)alloc((size_t)CC * CC * 4);
  float* scalars = (float*)alloc(64);
  float* colsum = (float*)alloc(1024);
  float* colsq  = (float*)alloc(1024);
  float* bnA    = (float*)alloc(1024);
  float* bnB    = (float*)alloc(1024);
  (void)ws_size; (void)in_sizes; (void)n_in; (void)out_size;

  float* out   = (float*)d_out;
  float* s1    = out;                          // N*C
  float* outsc = out + (size_t)NN * CC;        // 5 scalars
  float* emb   = out + (size_t)NN * CC + 5;    // N*D

  // zero accumulators (G..scalars contiguous region) + BN stats + s1T pad rows
  hipMemsetAsync(G, 0, (size_t)((char*)scalars + 64 - (char*)G), stream);
  hipMemsetAsync(colsum, 0, 2048, stream);
  hipMemsetAsync(s1T, 0, (size_t)208 * NN * 2, stream);

  // adj -> bf16 (+ sum adj^2)
  k_cvt_adj<<<2048, 256, 0, stream>>>(adj, adj_h, scalars);
  k_xn<<<NN / 4, 256, 0, stream>>>(x, xn);

  // conv1
  k_proj_t<<<512, 256, 0, stream>>>(x, W1r, W1root, mT, rootb, FF);
  k_adjmm<<<dim3(NN / 64, KS), 256, 0, stream>>>(adj_h, mT, part);
  k_epi32<<<NN * HH / 256, 256, 0, stream>>>(part, b1, rootb, t, colsum, colsq);
  k_bnfinal<<<1, 256, 0, stream>>>(colsum, colsq, g1, be1, bnA, bnB, HH);
  k_bnapply32<<<NN * HH / 256, 256, 0, stream>>>(t, bnA, bnB, x1, emb, 0, (unsigned short*)nullptr);

  // conv2
  hipMemsetAsync(colsum, 0, 2048, stream);
  k_proj_t<<<512, 256, 0, stream>>>(x1, W2r, W2root, mT, rootb, HH);
  k_adjmm<<<dim3(NN / 64, KS), 256, 0, stream>>>(adj_h, mT, part);
  k_epi32<<<NN * HH / 256, 256, 0, stream>>>(part, b2, rootb, t, colsum, colsq);
  k_bnfinal<<<1, 256, 0, stream>>>(colsum, colsq, g2, be2, bnA, bnB, HH);
  k_bnapply32<<<NN * HH / 256, 256, 0, stream>>>(t, bnA, bnB, x2, emb, HH, x2T);

  // conv3
  hipMemsetAsync(colsum, 0, 2048, stream);
  k_adjmm<<<dim3(NN / 64, KS), 256, 0, stream>>>(adj_h, x2T, part);
  k_epi3<<<NN / 16, 256, 0, stream>>>(part, W3r, b3, x2, W3root, t3, colsum, colsq);
  k_bnfinal<<<1, 256, 0, stream>>>(colsum, colsq, g3, be3, bnA, bnB, CC);
  k_bnapply205<<<NN, 256, 0, stream>>>(t3, bnA, bnB, x3, emb);

  // head
  k_layer4<<<NN / 16, 256, 0, stream>>>(x1, x2, x3, Wl1, bl1, s1, sn, s1T, scalars);

  // tr(S' A S) via MFMA
  k_normmfma<<<dim3(NN / 64, KS), 256, 0, stream>>>(adj_h, s1T, s1, scalars);

  // Grams + bilinear forms + sim + team loss + finalize
  k_gram4<<<dim3(4, 4, 32), 256, 0, stream>>>(xn, sn, s1, G, Gxs, Gs, Gs0);
  k_rowmm<<<NN / 16, 256, 0, stream>>>(xn, G, H1, FF, FF);
  k_rowmm<<<NN / 16, 256, 0, stream>>>(xn, Gxs, Uu, FF, CC);
  k_rowmm<<<NN / 16, 256, 0, stream>>>(sn, Gs, H2, CC, CC);
  k_simrow<<<NN / 4, 256, 0, stream>>>(H1, Uu, H2, xn, sn, scalars);
  k_embloss<<<LL, 256, 0, stream>>>(emb, teams, reps, scalars);
  k_final<<<1, 256, 0, stream>>>(Gs0, scalars, outsc);
}

// Round 3
// 685.865 us; speedup vs baseline: 1.3487x; 1.1167x over previous
//
#include <hip/hip_runtime.h>
#include <math.h>

#define NN 4096
#define FF 128
#define HH 32
#define CC 205
#define DD 269
#define LL 512
#define TT 12
#define RR 4
#define KS 16    // k-split for all adj MFMA passes

typedef __attribute__((ext_vector_type(8))) short bf16x8;
typedef __attribute__((ext_vector_type(4))) float f32x4;

// ---------------- helpers ----------------
__device__ __forceinline__ float wave_sum(float v) {
#pragma unroll
  for (int o = 32; o > 0; o >>= 1) v += __shfl_xor(v, o, 64);
  return v;
}
__device__ __forceinline__ float wave_max(float v) {
#pragma unroll
  for (int o = 32; o > 0; o >>= 1) v = fmaxf(v, __shfl_xor(v, o, 64));
  return v;
}
__device__ __forceinline__ unsigned short f2bf(float x) {  // RNE
  union { float f; unsigned u; } v; v.f = x;
  unsigned r = v.u + 0x7FFFu + ((v.u >> 16) & 1u);
  return (unsigned short)(r >> 16);
}

// ---------------- adj fp32 -> bf16 + sum(adj^2) ----------------
__global__ __launch_bounds__(256) void k_cvt_adj(const float* __restrict__ adj,
                                                 unsigned short* __restrict__ adj_h,
                                                 float* __restrict__ scalars) {
  const size_t nvec = (size_t)NN * NN / 4;
  float acc = 0.f;
  for (size_t i = (size_t)blockIdx.x * 256 + threadIdx.x; i < nvec; i += (size_t)gridDim.x * 256) {
    const float4 v = reinterpret_cast<const float4*>(adj)[i];
    acc += v.x * v.x + v.y * v.y + v.z * v.z + v.w * v.w;
    ushort4 h;
    h.x = f2bf(v.x); h.y = f2bf(v.y); h.z = f2bf(v.z); h.w = f2bf(v.w);
    reinterpret_cast<ushort4*>(adj_h)[i] = h;
  }
  acc = wave_sum(acc);
  if ((threadIdx.x & 63) == 0) atomicAdd(&scalars[1], acc);
}

// ---------------- dual projection: o1T(bf16,[32][N]) = (A@W1)^T, o2(f32,[N][32]) = A@W2 ----------------
__global__ __launch_bounds__(256) void k_proj_t(const float* __restrict__ A,
                                                const float* __restrict__ W1,
                                                const float* __restrict__ W2,
                                                unsigned short* __restrict__ o1T,
                                                float* __restrict__ o2, int K) {
  const int idx = blockIdx.x * 256 + threadIdx.x;  // N*32
  const int row = idx >> 5;
  const int c = idx & 31;
  float a1 = 0.f, a2 = 0.f;
  for (int k = 0; k < K; ++k) {
    const float av = A[(size_t)row * K + k];
    a1 = fmaf(av, W1[k * HH + c], a1);
    a2 = fmaf(av, W2[k * HH + c], a2);
  }
  o1T[(size_t)c * NN + row] = f2bf(a1);
  o2[idx] = a2;
}

// ---------------- row-normalize x -> xn ----------------
__global__ __launch_bounds__(256) void k_xn(const float* __restrict__ x, float* __restrict__ xn) {
  const int lane = threadIdx.x & 63;
  const int row = blockIdx.x * 4 + (threadIdx.x >> 6);
  float v0 = x[(size_t)row * FF + lane];
  float v1 = x[(size_t)row * FF + 64 + lane];
  float ss = wave_sum(v0 * v0 + v1 * v1);
  float n = fmaxf(sqrtf(ss), 1e-8f);
  xn[(size_t)row * FF + lane] = v0 / n;
  xn[(size_t)row * FF + 64 + lane] = v1 / n;
}

// ---------------- MFMA adj pass: part[split] = adj_h[rows] @ M  (M via BT bf16 [32][N]) ----------------
// grid (NN/64, KS), 4 waves/block; wave w owns 16 rows; 2 col-tiles of 16 (32 cols)
__global__ __launch_bounds__(256) void k_adjmm(const unsigned short* __restrict__ adj_h,
                                               const unsigned short* __restrict__ BT,
                                               float* __restrict__ part) {
  const int tid = threadIdx.x;
  const int lane = tid & 63;
  const int w = tid >> 6;
  const int rbase = blockIdx.x * 64 + w * 16;
  const int k0base = blockIdx.y * (NN / KS);
  const int l15 = lane & 15;
  const int kgrp = (lane >> 4) * 8;
  const size_t arow_off = (size_t)(rbase + l15) * NN;
  f32x4 acc0 = {0.f, 0.f, 0.f, 0.f}, acc1 = {0.f, 0.f, 0.f, 0.f};
#pragma unroll
  for (int k0 = 0; k0 < NN / KS; k0 += 32) {
    const int kk = k0base + k0 + kgrp;
    const bf16x8 a = *reinterpret_cast<const bf16x8*>(&adj_h[arow_off + kk]);
    const bf16x8 b0 = *reinterpret_cast<const bf16x8*>(&BT[(size_t)l15 * NN + kk]);
    const bf16x8 b1 = *reinterpret_cast<const bf16x8*>(&BT[(size_t)(16 + l15) * NN + kk]);
    acc0 = __builtin_amdgcn_mfma_f32_16x16x32_bf16(a, b0, acc0, 0, 0, 0);
    acc1 = __builtin_amdgcn_mfma_f32_16x16x32_bf16(a, b1, acc1, 0, 0, 0);
  }
  float* pp = part + (size_t)blockIdx.y * (NN * HH);
  const int rout = rbase + (lane >> 4) * 4;
#pragma unroll
  for (int r = 0; r < 4; ++r) {
    pp[(size_t)(rout + r) * HH + l15] = acc0[r];
    pp[(size_t)(rout + r) * HH + 16 + l15] = acc1[r];
  }
}

// ---------------- MFMA norm pass: scalars[0] += sum( (adj@S1)_partial .* s1 ) ----------------
// grid (NN/64, KS); S1 via s1T bf16 [208][N] (rows 205..207 zero)
__global__ __launch_bounds__(256) void k_normmfma(const unsigned short* __restrict__ adj_h,
                                                  const unsigned short* __restrict__ s1T,
                                                  const float* __restrict__ s1,
                                                  float* __restrict__ scalars) {
  const int tid = threadIdx.x;
  const int lane = tid & 63;
  const int w = tid >> 6;
  const int rbase = blockIdx.x * 64 + w * 16;
  const int k0base = blockIdx.y * (NN / KS);
  const int l15 = lane & 15;
  const int kgrp = (lane >> 4) * 8;
  const size_t arow_off = (size_t)(rbase + l15) * NN;
  f32x4 acc[13];
#pragma unroll
  for (int ct = 0; ct < 13; ++ct) acc[ct] = (f32x4){0.f, 0.f, 0.f, 0.f};
  for (int k0 = 0; k0 < NN / KS; k0 += 32) {
    const int kk = k0base + k0 + kgrp;
    const bf16x8 a = *reinterpret_cast<const bf16x8*>(&adj_h[arow_off + kk]);
#pragma unroll
    for (int ct = 0; ct < 13; ++ct) {
      const bf16x8 b = *reinterpret_cast<const bf16x8*>(&s1T[(size_t)(ct * 16 + l15) * NN + kk]);
      acc[ct] = __builtin_amdgcn_mfma_f32_16x16x32_bf16(a, b, acc[ct], 0, 0, 0);
    }
  }
  const int rout = rbase + (lane >> 4) * 4;
  float sc = 0.f;
#pragma unroll
  for (int ct = 0; ct < 13; ++ct) {
    const int col = ct * 16 + l15;
    if (col < CC) {
#pragma unroll
      for (int r = 0; r < 4; ++r)
        sc = fmaf(acc[ct][r], s1[(size_t)(rout + r) * CC + col], sc);
    }
  }
  sc = wave_sum(sc);
  if (lane == 0) atomicAdd(&scalars[0], sc);
}

// ---------------- conv epilogue (32-wide): sum partials + bias + root, relu, BN stats ----------------
__global__ __launch_bounds__(256) void k_epi32(const float* __restrict__ part,
                                               const float* __restrict__ bias,
                                               const float* __restrict__ root,
                                               float* __restrict__ t,
                                               float* __restrict__ colsum,
                                               float* __restrict__ colsq) {
  __shared__ float ls[HH], lq[HH];
  const int tid = threadIdx.x;
  const int idx = blockIdx.x * 256 + tid;
  const int c = idx & (HH - 1);
  if (tid < HH) { ls[tid] = 0.f; lq[tid] = 0.f; }
  __syncthreads();
  float s = bias[c] + root[idx];
#pragma unroll
  for (int sp = 0; sp < KS; ++sp) s += part[(size_t)sp * (NN * HH) + idx];
  s = fmaxf(s, 0.f);
  t[idx] = s;
  atomicAdd(&ls[c], s);
  atomicAdd(&lq[c], s * s);
  __syncthreads();
  if (tid < HH) {
    atomicAdd(&colsum[tid], ls[tid]);
    atomicAdd(&colsq[tid], lq[tid]);
  }
}

// ---------------- BN finalize (also re-zeroes the stats accumulators for the next use) ----------------
__global__ void k_bnfinal(float* __restrict__ colsum, float* __restrict__ colsq,
                          const float* __restrict__ g, const float* __restrict__ be,
                          float* __restrict__ A, float* __restrict__ B, int Ccols) {
  const int c = threadIdx.x;
  const float cs = colsum[c];
  const float cq = colsq[c];
  colsum[c] = 0.f;
  colsq[c] = 0.f;
  if (c >= Ccols) return;
  const float m = cs * (1.f / NN);
  const float var = fmaxf(cq * (1.f / NN) - m * m, 0.f);
  const float a = g[c] / sqrtf(var + 1e-5f);
  A[c] = a;
  B[c] = be[c] - m * a;
}

// xT (optional): bf16 transposed copy [32][N] for the next adj pass
__global__ __launch_bounds__(256) void k_bnapply32(const float* __restrict__ t,
                                                   const float* __restrict__ A,
                                                   const float* __restrict__ B,
                                                   float* __restrict__ xo,
                                                   float* __restrict__ emb, int embOff,
                                                   unsigned short* __restrict__ xT) {
  const int idx = blockIdx.x * 256 + threadIdx.x;
  const int c = idx & (HH - 1);
  const int row = idx >> 5;
  const float v = fmaf(A[c], t[idx], B[c]);
  xo[idx] = v;
  emb[(size_t)row * DD + embOff + c] = v;
  if (xT) xT[(size_t)c * NN + row] = f2bf(v);
}

// ---------------- conv3 epilogue ----------------
__global__ __launch_bounds__(256) void k_epi3(const float* __restrict__ part,
                                              const float* __restrict__ W3r,
                                              const float* __restrict__ b3,
                                              const float* __restrict__ x2,
                                              const float* __restrict__ W3root,
                                              float* __restrict__ t3,
                                              float* __restrict__ colsum,
                                              float* __restrict__ colsq) {
  __shared__ float z[16][33];
  __shared__ float xr[16][33];
  const int row0 = blockIdx.x * 16;
  for (int s = threadIdx.x; s < 16 * 32; s += 256) {
    const int r = s >> 5, k = s & 31;
    float a = 0.f;
#pragma unroll
    for (int sp = 0; sp < KS; ++sp)
      a += part[(size_t)sp * (NN * HH) + (size_t)(row0 + r) * HH + k];
    z[r][k] = a;
    xr[r][k] = x2[(size_t)(row0 + r) * HH + k];
  }
  __syncthreads();
  const int c = threadIdx.x;
  if (c >= CC) return;
  float acc[16];
  const float bb = b3[c];
#pragma unroll
  for (int r = 0; r < 16; ++r) acc[r] = bb;
  for (int k = 0; k < 32; ++k) {
    const float w1 = W3r[k * CC + c];
    const float w2 = W3root[k * CC + c];
#pragma unroll
    for (int r = 0; r < 16; ++r) acc[r] += z[r][k] * w1 + xr[r][k] * w2;
  }
  float lsm = 0.f, lqm = 0.f;
#pragma unroll
  for (int r = 0; r < 16; ++r) {
    const float v = fmaxf(acc[r], 0.f);
    t3[(size_t)(row0 + r) * CC + c] = v;
    lsm += v;
    lqm += v * v;
  }
  atomicAdd(&colsum[c], lsm);
  atomicAdd(&colsq[c], lqm);
}

__global__ void k_bnapply205(const float* __restrict__ t3, const float* __restrict__ A,
                             const float* __restrict__ B, float* __restrict__ x3,
                             float* __restrict__ emb) {
  const int row = blockIdx.x;
  const int c = threadIdx.x;
  if (c >= CC) return;
  const float v = fmaf(A[c], t3[(size_t)row * CC + c], B[c]);
  x3[(size_t)row * CC + c] = v;
  emb[(size_t)row * DD + 2 * HH + c] = v;
}

// ---------------- layer4 (wave-parallel): logits -> relu -> softmax (s1) + sn + s1T + entropy ----------------
// grid NN/8; 4 waves/block; each wave owns 2 rows; lane owns cols {lane, lane+64, lane+128, lane+192}
__global__ __launch_bounds__(256) void k_layer4(const float* __restrict__ x1,
                                                const float* __restrict__ x2,
                                                const float* __restrict__ x3,
                                                const float* __restrict__ Wl1,
                                                const float* __restrict__ bl1,
                                                float* __restrict__ s1,
                                                float* __restrict__ sn,
                                                unsigned short* __restrict__ s1T,
                                                float* __restrict__ scalars) {
  __shared__ float xr[8][DD + 3];
  const int row0 = blockIdx.x * 8;
  const int tid = threadIdx.x;
  for (int s = tid; s < 8 * DD; s += 256) {
    const int r = s / DD, d = s - r * DD;
    const int row = row0 + r;
    float v;
    if (d < HH) v = x1[(size_t)row * HH + d];
    else if (d < 2 * HH) v = x2[(size_t)row * HH + (d - HH)];
    else v = x3[(size_t)row * CC + (d - 2 * HH)];
    xr[r][d] = v;
  }
  __syncthreads();
  const int w = tid >> 6;
  const int lane = tid & 63;
  const int r0 = w * 2;  // this wave's 2 rows (local)
  float bl[4];
#pragma unroll
  for (int j = 0; j < 4; ++j) {
    const int c = lane + 64 * j;
    bl[j] = (c < CC) ? bl1[c] : 0.f;
  }
  float acc[2][4];
#pragma unroll
  for (int r = 0; r < 2; ++r)
#pragma unroll
    for (int j = 0; j < 4; ++j) acc[r][j] = 0.f;
  const float* xa = xr[r0];
  const float* xb = xr[r0 + 1];
#pragma unroll 4
  for (int k = 0; k < DD; ++k) {
    float wv[4];
#pragma unroll
    for (int j = 0; j < 4; ++j) {
      const int c = lane + 64 * j;
      wv[j] = (c < CC) ? Wl1[(size_t)k * CC + c] : 0.f;
    }
    const float va = xa[k];
    const float vb = xb[k];
#pragma unroll
    for (int j = 0; j < 4; ++j) {
      acc[0][j] = fmaf(va, wv[j], acc[0][j]);
      acc[1][j] = fmaf(vb, wv[j], acc[1][j]);
    }
  }
  float ent_acc = 0.f;
#pragma unroll
  for (int r = 0; r < 2; ++r) {
    const int row = row0 + r0 + r;
    float v[4];
    float ml = -1e30f;
#pragma unroll
    for (int j = 0; j < 4; ++j) {
      const int c = lane + 64 * j;
      v[j] = (c < CC) ? fmaxf(acc[r][j] + bl[j], 0.f) : -1e30f;
      ml = fmaxf(ml, v[j]);
    }
    const float m = wave_max(ml);
    float e[4];
    float sl = 0.f;
#pragma unroll
    for (int j = 0; j < 4; ++j) {
      const int c = lane + 64 * j;
      e[j] = (c < CC) ? __expf(v[j] - m) : 0.f;
      sl += e[j];
    }
    const float S = wave_sum(sl);
    const float invS = 1.f / S;
    float p[4];
    float ql = 0.f;
#pragma unroll
    for (int j = 0; j < 4; ++j) {
      p[j] = e[j] * invS;
      ql += p[j] * p[j];
    }
    const float q = wave_sum(ql);
    const float inv = 1.f / fmaxf(sqrtf(q), 1e-8f);
    float m2l = -1e30f;
#pragma unroll
    for (int j = 0; j < 4; ++j) {
      const int c = lane + 64 * j;
      if (c < CC) {
        s1[(size_t)row * CC + c] = p[j];
        sn[(size_t)row * CC + c] = p[j] * inv;
        m2l = fmaxf(m2l, p[j]);
      }
      if (c < 208) s1T[(size_t)c * NN + row] = f2bf(p[j]);
    }
    const float m2 = wave_max(m2l);
    float e2[4];
    float s2l = 0.f;
#pragma unroll
    for (int j = 0; j < 4; ++j) {
      const int c = lane + 64 * j;
      e2[j] = (c < CC) ? __expf(p[j] - m2) : 0.f;
      s2l += e2[j];
    }
    const float S2 = wave_sum(s2l);
    const float invS2 = 1.f / S2;
    float tl = 0.f;
#pragma unroll
    for (int j = 0; j < 4; ++j) {
      const int c = lane + 64 * j;
      if (c < CC) {
        const float sp = e2[j] * invS2;
        tl -= sp * logf(sp + 1e-15f);
      }
    }
    ent_acc += tl;
  }
  ent_acc = wave_sum(ent_acc);
  if (lane == 0) atomicAdd(&scalars[2], ent_acc);
}

// ---------------- four Gram matrices ----------------
__global__ __launch_bounds__(256) void k_gram4(const float* __restrict__ xn,
                                               const float* __restrict__ sn,
                                               const float* __restrict__ s1f,
                                               float* __restrict__ G, float* __restrict__ Gxs,
                                               float* __restrict__ Gs, float* __restrict__ Gs0) {
  const int gid = blockIdx.z >> 3;
  const int split = blockIdx.z & 7;
  const float *A, *B;
  float* Cp;
  int Wa, Wb;
  if (gid == 0)      { A = xn;  B = xn;  Cp = G;   Wa = FF; Wb = FF; }
  else if (gid == 1) { A = xn;  B = sn;  Cp = Gxs; Wa = FF; Wb = CC; }
  else if (gid == 2) { A = sn;  B = sn;  Cp = Gs;  Wa = CC; Wb = CC; }
  else               { A = s1f; B = s1f; Cp = Gs0; Wa = CC; Wb = CC; }
  const int tx = blockIdx.x, ty = blockIdx.y;
  if (tx * 64 >= Wa || ty * 64 >= Wb) return;
  __shared__ float sA[32][68];
  __shared__ float sB[32][68];
  const int tid = threadIdx.x;
  const int a0 = (tid >> 4) << 2;
  const int b0 = (tid & 15) << 2;
  const int kb0 = split * (NN / 8);
  float acc[4][4];
#pragma unroll
  for (int i = 0; i < 4; ++i)
#pragma unroll
    for (int j = 0; j < 4; ++j) acc[i][j] = 0.f;

  for (int kb = 0; kb < NN / 8; kb += 32) {
    for (int s = tid; s < 2048; s += 256) {
      const int k = s >> 6, cl = s & 63;
      const int ca = tx * 64 + cl, cb = ty * 64 + cl;
      sA[k][cl] = (ca < Wa) ? A[(size_t)(kb0 + kb + k) * Wa + ca] : 0.f;
      sB[k][cl] = (cb < Wb) ? B[(size_t)(kb0 + kb + k) * Wb + cb] : 0.f;
    }
    __syncthreads();
#pragma unroll 8
    for (int k = 0; k < 32; ++k) {
      const float4 av = *reinterpret_cast<const float4*>(&sA[k][a0]);
      const float4 bv = *reinterpret_cast<const float4*>(&sB[k][b0]);
      acc[0][0] = fmaf(av.x, bv.x, acc[0][0]); acc[0][1] = fmaf(av.x, bv.y, acc[0][1]);
      acc[0][2] = fmaf(av.x, bv.z, acc[0][2]); acc[0][3] = fmaf(av.x, bv.w, acc[0][3]);
      acc[1][0] = fmaf(av.y, bv.x, acc[1][0]); acc[1][1] = fmaf(av.y, bv.y, acc[1][1]);
      acc[1][2] = fmaf(av.y, bv.z, acc[1][2]); acc[1][3] = fmaf(av.y, bv.w, acc[1][3]);
      acc[2][0] = fmaf(av.z, bv.x, acc[2][0]); acc[2][1] = fmaf(av.z, bv.y, acc[2][1]);
      acc[2][2] = fmaf(av.z, bv.z, acc[2][2]); acc[2][3] = fmaf(av.z, bv.w, acc[2][3]);
      acc[3][0] = fmaf(av.w, bv.x, acc[3][0]); acc[3][1] = fmaf(av.w, bv.y, acc[3][1]);
      acc[3][2] = fmaf(av.w, bv.z, acc[3][2]); acc[3][3] = fmaf(av.w, bv.w, acc[3][3]);
    }
    __syncthreads();
  }
#pragma unroll
  for (int r = 0; r < 4; ++r) {
#pragma unroll
    for (int cc = 0; cc < 4; ++cc) {
      const int ca = tx * 64 + a0 + r, cb = ty * 64 + b0 + cc;
      if (ca < Wa && cb < Wb) atomicAdd(&Cp[(size_t)ca * Wb + cb], acc[r][cc]);
    }
  }
}

// ---------------- thin GEMMs (3 in one launch, blockIdx.y selects) ----------------
__global__ __launch_bounds__(256) void k_rowmm3(const float* __restrict__ xn,
                                                const float* __restrict__ sn,
                                                const float* __restrict__ G,
                                                const float* __restrict__ Gxs,
                                                const float* __restrict__ Gs,
                                                float* __restrict__ H1,
                                                float* __restrict__ Uu,
                                                float* __restrict__ H2) {
  const float *A, *B;
  float* Cm;
  int K, Nc;
  if (blockIdx.y == 0)      { A = xn; B = G;   Cm = H1; K = FF; Nc = FF; }
  else if (blockIdx.y == 1) { A = xn; B = Gxs; Cm = Uu; K = FF; Nc = CC; }
  else                      { A = sn; B = Gs;  Cm = H2; K = CC; Nc = CC; }
  __shared__ float sA[16][208];
  const int row0 = blockIdx.x * 16;
  for (int s = threadIdx.x; s < 16 * K; s += 256) {
    const int r = s / K, k = s - r * K;
    sA[r][k] = A[(size_t)(row0 + r) * K + k];
  }
  __syncthreads();
  const int c = threadIdx.x;
  if (c >= Nc) return;
  float acc[16];
#pragma unroll
  for (int r = 0; r < 16; ++r) acc[r] = 0.f;
  for (int k = 0; k < K; ++k) {
    const float w = B[(size_t)k * Nc + c];
#pragma unroll
    for (int r = 0; r < 16; ++r) acc[r] = fmaf(sA[r][k], w, acc[r]);
  }
#pragma unroll
  for (int r = 0; r < 16; ++r) Cm[(size_t)(row0 + r) * Nc + c] = acc[r];
}

// ---------------- per-row sim + team embedding loss (merged) ----------------
__global__ __launch_bounds__(256) void k_losses(const float* __restrict__ H1,
                                                const float* __restrict__ Uu,
                                                const float* __restrict__ H2,
                                                const float* __restrict__ xn,
                                                const float* __restrict__ sn,
                                                const float* __restrict__ emb,
                                                const int* __restrict__ teams,
                                                const int* __restrict__ reps,
                                                float* __restrict__ scalars) {
  if (blockIdx.x < NN / 4) {
    const int lane = threadIdx.x & 63;
    const int row = blockIdx.x * 4 + (threadIdx.x >> 6);
    float suu = 0.f, suv = 0.f, svv = 0.f;
#pragma unroll
    for (int c0 = 0; c0 < FF; c0 += 64) {
      const float xv = xn[(size_t)row * FF + c0 + lane];
      suu = fmaf(H1[(size_t)row * FF + c0 + lane], xv, suu);
    }
    for (int cb = lane; cb < CC; cb += 64) {
      const float sv = sn[(size_t)row * CC + cb];
      suv = fmaf(Uu[(size_t)row * CC + cb], sv, suv);
      svv = fmaf(H2[(size_t)row * CC + cb], sv, svv);
    }
    suu = wave_sum(suu);
    suv = wave_sum(suv);
    svv = wave_sum(svv);
    if (lane == 0) atomicAdd(&scalars[3], suv / sqrtf(suu * svv));
  } else {
    const int team = blockIdx.x - NN / 4;
    float part = 0.f;
    for (int d = threadIdx.x; d < DD; d += 256) {
      float a = 0.f, b = 0.f;
#pragma unroll
      for (int m = 0; m < RR; ++m) a += emb[(size_t)reps[team * RR + m] * DD + d];
#pragma unroll
      for (int m = RR; m < TT; ++m) b += emb[(size_t)teams[team * TT + m] * DD + d];
      part += fabsf(a * (1.f / RR) - b * (1.f / (TT - RR)));
    }
    part = wave_sum(part);
    if ((threadIdx.x & 63) == 0) atomicAdd(&scalars[4], part);
  }
}

// ---------------- finalize ----------------
__global__ void k_final(const float* __restrict__ Gs0, const float* __restrict__ scalars,
                        float* __restrict__ outsc) {
  __shared__ float red[4];
  float p = 0.f;
  for (int i = threadIdx.x; i < CC * CC; i += 256) {
    const float v = Gs0[i];
    p = fmaf(v, v, p);
  }
  p = wave_sum(p);
  if ((threadIdx.x & 63) == 0) red[threadIdx.x >> 6] = p;
  __syncthreads();
  if (threadIdx.x == 0) {
    const float sumP2 = red[0] + red[1] + red[2] + red[3];
    const float normsq = fmaxf(sumP2 - 2.f * scalars[0] + scalars[1], 0.f);
    const float norm = sqrtf(normsq);
    const float e1 = scalars[2] * (1.f / NN);
    const float sim = -scalars[3] * (1.f / NN);
    const float embl = scalars[4] * (1.f / LL);
    outsc[0] = norm;
    outsc[1] = e1;
    outsc[2] = sim;
    outsc[3] = 100.f * norm + 10.f * e1 + 100.f * sim + embl;
    outsc[4] = embl;
  }
}

// ================= launch =================
extern "C" void kernel_launch(void* const* d_in, const int* in_sizes, int n_in,
                              void* d_out, int out_size, void* d_ws, size_t ws_size,
                              hipStream_t stream) {
  const float* x      = (const float*)d_in[0];
  const float* adj    = (const float*)d_in[1];
  const int*   teams  = (const int*)d_in[2];
  const int*   reps   = (const int*)d_in[3];
  const float* W1r    = (const float*)d_in[4];
  const float* b1     = (const float*)d_in[5];
  const float* W1root = (const float*)d_in[6];
  const float* g1     = (const float*)d_in[7];
  const float* be1    = (const float*)d_in[8];
  const float* W2r    = (const float*)d_in[9];
  const float* b2     = (const float*)d_in[10];
  const float* W2root = (const float*)d_in[11];
  const float* g2     = (const float*)d_in[12];
  const float* be2    = (const float*)d_in[13];
  const float* W3r    = (const float*)d_in[14];
  const float* b3     = (const float*)d_in[15];
  const float* W3root = (const float*)d_in[16];
  const float* g3     = (const float*)d_in[17];
  const float* be3    = (const float*)d_in[18];
  const float* Wl1    = (const float*)d_in[19];
  const float* bl1    = (const float*)d_in[20];

  char* wp = (char*)d_ws;
  auto alloc = [&](size_t bytes) { char* p = wp; wp += (bytes + 255) & ~(size_t)255; return p; };
  unsigned short* adj_h = (unsigned short*)alloc((size_t)NN * NN * 2);
  unsigned short* mT    = (unsigned short*)alloc((size_t)HH * NN * 2);
  unsigned short* x2T   = (unsigned short*)alloc((size_t)HH * NN * 2);
  unsigned short* s1T   = (unsigned short*)alloc((size_t)208 * NN * 2);
  float* rootb  = (float*)alloc((size_t)NN * HH * 4);
  float* t      = (float*)alloc((size_t)NN * HH * 4);
  float* x1     = (float*)alloc((size_t)NN * HH * 4);
  float* x2     = (float*)alloc((size_t)NN * HH * 4);
  float* part   = (float*)alloc((size_t)KS * NN * HH * 4);
  float* t3     = (float*)alloc((size_t)NN * CC * 4);
  float* x3     = (float*)alloc((size_t)NN * CC * 4);
  float* sn     = (float*)alloc((size_t)NN * CC * 4);
  float* xn     = (float*)alloc((size_t)NN * FF * 4);
  float* H1     = (float*)alloc((size_t)NN * FF * 4);
  float* Uu     = (float*)alloc((size_t)NN * CC * 4);
  float* H2     = (float*)alloc((size_t)NN * CC * 4);
  float* G      = (float*)alloc((size_t)FF * FF * 4);
  float* Gxs    = (float*)alloc((size_t)FF * CC * 4);
  float* Gs     = (float*)alloc((size_t)CC * CC * 4);
  float* Gs0    = (float*)alloc((size_t)CC * CC * 4);
  float* scalars = (float*)alloc(64);
  float* colsum = (float*)alloc(1024);
  float* colsq  = (float*)alloc(1024);
  float* bnA    = (float*)alloc(1024);
  float* bnB    = (float*)alloc(1024);
  (void)ws_size; (void)in_sizes; (void)n_in; (void)out_size;

  float* out   = (float*)d_out;
  float* s1    = out;                          // N*C
  float* outsc = out + (size_t)NN * CC;        // 5 scalars
  float* emb   = out + (size_t)NN * CC + 5;    // N*D

  // zero accumulators (G..scalars contiguous region) + BN stats (bnfinal re-zeroes between convs)
  hipMemsetAsync(G, 0, (size_t)((char*)scalars + 64 - (char*)G), stream);
  hipMemsetAsync(colsum, 0, 2048, stream);

  // adj -> bf16 (+ sum adj^2)
  k_cvt_adj<<<2048, 256, 0, stream>>>(adj, adj_h, scalars);
  k_xn<<<NN / 4, 256, 0, stream>>>(x, xn);

  // conv1
  k_proj_t<<<512, 256, 0, stream>>>(x, W1r, W1root, mT, rootb, FF);
  k_adjmm<<<dim3(NN / 64, KS), 256, 0, stream>>>(adj_h, mT, part);
  k_epi32<<<NN * HH / 256, 256, 0, stream>>>(part, b1, rootb, t, colsum, colsq);
  k_bnfinal<<<1, 256, 0, stream>>>(colsum, colsq, g1, be1, bnA, bnB, HH);
  k_bnapply32<<<NN * HH / 256, 256, 0, stream>>>(t, bnA, bnB, x1, emb, 0, (unsigned short*)nullptr);

  // conv2
  k_proj_t<<<512, 256, 0, stream>>>(x1, W2r, W2root, mT, rootb, HH);
  k_adjmm<<<dim3(NN / 64, KS), 256, 0, stream>>>(adj_h, mT, part);
  k_epi32<<<NN * HH / 256, 256, 0, stream>>>(part, b2, rootb, t, colsum, colsq);
  k_bnfinal<<<1, 256, 0, stream>>>(colsum, colsq, g2, be2, bnA, bnB, HH);
  k_bnapply32<<<NN * HH / 256, 256, 0, stream>>>(t, bnA, bnB, x2, emb, HH, x2T);

  // conv3
  k_adjmm<<<dim3(NN / 64, KS), 256, 0, stream>>>(adj_h, x2T, part);
  k_epi3<<<NN / 16, 256, 0, stream>>>(part, W3r, b3, x2, W3root, t3, colsum, colsq);
  k_bnfinal<<<1, 256, 0, stream>>>(colsum, colsq, g3, be3, bnA, bnB, CC);
  k_bnapply205<<<NN, 256, 0, stream>>>(t3, bnA, bnB, x3, emb);

  // head (wave-parallel softmax; also zero-fills s1T pad cols 205..207)
  k_layer4<<<NN / 8, 256, 0, stream>>>(x1, x2, x3, Wl1, bl1, s1, sn, s1T, scalars);

  // tr(S' A S) via MFMA
  k_normmfma<<<dim3(NN / 64, KS), 256, 0, stream>>>(adj_h, s1T, s1, scalars);

  // Grams + bilinear forms + losses + finalize
  k_gram4<<<dim3(4, 4, 32), 256, 0, stream>>>(xn, sn, s1, G, Gxs, Gs, Gs0);
  k_rowmm3<<<dim3(NN / 16, 3), 256, 0, stream>>>(xn, sn, G, Gxs, Gs, H1, Uu, H2);
  k_losses<<<NN / 4 + LL, 256, 0, stream>>>(H1, Uu, H2, xn, sn, emb, teams, reps, scalars);
  k_final<<<1, 256, 0, stream>>>(Gs0, scalars, outsc);
}

// Round 4
// 497.041 us; speedup vs baseline: 1.8611x; 1.3799x over previous
//
#include <hip/hip_runtime.h>
#include <math.h>

#define NN 4096
#define FF 128
#define HH 32
#define CC 205
#define DD 269
#define LL 512
#define TT 12
#define RR 4
#define KS 16    // k-split for all adj MFMA passes

// padded scalar slots (one cache line apart): 0=trSAS 1=adjsq 2=entropy 3=sim 4=embloss
#define SC(i) ((i) * 32)

typedef __attribute__((ext_vector_type(8))) short bf16x8;
typedef __attribute__((ext_vector_type(4))) float f32x4;

// ---------------- helpers ----------------
__device__ __forceinline__ float wave_sum(float v) {
#pragma unroll
  for (int o = 32; o > 0; o >>= 1) v += __shfl_xor(v, o, 64);
  return v;
}
__device__ __forceinline__ float wave_max(float v) {
#pragma unroll
  for (int o = 32; o > 0; o >>= 1) v = fmaxf(v, __shfl_xor(v, o, 64));
  return v;
}
__device__ __forceinline__ unsigned short f2bf(float x) {  // RNE
  union { float f; unsigned u; } v; v.f = x;
  unsigned r = v.u + 0x7FFFu + ((v.u >> 16) & 1u);
  return (unsigned short)(r >> 16);
}

// ---------------- dual projection: o1T(bf16,[32][N]) = (A@W1)^T, o2(f32,[N][32]) = A@W2 ----------------
__global__ __launch_bounds__(256) void k_proj_t(const float* __restrict__ A,
                                                const float* __restrict__ W1,
                                                const float* __restrict__ W2,
                                                unsigned short* __restrict__ o1T,
                                                float* __restrict__ o2, int K) {
  const int idx = blockIdx.x * 256 + threadIdx.x;  // N*32
  const int row = idx >> 5;
  const int c = idx & 31;
  float a1 = 0.f, a2 = 0.f;
  for (int k = 0; k < K; ++k) {
    const float av = A[(size_t)row * K + k];
    a1 = fmaf(av, W1[k * HH + c], a1);
    a2 = fmaf(av, W2[k * HH + c], a2);
  }
  o1T[(size_t)c * NN + row] = f2bf(a1);
  o2[idx] = a2;
}

// ---------------- row-normalize x -> xn ----------------
__global__ __launch_bounds__(256) void k_xn(const float* __restrict__ x, float* __restrict__ xn) {
  const int lane = threadIdx.x & 63;
  const int row = blockIdx.x * 4 + (threadIdx.x >> 6);
  float v0 = x[(size_t)row * FF + lane];
  float v1 = x[(size_t)row * FF + 64 + lane];
  float ss = wave_sum(v0 * v0 + v1 * v1);
  float n = fmaxf(sqrtf(ss), 1e-8f);
  xn[(size_t)row * FF + lane] = v0 / n;
  xn[(size_t)row * FF + 64 + lane] = v1 / n;
}

// ---------------- FUSED conv1 adj pass: fp32 adj -> bf16 (write adj_h) + sum(adj^2) + MFMA ----------------
// grid (NN/64, KS), 256 threads. Block owns a disjoint 64-row x 256-col tile of adj.
__global__ __launch_bounds__(256) void k_conv1f(const float* __restrict__ adj,
                                                unsigned short* __restrict__ adj_h,
                                                const unsigned short* __restrict__ BT,
                                                float* __restrict__ part,
                                                float* __restrict__ scalars) {
  __shared__ unsigned short sA[64][264];
  __shared__ float red[4];
  const int tid = threadIdx.x;
  const int rbase_blk = blockIdx.x * 64;
  const int kbase = blockIdx.y * 256;
  float adjsq = 0.f;
#pragma unroll
  for (int i = 0; i < 16; ++i) {
    const int fi = i * 256 + tid;  // 0..4095 float4s of the 64x256 tile
    const int r = fi >> 6;
    const int c4 = fi & 63;
    const size_t goff = (size_t)(rbase_blk + r) * NN + kbase + c4 * 4;
    const float4 v = *reinterpret_cast<const float4*>(&adj[goff]);
    adjsq += v.x * v.x + v.y * v.y + v.z * v.z + v.w * v.w;
    ushort4 h;
    h.x = f2bf(v.x); h.y = f2bf(v.y); h.z = f2bf(v.z); h.w = f2bf(v.w);
    *reinterpret_cast<ushort4*>(&adj_h[goff]) = h;
    *reinterpret_cast<ushort4*>(&sA[r][c4 * 4]) = h;
  }
  __syncthreads();
  const int lane = tid & 63;
  const int w = tid >> 6;
  const int l15 = lane & 15;
  const int kgrp = (lane >> 4) * 8;
  const int rloc = w * 16 + l15;
  f32x4 acc0 = {0.f, 0.f, 0.f, 0.f}, acc1 = {0.f, 0.f, 0.f, 0.f};
#pragma unroll
  for (int k0 = 0; k0 < 256; k0 += 32) {
    const bf16x8 a = *reinterpret_cast<const bf16x8*>(&sA[rloc][k0 + kgrp]);
    const bf16x8 b0 = *reinterpret_cast<const bf16x8*>(&BT[(size_t)l15 * NN + kbase + k0 + kgrp]);
    const bf16x8 b1 = *reinterpret_cast<const bf16x8*>(&BT[(size_t)(16 + l15) * NN + kbase + k0 + kgrp]);
    acc0 = __builtin_amdgcn_mfma_f32_16x16x32_bf16(a, b0, acc0, 0, 0, 0);
    acc1 = __builtin_amdgcn_mfma_f32_16x16x32_bf16(a, b1, acc1, 0, 0, 0);
  }
  float* pp = part + (size_t)blockIdx.y * (NN * HH);
  const int rout = rbase_blk + w * 16 + (lane >> 4) * 4;
#pragma unroll
  for (int r = 0; r < 4; ++r) {
    pp[(size_t)(rout + r) * HH + l15] = acc0[r];
    pp[(size_t)(rout + r) * HH + 16 + l15] = acc1[r];
  }
  adjsq = wave_sum(adjsq);
  if (lane == 0) red[w] = adjsq;
  __syncthreads();
  if (tid == 0) atomicAdd(&scalars[SC(1)], red[0] + red[1] + red[2] + red[3]);
}

// ---------------- MFMA adj pass: part[split] = adj_h[rows] @ M  (M via BT bf16 [32][N]) ----------------
__global__ __launch_bounds__(256) void k_adjmm(const unsigned short* __restrict__ adj_h,
                                               const unsigned short* __restrict__ BT,
                                               float* __restrict__ part) {
  const int tid = threadIdx.x;
  const int lane = tid & 63;
  const int w = tid >> 6;
  const int rbase = blockIdx.x * 64 + w * 16;
  const int k0base = blockIdx.y * (NN / KS);
  const int l15 = lane & 15;
  const int kgrp = (lane >> 4) * 8;
  const size_t arow_off = (size_t)(rbase + l15) * NN;
  f32x4 acc0 = {0.f, 0.f, 0.f, 0.f}, acc1 = {0.f, 0.f, 0.f, 0.f};
#pragma unroll
  for (int k0 = 0; k0 < NN / KS; k0 += 32) {
    const int kk = k0base + k0 + kgrp;
    const bf16x8 a = *reinterpret_cast<const bf16x8*>(&adj_h[arow_off + kk]);
    const bf16x8 b0 = *reinterpret_cast<const bf16x8*>(&BT[(size_t)l15 * NN + kk]);
    const bf16x8 b1 = *reinterpret_cast<const bf16x8*>(&BT[(size_t)(16 + l15) * NN + kk]);
    acc0 = __builtin_amdgcn_mfma_f32_16x16x32_bf16(a, b0, acc0, 0, 0, 0);
    acc1 = __builtin_amdgcn_mfma_f32_16x16x32_bf16(a, b1, acc1, 0, 0, 0);
  }
  float* pp = part + (size_t)blockIdx.y * (NN * HH);
  const int rout = rbase + (lane >> 4) * 4;
#pragma unroll
  for (int r = 0; r < 4; ++r) {
    pp[(size_t)(rout + r) * HH + l15] = acc0[r];
    pp[(size_t)(rout + r) * HH + 16 + l15] = acc1[r];
  }
}

// ---------------- MFMA norm pass: scalars[0] += sum( (adj@S1)_partial .* s1 ) ----------------
__global__ __launch_bounds__(256) void k_normmfma(const unsigned short* __restrict__ adj_h,
                                                  const unsigned short* __restrict__ s1T,
                                                  const float* __restrict__ s1,
                                                  float* __restrict__ scalars) {
  __shared__ float red[4];
  const int tid = threadIdx.x;
  const int lane = tid & 63;
  const int w = tid >> 6;
  const int rbase = blockIdx.x * 64 + w * 16;
  const int k0base = blockIdx.y * (NN / KS);
  const int l15 = lane & 15;
  const int kgrp = (lane >> 4) * 8;
  const size_t arow_off = (size_t)(rbase + l15) * NN;
  f32x4 acc[13];
#pragma unroll
  for (int ct = 0; ct < 13; ++ct) acc[ct] = (f32x4){0.f, 0.f, 0.f, 0.f};
#pragma unroll 2
  for (int k0 = 0; k0 < NN / KS; k0 += 32) {
    const int kk = k0base + k0 + kgrp;
    const bf16x8 a = *reinterpret_cast<const bf16x8*>(&adj_h[arow_off + kk]);
#pragma unroll
    for (int ct = 0; ct < 13; ++ct) {
      const bf16x8 b = *reinterpret_cast<const bf16x8*>(&s1T[(size_t)(ct * 16 + l15) * NN + kk]);
      acc[ct] = __builtin_amdgcn_mfma_f32_16x16x32_bf16(a, b, acc[ct], 0, 0, 0);
    }
  }
  const int rout = rbase + (lane >> 4) * 4;
  float sc = 0.f;
#pragma unroll
  for (int ct = 0; ct < 13; ++ct) {
    const int col = ct * 16 + l15;
    if (col < CC) {
#pragma unroll
      for (int r = 0; r < 4; ++r)
        sc = fmaf(acc[ct][r], s1[(size_t)(rout + r) * CC + col], sc);
    }
  }
  sc = wave_sum(sc);
  if (lane == 0) red[w] = sc;
  __syncthreads();
  if (tid == 0) atomicAdd(&scalars[SC(0)], red[0] + red[1] + red[2] + red[3]);
}

// ---------------- conv epilogue (32-wide): sum partials + bias + root, relu, BN stats ----------------
// colsum/colsq are stride-16 padded (one address per 64B)
__global__ __launch_bounds__(256) void k_epi32(const float* __restrict__ part,
                                               const float* __restrict__ bias,
                                               const float* __restrict__ root,
                                               float* __restrict__ t,
                                               float* __restrict__ colsum,
                                               float* __restrict__ colsq) {
  __shared__ float ls[HH], lq[HH];
  const int tid = threadIdx.x;
  const int idx = blockIdx.x * 256 + tid;
  const int c = idx & (HH - 1);
  if (tid < HH) { ls[tid] = 0.f; lq[tid] = 0.f; }
  __syncthreads();
  float s = bias[c] + root[idx];
#pragma unroll
  for (int sp = 0; sp < KS; ++sp) s += part[(size_t)sp * (NN * HH) + idx];
  s = fmaxf(s, 0.f);
  t[idx] = s;
  atomicAdd(&ls[c], s);
  atomicAdd(&lq[c], s * s);
  __syncthreads();
  if (tid < HH) {
    atomicAdd(&colsum[tid * 16], ls[tid]);
    atomicAdd(&colsq[tid * 16], lq[tid]);
  }
}

// ---------------- BN finalize (stride-16 padded stats; re-zeroes them for next use) ----------------
__global__ void k_bnfinal(float* __restrict__ colsum, float* __restrict__ colsq,
                          const float* __restrict__ g, const float* __restrict__ be,
                          float* __restrict__ A, float* __restrict__ B, int Ccols) {
  const int c = threadIdx.x;
  float cs = 0.f, cq = 0.f;
  if (c < Ccols) { cs = colsum[c * 16]; cq = colsq[c * 16]; }
  __syncthreads();
  for (int i = threadIdx.x; i < 4096; i += 256) { colsum[i] = 0.f; colsq[i] = 0.f; }
  if (c >= Ccols) return;
  const float m = cs * (1.f / NN);
  const float var = fmaxf(cq * (1.f / NN) - m * m, 0.f);
  const float a = g[c] / sqrtf(var + 1e-5f);
  A[c] = a;
  B[c] = be[c] - m * a;
}

// xT (optional): bf16 transposed copy [32][N] for the next adj pass
__global__ __launch_bounds__(256) void k_bnapply32(const float* __restrict__ t,
                                                   const float* __restrict__ A,
                                                   const float* __restrict__ B,
                                                   float* __restrict__ xo,
                                                   float* __restrict__ emb, int embOff,
                                                   unsigned short* __restrict__ xT) {
  const int idx = blockIdx.x * 256 + threadIdx.x;
  const int c = idx & (HH - 1);
  const int row = idx >> 5;
  const float v = fmaf(A[c], t[idx], B[c]);
  xo[idx] = v;
  emb[(size_t)row * DD + embOff + c] = v;
  if (xT) xT[(size_t)c * NN + row] = f2bf(v);
}

// ---------------- conv3 epilogue ----------------
__global__ __launch_bounds__(256) void k_epi3(const float* __restrict__ part,
                                              const float* __restrict__ W3r,
                                              const float* __restrict__ b3,
                                              const float* __restrict__ x2,
                                              const float* __restrict__ W3root,
                                              float* __restrict__ t3,
                                              float* __restrict__ colsum,
                                              float* __restrict__ colsq) {
  __shared__ float z[16][33];
  __shared__ float xr[16][33];
  const int row0 = blockIdx.x * 16;
  for (int s = threadIdx.x; s < 16 * 32; s += 256) {
    const int r = s >> 5, k = s & 31;
    float a = 0.f;
#pragma unroll
    for (int sp = 0; sp < KS; ++sp)
      a += part[(size_t)sp * (NN * HH) + (size_t)(row0 + r) * HH + k];
    z[r][k] = a;
    xr[r][k] = x2[(size_t)(row0 + r) * HH + k];
  }
  __syncthreads();
  const int c = threadIdx.x;
  if (c >= CC) return;
  float acc[16];
  const float bb = b3[c];
#pragma unroll
  for (int r = 0; r < 16; ++r) acc[r] = bb;
  for (int k = 0; k < 32; ++k) {
    const float w1 = W3r[k * CC + c];
    const float w2 = W3root[k * CC + c];
#pragma unroll
    for (int r = 0; r < 16; ++r) acc[r] += z[r][k] * w1 + xr[r][k] * w2;
  }
  float lsm = 0.f, lqm = 0.f;
#pragma unroll
  for (int r = 0; r < 16; ++r) {
    const float v = fmaxf(acc[r], 0.f);
    t3[(size_t)(row0 + r) * CC + c] = v;
    lsm += v;
    lqm += v * v;
  }
  atomicAdd(&colsum[c * 16], lsm);
  atomicAdd(&colsq[c * 16], lqm);
}

__global__ void k_bnapply205(const float* __restrict__ t3, const float* __restrict__ A,
                             const float* __restrict__ B, float* __restrict__ x3,
                             float* __restrict__ emb) {
  const int row = blockIdx.x;
  const int c = threadIdx.x;
  if (c >= CC) return;
  const float v = fmaf(A[c], t3[(size_t)row * CC + c], B[c]);
  x3[(size_t)row * CC + c] = v;
  emb[(size_t)row * DD + 2 * HH + c] = v;
}

// ---------------- layer4 (wave-parallel): logits -> relu -> softmax (s1) + sn + s1T + entropy ----------------
__global__ __launch_bounds__(256) void k_layer4(const float* __restrict__ x1,
                                                const float* __restrict__ x2,
                                                const float* __restrict__ x3,
                                                const float* __restrict__ Wl1,
                                                const float* __restrict__ bl1,
                                                float* __restrict__ s1,
                                                float* __restrict__ sn,
                                                unsigned short* __restrict__ s1T,
                                                float* __restrict__ scalars) {
  __shared__ float xr[8][DD + 3];
  __shared__ float redE[4];
  const int row0 = blockIdx.x * 8;
  const int tid = threadIdx.x;
  for (int s = tid; s < 8 * DD; s += 256) {
    const int r = s / DD, d = s - r * DD;
    const int row = row0 + r;
    float v;
    if (d < HH) v = x1[(size_t)row * HH + d];
    else if (d < 2 * HH) v = x2[(size_t)row * HH + (d - HH)];
    else v = x3[(size_t)row * CC + (d - 2 * HH)];
    xr[r][d] = v;
  }
  __syncthreads();
  const int w = tid >> 6;
  const int lane = tid & 63;
  const int r0 = w * 2;
  float bl[4];
#pragma unroll
  for (int j = 0; j < 4; ++j) {
    const int c = lane + 64 * j;
    bl[j] = (c < CC) ? bl1[c] : 0.f;
  }
  float acc[2][4];
#pragma unroll
  for (int r = 0; r < 2; ++r)
#pragma unroll
    for (int j = 0; j < 4; ++j) acc[r][j] = 0.f;
  const float* xa = xr[r0];
  const float* xb = xr[r0 + 1];
#pragma unroll 4
  for (int k = 0; k < DD; ++k) {
    float wv[4];
#pragma unroll
    for (int j = 0; j < 4; ++j) {
      const int c = lane + 64 * j;
      wv[j] = (c < CC) ? Wl1[(size_t)k * CC + c] : 0.f;
    }
    const float va = xa[k];
    const float vb = xb[k];
#pragma unroll
    for (int j = 0; j < 4; ++j) {
      acc[0][j] = fmaf(va, wv[j], acc[0][j]);
      acc[1][j] = fmaf(vb, wv[j], acc[1][j]);
    }
  }
  float ent_acc = 0.f;
#pragma unroll
  for (int r = 0; r < 2; ++r) {
    const int row = row0 + r0 + r;
    float v[4];
    float ml = -1e30f;
#pragma unroll
    for (int j = 0; j < 4; ++j) {
      const int c = lane + 64 * j;
      v[j] = (c < CC) ? fmaxf(acc[r][j] + bl[j], 0.f) : -1e30f;
      ml = fmaxf(ml, v[j]);
    }
    const float m = wave_max(ml);
    float e[4];
    float sl = 0.f;
#pragma unroll
    for (int j = 0; j < 4; ++j) {
      const int c = lane + 64 * j;
      e[j] = (c < CC) ? __expf(v[j] - m) : 0.f;
      sl += e[j];
    }
    const float S = wave_sum(sl);
    const float invS = 1.f / S;
    float p[4];
    float ql = 0.f;
#pragma unroll
    for (int j = 0; j < 4; ++j) {
      p[j] = e[j] * invS;
      ql += p[j] * p[j];
    }
    const float q = wave_sum(ql);
    const float inv = 1.f / fmaxf(sqrtf(q), 1e-8f);
    float m2l = -1e30f;
#pragma unroll
    for (int j = 0; j < 4; ++j) {
      const int c = lane + 64 * j;
      if (c < CC) {
        s1[(size_t)row * CC + c] = p[j];
        sn[(size_t)row * CC + c] = p[j] * inv;
        m2l = fmaxf(m2l, p[j]);
      }
      if (c < 208) s1T[(size_t)c * NN + row] = f2bf(p[j]);
    }
    const float m2 = wave_max(m2l);
    float e2[4];
    float s2l = 0.f;
#pragma unroll
    for (int j = 0; j < 4; ++j) {
      const int c = lane + 64 * j;
      e2[j] = (c < CC) ? __expf(p[j] - m2) : 0.f;
      s2l += e2[j];
    }
    const float S2 = wave_sum(s2l);
    const float invS2 = 1.f / S2;
    float tl = 0.f;
#pragma unroll
    for (int j = 0; j < 4; ++j) {
      const int c = lane + 64 * j;
      if (c < CC) {
        const float sp = e2[j] * invS2;
        tl -= sp * logf(sp + 1e-15f);
      }
    }
    ent_acc += tl;
  }
  ent_acc = wave_sum(ent_acc);
  if (lane == 0) redE[w] = ent_acc;
  __syncthreads();
  if (tid == 0) atomicAdd(&scalars[SC(2)], redE[0] + redE[1] + redE[2] + redE[3]);
}

// ---------------- four Gram matrices ----------------
__global__ __launch_bounds__(256) void k_gram4(const float* __restrict__ xn,
                                               const float* __restrict__ sn,
                                               const float* __restrict__ s1f,
                                               float* __restrict__ G, float* __restrict__ Gxs,
                                               float* __restrict__ Gs, float* __restrict__ Gs0) {
  const int gid = blockIdx.z >> 3;
  const int split = blockIdx.z & 7;
  const float *A, *B;
  float* Cp;
  int Wa, Wb;
  if (gid == 0)      { A = xn;  B = xn;  Cp = G;   Wa = FF; Wb = FF; }
  else if (gid == 1) { A = xn;  B = sn;  Cp = Gxs; Wa = FF; Wb = CC; }
  else if (gid == 2) { A = sn;  B = sn;  Cp = Gs;  Wa = CC; Wb = CC; }
  else               { A = s1f; B = s1f; Cp = Gs0; Wa = CC; Wb = CC; }
  const int tx = blockIdx.x, ty = blockIdx.y;
  if (tx * 64 >= Wa || ty * 64 >= Wb) return;
  __shared__ float sA[32][68];
  __shared__ float sB[32][68];
  const int tid = threadIdx.x;
  const int a0 = (tid >> 4) << 2;
  const int b0 = (tid & 15) << 2;
  const int kb0 = split * (NN / 8);
  float acc[4][4];
#pragma unroll
  for (int i = 0; i < 4; ++i)
#pragma unroll
    for (int j = 0; j < 4; ++j) acc[i][j] = 0.f;

  for (int kb = 0; kb < NN / 8; kb += 32) {
    for (int s = tid; s < 2048; s += 256) {
      const int k = s >> 6, cl = s & 63;
      const int ca = tx * 64 + cl, cb = ty * 64 + cl;
      sA[k][cl] = (ca < Wa) ? A[(size_t)(kb0 + kb + k) * Wa + ca] : 0.f;
      sB[k][cl] = (cb < Wb) ? B[(size_t)(kb0 + kb + k) * Wb + cb] : 0.f;
    }
    __syncthreads();
#pragma unroll 8
    for (int k = 0; k < 32; ++k) {
      const float4 av = *reinterpret_cast<const float4*>(&sA[k][a0]);
      const float4 bv = *reinterpret_cast<const float4*>(&sB[k][b0]);
      acc[0][0] = fmaf(av.x, bv.x, acc[0][0]); acc[0][1] = fmaf(av.x, bv.y, acc[0][1]);
      acc[0][2] = fmaf(av.x, bv.z, acc[0][2]); acc[0][3] = fmaf(av.x, bv.w, acc[0][3]);
      acc[1][0] = fmaf(av.y, bv.x, acc[1][0]); acc[1][1] = fmaf(av.y, bv.y, acc[1][1]);
      acc[1][2] = fmaf(av.y, bv.z, acc[1][2]); acc[1][3] = fmaf(av.y, bv.w, acc[1][3]);
      acc[2][0] = fmaf(av.z, bv.x, acc[2][0]); acc[2][1] = fmaf(av.z, bv.y, acc[2][1]);
      acc[2][2] = fmaf(av.z, bv.z, acc[2][2]); acc[2][3] = fmaf(av.z, bv.w, acc[2][3]);
      acc[3][0] = fmaf(av.w, bv.x, acc[3][0]); acc[3][1] = fmaf(av.w, bv.y, acc[3][1]);
      acc[3][2] = fmaf(av.w, bv.z, acc[3][2]); acc[3][3] = fmaf(av.w, bv.w, acc[3][3]);
    }
    __syncthreads();
  }
#pragma unroll
  for (int r = 0; r < 4; ++r) {
#pragma unroll
    for (int cc = 0; cc < 4; ++cc) {
      const int ca = tx * 64 + a0 + r, cb = ty * 64 + b0 + cc;
      if (ca < Wa && cb < Wb) atomicAdd(&Cp[(size_t)ca * Wb + cb], acc[r][cc]);
    }
  }
}

// ---------------- thin GEMMs (3 in one launch, blockIdx.y selects) ----------------
__global__ __launch_bounds__(256) void k_rowmm3(const float* __restrict__ xn,
                                                const float* __restrict__ sn,
                                                const float* __restrict__ G,
                                                const float* __restrict__ Gxs,
                                                const float* __restrict__ Gs,
                                                float* __restrict__ H1,
                                                float* __restrict__ Uu,
                                                float* __restrict__ H2) {
  const float *A, *B;
  float* Cm;
  int K, Nc;
  if (blockIdx.y == 0)      { A = xn; B = G;   Cm = H1; K = FF; Nc = FF; }
  else if (blockIdx.y == 1) { A = xn; B = Gxs; Cm = Uu; K = FF; Nc = CC; }
  else                      { A = sn; B = Gs;  Cm = H2; K = CC; Nc = CC; }
  __shared__ float sA[16][208];
  const int row0 = blockIdx.x * 16;
  for (int s = threadIdx.x; s < 16 * K; s += 256) {
    const int r = s / K, k = s - r * K;
    sA[r][k] = A[(size_t)(row0 + r) * K + k];
  }
  __syncthreads();
  const int c = threadIdx.x;
  if (c >= Nc) return;
  float acc[16];
#pragma unroll
  for (int r = 0; r < 16; ++r) acc[r] = 0.f;
  for (int k = 0; k < K; ++k) {
    const float w = B[(size_t)k * Nc + c];
#pragma unroll
    for (int r = 0; r < 16; ++r) acc[r] = fmaf(sA[r][k], w, acc[r]);
  }
#pragma unroll
  for (int r = 0; r < 16; ++r) Cm[(size_t)(row0 + r) * Nc + c] = acc[r];
}

// ---------------- per-row sim + team embedding loss (merged, block-level atomics) ----------------
__global__ __launch_bounds__(256) void k_losses(const float* __restrict__ H1,
                                                const float* __restrict__ Uu,
                                                const float* __restrict__ H2,
                                                const float* __restrict__ xn,
                                                const float* __restrict__ sn,
                                                const float* __restrict__ emb,
                                                const int* __restrict__ teams,
                                                const int* __restrict__ reps,
                                                float* __restrict__ scalars) {
  __shared__ float red[4];
  const int tid = threadIdx.x;
  const int lane = tid & 63;
  const int w = tid >> 6;
  if (blockIdx.x < NN / 4) {
    const int row = blockIdx.x * 4 + w;
    float suu = 0.f, suv = 0.f, svv = 0.f;
#pragma unroll
    for (int c0 = 0; c0 < FF; c0 += 64) {
      const float xv = xn[(size_t)row * FF + c0 + lane];
      suu = fmaf(H1[(size_t)row * FF + c0 + lane], xv, suu);
    }
    for (int cb = lane; cb < CC; cb += 64) {
      const float sv = sn[(size_t)row * CC + cb];
      suv = fmaf(Uu[(size_t)row * CC + cb], sv, suv);
      svv = fmaf(H2[(size_t)row * CC + cb], sv, svv);
    }
    suu = wave_sum(suu);
    suv = wave_sum(suv);
    svv = wave_sum(svv);
    if (lane == 0) red[w] = suv / sqrtf(suu * svv);
    __syncthreads();
    if (tid == 0) atomicAdd(&scalars[SC(3)], red[0] + red[1] + red[2] + red[3]);
  } else {
    const int team = blockIdx.x - NN / 4;
    float part = 0.f;
    for (int d = tid; d < DD; d += 256) {
      float a = 0.f, b = 0.f;
#pragma unroll
      for (int m = 0; m < RR; ++m) a += emb[(size_t)reps[team * RR + m] * DD + d];
#pragma unroll
      for (int m = RR; m < TT; ++m) b += emb[(size_t)teams[team * TT + m] * DD + d];
      part += fabsf(a * (1.f / RR) - b * (1.f / (TT - RR)));
    }
    part = wave_sum(part);
    if (lane == 0) red[w] = part;
    __syncthreads();
    if (tid == 0) atomicAdd(&scalars[SC(4)], red[0] + red[1] + red[2] + red[3]);
  }
}

// ---------------- finalize ----------------
__global__ void k_final(const float* __restrict__ Gs0, const float* __restrict__ scalars,
                        float* __restrict__ outsc) {
  __shared__ float red[4];
  float p = 0.f;
  for (int i = threadIdx.x; i < CC * CC; i += 256) {
    const float v = Gs0[i];
    p = fmaf(v, v, p);
  }
  p = wave_sum(p);
  if ((threadIdx.x & 63) == 0) red[threadIdx.x >> 6] = p;
  __syncthreads();
  if (threadIdx.x == 0) {
    const float sumP2 = red[0] + red[1] + red[2] + red[3];
    const float normsq = fmaxf(sumP2 - 2.f * scalars[SC(0)] + scalars[SC(1)], 0.f);
    const float norm = sqrtf(normsq);
    const float e1 = scalars[SC(2)] * (1.f / NN);
    const float sim = -scalars[SC(3)] * (1.f / NN);
    const float embl = scalars[SC(4)] * (1.f / LL);
    outsc[0] = norm;
    outsc[1] = e1;
    outsc[2] = sim;
    outsc[3] = 100.f * norm + 10.f * e1 + 100.f * sim + embl;
    outsc[4] = embl;
  }
}

// ================= launch =================
extern "C" void kernel_launch(void* const* d_in, const int* in_sizes, int n_in,
                              void* d_out, int out_size, void* d_ws, size_t ws_size,
                              hipStream_t stream) {
  const float* x      = (const float*)d_in[0];
  const float* adj    = (const float*)d_in[1];
  const int*   teams  = (const int*)d_in[2];
  const int*   reps   = (const int*)d_in[3];
  const float* W1r    = (const float*)d_in[4];
  const float* b1     = (const float*)d_in[5];
  const float* W1root = (const float*)d_in[6];
  const float* g1     = (const float*)d_in[7];
  const float* be1    = (const float*)d_in[8];
  const float* W2r    = (const float*)d_in[9];
  const float* b2     = (const float*)d_in[10];
  const float* W2root = (const float*)d_in[11];
  const float* g2     = (const float*)d_in[12];
  const float* be2    = (const float*)d_in[13];
  const float* W3r    = (const float*)d_in[14];
  const float* b3     = (const float*)d_in[15];
  const float* W3root = (const float*)d_in[16];
  const float* g3     = (const float*)d_in[17];
  const float* be3    = (const float*)d_in[18];
  const float* Wl1    = (const float*)d_in[19];
  const float* bl1    = (const float*)d_in[20];

  char* wp = (char*)d_ws;
  auto alloc = [&](size_t bytes) { char* p = wp; wp += (bytes + 255) & ~(size_t)255; return p; };
  unsigned short* adj_h = (unsigned short*)alloc((size_t)NN * NN * 2);
  unsigned short* mT    = (unsigned short*)alloc((size_t)HH * NN * 2);
  unsigned short* x2T   = (unsigned short*)alloc((size_t)HH * NN * 2);
  unsigned short* s1T   = (unsigned short*)alloc((size_t)208 * NN * 2);
  float* rootb  = (float*)alloc((size_t)NN * HH * 4);
  float* t      = (float*)alloc((size_t)NN * HH * 4);
  float* x1     = (float*)alloc((size_t)NN * HH * 4);
  float* x2     = (float*)alloc((size_t)NN * HH * 4);
  float* part   = (float*)alloc((size_t)KS * NN * HH * 4);
  float* t3     = (float*)alloc((size_t)NN * CC * 4);
  float* x3     = (float*)alloc((size_t)NN * CC * 4);
  float* sn     = (float*)alloc((size_t)NN * CC * 4);
  float* xn     = (float*)alloc((size_t)NN * FF * 4);
  float* H1     = (float*)alloc((size_t)NN * FF * 4);
  float* Uu     = (float*)alloc((size_t)NN * CC * 4);
  float* H2     = (float*)alloc((size_t)NN * CC * 4);
  float* G      = (float*)alloc((size_t)FF * FF * 4);
  float* Gxs    = (float*)alloc((size_t)FF * CC * 4);
  float* Gs     = (float*)alloc((size_t)CC * CC * 4);
  float* Gs0    = (float*)alloc((size_t)CC * CC * 4);
  float* scalars = (float*)alloc(160 * 4);
  float* colsum = (float*)alloc(4096 * 4);
  float* colsq  = (float*)alloc(4096 * 4);
  float* bnA    = (float*)alloc(1024);
  float* bnB    = (float*)alloc(1024);
  (void)ws_size; (void)in_sizes; (void)n_in; (void)out_size;

  float* out   = (float*)d_out;
  float* s1    = out;                          // N*C
  float* outsc = out + (size_t)NN * CC;        // 5 scalars
  float* emb   = out + (size_t)NN * CC + 5;    // N*D

  // zero accumulators (G..scalars contiguous region) + padded BN stats (bnfinal re-zeroes between convs)
  hipMemsetAsync(G, 0, (size_t)((char*)scalars + 160 * 4 - (char*)G), stream);
  hipMemsetAsync(colsum, 0, 2 * 4096 * 4, stream);

  k_xn<<<NN / 4, 256, 0, stream>>>(x, xn);

  // conv1 (fused: adj cvt + adj^2 + MFMA)
  k_proj_t<<<512, 256, 0, stream>>>(x, W1r, W1root, mT, rootb, FF);
  k_conv1f<<<dim3(NN / 64, KS), 256, 0, stream>>>(adj, adj_h, mT, part, scalars);
  k_epi32<<<NN * HH / 256, 256, 0, stream>>>(part, b1, rootb, t, colsum, colsq);
  k_bnfinal<<<1, 256, 0, stream>>>(colsum, colsq, g1, be1, bnA, bnB, HH);
  k_bnapply32<<<NN * HH / 256, 256, 0, stream>>>(t, bnA, bnB, x1, emb, 0, (unsigned short*)nullptr);

  // conv2
  k_proj_t<<<512, 256, 0, stream>>>(x1, W2r, W2root, mT, rootb, HH);
  k_adjmm<<<dim3(NN / 64, KS), 256, 0, stream>>>(adj_h, mT, part);
  k_epi32<<<NN * HH / 256, 256, 0, stream>>>(part, b2, rootb, t, colsum, colsq);
  k_bnfinal<<<1, 256, 0, stream>>>(colsum, colsq, g2, be2, bnA, bnB, HH);
  k_bnapply32<<<NN * HH / 256, 256, 0, stream>>>(t, bnA, bnB, x2, emb, HH, x2T);

  // conv3
  k_adjmm<<<dim3(NN / 64, KS), 256, 0, stream>>>(adj_h, x2T, part);
  k_epi3<<<NN / 16, 256, 0, stream>>>(part, W3r, b3, x2, W3root, t3, colsum, colsq);
  k_bnfinal<<<1, 256, 0, stream>>>(colsum, colsq, g3, be3, bnA, bnB, CC);
  k_bnapply205<<<NN, 256, 0, stream>>>(t3, bnA, bnB, x3, emb);

  // head (wave-parallel softmax; also zero-fills s1T pad cols 205..207)
  k_layer4<<<NN / 8, 256, 0, stream>>>(x1, x2, x3, Wl1, bl1, s1, sn, s1T, scalars);

  // tr(S' A S) via MFMA
  k_normmfma<<<dim3(NN / 64, KS), 256, 0, stream>>>(adj_h, s1T, s1, scalars);

  // Grams + bilinear forms + losses + finalize
  k_gram4<<<dim3(4, 4, 32), 256, 0, stream>>>(xn, sn, s1, G, Gxs, Gs, Gs0);
  k_rowmm3<<<dim3(NN / 16, 3), 256, 0, stream>>>(xn, sn, G, Gxs, Gs, H1, Uu, H2);
  k_losses<<<NN / 4 + LL, 256, 0, stream>>>(H1, Uu, H2, xn, sn, emb, teams, reps, scalars);
  k_final<<<1, 256, 0, stream>>>(Gs0, scalars, outsc);
}

// Round 5
// 430.312 us; speedup vs baseline: 2.1497x; 1.1551x over previous
//
#include <hip/hip_runtime.h>
#include <math.h>

#define NN 4096
#define FF 128
#define HH 32
#define CC 205
#define DD 269
#define LL 512
#define TT 12
#define RR 4
#define KS 16    // k-split for all adj MFMA passes
#define GP 208   // padded gram dim

// padded scalar slots (one cache line apart): 0=trSAS 1=adjsq 2=entropy 3=sim 4=embloss
#define SC(i) ((i) * 32)

typedef __attribute__((ext_vector_type(8))) short bf16x8;
typedef __attribute__((ext_vector_type(4))) float f32x4;

// ---------------- helpers ----------------
__device__ __forceinline__ float wave_sum(float v) {
#pragma unroll
  for (int o = 32; o > 0; o >>= 1) v += __shfl_xor(v, o, 64);
  return v;
}
__device__ __forceinline__ float wave_max(float v) {
#pragma unroll
  for (int o = 32; o > 0; o >>= 1) v = fmaxf(v, __shfl_xor(v, o, 64));
  return v;
}
__device__ __forceinline__ unsigned short f2bf(float x) {  // RNE
  union { float f; unsigned u; } v; v.f = x;
  unsigned r = v.u + 0x7FFFu + ((v.u >> 16) & 1u);
  return (unsigned short)(r >> 16);
}

// ---------------- dual projection: o1T(bf16,[32][N]) = (A@W1)^T, o2(f32,[N][32]) = A@W2 ----------------
__global__ __launch_bounds__(256) void k_proj_t(const float* __restrict__ A,
                                                const float* __restrict__ W1,
                                                const float* __restrict__ W2,
                                                unsigned short* __restrict__ o1T,
                                                float* __restrict__ o2, int K) {
  const int idx = blockIdx.x * 256 + threadIdx.x;  // N*32
  const int row = idx >> 5;
  const int c = idx & 31;
  float a1 = 0.f, a2 = 0.f;
  for (int k = 0; k < K; ++k) {
    const float av = A[(size_t)row * K + k];
    a1 = fmaf(av, W1[k * HH + c], a1);
    a2 = fmaf(av, W2[k * HH + c], a2);
  }
  o1T[(size_t)c * NN + row] = f2bf(a1);
  o2[idx] = a2;
}

// ---------------- row-normalize x -> xn (+ bf16 transposed xnT [208][N], pad rows zero) ----------------
__global__ __launch_bounds__(256) void k_xn(const float* __restrict__ x, float* __restrict__ xn,
                                            unsigned short* __restrict__ xnT) {
  const int lane = threadIdx.x & 63;
  const int row = blockIdx.x * 4 + (threadIdx.x >> 6);
  float v0 = x[(size_t)row * FF + lane];
  float v1 = x[(size_t)row * FF + 64 + lane];
  float ss = wave_sum(v0 * v0 + v1 * v1);
  float n = fmaxf(sqrtf(ss), 1e-8f);
  const float a = v0 / n, b = v1 / n;
  xn[(size_t)row * FF + lane] = a;
  xn[(size_t)row * FF + 64 + lane] = b;
  xnT[(size_t)lane * NN + row] = f2bf(a);
  xnT[(size_t)(64 + lane) * NN + row] = f2bf(b);
  xnT[(size_t)(128 + lane) * NN + row] = 0;
  if (lane < 16) xnT[(size_t)(192 + lane) * NN + row] = 0;
}

// ---------------- FUSED conv1 adj pass: fp32 adj -> bf16 (write adj_h) + sum(adj^2) + MFMA ----------------
// grid (NN/64, KS), 256 threads. Block owns a disjoint 64-row x 256-col tile of adj.
__global__ __launch_bounds__(256) void k_conv1f(const float* __restrict__ adj,
                                                unsigned short* __restrict__ adj_h,
                                                const unsigned short* __restrict__ BT,
                                                float* __restrict__ part,
                                                float* __restrict__ scalars) {
  __shared__ unsigned short sA[64][264];
  __shared__ float red[4];
  const int tid = threadIdx.x;
  const int rbase_blk = blockIdx.x * 64;
  const int kbase = blockIdx.y * 256;
  float adjsq = 0.f;
#pragma unroll
  for (int i = 0; i < 16; ++i) {
    const int fi = i * 256 + tid;  // 0..4095 float4s of the 64x256 tile
    const int r = fi >> 6;
    const int c4 = fi & 63;
    const size_t goff = (size_t)(rbase_blk + r) * NN + kbase + c4 * 4;
    const float4 v = *reinterpret_cast<const float4*>(&adj[goff]);
    adjsq += v.x * v.x + v.y * v.y + v.z * v.z + v.w * v.w;
    ushort4 h;
    h.x = f2bf(v.x); h.y = f2bf(v.y); h.z = f2bf(v.z); h.w = f2bf(v.w);
    *reinterpret_cast<ushort4*>(&adj_h[goff]) = h;
    *reinterpret_cast<ushort4*>(&sA[r][c4 * 4]) = h;
  }
  __syncthreads();
  const int lane = tid & 63;
  const int w = tid >> 6;
  const int l15 = lane & 15;
  const int kgrp = (lane >> 4) * 8;
  const int rloc = w * 16 + l15;
  f32x4 acc0 = {0.f, 0.f, 0.f, 0.f}, acc1 = {0.f, 0.f, 0.f, 0.f};
#pragma unroll
  for (int k0 = 0; k0 < 256; k0 += 32) {
    const bf16x8 a = *reinterpret_cast<const bf16x8*>(&sA[rloc][k0 + kgrp]);
    const bf16x8 b0 = *reinterpret_cast<const bf16x8*>(&BT[(size_t)l15 * NN + kbase + k0 + kgrp]);
    const bf16x8 b1 = *reinterpret_cast<const bf16x8*>(&BT[(size_t)(16 + l15) * NN + kbase + k0 + kgrp]);
    acc0 = __builtin_amdgcn_mfma_f32_16x16x32_bf16(a, b0, acc0, 0, 0, 0);
    acc1 = __builtin_amdgcn_mfma_f32_16x16x32_bf16(a, b1, acc1, 0, 0, 0);
  }
  float* pp = part + (size_t)blockIdx.y * (NN * HH);
  const int rout = rbase_blk + w * 16 + (lane >> 4) * 4;
#pragma unroll
  for (int r = 0; r < 4; ++r) {
    pp[(size_t)(rout + r) * HH + l15] = acc0[r];
    pp[(size_t)(rout + r) * HH + 16 + l15] = acc1[r];
  }
  adjsq = wave_sum(adjsq);
  if (lane == 0) red[w] = adjsq;
  __syncthreads();
  if (tid == 0) atomicAdd(&scalars[SC(1)], red[0] + red[1] + red[2] + red[3]);
}

// ---------------- MFMA adj pass: part[split] = adj_h[rows] @ M  (M via BT bf16 [32][N]) ----------------
__global__ __launch_bounds__(256) void k_adjmm(const unsigned short* __restrict__ adj_h,
                                               const unsigned short* __restrict__ BT,
                                               float* __restrict__ part) {
  const int tid = threadIdx.x;
  const int lane = tid & 63;
  const int w = tid >> 6;
  const int rbase = blockIdx.x * 64 + w * 16;
  const int k0base = blockIdx.y * (NN / KS);
  const int l15 = lane & 15;
  const int kgrp = (lane >> 4) * 8;
  const size_t arow_off = (size_t)(rbase + l15) * NN;
  f32x4 acc0 = {0.f, 0.f, 0.f, 0.f}, acc1 = {0.f, 0.f, 0.f, 0.f};
#pragma unroll
  for (int k0 = 0; k0 < NN / KS; k0 += 32) {
    const int kk = k0base + k0 + kgrp;
    const bf16x8 a = *reinterpret_cast<const bf16x8*>(&adj_h[arow_off + kk]);
    const bf16x8 b0 = *reinterpret_cast<const bf16x8*>(&BT[(size_t)l15 * NN + kk]);
    const bf16x8 b1 = *reinterpret_cast<const bf16x8*>(&BT[(size_t)(16 + l15) * NN + kk]);
    acc0 = __builtin_amdgcn_mfma_f32_16x16x32_bf16(a, b0, acc0, 0, 0, 0);
    acc1 = __builtin_amdgcn_mfma_f32_16x16x32_bf16(a, b1, acc1, 0, 0, 0);
  }
  float* pp = part + (size_t)blockIdx.y * (NN * HH);
  const int rout = rbase + (lane >> 4) * 4;
#pragma unroll
  for (int r = 0; r < 4; ++r) {
    pp[(size_t)(rout + r) * HH + l15] = acc0[r];
    pp[(size_t)(rout + r) * HH + 16 + l15] = acc1[r];
  }
}

// ---------------- MFMA norm pass: scalars[0] += sum( (adj@S1)_partial .* s1 ) ----------------
__global__ __launch_bounds__(256) void k_normmfma(const unsigned short* __restrict__ adj_h,
                                                  const unsigned short* __restrict__ s1T,
                                                  const float* __restrict__ s1,
                                                  float* __restrict__ scalars) {
  __shared__ float red[4];
  const int tid = threadIdx.x;
  const int lane = tid & 63;
  const int w = tid >> 6;
  const int rbase = blockIdx.x * 64 + w * 16;
  const int k0base = blockIdx.y * (NN / KS);
  const int l15 = lane & 15;
  const int kgrp = (lane >> 4) * 8;
  const size_t arow_off = (size_t)(rbase + l15) * NN;
  f32x4 acc[13];
#pragma unroll
  for (int ct = 0; ct < 13; ++ct) acc[ct] = (f32x4){0.f, 0.f, 0.f, 0.f};
#pragma unroll 2
  for (int k0 = 0; k0 < NN / KS; k0 += 32) {
    const int kk = k0base + k0 + kgrp;
    const bf16x8 a = *reinterpret_cast<const bf16x8*>(&adj_h[arow_off + kk]);
#pragma unroll
    for (int ct = 0; ct < 13; ++ct) {
      const bf16x8 b = *reinterpret_cast<const bf16x8*>(&s1T[(size_t)(ct * 16 + l15) * NN + kk]);
      acc[ct] = __builtin_amdgcn_mfma_f32_16x16x32_bf16(a, b, acc[ct], 0, 0, 0);
    }
  }
  const int rout = rbase + (lane >> 4) * 4;
  float sc = 0.f;
#pragma unroll
  for (int ct = 0; ct < 13; ++ct) {
    const int col = ct * 16 + l15;
    if (col < CC) {
#pragma unroll
      for (int r = 0; r < 4; ++r)
        sc = fmaf(acc[ct][r], s1[(size_t)(rout + r) * CC + col], sc);
    }
  }
  sc = wave_sum(sc);
  if (lane == 0) red[w] = sc;
  __syncthreads();
  if (tid == 0) atomicAdd(&scalars[SC(0)], red[0] + red[1] + red[2] + red[3]);
}

// ---------------- conv epilogue (32-wide): sum partials + bias + root, relu, BN stats ----------------
// colsum/colsq are stride-16 padded (one address per 64B)
__global__ __launch_bounds__(256) void k_epi32(const float* __restrict__ part,
                                               const float* __restrict__ bias,
                                               const float* __restrict__ root,
                                               float* __restrict__ t,
                                               float* __restrict__ colsum,
                                               float* __restrict__ colsq) {
  __shared__ float ls[HH], lq[HH];
  const int tid = threadIdx.x;
  const int idx = blockIdx.x * 256 + tid;
  const int c = idx & (HH - 1);
  if (tid < HH) { ls[tid] = 0.f; lq[tid] = 0.f; }
  __syncthreads();
  float s = bias[c] + root[idx];
#pragma unroll
  for (int sp = 0; sp < KS; ++sp) s += part[(size_t)sp * (NN * HH) + idx];
  s = fmaxf(s, 0.f);
  t[idx] = s;
  atomicAdd(&ls[c], s);
  atomicAdd(&lq[c], s * s);
  __syncthreads();
  if (tid < HH) {
    atomicAdd(&colsum[tid * 16], ls[tid]);
    atomicAdd(&colsq[tid * 16], lq[tid]);
  }
}

// ---------------- BN finalize (stride-16 padded stats; re-zeroes them for next use) ----------------
__global__ void k_bnfinal(float* __restrict__ colsum, float* __restrict__ colsq,
                          const float* __restrict__ g, const float* __restrict__ be,
                          float* __restrict__ A, float* __restrict__ B, int Ccols) {
  const int c = threadIdx.x;
  float cs = 0.f, cq = 0.f;
  if (c < Ccols) { cs = colsum[c * 16]; cq = colsq[c * 16]; }
  __syncthreads();
  for (int i = threadIdx.x; i < 4096; i += 256) { colsum[i] = 0.f; colsq[i] = 0.f; }
  if (c >= Ccols) return;
  const float m = cs * (1.f / NN);
  const float var = fmaxf(cq * (1.f / NN) - m * m, 0.f);
  const float a = g[c] / sqrtf(var + 1e-5f);
  A[c] = a;
  B[c] = be[c] - m * a;
}

// xT (optional): bf16 transposed copy [32][N] for the next adj pass
__global__ __launch_bounds__(256) void k_bnapply32(const float* __restrict__ t,
                                                   const float* __restrict__ A,
                                                   const float* __restrict__ B,
                                                   float* __restrict__ xo,
                                                   float* __restrict__ emb, int embOff,
                                                   unsigned short* __restrict__ xT) {
  const int idx = blockIdx.x * 256 + threadIdx.x;
  const int c = idx & (HH - 1);
  const int row = idx >> 5;
  const float v = fmaf(A[c], t[idx], B[c]);
  xo[idx] = v;
  emb[(size_t)row * DD + embOff + c] = v;
  if (xT) xT[(size_t)c * NN + row] = f2bf(v);
}

// ---------------- conv3 epilogue ----------------
__global__ __launch_bounds__(256) void k_epi3(const float* __restrict__ part,
                                              const float* __restrict__ W3r,
                                              const float* __restrict__ b3,
                                              const float* __restrict__ x2,
                                              const float* __restrict__ W3root,
                                              float* __restrict__ t3,
                                              float* __restrict__ colsum,
                                              float* __restrict__ colsq) {
  __shared__ float z[16][33];
  __shared__ float xr[16][33];
  const int row0 = blockIdx.x * 16;
  for (int s = threadIdx.x; s < 16 * 32; s += 256) {
    const int r = s >> 5, k = s & 31;
    float a = 0.f;
#pragma unroll
    for (int sp = 0; sp < KS; ++sp)
      a += part[(size_t)sp * (NN * HH) + (size_t)(row0 + r) * HH + k];
    z[r][k] = a;
    xr[r][k] = x2[(size_t)(row0 + r) * HH + k];
  }
  __syncthreads();
  const int c = threadIdx.x;
  if (c >= CC) return;
  float acc[16];
  const float bb = b3[c];
#pragma unroll
  for (int r = 0; r < 16; ++r) acc[r] = bb;
  for (int k = 0; k < 32; ++k) {
    const float w1 = W3r[k * CC + c];
    const float w2 = W3root[k * CC + c];
#pragma unroll
    for (int r = 0; r < 16; ++r) acc[r] += z[r][k] * w1 + xr[r][k] * w2;
  }
  float lsm = 0.f, lqm = 0.f;
#pragma unroll
  for (int r = 0; r < 16; ++r) {
    const float v = fmaxf(acc[r], 0.f);
    t3[(size_t)(row0 + r) * CC + c] = v;
    lsm += v;
    lqm += v * v;
  }
  atomicAdd(&colsum[c * 16], lsm);
  atomicAdd(&colsq[c * 16], lqm);
}

__global__ void k_bnapply205(const float* __restrict__ t3, const float* __restrict__ A,
                             const float* __restrict__ B, float* __restrict__ x3,
                             float* __restrict__ emb) {
  const int row = blockIdx.x;
  const int c = threadIdx.x;
  if (c >= CC) return;
  const float v = fmaf(A[c], t3[(size_t)row * CC + c], B[c]);
  x3[(size_t)row * CC + c] = v;
  emb[(size_t)row * DD + 2 * HH + c] = v;
}

// ---------------- layer4 (wave-parallel): logits -> relu -> softmax (s1) + sn/snT + s1T + entropy ----------------
__global__ __launch_bounds__(256) void k_layer4(const float* __restrict__ x1,
                                                const float* __restrict__ x2,
                                                const float* __restrict__ x3,
                                                const float* __restrict__ Wl1,
                                                const float* __restrict__ bl1,
                                                float* __restrict__ s1,
                                                float* __restrict__ sn,
                                                unsigned short* __restrict__ s1T,
                                                unsigned short* __restrict__ snT,
                                                float* __restrict__ scalars) {
  __shared__ float xr[8][DD + 3];
  __shared__ float redE[4];
  const int row0 = blockIdx.x * 8;
  const int tid = threadIdx.x;
  for (int s = tid; s < 8 * DD; s += 256) {
    const int r = s / DD, d = s - r * DD;
    const int row = row0 + r;
    float v;
    if (d < HH) v = x1[(size_t)row * HH + d];
    else if (d < 2 * HH) v = x2[(size_t)row * HH + (d - HH)];
    else v = x3[(size_t)row * CC + (d - 2 * HH)];
    xr[r][d] = v;
  }
  __syncthreads();
  const int w = tid >> 6;
  const int lane = tid & 63;
  const int r0 = w * 2;
  float bl[4];
#pragma unroll
  for (int j = 0; j < 4; ++j) {
    const int c = lane + 64 * j;
    bl[j] = (c < CC) ? bl1[c] : 0.f;
  }
  float acc[2][4];
#pragma unroll
  for (int r = 0; r < 2; ++r)
#pragma unroll
    for (int j = 0; j < 4; ++j) acc[r][j] = 0.f;
  const float* xa = xr[r0];
  const float* xb = xr[r0 + 1];
#pragma unroll 4
  for (int k = 0; k < DD; ++k) {
    float wv[4];
#pragma unroll
    for (int j = 0; j < 4; ++j) {
      const int c = lane + 64 * j;
      wv[j] = (c < CC) ? Wl1[(size_t)k * CC + c] : 0.f;
    }
    const float va = xa[k];
    const float vb = xb[k];
#pragma unroll
    for (int j = 0; j < 4; ++j) {
      acc[0][j] = fmaf(va, wv[j], acc[0][j]);
      acc[1][j] = fmaf(vb, wv[j], acc[1][j]);
    }
  }
  float ent_acc = 0.f;
#pragma unroll
  for (int r = 0; r < 2; ++r) {
    const int row = row0 + r0 + r;
    float v[4];
    float ml = -1e30f;
#pragma unroll
    for (int j = 0; j < 4; ++j) {
      const int c = lane + 64 * j;
      v[j] = (c < CC) ? fmaxf(acc[r][j] + bl[j], 0.f) : -1e30f;
      ml = fmaxf(ml, v[j]);
    }
    const float m = wave_max(ml);
    float e[4];
    float sl = 0.f;
#pragma unroll
    for (int j = 0; j < 4; ++j) {
      const int c = lane + 64 * j;
      e[j] = (c < CC) ? __expf(v[j] - m) : 0.f;
      sl += e[j];
    }
    const float S = wave_sum(sl);
    const float invS = 1.f / S;
    float p[4];
    float ql = 0.f;
#pragma unroll
    for (int j = 0; j < 4; ++j) {
      p[j] = e[j] * invS;
      ql += p[j] * p[j];
    }
    const float q = wave_sum(ql);
    const float inv = 1.f / fmaxf(sqrtf(q), 1e-8f);
    float m2l = -1e30f;
#pragma unroll
    for (int j = 0; j < 4; ++j) {
      const int c = lane + 64 * j;
      if (c < CC) {
        s1[(size_t)row * CC + c] = p[j];
        sn[(size_t)row * CC + c] = p[j] * inv;
        m2l = fmaxf(m2l, p[j]);
      }
      if (c < GP) {
        s1T[(size_t)c * NN + row] = f2bf(p[j]);
        snT[(size_t)c * NN + row] = f2bf(p[j] * inv);
      }
    }
    const float m2 = wave_max(m2l);
    float e2[4];
    float s2l = 0.f;
#pragma unroll
    for (int j = 0; j < 4; ++j) {
      const int c = lane + 64 * j;
      e2[j] = (c < CC) ? __expf(p[j] - m2) : 0.f;
      s2l += e2[j];
    }
    const float S2 = wave_sum(s2l);
    const float invS2 = 1.f / S2;
    float tl = 0.f;
#pragma unroll
    for (int j = 0; j < 4; ++j) {
      const int c = lane + 64 * j;
      if (c < CC) {
        const float sp = e2[j] * invS2;
        tl -= sp * logf(sp + 1e-15f);
      }
    }
    ent_acc += tl;
  }
  ent_acc = wave_sum(ent_acc);
  if (lane == 0) redE[w] = ent_acc;
  __syncthreads();
  if (tid == 0) atomicAdd(&scalars[SC(2)], redE[0] + redE[1] + redE[2] + redE[3]);
}

// ---------------- MFMA Gram: Cp[GP][GP] = P^T Q from transposed bf16 [GP][NN] operands ----------------
// grid (13, 13, 4); 4 waves/block, wave w = k-quarter; LDS reduce; direct store (no atomics)
__global__ __launch_bounds__(256) void k_gramm(const unsigned short* __restrict__ xnT,
                                               const unsigned short* __restrict__ snT,
                                               const unsigned short* __restrict__ s1T,
                                               float* __restrict__ G, float* __restrict__ Gxs,
                                               float* __restrict__ Gs, float* __restrict__ Gs0) {
  const int gid = blockIdx.z;
  const int tp = blockIdx.x * 16;
  const int tq = blockIdx.y * 16;
  const unsigned short *PT, *QT;
  float* Cp;
  if (gid == 0)      { PT = xnT; QT = xnT; Cp = G;   if (tp >= FF || tq >= FF) return; }
  else if (gid == 1) { PT = xnT; QT = snT; Cp = Gxs; if (tp >= FF) return; }
  else if (gid == 2) { PT = snT; QT = snT; Cp = Gs; }
  else               { PT = s1T; QT = s1T; Cp = Gs0; }
  const int tid = threadIdx.x;
  const int lane = tid & 63;
  const int w = tid >> 6;
  const int l15 = lane & 15;
  const int kgrp = (lane >> 4) * 8;
  const int kb0 = w * (NN / 4);
  f32x4 acc = {0.f, 0.f, 0.f, 0.f};
#pragma unroll 8
  for (int k0 = 0; k0 < NN / 4; k0 += 32) {
    const int kk = kb0 + k0 + kgrp;
    const bf16x8 a = *reinterpret_cast<const bf16x8*>(&PT[(size_t)(tp + l15) * NN + kk]);
    const bf16x8 b = *reinterpret_cast<const bf16x8*>(&QT[(size_t)(tq + l15) * NN + kk]);
    acc = __builtin_amdgcn_mfma_f32_16x16x32_bf16(a, b, acc, 0, 0, 0);
  }
  __shared__ float red[4][16][17];
  const int crow = (lane >> 4) * 4;
#pragma unroll
  for (int r = 0; r < 4; ++r) red[w][crow + r][l15] = acc[r];
  __syncthreads();
  const int rr = tid >> 4, cc = tid & 15;
  const float v = red[0][rr][cc] + red[1][rr][cc] + red[2][rr][cc] + red[3][rr][cc];
  Cp[(size_t)(tp + rr) * GP + (tq + cc)] = v;
}

// ---------------- thin GEMMs (3 in one launch, blockIdx.y selects); B has stride GP ----------------
__global__ __launch_bounds__(256) void k_rowmm3(const float* __restrict__ xn,
                                                const float* __restrict__ sn,
                                                const float* __restrict__ G,
                                                const float* __restrict__ Gxs,
                                                const float* __restrict__ Gs,
                                                float* __restrict__ H1,
                                                float* __restrict__ Uu,
                                                float* __restrict__ H2) {
  const float *A, *B;
  float* Cm;
  int K, Nc;
  if (blockIdx.y == 0)      { A = xn; B = G;   Cm = H1; K = FF; Nc = FF; }
  else if (blockIdx.y == 1) { A = xn; B = Gxs; Cm = Uu; K = FF; Nc = CC; }
  else                      { A = sn; B = Gs;  Cm = H2; K = CC; Nc = CC; }
  __shared__ float sA[16][208];
  const int row0 = blockIdx.x * 16;
  for (int s = threadIdx.x; s < 16 * K; s += 256) {
    const int r = s / K, k = s - r * K;
    sA[r][k] = A[(size_t)(row0 + r) * K + k];
  }
  __syncthreads();
  const int c = threadIdx.x;
  if (c >= Nc) return;
  float acc[16];
#pragma unroll
  for (int r = 0; r < 16; ++r) acc[r] = 0.f;
  for (int k = 0; k < K; ++k) {
    const float w = B[(size_t)k * GP + c];
#pragma unroll
    for (int r = 0; r < 16; ++r) acc[r] = fmaf(sA[r][k], w, acc[r]);
  }
#pragma unroll
  for (int r = 0; r < 16; ++r) Cm[(size_t)(row0 + r) * Nc + c] = acc[r];
}

// ---------------- per-row sim + team embedding loss (merged, block-level atomics) ----------------
__global__ __launch_bounds__(256) void k_losses(const float* __restrict__ H1,
                                                const float* __restrict__ Uu,
                                                const float* __restrict__ H2,
                                                const float* __restrict__ xn,
                                                const float* __restrict__ sn,
                                                const float* __restrict__ emb,
                                                const int* __restrict__ teams,
                                                const int* __restrict__ reps,
                                                float* __restrict__ scalars) {
  __shared__ float red[4];
  const int tid = threadIdx.x;
  const int lane = tid & 63;
  const int w = tid >> 6;
  if (blockIdx.x < NN / 4) {
    const int row = blockIdx.x * 4 + w;
    float suu = 0.f, suv = 0.f, svv = 0.f;
#pragma unroll
    for (int c0 = 0; c0 < FF; c0 += 64) {
      const float xv = xn[(size_t)row * FF + c0 + lane];
      suu = fmaf(H1[(size_t)row * FF + c0 + lane], xv, suu);
    }
    for (int cb = lane; cb < CC; cb += 64) {
      const float sv = sn[(size_t)row * CC + cb];
      suv = fmaf(Uu[(size_t)row * CC + cb], sv, suv);
      svv = fmaf(H2[(size_t)row * CC + cb], sv, svv);
    }
    suu = wave_sum(suu);
    suv = wave_sum(suv);
    svv = wave_sum(svv);
    if (lane == 0) red[w] = suv / sqrtf(suu * svv);
    __syncthreads();
    if (tid == 0) atomicAdd(&scalars[SC(3)], red[0] + red[1] + red[2] + red[3]);
  } else {
    const int team = blockIdx.x - NN / 4;
    float part = 0.f;
    for (int d = tid; d < DD; d += 256) {
      float a = 0.f, b = 0.f;
#pragma unroll
      for (int m = 0; m < RR; ++m) a += emb[(size_t)reps[team * RR + m] * DD + d];
#pragma unroll
      for (int m = RR; m < TT; ++m) b += emb[(size_t)teams[team * TT + m] * DD + d];
      part += fabsf(a * (1.f / RR) - b * (1.f / (TT - RR)));
    }
    part = wave_sum(part);
    if (lane == 0) red[w] = part;
    __syncthreads();
    if (tid == 0) atomicAdd(&scalars[SC(4)], red[0] + red[1] + red[2] + red[3]);
  }
}

// ---------------- finalize ----------------
__global__ void k_final(const float* __restrict__ Gs0, const float* __restrict__ scalars,
                        float* __restrict__ outsc) {
  __shared__ float red[4];
  float p = 0.f;
  for (int i = threadIdx.x; i < GP * GP; i += 256) {
    const float v = Gs0[i];
    p = fmaf(v, v, p);
  }
  p = wave_sum(p);
  if ((threadIdx.x & 63) == 0) red[threadIdx.x >> 6] = p;
  __syncthreads();
  if (threadIdx.x == 0) {
    const float sumP2 = red[0] + red[1] + red[2] + red[3];
    const float normsq = fmaxf(sumP2 - 2.f * scalars[SC(0)] + scalars[SC(1)], 0.f);
    const float norm = sqrtf(normsq);
    const float e1 = scalars[SC(2)] * (1.f / NN);
    const float sim = -scalars[SC(3)] * (1.f / NN);
    const float embl = scalars[SC(4)] * (1.f / LL);
    outsc[0] = norm;
    outsc[1] = e1;
    outsc[2] = sim;
    outsc[3] = 100.f * norm + 10.f * e1 + 100.f * sim + embl;
    outsc[4] = embl;
  }
}

// ================= launch =================
extern "C" void kernel_launch(void* const* d_in, const int* in_sizes, int n_in,
                              void* d_out, int out_size, void* d_ws, size_t ws_size,
                              hipStream_t stream) {
  const float* x      = (const float*)d_in[0];
  const float* adj    = (const float*)d_in[1];
  const int*   teams  = (const int*)d_in[2];
  const int*   reps   = (const int*)d_in[3];
  const float* W1r    = (const float*)d_in[4];
  const float* b1     = (const float*)d_in[5];
  const float* W1root = (const float*)d_in[6];
  const float* g1     = (const float*)d_in[7];
  const float* be1    = (const float*)d_in[8];
  const float* W2r    = (const float*)d_in[9];
  const float* b2     = (const float*)d_in[10];
  const float* W2root = (const float*)d_in[11];
  const float* g2     = (const float*)d_in[12];
  const float* be2    = (const float*)d_in[13];
  const float* W3r    = (const float*)d_in[14];
  const float* b3     = (const float*)d_in[15];
  const float* W3root = (const float*)d_in[16];
  const float* g3     = (const float*)d_in[17];
  const float* be3    = (const float*)d_in[18];
  const float* Wl1    = (const float*)d_in[19];
  const float* bl1    = (const float*)d_in[20];

  char* wp = (char*)d_ws;
  auto alloc = [&](size_t bytes) { char* p = wp; wp += (bytes + 255) & ~(size_t)255; return p; };
  unsigned short* adj_h = (unsigned short*)alloc((size_t)NN * NN * 2);
  unsigned short* mT    = (unsigned short*)alloc((size_t)HH * NN * 2);
  unsigned short* x2T   = (unsigned short*)alloc((size_t)HH * NN * 2);
  unsigned short* s1T   = (unsigned short*)alloc((size_t)GP * NN * 2);
  unsigned short* snT   = (unsigned short*)alloc((size_t)GP * NN * 2);
  unsigned short* xnT   = (unsigned short*)alloc((size_t)GP * NN * 2);
  float* rootb  = (float*)alloc((size_t)NN * HH * 4);
  float* t      = (float*)alloc((size_t)NN * HH * 4);
  float* x1     = (float*)alloc((size_t)NN * HH * 4);
  float* x2     = (float*)alloc((size_t)NN * HH * 4);
  float* part   = (float*)alloc((size_t)KS * NN * HH * 4);
  float* t3     = (float*)alloc((size_t)NN * CC * 4);
  float* x3     = (float*)alloc((size_t)NN * CC * 4);
  float* sn     = (float*)alloc((size_t)NN * CC * 4);
  float* xn     = (float*)alloc((size_t)NN * FF * 4);
  float* H1     = (float*)alloc((size_t)NN * FF * 4);
  float* Uu     = (float*)alloc((size_t)NN * CC * 4);
  float* H2     = (float*)alloc((size_t)NN * CC * 4);
  float* G      = (float*)alloc((size_t)GP * GP * 4);
  float* Gxs    = (float*)alloc((size_t)GP * GP * 4);
  float* Gs     = (float*)alloc((size_t)GP * GP * 4);
  float* Gs0    = (float*)alloc((size_t)GP * GP * 4);
  float* scalars = (float*)alloc(160 * 4);
  float* colsum = (float*)alloc(4096 * 4);
  float* colsq  = (float*)alloc(4096 * 4);
  float* bnA    = (float*)alloc(1024);
  float* bnB    = (float*)alloc(1024);
  (void)ws_size; (void)in_sizes; (void)n_in; (void)out_size;

  float* out   = (float*)d_out;
  float* s1    = out;                          // N*C
  float* outsc = out + (size_t)NN * CC;        // 5 scalars
  float* emb   = out + (size_t)NN * CC + 5;    // N*D

  // zero scalar accumulators + padded BN stats (bnfinal re-zeroes between convs)
  hipMemsetAsync(scalars, 0, 160 * 4, stream);
  hipMemsetAsync(colsum, 0, 2 * 4096 * 4, stream);

  k_xn<<<NN / 4, 256, 0, stream>>>(x, xn, xnT);

  // conv1 (fused: adj cvt + adj^2 + MFMA)
  k_proj_t<<<512, 256, 0, stream>>>(x, W1r, W1root, mT, rootb, FF);
  k_conv1f<<<dim3(NN / 64, KS), 256, 0, stream>>>(adj, adj_h, mT, part, scalars);
  k_epi32<<<NN * HH / 256, 256, 0, stream>>>(part, b1, rootb, t, colsum, colsq);
  k_bnfinal<<<1, 256, 0, stream>>>(colsum, colsq, g1, be1, bnA, bnB, HH);
  k_bnapply32<<<NN * HH / 256, 256, 0, stream>>>(t, bnA, bnB, x1, emb, 0, (unsigned short*)nullptr);

  // conv2
  k_proj_t<<<512, 256, 0, stream>>>(x1, W2r, W2root, mT, rootb, HH);
  k_adjmm<<<dim3(NN / 64, KS), 256, 0, stream>>>(adj_h, mT, part);
  k_epi32<<<NN * HH / 256, 256, 0, stream>>>(part, b2, rootb, t, colsum, colsq);
  k_bnfinal<<<1, 256, 0, stream>>>(colsum, colsq, g2, be2, bnA, bnB, HH);
  k_bnapply32<<<NN * HH / 256, 256, 0, stream>>>(t, bnA, bnB, x2, emb, HH, x2T);

  // conv3
  k_adjmm<<<dim3(NN / 64, KS), 256, 0, stream>>>(adj_h, x2T, part);
  k_epi3<<<NN / 16, 256, 0, stream>>>(part, W3r, b3, x2, W3root, t3, colsum, colsq);
  k_bnfinal<<<1, 256, 0, stream>>>(colsum, colsq, g3, be3, bnA, bnB, CC);
  k_bnapply205<<<NN, 256, 0, stream>>>(t3, bnA, bnB, x3, emb);

  // head (wave-parallel softmax; also fills s1T/snT incl. pad rows)
  k_layer4<<<NN / 8, 256, 0, stream>>>(x1, x2, x3, Wl1, bl1, s1, sn, s1T, snT, scalars);

  // tr(S' A S) via MFMA
  k_normmfma<<<dim3(NN / 64, KS), 256, 0, stream>>>(adj_h, s1T, s1, scalars);

  // Grams (MFMA, no atomics) + bilinear forms + losses + finalize
  k_gramm<<<dim3(13, 13, 4), 256, 0, stream>>>(xnT, snT, s1T, G, Gxs, Gs, Gs0);
  k_rowmm3<<<dim3(NN / 16, 3), 256, 0, stream>>>(xn, sn, G, Gxs, Gs, H1, Uu, H2);
  k_losses<<<NN / 4 + LL, 256, 0, stream>>>(H1, Uu, H2, xn, sn, emb, teams, reps, scalars);
  k_final<<<1, 256, 0, stream>>>(Gs0, scalars, outsc);
}

// Round 6
// 420.641 us; speedup vs baseline: 2.1991x; 1.0230x over previous
//
#include <hip/hip_runtime.h>
#include <math.h>

#define NN 4096
#define FF 128
#define HH 32
#define CC 205
#define DD 269
#define LL 512
#define TT 12
#define RR 4
#define KS 16    // k-split for all adj MFMA passes
#define GP 208   // padded gram dim

// padded scalar slots (one cache line apart): 0=trSAS 1=adjsq 2=entropy 3=sim 4=embloss
#define SC(i) ((i) * 32)

typedef __attribute__((ext_vector_type(8))) short bf16x8;
typedef __attribute__((ext_vector_type(4))) float f32x4;
typedef __attribute__((ext_vector_type(8))) unsigned short u16x8;
typedef __attribute__((ext_vector_type(4))) unsigned short u16x4;

// ---------------- helpers ----------------
__device__ __forceinline__ float wave_sum(float v) {
#pragma unroll
  for (int o = 32; o > 0; o >>= 1) v += __shfl_xor(v, o, 64);
  return v;
}
__device__ __forceinline__ float wave_max(float v) {
#pragma unroll
  for (int o = 32; o > 0; o >>= 1) v = fmaxf(v, __shfl_xor(v, o, 64));
  return v;
}
__device__ __forceinline__ unsigned short f2bf(float x) {  // RNE
  union { float f; unsigned u; } v; v.f = x;
  unsigned r = v.u + 0x7FFFu + ((v.u >> 16) & 1u);
  return (unsigned short)(r >> 16);
}

// ---------------- pad Wl1 -> Wl1p [272][208] fp32 (zeros outside) ----------------
__global__ __launch_bounds__(256) void k_padW(const float* __restrict__ Wl1,
                                              float* __restrict__ Wl1p) {
  const int idx = blockIdx.x * 256 + threadIdx.x;  // < 272*208 = 56576
  const int k = idx / GP, c = idx - k * GP;
  Wl1p[idx] = (k < DD && c < CC) ? Wl1[(size_t)k * CC + c] : 0.f;
}

// ---------------- dual projection: o1T(bf16,[32][N]) = (A@W1)^T, o2(f32,[N][32]) = A@W2 ----------------
// LDS-staged transposed store: block owns 8 rows x 32 c
__global__ __launch_bounds__(256) void k_proj_t(const float* __restrict__ A,
                                                const float* __restrict__ W1,
                                                const float* __restrict__ W2,
                                                unsigned short* __restrict__ o1T,
                                                float* __restrict__ o2, int K) {
  __shared__ unsigned short sT[8][36];
  const int tid = threadIdx.x;
  const int idx = blockIdx.x * 256 + tid;  // N*32
  const int row = idx >> 5;
  const int c = idx & 31;
  const int lr = tid >> 5;
  float a1 = 0.f, a2 = 0.f;
  for (int k = 0; k < K; ++k) {
    const float av = A[(size_t)row * K + k];
    a1 = fmaf(av, W1[k * HH + c], a1);
    a2 = fmaf(av, W2[k * HH + c], a2);
  }
  o2[idx] = a2;
  sT[lr][c] = f2bf(a1);
  __syncthreads();
  if (tid < 32) {
    u16x8 v;
#pragma unroll
    for (int r = 0; r < 8; ++r) v[r] = sT[r][tid];
    *reinterpret_cast<u16x8*>(&o1T[(size_t)tid * NN + blockIdx.x * 8]) = v;
  }
}

// ---------------- row-normalize x -> xn (+ bf16 transposed xnT rows 0..127; pad rows via memset) ----------------
__global__ __launch_bounds__(256) void k_xn(const float* __restrict__ x, float* __restrict__ xn,
                                            unsigned short* __restrict__ xnT) {
  __shared__ unsigned short sT[4][132];
  const int tid = threadIdx.x;
  const int lane = tid & 63;
  const int lr = tid >> 6;
  const int row = blockIdx.x * 4 + lr;
  float v0 = x[(size_t)row * FF + lane];
  float v1 = x[(size_t)row * FF + 64 + lane];
  float ss = wave_sum(v0 * v0 + v1 * v1);
  float n = fmaxf(sqrtf(ss), 1e-8f);
  const float a = v0 / n, b = v1 / n;
  xn[(size_t)row * FF + lane] = a;
  xn[(size_t)row * FF + 64 + lane] = b;
  sT[lr][lane] = f2bf(a);
  sT[lr][64 + lane] = f2bf(b);
  __syncthreads();
  if (tid < FF) {
    u16x4 v;
#pragma unroll
    for (int r = 0; r < 4; ++r) v[r] = sT[r][tid];
    *reinterpret_cast<u16x4*>(&xnT[(size_t)tid * NN + blockIdx.x * 4]) = v;
  }
}

// ---------------- FUSED conv1 adj pass: fp32 adj -> bf16 (write adj_h) + sum(adj^2) + MFMA ----------------
// grid (NN/64, KS), 256 threads. Block owns a disjoint 64-row x 256-col tile of adj.
__global__ __launch_bounds__(256) void k_conv1f(const float* __restrict__ adj,
                                                unsigned short* __restrict__ adj_h,
                                                const unsigned short* __restrict__ BT,
                                                float* __restrict__ part,
                                                float* __restrict__ scalars) {
  __shared__ unsigned short sA[64][264];
  __shared__ float red[4];
  const int tid = threadIdx.x;
  const int rbase_blk = blockIdx.x * 64;
  const int kbase = blockIdx.y * 256;
  float adjsq = 0.f;
#pragma unroll
  for (int i = 0; i < 16; ++i) {
    const int fi = i * 256 + tid;  // 0..4095 float4s of the 64x256 tile
    const int r = fi >> 6;
    const int c4 = fi & 63;
    const size_t goff = (size_t)(rbase_blk + r) * NN + kbase + c4 * 4;
    const float4 v = *reinterpret_cast<const float4*>(&adj[goff]);
    adjsq += v.x * v.x + v.y * v.y + v.z * v.z + v.w * v.w;
    ushort4 h;
    h.x = f2bf(v.x); h.y = f2bf(v.y); h.z = f2bf(v.z); h.w = f2bf(v.w);
    *reinterpret_cast<ushort4*>(&adj_h[goff]) = h;
    *reinterpret_cast<ushort4*>(&sA[r][c4 * 4]) = h;
  }
  __syncthreads();
  const int lane = tid & 63;
  const int w = tid >> 6;
  const int l15 = lane & 15;
  const int kgrp = (lane >> 4) * 8;
  const int rloc = w * 16 + l15;
  f32x4 acc0 = {0.f, 0.f, 0.f, 0.f}, acc1 = {0.f, 0.f, 0.f, 0.f};
#pragma unroll
  for (int k0 = 0; k0 < 256; k0 += 32) {
    const bf16x8 a = *reinterpret_cast<const bf16x8*>(&sA[rloc][k0 + kgrp]);
    const bf16x8 b0 = *reinterpret_cast<const bf16x8*>(&BT[(size_t)l15 * NN + kbase + k0 + kgrp]);
    const bf16x8 b1 = *reinterpret_cast<const bf16x8*>(&BT[(size_t)(16 + l15) * NN + kbase + k0 + kgrp]);
    acc0 = __builtin_amdgcn_mfma_f32_16x16x32_bf16(a, b0, acc0, 0, 0, 0);
    acc1 = __builtin_amdgcn_mfma_f32_16x16x32_bf16(a, b1, acc1, 0, 0, 0);
  }
  float* pp = part + (size_t)blockIdx.y * (NN * HH);
  const int rout = rbase_blk + w * 16 + (lane >> 4) * 4;
#pragma unroll
  for (int r = 0; r < 4; ++r) {
    pp[(size_t)(rout + r) * HH + l15] = acc0[r];
    pp[(size_t)(rout + r) * HH + 16 + l15] = acc1[r];
  }
  adjsq = wave_sum(adjsq);
  if (lane == 0) red[w] = adjsq;
  __syncthreads();
  if (tid == 0) atomicAdd(&scalars[SC(1)], red[0] + red[1] + red[2] + red[3]);
}

// ---------------- MFMA adj pass: part[split] = adj_h[rows] @ M  (M via BT bf16 [32][N]) ----------------
__global__ __launch_bounds__(256) void k_adjmm(const unsigned short* __restrict__ adj_h,
                                               const unsigned short* __restrict__ BT,
                                               float* __restrict__ part) {
  const int tid = threadIdx.x;
  const int lane = tid & 63;
  const int w = tid >> 6;
  const int rbase = blockIdx.x * 64 + w * 16;
  const int k0base = blockIdx.y * (NN / KS);
  const int l15 = lane & 15;
  const int kgrp = (lane >> 4) * 8;
  const size_t arow_off = (size_t)(rbase + l15) * NN;
  f32x4 acc0 = {0.f, 0.f, 0.f, 0.f}, acc1 = {0.f, 0.f, 0.f, 0.f};
#pragma unroll
  for (int k0 = 0; k0 < NN / KS; k0 += 32) {
    const int kk = k0base + k0 + kgrp;
    const bf16x8 a = *reinterpret_cast<const bf16x8*>(&adj_h[arow_off + kk]);
    const bf16x8 b0 = *reinterpret_cast<const bf16x8*>(&BT[(size_t)l15 * NN + kk]);
    const bf16x8 b1 = *reinterpret_cast<const bf16x8*>(&BT[(size_t)(16 + l15) * NN + kk]);
    acc0 = __builtin_amdgcn_mfma_f32_16x16x32_bf16(a, b0, acc0, 0, 0, 0);
    acc1 = __builtin_amdgcn_mfma_f32_16x16x32_bf16(a, b1, acc1, 0, 0, 0);
  }
  float* pp = part + (size_t)blockIdx.y * (NN * HH);
  const int rout = rbase + (lane >> 4) * 4;
#pragma unroll
  for (int r = 0; r < 4; ++r) {
    pp[(size_t)(rout + r) * HH + l15] = acc0[r];
    pp[(size_t)(rout + r) * HH + 16 + l15] = acc1[r];
  }
}

// ---------------- MFMA norm pass: scalars[0] += sum( (adj@S1)_partial .* s1 ) ----------------
__global__ __launch_bounds__(256) void k_normmfma(const unsigned short* __restrict__ adj_h,
                                                  const unsigned short* __restrict__ s1T,
                                                  const float* __restrict__ s1,
                                                  float* __restrict__ scalars) {
  __shared__ float red[4];
  const int tid = threadIdx.x;
  const int lane = tid & 63;
  const int w = tid >> 6;
  const int rbase = blockIdx.x * 64 + w * 16;
  const int k0base = blockIdx.y * (NN / KS);
  const int l15 = lane & 15;
  const int kgrp = (lane >> 4) * 8;
  const size_t arow_off = (size_t)(rbase + l15) * NN;
  f32x4 acc[13];
#pragma unroll
  for (int ct = 0; ct < 13; ++ct) acc[ct] = (f32x4){0.f, 0.f, 0.f, 0.f};
#pragma unroll 2
  for (int k0 = 0; k0 < NN / KS; k0 += 32) {
    const int kk = k0base + k0 + kgrp;
    const bf16x8 a = *reinterpret_cast<const bf16x8*>(&adj_h[arow_off + kk]);
#pragma unroll
    for (int ct = 0; ct < 13; ++ct) {
      const bf16x8 b = *reinterpret_cast<const bf16x8*>(&s1T[(size_t)(ct * 16 + l15) * NN + kk]);
      acc[ct] = __builtin_amdgcn_mfma_f32_16x16x32_bf16(a, b, acc[ct], 0, 0, 0);
    }
  }
  const int rout = rbase + (lane >> 4) * 4;
  float sc = 0.f;
#pragma unroll
  for (int ct = 0; ct < 13; ++ct) {
    const int col = ct * 16 + l15;
    if (col < CC) {
#pragma unroll
      for (int r = 0; r < 4; ++r)
        sc = fmaf(acc[ct][r], s1[(size_t)(rout + r) * CC + col], sc);
    }
  }
  sc = wave_sum(sc);
  if (lane == 0) red[w] = sc;
  __syncthreads();
  if (tid == 0) atomicAdd(&scalars[SC(0)], red[0] + red[1] + red[2] + red[3]);
}

// ---------------- conv epilogue (32-wide): sum partials + bias + root, relu, BN stats ----------------
__global__ __launch_bounds__(256) void k_epi32(const float* __restrict__ part,
                                               const float* __restrict__ bias,
                                               const float* __restrict__ root,
                                               float* __restrict__ t,
                                               float* __restrict__ colsum,
                                               float* __restrict__ colsq) {
  __shared__ float ls[HH], lq[HH];
  const int tid = threadIdx.x;
  const int idx = blockIdx.x * 256 + tid;
  const int c = idx & (HH - 1);
  if (tid < HH) { ls[tid] = 0.f; lq[tid] = 0.f; }
  __syncthreads();
  float s = bias[c] + root[idx];
#pragma unroll
  for (int sp = 0; sp < KS; ++sp) s += part[(size_t)sp * (NN * HH) + idx];
  s = fmaxf(s, 0.f);
  t[idx] = s;
  atomicAdd(&ls[c], s);
  atomicAdd(&lq[c], s * s);
  __syncthreads();
  if (tid < HH) {
    atomicAdd(&colsum[tid * 16], ls[tid]);
    atomicAdd(&colsq[tid * 16], lq[tid]);
  }
}

// ---------------- BN finalize (stride-16 padded stats; re-zeroes them for next use) ----------------
__global__ void k_bnfinal(float* __restrict__ colsum, float* __restrict__ colsq,
                          const float* __restrict__ g, const float* __restrict__ be,
                          float* __restrict__ A, float* __restrict__ B, int Ccols) {
  const int c = threadIdx.x;
  float cs = 0.f, cq = 0.f;
  if (c < Ccols) { cs = colsum[c * 16]; cq = colsq[c * 16]; }
  __syncthreads();
  for (int i = threadIdx.x; i < 4096; i += 256) { colsum[i] = 0.f; colsq[i] = 0.f; }
  if (c >= Ccols) return;
  const float m = cs * (1.f / NN);
  const float var = fmaxf(cq * (1.f / NN) - m * m, 0.f);
  const float a = g[c] / sqrtf(var + 1e-5f);
  A[c] = a;
  B[c] = be[c] - m * a;
}

// xT (optional): bf16 transposed copy via LDS staging (block = 8 rows x 32 c)
__global__ __launch_bounds__(256) void k_bnapply32(const float* __restrict__ t,
                                                   const float* __restrict__ A,
                                                   const float* __restrict__ B,
                                                   float* __restrict__ xo,
                                                   float* __restrict__ emb, int embOff,
                                                   unsigned short* __restrict__ xT) {
  __shared__ unsigned short sT[8][36];
  const int tid = threadIdx.x;
  const int idx = blockIdx.x * 256 + tid;
  const int c = idx & (HH - 1);
  const int row = idx >> 5;
  const float v = fmaf(A[c], t[idx], B[c]);
  xo[idx] = v;
  emb[(size_t)row * DD + embOff + c] = v;
  if (xT) {
    sT[tid >> 5][c] = f2bf(v);
    __syncthreads();
    if (tid < 32) {
      u16x8 o;
#pragma unroll
      for (int r = 0; r < 8; ++r) o[r] = sT[r][tid];
      *reinterpret_cast<u16x8*>(&xT[(size_t)tid * NN + blockIdx.x * 8]) = o;
    }
  }
}

// ---------------- conv3 epilogue ----------------
__global__ __launch_bounds__(256) void k_epi3(const float* __restrict__ part,
                                              const float* __restrict__ W3r,
                                              const float* __restrict__ b3,
                                              const float* __restrict__ x2,
                                              const float* __restrict__ W3root,
                                              float* __restrict__ t3,
                                              float* __restrict__ colsum,
                                              float* __restrict__ colsq) {
  __shared__ float z[16][33];
  __shared__ float xr[16][33];
  const int row0 = blockIdx.x * 16;
  for (int s = threadIdx.x; s < 16 * 32; s += 256) {
    const int r = s >> 5, k = s & 31;
    float a = 0.f;
#pragma unroll
    for (int sp = 0; sp < KS; ++sp)
      a += part[(size_t)sp * (NN * HH) + (size_t)(row0 + r) * HH + k];
    z[r][k] = a;
    xr[r][k] = x2[(size_t)(row0 + r) * HH + k];
  }
  __syncthreads();
  const int c = threadIdx.x;
  if (c >= CC) return;
  float acc[16];
  const float bb = b3[c];
#pragma unroll
  for (int r = 0; r < 16; ++r) acc[r] = bb;
  for (int k = 0; k < 32; ++k) {
    const float w1 = W3r[k * CC + c];
    const float w2 = W3root[k * CC + c];
#pragma unroll
    for (int r = 0; r < 16; ++r) acc[r] += z[r][k] * w1 + xr[r][k] * w2;
  }
  float lsm = 0.f, lqm = 0.f;
#pragma unroll
  for (int r = 0; r < 16; ++r) {
    const float v = fmaxf(acc[r], 0.f);
    t3[(size_t)(row0 + r) * CC + c] = v;
    lsm += v;
    lqm += v * v;
  }
  atomicAdd(&colsum[c * 16], lsm);
  atomicAdd(&colsq[c * 16], lqm);
}

__global__ void k_bnapply205(const float* __restrict__ t3, const float* __restrict__ A,
                             const float* __restrict__ B, float* __restrict__ x3,
                             float* __restrict__ emb) {
  const int row = blockIdx.x;
  const int c = threadIdx.x;
  if (c >= CC) return;
  const float v = fmaf(A[c], t3[(size_t)row * CC + c], B[c]);
  x3[(size_t)row * CC + c] = v;
  emb[(size_t)row * DD + 2 * HH + c] = v;
}

// ---------------- layer4 (wave-parallel, float4 weights, LDS-staged transposed stores) ----------------
// grid NN/8; 4 waves/block; wave owns 2 rows; lane owns cols {4*lane .. 4*lane+3} (lanes >=52 idle)
__global__ __launch_bounds__(256) void k_layer4(const float* __restrict__ x1,
                                                const float* __restrict__ x2,
                                                const float* __restrict__ x3,
                                                const float* __restrict__ Wl1p,
                                                const float* __restrict__ bl1,
                                                float* __restrict__ s1,
                                                float* __restrict__ sn,
                                                unsigned short* __restrict__ s1T,
                                                unsigned short* __restrict__ snT,
                                                float* __restrict__ scalars) {
  __shared__ float xr[8][DD + 3];
  __shared__ unsigned short sTa[8][212];
  __shared__ unsigned short sTb[8][212];
  __shared__ float redE[4];
  const int row0 = blockIdx.x * 8;
  const int tid = threadIdx.x;
  for (int s = tid; s < 8 * DD; s += 256) {
    const int r = s / DD, d = s - r * DD;
    const int row = row0 + r;
    float v;
    if (d < HH) v = x1[(size_t)row * HH + d];
    else if (d < 2 * HH) v = x2[(size_t)row * HH + (d - HH)];
    else v = x3[(size_t)row * CC + (d - 2 * HH)];
    xr[r][d] = v;
  }
  __syncthreads();
  const int w = tid >> 6;
  const int lane = tid & 63;
  const int r0 = w * 2;
  const int c0 = lane * 4;
  float bl[4];
#pragma unroll
  for (int j = 0; j < 4; ++j) bl[j] = (c0 + j < CC) ? bl1[c0 + j] : 0.f;
  f32x4 acc0 = {0.f, 0.f, 0.f, 0.f}, acc1 = {0.f, 0.f, 0.f, 0.f};
  const float* xa = xr[r0];
  const float* xb = xr[r0 + 1];
  const bool active = (c0 < GP);
#pragma unroll 4
  for (int k = 0; k < DD; ++k) {
    const float4 wv = *reinterpret_cast<const float4*>(&Wl1p[(size_t)k * GP + (active ? c0 : 0)]);
    const float va = xa[k];
    const float vb = xb[k];
    acc0[0] = fmaf(va, wv.x, acc0[0]); acc0[1] = fmaf(va, wv.y, acc0[1]);
    acc0[2] = fmaf(va, wv.z, acc0[2]); acc0[3] = fmaf(va, wv.w, acc0[3]);
    acc1[0] = fmaf(vb, wv.x, acc1[0]); acc1[1] = fmaf(vb, wv.y, acc1[1]);
    acc1[2] = fmaf(vb, wv.z, acc1[2]); acc1[3] = fmaf(vb, wv.w, acc1[3]);
  }
  float ent_acc = 0.f;
#pragma unroll
  for (int r = 0; r < 2; ++r) {
    const int row = row0 + r0 + r;
    const f32x4& ac = (r == 0) ? acc0 : acc1;
    float v[4];
    float ml = -1e30f;
#pragma unroll
    for (int j = 0; j < 4; ++j) {
      const int c = c0 + j;
      v[j] = (c < CC) ? fmaxf(ac[j] + bl[j], 0.f) : -1e30f;
      ml = fmaxf(ml, v[j]);
    }
    const float m = wave_max(ml);
    float e[4];
    float sl = 0.f;
#pragma unroll
    for (int j = 0; j < 4; ++j) {
      const int c = c0 + j;
      e[j] = (c < CC) ? __expf(v[j] - m) : 0.f;
      sl += e[j];
    }
    const float S = wave_sum(sl);
    const float invS = 1.f / S;
    float p[4];
    float ql = 0.f;
#pragma unroll
    for (int j = 0; j < 4; ++j) {
      p[j] = e[j] * invS;
      ql += p[j] * p[j];
    }
    const float q = wave_sum(ql);
    const float inv = 1.f / fmaxf(sqrtf(q), 1e-8f);
    float m2l = -1e30f;
#pragma unroll
    for (int j = 0; j < 4; ++j) {
      const int c = c0 + j;
      if (c < CC) {
        s1[(size_t)row * CC + c] = p[j];
        sn[(size_t)row * CC + c] = p[j] * inv;
        m2l = fmaxf(m2l, p[j]);
      }
    }
    if (active) {
#pragma unroll
      for (int j = 0; j < 4; ++j) {
        const int c = c0 + j;
        const bool ok = (c < CC);
        sTa[r0 + r][c] = ok ? f2bf(p[j]) : (unsigned short)0;
        sTb[r0 + r][c] = ok ? f2bf(p[j] * inv) : (unsigned short)0;
      }
    }
    const float m2 = wave_max(m2l);
    float e2[4];
    float s2l = 0.f;
#pragma unroll
    for (int j = 0; j < 4; ++j) {
      const int c = c0 + j;
      e2[j] = (c < CC) ? __expf(p[j] - m2) : 0.f;
      s2l += e2[j];
    }
    const float S2 = wave_sum(s2l);
    const float invS2 = 1.f / S2;
    float tl = 0.f;
#pragma unroll
    for (int j = 0; j < 4; ++j) {
      const int c = c0 + j;
      if (c < CC) {
        const float sp = e2[j] * invS2;
        tl -= sp * logf(sp + 1e-15f);
      }
    }
    ent_acc += tl;
  }
  ent_acc = wave_sum(ent_acc);
  if (lane == 0) redE[w] = ent_acc;
  __syncthreads();
  if (tid == 0) atomicAdd(&scalars[SC(2)], redE[0] + redE[1] + redE[2] + redE[3]);
  // coalesced transposed write-out: thread c emits one 16B store per array
  if (tid < GP) {
    u16x8 oa, ob;
#pragma unroll
    for (int r = 0; r < 8; ++r) { oa[r] = sTa[r][tid]; ob[r] = sTb[r][tid]; }
    *reinterpret_cast<u16x8*>(&s1T[(size_t)tid * NN + row0]) = oa;
    *reinterpret_cast<u16x8*>(&snT[(size_t)tid * NN + row0]) = ob;
  }
}

// ---------------- MFMA Gram: Cp[GP][GP] = P^T Q from transposed bf16 [GP][NN] operands ----------------
__global__ __launch_bounds__(256) void k_gramm(const unsigned short* __restrict__ xnT,
                                               const unsigned short* __restrict__ snT,
                                               const unsigned short* __restrict__ s1T,
                                               float* __restrict__ G, float* __restrict__ Gxs,
                                               float* __restrict__ Gs, float* __restrict__ Gs0) {
  const int gid = blockIdx.z;
  const int tp = blockIdx.x * 16;
  const int tq = blockIdx.y * 16;
  const unsigned short *PT, *QT;
  float* Cp;
  if (gid == 0)      { PT = xnT; QT = xnT; Cp = G;   if (tp >= FF || tq >= FF) return; }
  else if (gid == 1) { PT = xnT; QT = snT; Cp = Gxs; if (tp >= FF) return; }
  else if (gid == 2) { PT = snT; QT = snT; Cp = Gs; }
  else               { PT = s1T; QT = s1T; Cp = Gs0; }
  const int tid = threadIdx.x;
  const int lane = tid & 63;
  const int w = tid >> 6;
  const int l15 = lane & 15;
  const int kgrp = (lane >> 4) * 8;
  const int kb0 = w * (NN / 4);
  f32x4 acc = {0.f, 0.f, 0.f, 0.f};
#pragma unroll 8
  for (int k0 = 0; k0 < NN / 4; k0 += 32) {
    const int kk = kb0 + k0 + kgrp;
    const bf16x8 a = *reinterpret_cast<const bf16x8*>(&PT[(size_t)(tp + l15) * NN + kk]);
    const bf16x8 b = *reinterpret_cast<const bf16x8*>(&QT[(size_t)(tq + l15) * NN + kk]);
    acc = __builtin_amdgcn_mfma_f32_16x16x32_bf16(a, b, acc, 0, 0, 0);
  }
  __shared__ float red[4][16][17];
  const int crow = (lane >> 4) * 4;
#pragma unroll
  for (int r = 0; r < 4; ++r) red[w][crow + r][l15] = acc[r];
  __syncthreads();
  const int rr = tid >> 4, cc = tid & 15;
  const float v = red[0][rr][cc] + red[1][rr][cc] + red[2][rr][cc] + red[3][rr][cc];
  Cp[(size_t)(tp + rr) * GP + (tq + cc)] = v;
}

// ---------------- thin GEMMs (3 in one launch, blockIdx.y selects); B has stride GP ----------------
__global__ __launch_bounds__(256) void k_rowmm3(const float* __restrict__ xn,
                                                const float* __restrict__ sn,
                                                const float* __restrict__ G,
                                                const float* __restrict__ Gxs,
                                                const float* __restrict__ Gs,
                                                float* __restrict__ H1,
                                                float* __restrict__ Uu,
                                                float* __restrict__ H2) {
  const float *A, *B;
  float* Cm;
  int K, Nc;
  if (blockIdx.y == 0)      { A = xn; B = G;   Cm = H1; K = FF; Nc = FF; }
  else if (blockIdx.y == 1) { A = xn; B = Gxs; Cm = Uu; K = FF; Nc = CC; }
  else                      { A = sn; B = Gs;  Cm = H2; K = CC; Nc = CC; }
  __shared__ float sA[16][208];
  const int row0 = blockIdx.x * 16;
  for (int s = threadIdx.x; s < 16 * K; s += 256) {
    const int r = s / K, k = s - r * K;
    sA[r][k] = A[(size_t)(row0 + r) * K + k];
  }
  __syncthreads();
  const int c = threadIdx.x;
  if (c >= Nc) return;
  float acc[16];
#pragma unroll
  for (int r = 0; r < 16; ++r) acc[r] = 0.f;
  for (int k = 0; k < K; ++k) {
    const float w = B[(size_t)k * GP + c];
#pragma unroll
    for (int r = 0; r < 16; ++r) acc[r] = fmaf(sA[r][k], w, acc[r]);
  }
#pragma unroll
  for (int r = 0; r < 16; ++r) Cm[(size_t)(row0 + r) * Nc + c] = acc[r];
}

// ---------------- per-row sim + team embedding loss (merged, block-level atomics) ----------------
__global__ __launch_bounds__(256) void k_losses(const float* __restrict__ H1,
                                                const float* __restrict__ Uu,
                                                const float* __restrict__ H2,
                                                const float* __restrict__ xn,
                                                const float* __restrict__ sn,
                                                const float* __restrict__ emb,
                                                const int* __restrict__ teams,
                                                const int* __restrict__ reps,
                                                float* __restrict__ scalars) {
  __shared__ float red[4];
  const int tid = threadIdx.x;
  const int lane = tid & 63;
  const int w = tid >> 6;
  if (blockIdx.x < NN / 4) {
    const int row = blockIdx.x * 4 + w;
    float suu = 0.f, suv = 0.f, svv = 0.f;
#pragma unroll
    for (int c0 = 0; c0 < FF; c0 += 64) {
      const float xv = xn[(size_t)row * FF + c0 + lane];
      suu = fmaf(H1[(size_t)row * FF + c0 + lane], xv, suu);
    }
    for (int cb = lane; cb < CC; cb += 64) {
      const float sv = sn[(size_t)row * CC + cb];
      suv = fmaf(Uu[(size_t)row * CC + cb], sv, suv);
      svv = fmaf(H2[(size_t)row * CC + cb], sv, svv);
    }
    suu = wave_sum(suu);
    suv = wave_sum(suv);
    svv = wave_sum(svv);
    if (lane == 0) red[w] = suv / sqrtf(suu * svv);
    __syncthreads();
    if (tid == 0) atomicAdd(&scalars[SC(3)], red[0] + red[1] + red[2] + red[3]);
  } else {
    const int team = blockIdx.x - NN / 4;
    float part = 0.f;
    for (int d = tid; d < DD; d += 256) {
      float a = 0.f, b = 0.f;
#pragma unroll
      for (int m = 0; m < RR; ++m) a += emb[(size_t)reps[team * RR + m] * DD + d];
#pragma unroll
      for (int m = RR; m < TT; ++m) b += emb[(size_t)teams[team * TT + m] * DD + d];
      part += fabsf(a * (1.f / RR) - b * (1.f / (TT - RR)));
    }
    part = wave_sum(part);
    if (lane == 0) red[w] = part;
    __syncthreads();
    if (tid == 0) atomicAdd(&scalars[SC(4)], red[0] + red[1] + red[2] + red[3]);
  }
}

// ---------------- finalize ----------------
__global__ void k_final(const float* __restrict__ Gs0, const float* __restrict__ scalars,
                        float* __restrict__ outsc) {
  __shared__ float red[4];
  float p = 0.f;
  for (int i = threadIdx.x; i < GP * GP; i += 256) {
    const float v = Gs0[i];
    p = fmaf(v, v, p);
  }
  p = wave_sum(p);
  if ((threadIdx.x & 63) == 0) red[threadIdx.x >> 6] = p;
  __syncthreads();
  if (threadIdx.x == 0) {
    const float sumP2 = red[0] + red[1] + red[2] + red[3];
    const float normsq = fmaxf(sumP2 - 2.f * scalars[SC(0)] + scalars[SC(1)], 0.f);
    const float norm = sqrtf(normsq);
    const float e1 = scalars[SC(2)] * (1.f / NN);
    const float sim = -scalars[SC(3)] * (1.f / NN);
    const float embl = scalars[SC(4)] * (1.f / LL);
    outsc[0] = norm;
    outsc[1] = e1;
    outsc[2] = sim;
    outsc[3] = 100.f * norm + 10.f * e1 + 100.f * sim + embl;
    outsc[4] = embl;
  }
}

// ================= launch =================
extern "C" void kernel_launch(void* const* d_in, const int* in_sizes, int n_in,
                              void* d_out, int out_size, void* d_ws, size_t ws_size,
                              hipStream_t stream) {
  const float* x      = (const float*)d_in[0];
  const float* adj    = (const float*)d_in[1];
  const int*   teams  = (const int*)d_in[2];
  const int*   reps   = (const int*)d_in[3];
  const float* W1r    = (const float*)d_in[4];
  const float* b1     = (const float*)d_in[5];
  const float* W1root = (const float*)d_in[6];
  const float* g1     = (const float*)d_in[7];
  const float* be1    = (const float*)d_in[8];
  const float* W2r    = (const float*)d_in[9];
  const float* b2     = (const float*)d_in[10];
  const float* W2root = (const float*)d_in[11];
  const float* g2     = (const float*)d_in[12];
  const float* be2    = (const float*)d_in[13];
  const float* W3r    = (const float*)d_in[14];
  const float* b3     = (const float*)d_in[15];
  const float* W3root = (const float*)d_in[16];
  const float* g3     = (const float*)d_in[17];
  const float* be3    = (const float*)d_in[18];
  const float* Wl1    = (const float*)d_in[19];
  const float* bl1    = (const float*)d_in[20];

  char* wp = (char*)d_ws;
  auto alloc = [&](size_t bytes) { char* p = wp; wp += (bytes + 255) & ~(size_t)255; return p; };
  unsigned short* adj_h = (unsigned short*)alloc((size_t)NN * NN * 2);
  unsigned short* mT    = (unsigned short*)alloc((size_t)HH * NN * 2);
  unsigned short* x2T   = (unsigned short*)alloc((size_t)HH * NN * 2);
  unsigned short* s1T   = (unsigned short*)alloc((size_t)GP * NN * 2);
  unsigned short* snT   = (unsigned short*)alloc((size_t)GP * NN * 2);
  unsigned short* xnT   = (unsigned short*)alloc((size_t)GP * NN * 2);
  float* Wl1p   = (float*)alloc((size_t)272 * GP * 4);
  float* rootb  = (float*)alloc((size_t)NN * HH * 4);
  float* t      = (float*)alloc((size_t)NN * HH * 4);
  float* x1     = (float*)alloc((size_t)NN * HH * 4);
  float* x2     = (float*)alloc((size_t)NN * HH * 4);
  float* part   = (float*)alloc((size_t)KS * NN * HH * 4);
  float* t3     = (float*)alloc((size_t)NN * CC * 4);
  float* x3     = (float*)alloc((size_t)NN * CC * 4);
  float* sn     = (float*)alloc((size_t)NN * CC * 4);
  float* xn     = (float*)alloc((size_t)NN * FF * 4);
  float* H1     = (float*)alloc((size_t)NN * FF * 4);
  float* Uu     = (float*)alloc((size_t)NN * CC * 4);
  float* H2     = (float*)alloc((size_t)NN * CC * 4);
  float* G      = (float*)alloc((size_t)GP * GP * 4);
  float* Gxs    = (float*)alloc((size_t)GP * GP * 4);
  float* Gs     = (float*)alloc((size_t)GP * GP * 4);
  float* Gs0    = (float*)alloc((size_t)GP * GP * 4);
  float* scalars = (float*)alloc(160 * 4);
  float* colsum = (float*)alloc(4096 * 4);
  float* colsq  = (float*)alloc(4096 * 4);
  float* bnA    = (float*)alloc(1024);
  float* bnB    = (float*)alloc(1024);
  (void)ws_size; (void)in_sizes; (void)n_in; (void)out_size;

  float* out   = (float*)d_out;
  float* s1    = out;                          // N*C
  float* outsc = out + (size_t)NN * CC;        // 5 scalars
  float* emb   = out + (size_t)NN * CC + 5;    // N*D

  // zero scalar accumulators + padded BN stats + xnT pad rows (contiguous region)
  hipMemsetAsync(scalars, 0, 160 * 4, stream);
  hipMemsetAsync(colsum, 0, 2 * 4096 * 4, stream);
  hipMemsetAsync(xnT + (size_t)FF * NN, 0, (size_t)(GP - FF) * NN * 2, stream);

  k_padW<<<221, 256, 0, stream>>>(Wl1, Wl1p);
  k_xn<<<NN / 4, 256, 0, stream>>>(x, xn, xnT);

  // conv1 (fused: adj cvt + adj^2 + MFMA)
  k_proj_t<<<512, 256, 0, stream>>>(x, W1r, W1root, mT, rootb, FF);
  k_conv1f<<<dim3(NN / 64, KS), 256, 0, stream>>>(adj, adj_h, mT, part, scalars);
  k_epi32<<<NN * HH / 256, 256, 0, stream>>>(part, b1, rootb, t, colsum, colsq);
  k_bnfinal<<<1, 256, 0, stream>>>(colsum, colsq, g1, be1, bnA, bnB, HH);
  k_bnapply32<<<NN * HH / 256, 256, 0, stream>>>(t, bnA, bnB, x1, emb, 0, (unsigned short*)nullptr);

  // conv2
  k_proj_t<<<512, 256, 0, stream>>>(x1, W2r, W2root, mT, rootb, HH);
  k_adjmm<<<dim3(NN / 64, KS), 256, 0, stream>>>(adj_h, mT, part);
  k_epi32<<<NN * HH / 256, 256, 0, stream>>>(part, b2, rootb, t, colsum, colsq);
  k_bnfinal<<<1, 256, 0, stream>>>(colsum, colsq, g2, be2, bnA, bnB, HH);
  k_bnapply32<<<NN * HH / 256, 256, 0, stream>>>(t, bnA, bnB, x2, emb, HH, x2T);

  // conv3
  k_adjmm<<<dim3(NN / 64, KS), 256, 0, stream>>>(adj_h, x2T, part);
  k_epi3<<<NN / 16, 256, 0, stream>>>(part, W3r, b3, x2, W3root, t3, colsum, colsq);
  k_bnfinal<<<1, 256, 0, stream>>>(colsum, colsq, g3, be3, bnA, bnB, CC);
  k_bnapply205<<<NN, 256, 0, stream>>>(t3, bnA, bnB, x3, emb);

  // head (wave-parallel softmax, float4 weights, staged transposed outputs)
  k_layer4<<<NN / 8, 256, 0, stream>>>(x1, x2, x3, Wl1p, bl1, s1, sn, s1T, snT, scalars);

  // tr(S' A S) via MFMA
  k_normmfma<<<dim3(NN / 64, KS), 256, 0, stream>>>(adj_h, s1T, s1, scalars);

  // Grams (MFMA, no atomics) + bilinear forms + losses + finalize
  k_gramm<<<dim3(13, 13, 4), 256, 0, stream>>>(xnT, snT, s1T, G, Gxs, Gs, Gs0);
  k_rowmm3<<<dim3(NN / 16, 3), 256, 0, stream>>>(xn, sn, G, Gxs, Gs, H1, Uu, H2);
  k_losses<<<NN / 4 + LL, 256, 0, stream>>>(H1, Uu, H2, xn, sn, emb, teams, reps, scalars);
  k_final<<<1, 256, 0, stream>>>(Gs0, scalars, outsc);
}

// Round 7
// 360.045 us; speedup vs baseline: 2.5692x; 1.1683x over previous
//
#include <hip/hip_runtime.h>
#include <math.h>

#define NN 4096
#define FF 128
#define HH 32
#define CC 205
#define DD 269
#define LL 512
#define TT 12
#define RR 4
#define KS 16    // k-split for all adj MFMA passes
#define GP 208   // padded gram dim

// padded scalar slots: 0=trSAS 1=adjsq 2=entropy 3=sim 4=embloss
#define SC(i) ((i) * 32)

typedef __attribute__((ext_vector_type(8))) short bf16x8;
typedef __attribute__((ext_vector_type(4))) float f32x4;
typedef __attribute__((ext_vector_type(8))) unsigned short u16x8;

// ---------------- helpers ----------------
__device__ __forceinline__ float wave_sum(float v) {
#pragma unroll
  for (int o = 32; o > 0; o >>= 1) v += __shfl_xor(v, o, 64);
  return v;
}
__device__ __forceinline__ float wave_max(float v) {
#pragma unroll
  for (int o = 32; o > 0; o >>= 1) v = fmaxf(v, __shfl_xor(v, o, 64));
  return v;
}
__device__ __forceinline__ unsigned short f2bf(float x) {  // RNE
  union { float f; unsigned u; } v; v.f = x;
  unsigned r = v.u + 0x7FFFu + ((v.u >> 16) & 1u);
  return (unsigned short)(r >> 16);
}

// ---------------- pad Wl1 -> Wl1p [272][208] fp32 ----------------
__global__ __launch_bounds__(256) void k_padW(const float* __restrict__ Wl1,
                                              float* __restrict__ Wl1p) {
  const int idx = blockIdx.x * 256 + threadIdx.x;
  const int k = idx / GP, c = idx - k * GP;
  Wl1p[idx] = (k < DD && c < CC) ? Wl1[(size_t)k * CC + c] : 0.f;
}

// ---------------- dual projection: mB (bf16 tiled [kb][32][32]) = (A@W1)^T tiles, o2 = A@W2 ----------------
// grid NN/32; block owns 32 nodes (one k-block)
__global__ __launch_bounds__(256) void k_proj_t(const float* __restrict__ A,
                                                const float* __restrict__ W1,
                                                const float* __restrict__ W2,
                                                unsigned short* __restrict__ mB,
                                                float* __restrict__ o2, int K) {
  __shared__ float sX[32][132];
  __shared__ unsigned short sT[32][34];
  const int tid = threadIdx.x;
  const int kb = blockIdx.x;
  const int nf4 = K >> 2;
  const int tot4 = 32 * nf4;
  for (int p = tid; p < tot4; p += 256) {
    const int node = p / nf4, c4 = p - node * nf4;
    const float4 v = *reinterpret_cast<const float4*>(&A[((size_t)(kb * 32 + node)) * K + c4 * 4]);
    sX[node][c4 * 4 + 0] = v.x; sX[node][c4 * 4 + 1] = v.y;
    sX[node][c4 * 4 + 2] = v.z; sX[node][c4 * 4 + 3] = v.w;
  }
  __syncthreads();
  const int c = tid & 31, g = tid >> 5;
  float a1[4] = {0.f, 0.f, 0.f, 0.f}, a2[4] = {0.f, 0.f, 0.f, 0.f};
  for (int k = 0; k < K; ++k) {
    const float w1 = W1[k * HH + c];
    const float w2 = W2[k * HH + c];
#pragma unroll
    for (int ni = 0; ni < 4; ++ni) {
      const float av = sX[g * 4 + ni][k];
      a1[ni] = fmaf(av, w1, a1[ni]);
      a2[ni] = fmaf(av, w2, a2[ni]);
    }
  }
#pragma unroll
  for (int ni = 0; ni < 4; ++ni) {
    o2[((size_t)kb * 32 + g * 4 + ni) * HH + c] = a2[ni];
    sT[c][g * 4 + ni] = f2bf(a1[ni]);
  }
  __syncthreads();
  if (tid < 128) {
    const int row = tid >> 2, seg = tid & 3;
    u16x8 v;
#pragma unroll
    for (int j = 0; j < 8; ++j) v[j] = sT[row][seg * 8 + j];
    *reinterpret_cast<u16x8*>(&mB[((size_t)kb * 32 + row) * 32 + seg * 8]) = v;
  }
}

// ---------------- row-normalize x -> xn ----------------
__global__ __launch_bounds__(256) void k_xn(const float* __restrict__ x, float* __restrict__ xn) {
  const int lane = threadIdx.x & 63;
  const int row = blockIdx.x * 4 + (threadIdx.x >> 6);
  float v0 = x[(size_t)row * FF + lane];
  float v1 = x[(size_t)row * FF + 64 + lane];
  float ss = wave_sum(v0 * v0 + v1 * v1);
  float n = fmaxf(sqrtf(ss), 1e-8f);
  xn[(size_t)row * FF + lane] = v0 / n;
  xn[(size_t)row * FF + 64 + lane] = v1 / n;
}

// ---------------- xn -> xnB bf16 tiled [kb][GP][32] (rows 0..127; pad rows pre-zeroed) ----------------
__global__ __launch_bounds__(256) void k_xnB(const float* __restrict__ xn,
                                             unsigned short* __restrict__ xnB) {
  __shared__ unsigned short sT[FF][34];
  const int tid = threadIdx.x;
  const int kb = blockIdx.x;
  for (int p = tid; p < 1024; p += 256) {  // 32 nodes x 32 float4
    const int node = p >> 5, c4 = p & 31;
    const float4 v = *reinterpret_cast<const float4*>(&xn[((size_t)(kb * 32 + node)) * FF + c4 * 4]);
    sT[c4 * 4 + 0][node] = f2bf(v.x);
    sT[c4 * 4 + 1][node] = f2bf(v.y);
    sT[c4 * 4 + 2][node] = f2bf(v.z);
    sT[c4 * 4 + 3][node] = f2bf(v.w);
  }
  __syncthreads();
  const int row = tid >> 1, seg = (tid & 1) * 16;
  if (row < FF) {
    u16x8 a, b;
#pragma unroll
    for (int j = 0; j < 8; ++j) { a[j] = sT[row][seg + j]; b[j] = sT[row][seg + 8 + j]; }
    *reinterpret_cast<u16x8*>(&xnB[((size_t)kb * GP + row) * 32 + seg]) = a;
    *reinterpret_cast<u16x8*>(&xnB[((size_t)kb * GP + row) * 32 + seg + 8]) = b;
  }
}

// ---------------- FUSED conv1: fp32 adj -> bf16 tiled adj_t + sum(adj^2) + MFMA ----------------
// grid (NN/64, KS). Block owns 64 rows x 256 k of adj.
__global__ __launch_bounds__(256) void k_conv1f(const float* __restrict__ adj,
                                                unsigned short* __restrict__ adj_t,
                                                const unsigned short* __restrict__ mB,
                                                float* __restrict__ part,
                                                float* __restrict__ scalars) {
  __shared__ unsigned short sA[64][264];
  __shared__ float red[4];
  const int tid = threadIdx.x;
  const int rbase_blk = blockIdx.x * 64;
  const int kbase = blockIdx.y * 256;
  const int rb0 = blockIdx.x * 4;   // row-tile base
  const int kb0 = blockIdx.y * 8;   // k-tile base
  float adjsq = 0.f;
#pragma unroll
  for (int i = 0; i < 16; ++i) {
    const int fi = i * 256 + tid;
    const int r = fi >> 6;
    const int c4 = fi & 63;
    const size_t goff = (size_t)(rbase_blk + r) * NN + kbase + c4 * 4;
    const float4 v = *reinterpret_cast<const float4*>(&adj[goff]);
    adjsq += v.x * v.x + v.y * v.y + v.z * v.z + v.w * v.w;
    ushort4 h;
    h.x = f2bf(v.x); h.y = f2bf(v.y); h.z = f2bf(v.z); h.w = f2bf(v.w);
    // tiled store: [rb][kb][16][32]
    const size_t toff = ((size_t)(rb0 + (r >> 4)) * (NN / 32) + kb0 + (c4 >> 3)) * 512 +
                        (r & 15) * 32 + (c4 & 7) * 4;
    *reinterpret_cast<ushort4*>(&adj_t[toff]) = h;
    *reinterpret_cast<ushort4*>(&sA[r][c4 * 4]) = h;
  }
  __syncthreads();
  const int lane = tid & 63;
  const int w = tid >> 6;
  const int l15 = lane & 15;
  const int kgrp = (lane >> 4) * 8;
  const int rloc = w * 16 + l15;
  f32x4 acc0 = {0.f, 0.f, 0.f, 0.f}, acc1 = {0.f, 0.f, 0.f, 0.f};
#pragma unroll
  for (int k0 = 0; k0 < 256; k0 += 32) {
    const size_t boff = ((size_t)(kb0 + (k0 >> 5)) * 32) * 32;
    const bf16x8 a = *reinterpret_cast<const bf16x8*>(&sA[rloc][k0 + kgrp]);
    const bf16x8 b0 = *reinterpret_cast<const bf16x8*>(&mB[boff + (size_t)l15 * 32 + kgrp]);
    const bf16x8 b1 = *reinterpret_cast<const bf16x8*>(&mB[boff + (size_t)(16 + l15) * 32 + kgrp]);
    acc0 = __builtin_amdgcn_mfma_f32_16x16x32_bf16(a, b0, acc0, 0, 0, 0);
    acc1 = __builtin_amdgcn_mfma_f32_16x16x32_bf16(a, b1, acc1, 0, 0, 0);
  }
  float* pp = part + (size_t)blockIdx.y * (NN * HH);
  const int rout = rbase_blk + w * 16 + (lane >> 4) * 4;
#pragma unroll
  for (int r = 0; r < 4; ++r) {
    pp[(size_t)(rout + r) * HH + l15] = acc0[r];
    pp[(size_t)(rout + r) * HH + 16 + l15] = acc1[r];
  }
  adjsq = wave_sum(adjsq);
  if (lane == 0) red[w] = adjsq;
  __syncthreads();
  if (tid == 0) atomicAdd(&scalars[SC(1)], red[0] + red[1] + red[2] + red[3]);
}

// ---------------- MFMA adj pass (tiled A, tiled B [kb][32][32]) ----------------
__global__ __launch_bounds__(256) void k_adjmm(const unsigned short* __restrict__ adj_t,
                                               const unsigned short* __restrict__ mB,
                                               float* __restrict__ part) {
  const int tid = threadIdx.x;
  const int lane = tid & 63;
  const int w = tid >> 6;
  const int rb = blockIdx.x * 4 + w;
  const int kb0 = blockIdx.y * 8;
  const int l15 = lane & 15;
  const int kgrp = (lane >> 4) * 8;
  f32x4 acc0 = {0.f, 0.f, 0.f, 0.f}, acc1 = {0.f, 0.f, 0.f, 0.f};
#pragma unroll
  for (int kt = 0; kt < 8; ++kt) {
    const size_t aoff = ((size_t)rb * (NN / 32) + kb0 + kt) * 512;
    const size_t boff = ((size_t)(kb0 + kt) * 32) * 32;
    const bf16x8 a = *reinterpret_cast<const bf16x8*>(&adj_t[aoff + l15 * 32 + kgrp]);
    const bf16x8 b0 = *reinterpret_cast<const bf16x8*>(&mB[boff + (size_t)l15 * 32 + kgrp]);
    const bf16x8 b1 = *reinterpret_cast<const bf16x8*>(&mB[boff + (size_t)(16 + l15) * 32 + kgrp]);
    acc0 = __builtin_amdgcn_mfma_f32_16x16x32_bf16(a, b0, acc0, 0, 0, 0);
    acc1 = __builtin_amdgcn_mfma_f32_16x16x32_bf16(a, b1, acc1, 0, 0, 0);
  }
  float* pp = part + (size_t)blockIdx.y * (NN * HH);
  const int rout = rb * 16 + (lane >> 4) * 4;
#pragma unroll
  for (int r = 0; r < 4; ++r) {
    pp[(size_t)(rout + r) * HH + l15] = acc0[r];
    pp[(size_t)(rout + r) * HH + 16 + l15] = acc1[r];
  }
}

// ---------------- MFMA norm pass (tiled A, tiled s1B [kb][GP][32]) ----------------
__global__ __launch_bounds__(256) void k_normmfma(const unsigned short* __restrict__ adj_t,
                                                  const unsigned short* __restrict__ s1B,
                                                  const float* __restrict__ s1,
                                                  float* __restrict__ scalars) {
  __shared__ float red[4];
  const int tid = threadIdx.x;
  const int lane = tid & 63;
  const int w = tid >> 6;
  const int rb = blockIdx.x * 4 + w;
  const int kb0 = blockIdx.y * 8;
  const int l15 = lane & 15;
  const int kgrp = (lane >> 4) * 8;
  f32x4 acc[13];
#pragma unroll
  for (int ct = 0; ct < 13; ++ct) acc[ct] = (f32x4){0.f, 0.f, 0.f, 0.f};
#pragma unroll 2
  for (int kt = 0; kt < 8; ++kt) {
    const size_t aoff = ((size_t)rb * (NN / 32) + kb0 + kt) * 512;
    const bf16x8 a = *reinterpret_cast<const bf16x8*>(&adj_t[aoff + l15 * 32 + kgrp]);
    const size_t bbase = ((size_t)(kb0 + kt) * GP) * 32 + (size_t)l15 * 32 + kgrp;
#pragma unroll
    for (int ct = 0; ct < 13; ++ct) {
      const bf16x8 b = *reinterpret_cast<const bf16x8*>(&s1B[bbase + (size_t)ct * 512]);
      acc[ct] = __builtin_amdgcn_mfma_f32_16x16x32_bf16(a, b, acc[ct], 0, 0, 0);
    }
  }
  const int rout = rb * 16 + (lane >> 4) * 4;
  float sc = 0.f;
#pragma unroll
  for (int ct = 0; ct < 13; ++ct) {
    const int col = ct * 16 + l15;
    if (col < CC) {
#pragma unroll
      for (int r = 0; r < 4; ++r)
        sc = fmaf(acc[ct][r], s1[(size_t)(rout + r) * CC + col], sc);
    }
  }
  sc = wave_sum(sc);
  if (lane == 0) red[w] = sc;
  __syncthreads();
  if (tid == 0) atomicAdd(&scalars[SC(0)], red[0] + red[1] + red[2] + red[3]);
}

// ---------------- conv epilogue (32-wide) ----------------
__global__ __launch_bounds__(256) void k_epi32(const float* __restrict__ part,
                                               const float* __restrict__ bias,
                                               const float* __restrict__ root,
                                               float* __restrict__ t,
                                               float* __restrict__ colsum,
                                               float* __restrict__ colsq) {
  __shared__ float ls[HH], lq[HH];
  const int tid = threadIdx.x;
  const int idx = blockIdx.x * 256 + tid;
  const int c = idx & (HH - 1);
  if (tid < HH) { ls[tid] = 0.f; lq[tid] = 0.f; }
  __syncthreads();
  float s = bias[c] + root[idx];
#pragma unroll
  for (int sp = 0; sp < KS; ++sp) s += part[(size_t)sp * (NN * HH) + idx];
  s = fmaxf(s, 0.f);
  t[idx] = s;
  atomicAdd(&ls[c], s);
  atomicAdd(&lq[c], s * s);
  __syncthreads();
  if (tid < HH) {
    atomicAdd(&colsum[tid * 16], ls[tid]);
    atomicAdd(&colsq[tid * 16], lq[tid]);
  }
}

// ---------------- BN finalize ----------------
__global__ void k_bnfinal(float* __restrict__ colsum, float* __restrict__ colsq,
                          const float* __restrict__ g, const float* __restrict__ be,
                          float* __restrict__ A, float* __restrict__ B, int Ccols) {
  const int c = threadIdx.x;
  float cs = 0.f, cq = 0.f;
  if (c < Ccols) { cs = colsum[c * 16]; cq = colsq[c * 16]; }
  __syncthreads();
  for (int i = threadIdx.x; i < 4096; i += 256) { colsum[i] = 0.f; colsq[i] = 0.f; }
  if (c >= Ccols) return;
  const float m = cs * (1.f / NN);
  const float var = fmaxf(cq * (1.f / NN) - m * m, 0.f);
  const float a = g[c] / sqrtf(var + 1e-5f);
  A[c] = a;
  B[c] = be[c] - m * a;
}

// ---------------- bn apply (32-wide) + optional bf16 tiled copy [kb][32][32] ----------------
// grid NN/32
__global__ __launch_bounds__(256) void k_bnapply32(const float* __restrict__ t,
                                                   const float* __restrict__ A,
                                                   const float* __restrict__ B,
                                                   float* __restrict__ xo,
                                                   float* __restrict__ emb, int embOff,
                                                   unsigned short* __restrict__ xB) {
  __shared__ unsigned short sT[32][34];
  const int tid = threadIdx.x;
  const int kb = blockIdx.x;
  const int c = tid & 31, g = tid >> 5;
  const float Ac = A[c], Bc = B[c];
#pragma unroll
  for (int ni = 0; ni < 4; ++ni) {
    const int n = kb * 32 + g * 4 + ni;
    const float v = fmaf(Ac, t[(size_t)n * HH + c], Bc);
    xo[(size_t)n * HH + c] = v;
    emb[(size_t)n * DD + embOff + c] = v;
    if (xB) sT[c][g * 4 + ni] = f2bf(v);
  }
  if (xB) {
    __syncthreads();
    if (tid < 128) {
      const int row = tid >> 2, seg = tid & 3;
      u16x8 o;
#pragma unroll
      for (int j = 0; j < 8; ++j) o[j] = sT[row][seg * 8 + j];
      *reinterpret_cast<u16x8*>(&xB[((size_t)kb * 32 + row) * 32 + seg * 8]) = o;
    }
  }
}

// ---------------- conv3 epilogue ----------------
__global__ __launch_bounds__(256) void k_epi3(const float* __restrict__ part,
                                              const float* __restrict__ W3r,
                                              const float* __restrict__ b3,
                                              const float* __restrict__ x2,
                                              const float* __restrict__ W3root,
                                              float* __restrict__ t3,
                                              float* __restrict__ colsum,
                                              float* __restrict__ colsq) {
  __shared__ float z[16][33];
  __shared__ float xr[16][33];
  const int row0 = blockIdx.x * 16;
  for (int s = threadIdx.x; s < 16 * 32; s += 256) {
    const int r = s >> 5, k = s & 31;
    float a = 0.f;
#pragma unroll
    for (int sp = 0; sp < KS; ++sp)
      a += part[(size_t)sp * (NN * HH) + (size_t)(row0 + r) * HH + k];
    z[r][k] = a;
    xr[r][k] = x2[(size_t)(row0 + r) * HH + k];
  }
  __syncthreads();
  const int c = threadIdx.x;
  if (c >= CC) return;
  float acc[16];
  const float bb = b3[c];
#pragma unroll
  for (int r = 0; r < 16; ++r) acc[r] = bb;
  for (int k = 0; k < 32; ++k) {
    const float w1 = W3r[k * CC + c];
    const float w2 = W3root[k * CC + c];
#pragma unroll
    for (int r = 0; r < 16; ++r) acc[r] += z[r][k] * w1 + xr[r][k] * w2;
  }
  float lsm = 0.f, lqm = 0.f;
#pragma unroll
  for (int r = 0; r < 16; ++r) {
    const float v = fmaxf(acc[r], 0.f);
    t3[(size_t)(row0 + r) * CC + c] = v;
    lsm += v;
    lqm += v * v;
  }
  atomicAdd(&colsum[c * 16], lsm);
  atomicAdd(&colsq[c * 16], lqm);
}

__global__ void k_bnapply205(const float* __restrict__ t3, const float* __restrict__ A,
                             const float* __restrict__ B, float* __restrict__ x3,
                             float* __restrict__ emb) {
  const int row = blockIdx.x;
  const int c = threadIdx.x;
  if (c >= CC) return;
  const float v = fmaf(A[c], t3[(size_t)row * CC + c], B[c]);
  x3[(size_t)row * CC + c] = v;
  emb[(size_t)row * DD + 2 * HH + c] = v;
}

// ---------------- layer4: wave-parallel softmax; outputs s1, sn, tiled s1B/snB ----------------
// grid NN/8; 4 waves/block; wave owns 2 rows; lane owns cols {4*lane..4*lane+3}
__global__ __launch_bounds__(256) void k_layer4(const float* __restrict__ x1,
                                                const float* __restrict__ x2,
                                                const float* __restrict__ x3,
                                                const float* __restrict__ Wl1p,
                                                const float* __restrict__ bl1,
                                                float* __restrict__ s1,
                                                float* __restrict__ sn,
                                                unsigned short* __restrict__ s1B,
                                                unsigned short* __restrict__ snB,
                                                float* __restrict__ scalars) {
  __shared__ float xr[8][DD + 3];
  __shared__ unsigned short sTa[8][212];
  __shared__ unsigned short sTb[8][212];
  __shared__ float redE[4];
  const int row0 = blockIdx.x * 8;
  const int tid = threadIdx.x;
  for (int s = tid; s < 8 * DD; s += 256) {
    const int r = s / DD, d = s - r * DD;
    const int row = row0 + r;
    float v;
    if (d < HH) v = x1[(size_t)row * HH + d];
    else if (d < 2 * HH) v = x2[(size_t)row * HH + (d - HH)];
    else v = x3[(size_t)row * CC + (d - 2 * HH)];
    xr[r][d] = v;
  }
  __syncthreads();
  const int w = tid >> 6;
  const int lane = tid & 63;
  const int r0 = w * 2;
  const int c0 = lane * 4;
  float bl[4];
#pragma unroll
  for (int j = 0; j < 4; ++j) bl[j] = (c0 + j < CC) ? bl1[c0 + j] : 0.f;
  f32x4 acc0 = {0.f, 0.f, 0.f, 0.f}, acc1 = {0.f, 0.f, 0.f, 0.f};
  const float* xa = xr[r0];
  const float* xb = xr[r0 + 1];
  const bool active = (c0 < GP);
#pragma unroll 4
  for (int k = 0; k < DD; ++k) {
    const float4 wv = *reinterpret_cast<const float4*>(&Wl1p[(size_t)k * GP + (active ? c0 : 0)]);
    const float va = xa[k];
    const float vb = xb[k];
    acc0[0] = fmaf(va, wv.x, acc0[0]); acc0[1] = fmaf(va, wv.y, acc0[1]);
    acc0[2] = fmaf(va, wv.z, acc0[2]); acc0[3] = fmaf(va, wv.w, acc0[3]);
    acc1[0] = fmaf(vb, wv.x, acc1[0]); acc1[1] = fmaf(vb, wv.y, acc1[1]);
    acc1[2] = fmaf(vb, wv.z, acc1[2]); acc1[3] = fmaf(vb, wv.w, acc1[3]);
  }
  float ent_acc = 0.f;
#pragma unroll
  for (int r = 0; r < 2; ++r) {
    const int row = row0 + r0 + r;
    const f32x4& ac = (r == 0) ? acc0 : acc1;
    float v[4];
    float ml = -1e30f;
#pragma unroll
    for (int j = 0; j < 4; ++j) {
      const int c = c0 + j;
      v[j] = (c < CC) ? fmaxf(ac[j] + bl[j], 0.f) : -1e30f;
      ml = fmaxf(ml, v[j]);
    }
    const float m = wave_max(ml);
    float e[4];
    float sl = 0.f;
#pragma unroll
    for (int j = 0; j < 4; ++j) {
      const int c = c0 + j;
      e[j] = (c < CC) ? __expf(v[j] - m) : 0.f;
      sl += e[j];
    }
    const float S = wave_sum(sl);
    const float invS = 1.f / S;
    float p[4];
    float ql = 0.f;
#pragma unroll
    for (int j = 0; j < 4; ++j) {
      p[j] = e[j] * invS;
      ql += p[j] * p[j];
    }
    const float q = wave_sum(ql);
    const float inv = 1.f / fmaxf(sqrtf(q), 1e-8f);
    float m2l = -1e30f;
#pragma unroll
    for (int j = 0; j < 4; ++j) {
      const int c = c0 + j;
      if (c < CC) {
        s1[(size_t)row * CC + c] = p[j];
        sn[(size_t)row * CC + c] = p[j] * inv;
        m2l = fmaxf(m2l, p[j]);
      }
    }
    if (active) {
#pragma unroll
      for (int j = 0; j < 4; ++j) {
        const int c = c0 + j;
        const bool ok = (c < CC);
        sTa[r0 + r][c] = ok ? f2bf(p[j]) : (unsigned short)0;
        sTb[r0 + r][c] = ok ? f2bf(p[j] * inv) : (unsigned short)0;
      }
    }
    const float m2 = wave_max(m2l);
    float e2[4];
    float s2l = 0.f;
#pragma unroll
    for (int j = 0; j < 4; ++j) {
      const int c = c0 + j;
      e2[j] = (c < CC) ? __expf(p[j] - m2) : 0.f;
      s2l += e2[j];
    }
    const float S2 = wave_sum(s2l);
    const float invS2 = 1.f / S2;
    float tl = 0.f;
#pragma unroll
    for (int j = 0; j < 4; ++j) {
      const int c = c0 + j;
      if (c < CC) {
        const float sp = e2[j] * invS2;
        tl -= sp * logf(sp + 1e-15f);
      }
    }
    ent_acc += tl;
  }
  ent_acc = wave_sum(ent_acc);
  if (lane == 0) redE[w] = ent_acc;
  __syncthreads();
  if (tid == 0) atomicAdd(&scalars[SC(2)], redE[0] + redE[1] + redE[2] + redE[3]);
  // tiled write-out: thread c emits one 16B store per array into [kb][c][32] tile
  if (tid < GP) {
    const int kb = row0 >> 5, no = row0 & 31;
    u16x8 oa, ob;
#pragma unroll
    for (int r = 0; r < 8; ++r) { oa[r] = sTa[r][tid]; ob[r] = sTb[r][tid]; }
    *reinterpret_cast<u16x8*>(&s1B[((size_t)kb * GP + tid) * 32 + no]) = oa;
    *reinterpret_cast<u16x8*>(&snB[((size_t)kb * GP + tid) * 32 + no]) = ob;
  }
}

// ---------------- MFMA Gram: Cp = P^T Q from tiled [kb][GP][32] operands ----------------
__global__ __launch_bounds__(256) void k_gramm(const unsigned short* __restrict__ xnB,
                                               const unsigned short* __restrict__ snB,
                                               const unsigned short* __restrict__ s1B,
                                               float* __restrict__ G, float* __restrict__ Gxs,
                                               float* __restrict__ Gs, float* __restrict__ Gs0) {
  const int gid = blockIdx.z;
  const int tp = blockIdx.x * 16;
  const int tq = blockIdx.y * 16;
  const unsigned short *PT, *QT;
  float* Cp;
  if (gid == 0)      { PT = xnB; QT = xnB; Cp = G;   if (tp >= FF || tq >= FF) return; }
  else if (gid == 1) { PT = xnB; QT = snB; Cp = Gxs; if (tp >= FF) return; }
  else if (gid == 2) { PT = snB; QT = snB; Cp = Gs; }
  else               { PT = s1B; QT = s1B; Cp = Gs0; }
  const int tid = threadIdx.x;
  const int lane = tid & 63;
  const int w = tid >> 6;
  const int l15 = lane & 15;
  const int kgrp = (lane >> 4) * 8;
  f32x4 acc = {0.f, 0.f, 0.f, 0.f};
#pragma unroll 8
  for (int kt = 0; kt < 32; ++kt) {
    const int kb = w * 32 + kt;
    const bf16x8 a = *reinterpret_cast<const bf16x8*>(&PT[((size_t)kb * GP + tp + l15) * 32 + kgrp]);
    const bf16x8 b = *reinterpret_cast<const bf16x8*>(&QT[((size_t)kb * GP + tq + l15) * 32 + kgrp]);
    acc = __builtin_amdgcn_mfma_f32_16x16x32_bf16(a, b, acc, 0, 0, 0);
  }
  __shared__ float red[4][16][17];
  const int crow = (lane >> 4) * 4;
#pragma unroll
  for (int r = 0; r < 4; ++r) red[w][crow + r][l15] = acc[r];
  __syncthreads();
  const int rr = tid >> 4, cc = tid & 15;
  const float v = red[0][rr][cc] + red[1][rr][cc] + red[2][rr][cc] + red[3][rr][cc];
  Cp[(size_t)(tp + rr) * GP + (tq + cc)] = v;
}

// ---------------- thin GEMMs (3 in one launch); B has stride GP ----------------
__global__ __launch_bounds__(256) void k_rowmm3(const float* __restrict__ xn,
                                                const float* __restrict__ sn,
                                                const float* __restrict__ G,
                                                const float* __restrict__ Gxs,
                                                const float* __restrict__ Gs,
                                                float* __restrict__ H1,
                                                float* __restrict__ Uu,
                                                float* __restrict__ H2) {
  const float *A, *B;
  float* Cm;
  int K, Nc;
  if (blockIdx.y == 0)      { A = xn; B = G;   Cm = H1; K = FF; Nc = FF; }
  else if (blockIdx.y == 1) { A = xn; B = Gxs; Cm = Uu; K = FF; Nc = CC; }
  else                      { A = sn; B = Gs;  Cm = H2; K = CC; Nc = CC; }
  __shared__ float sA[16][208];
  const int row0 = blockIdx.x * 16;
  for (int s = threadIdx.x; s < 16 * K; s += 256) {
    const int r = s / K, k = s - r * K;
    sA[r][k] = A[(size_t)(row0 + r) * K + k];
  }
  __syncthreads();
  const int c = threadIdx.x;
  if (c >= Nc) return;
  float acc[16];
#pragma unroll
  for (int r = 0; r < 16; ++r) acc[r] = 0.f;
  for (int k = 0; k < K; ++k) {
    const float w = B[(size_t)k * GP + c];
#pragma unroll
    for (int r = 0; r < 16; ++r) acc[r] = fmaf(sA[r][k], w, acc[r]);
  }
#pragma unroll
  for (int r = 0; r < 16; ++r) Cm[(size_t)(row0 + r) * Nc + c] = acc[r];
}

// ---------------- per-row sim + team embedding loss ----------------
__global__ __launch_bounds__(256) void k_losses(const float* __restrict__ H1,
                                                const float* __restrict__ Uu,
                                                const float* __restrict__ H2,
                                                const float* __restrict__ xn,
                                                const float* __restrict__ sn,
                                                const float* __restrict__ emb,
                                                const int* __restrict__ teams,
                                                const int* __restrict__ reps,
                                                float* __restrict__ scalars) {
  __shared__ float red[4];
  const int tid = threadIdx.x;
  const int lane = tid & 63;
  const int w = tid >> 6;
  if (blockIdx.x < NN / 4) {
    const int row = blockIdx.x * 4 + w;
    float suu = 0.f, suv = 0.f, svv = 0.f;
#pragma unroll
    for (int c0 = 0; c0 < FF; c0 += 64) {
      const float xv = xn[(size_t)row * FF + c0 + lane];
      suu = fmaf(H1[(size_t)row * FF + c0 + lane], xv, suu);
    }
    for (int cb = lane; cb < CC; cb += 64) {
      const float sv = sn[(size_t)row * CC + cb];
      suv = fmaf(Uu[(size_t)row * CC + cb], sv, suv);
      svv = fmaf(H2[(size_t)row * CC + cb], sv, svv);
    }
    suu = wave_sum(suu);
    suv = wave_sum(suv);
    svv = wave_sum(svv);
    if (lane == 0) red[w] = suv / sqrtf(suu * svv);
    __syncthreads();
    if (tid == 0) atomicAdd(&scalars[SC(3)], red[0] + red[1] + red[2] + red[3]);
  } else {
    const int team = blockIdx.x - NN / 4;
    float part = 0.f;
    for (int d = tid; d < DD; d += 256) {
      float a = 0.f, b = 0.f;
#pragma unroll
      for (int m = 0; m < RR; ++m) a += emb[(size_t)reps[team * RR + m] * DD + d];
#pragma unroll
      for (int m = RR; m < TT; ++m) b += emb[(size_t)teams[team * TT + m] * DD + d];
      part += fabsf(a * (1.f / RR) - b * (1.f / (TT - RR)));
    }
    part = wave_sum(part);
    if (lane == 0) red[w] = part;
    __syncthreads();
    if (tid == 0) atomicAdd(&scalars[SC(4)], red[0] + red[1] + red[2] + red[3]);
  }
}

// ---------------- finalize ----------------
__global__ void k_final(const float* __restrict__ Gs0, const float* __restrict__ scalars,
                        float* __restrict__ outsc) {
  __shared__ float red[4];
  float p = 0.f;
  for (int i = threadIdx.x; i < GP * GP; i += 256) {
    const float v = Gs0[i];
    p = fmaf(v, v, p);
  }
  p = wave_sum(p);
  if ((threadIdx.x & 63) == 0) red[threadIdx.x >> 6] = p;
  __syncthreads();
  if (threadIdx.x == 0) {
    const float sumP2 = red[0] + red[1] + red[2] + red[3];
    const float normsq = fmaxf(sumP2 - 2.f * scalars[SC(0)] + scalars[SC(1)], 0.f);
    const float norm = sqrtf(normsq);
    const float e1 = scalars[SC(2)] * (1.f / NN);
    const float sim = -scalars[SC(3)] * (1.f / NN);
    const float embl = scalars[SC(4)] * (1.f / LL);
    outsc[0] = norm;
    outsc[1] = e1;
    outsc[2] = sim;
    outsc[3] = 100.f * norm + 10.f * e1 + 100.f * sim + embl;
    outsc[4] = embl;
  }
}

// ================= launch =================
extern "C" void kernel_launch(void* const* d_in, const int* in_sizes, int n_in,
                              void* d_out, int out_size, void* d_ws, size_t ws_size,
                              hipStream_t stream) {
  const float* x      = (const float*)d_in[0];
  const float* adj    = (const float*)d_in[1];
  const int*   teams  = (const int*)d_in[2];
  const int*   reps   = (const int*)d_in[3];
  const float* W1r    = (const float*)d_in[4];
  const float* b1     = (const float*)d_in[5];
  const float* W1root = (const float*)d_in[6];
  const float* g1     = (const float*)d_in[7];
  const float* be1    = (const float*)d_in[8];
  const float* W2r    = (const float*)d_in[9];
  const float* b2     = (const float*)d_in[10];
  const float* W2root = (const float*)d_in[11];
  const float* g2     = (const float*)d_in[12];
  const float* be2    = (const float*)d_in[13];
  const float* W3r    = (const float*)d_in[14];
  const float* b3     = (const float*)d_in[15];
  const float* W3root = (const float*)d_in[16];
  const float* g3     = (const float*)d_in[17];
  const float* be3    = (const float*)d_in[18];
  const float* Wl1    = (const float*)d_in[19];
  const float* bl1    = (const float*)d_in[20];

  char* wp = (char*)d_ws;
  auto alloc = [&](size_t bytes) { char* p = wp; wp += (bytes + 255) & ~(size_t)255; return p; };
  unsigned short* adj_t = (unsigned short*)alloc((size_t)NN * NN * 2);
  unsigned short* mB    = (unsigned short*)alloc((size_t)HH * NN * 2);
  unsigned short* x2B   = (unsigned short*)alloc((size_t)HH * NN * 2);
  unsigned short* s1B   = (unsigned short*)alloc((size_t)GP * NN * 2);
  unsigned short* snB   = (unsigned short*)alloc((size_t)GP * NN * 2);
  unsigned short* xnB   = (unsigned short*)alloc((size_t)GP * NN * 2);
  float* Wl1p   = (float*)alloc((size_t)272 * GP * 4);
  float* rootb  = (float*)alloc((size_t)NN * HH * 4);
  float* t      = (float*)alloc((size_t)NN * HH * 4);
  float* x1     = (float*)alloc((size_t)NN * HH * 4);
  float* x2     = (float*)alloc((size_t)NN * HH * 4);
  float* part   = (float*)alloc((size_t)KS * NN * HH * 4);
  float* t3     = (float*)alloc((size_t)NN * CC * 4);
  float* x3     = (float*)alloc((size_t)NN * CC * 4);
  float* sn     = (float*)alloc((size_t)NN * CC * 4);
  float* xn     = (float*)alloc((size_t)NN * FF * 4);
  float* H1     = (float*)alloc((size_t)NN * FF * 4);
  float* Uu     = (float*)alloc((size_t)NN * CC * 4);
  float* H2     = (float*)alloc((size_t)NN * CC * 4);
  float* G      = (float*)alloc((size_t)GP * GP * 4);
  float* Gxs    = (float*)alloc((size_t)GP * GP * 4);
  float* Gs     = (float*)alloc((size_t)GP * GP * 4);
  float* Gs0    = (float*)alloc((size_t)GP * GP * 4);
  float* scalars = (float*)alloc(160 * 4);
  float* colsum = (float*)alloc(4096 * 4);
  float* colsq  = (float*)alloc(4096 * 4);
  float* bnA    = (float*)alloc(1024);
  float* bnB    = (float*)alloc(1024);
  (void)ws_size; (void)in_sizes; (void)n_in; (void)out_size;

  float* out   = (float*)d_out;
  float* s1    = out;                          // N*C
  float* outsc = out + (size_t)NN * CC;        // 5 scalars
  float* emb   = out + (size_t)NN * CC + 5;    // N*D

  // zero scalar accumulators + padded BN stats + xnB (pad rows must be zero)
  hipMemsetAsync(scalars, 0, 160 * 4, stream);
  hipMemsetAsync(colsum, 0, 2 * 4096 * 4, stream);
  hipMemsetAsync(xnB, 0, (size_t)GP * NN * 2, stream);

  k_padW<<<221, 256, 0, stream>>>(Wl1, Wl1p);
  k_xn<<<NN / 4, 256, 0, stream>>>(x, xn);
  k_xnB<<<NN / 32, 256, 0, stream>>>(xn, xnB);

  // conv1 (fused: adj cvt->tiled + adj^2 + MFMA)
  k_proj_t<<<NN / 32, 256, 0, stream>>>(x, W1r, W1root, mB, rootb, FF);
  k_conv1f<<<dim3(NN / 64, KS), 256, 0, stream>>>(adj, adj_t, mB, part, scalars);
  k_epi32<<<NN * HH / 256, 256, 0, stream>>>(part, b1, rootb, t, colsum, colsq);
  k_bnfinal<<<1, 256, 0, stream>>>(colsum, colsq, g1, be1, bnA, bnB, HH);
  k_bnapply32<<<NN / 32, 256, 0, stream>>>(t, bnA, bnB, x1, emb, 0, (unsigned short*)nullptr);

  // conv2
  k_proj_t<<<NN / 32, 256, 0, stream>>>(x1, W2r, W2root, mB, rootb, HH);
  k_adjmm<<<dim3(NN / 64, KS), 256, 0, stream>>>(adj_t, mB, part);
  k_epi32<<<NN * HH / 256, 256, 0, stream>>>(part, b2, rootb, t, colsum, colsq);
  k_bnfinal<<<1, 256, 0, stream>>>(colsum, colsq, g2, be2, bnA, bnB, HH);
  k_bnapply32<<<NN / 32, 256, 0, stream>>>(t, bnA, bnB, x2, emb, HH, x2B);

  // conv3
  k_adjmm<<<dim3(NN / 64, KS), 256, 0, stream>>>(adj_t, x2B, part);
  k_epi3<<<NN / 16, 256, 0, stream>>>(part, W3r, b3, x2, W3root, t3, colsum, colsq);
  k_bnfinal<<<1, 256, 0, stream>>>(colsum, colsq, g3, be3, bnA, bnB, CC);
  k_bnapply205<<<NN, 256, 0, stream>>>(t3, bnA, bnB, x3, emb);

  // head (fills s1B/snB tiles incl. pad rows)
  k_layer4<<<NN / 8, 256, 0, stream>>>(x1, x2, x3, Wl1p, bl1, s1, sn, s1B, snB, scalars);

  // tr(S' A S) via MFMA
  k_normmfma<<<dim3(NN / 64, KS), 256, 0, stream>>>(adj_t, s1B, s1, scalars);

  // Grams + bilinear forms + losses + finalize
  k_gramm<<<dim3(13, 13, 4), 256, 0, stream>>>(xnB, snB, s1B, G, Gxs, Gs, Gs0);
  k_rowmm3<<<dim3(NN / 16, 3), 256, 0, stream>>>(xn, sn, G, Gxs, Gs, H1, Uu, H2);
  k_losses<<<NN / 4 + LL, 256, 0, stream>>>(H1, Uu, H2, xn, sn, emb, teams, reps, scalars);
  k_final<<<1, 256, 0, stream>>>(Gs0, scalars, outsc);
}

// Round 8
// 334.322 us; speedup vs baseline: 2.7669x; 1.0769x over previous
//
#include <hip/hip_runtime.h>
#include <math.h>

#define NN 4096
#define FF 128
#define HH 32
#define CC 205
#define DD 269
#define LL 512
#define TT 12
#define RR 4
#define KS 16    // k-split for all adj MFMA passes
#define GP 208   // padded gram dim
#define DP 288   // padded D (k) dim for logits MFMA

// padded scalar slots: 0=trSAS 1=adjsq 2=entropy 3=sim 4=embloss
#define SC(i) ((i) * 32)

typedef __attribute__((ext_vector_type(8))) short bf16x8;
typedef __attribute__((ext_vector_type(4))) float f32x4;
typedef __attribute__((ext_vector_type(8))) unsigned short u16x8;

// ---------------- helpers ----------------
__device__ __forceinline__ float wave_sum(float v) {
#pragma unroll
  for (int o = 32; o > 0; o >>= 1) v += __shfl_xor(v, o, 64);
  return v;
}
__device__ __forceinline__ float wave_max(float v) {
#pragma unroll
  for (int o = 32; o > 0; o >>= 1) v = fmaxf(v, __shfl_xor(v, o, 64));
  return v;
}
__device__ __forceinline__ unsigned short f2bf(float x) {  // RNE
  union { float f; unsigned u; } v; v.f = x;
  unsigned r = v.u + 0x7FFFu + ((v.u >> 16) & 1u);
  return (unsigned short)(r >> 16);
}

// ---------------- Wl1 -> Wl1T bf16 [GP][DP] (transposed, zero-padded) ----------------
__global__ __launch_bounds__(256) void k_padWT(const float* __restrict__ Wl1,
                                               unsigned short* __restrict__ Wl1T) {
  const int idx = blockIdx.x * 256 + threadIdx.x;
  if (idx >= GP * DP) return;
  const int c = idx / DP, k = idx - c * DP;
  Wl1T[idx] = (c < CC && k < DD) ? f2bf(Wl1[(size_t)k * CC + c]) : (unsigned short)0;
}

// ---------------- emb fp32 [N][DD] -> embB bf16 [N][DP] (zero-padded) ----------------
__global__ __launch_bounds__(256) void k_embB(const float* __restrict__ emb,
                                              unsigned short* __restrict__ embB) {
  const int idx = blockIdx.x * 256 + threadIdx.x;  // NN*DP
  const int n = idx / DP, d = idx - n * DP;
  embB[idx] = (d < DD) ? f2bf(emb[(size_t)n * DD + d]) : (unsigned short)0;
}

// ---------------- dual projection: mB (bf16 tiled [kb][32][32]) = (A@W1)^T tiles, o2 = A@W2 ----------------
__global__ __launch_bounds__(256) void k_proj_t(const float* __restrict__ A,
                                                const float* __restrict__ W1,
                                                const float* __restrict__ W2,
                                                unsigned short* __restrict__ mB,
                                                float* __restrict__ o2, int K) {
  __shared__ float sX[32][132];
  __shared__ unsigned short sT[32][34];
  const int tid = threadIdx.x;
  const int kb = blockIdx.x;
  const int nf4 = K >> 2;
  const int tot4 = 32 * nf4;
  for (int p = tid; p < tot4; p += 256) {
    const int node = p / nf4, c4 = p - node * nf4;
    const float4 v = *reinterpret_cast<const float4*>(&A[((size_t)(kb * 32 + node)) * K + c4 * 4]);
    sX[node][c4 * 4 + 0] = v.x; sX[node][c4 * 4 + 1] = v.y;
    sX[node][c4 * 4 + 2] = v.z; sX[node][c4 * 4 + 3] = v.w;
  }
  __syncthreads();
  const int c = tid & 31, g = tid >> 5;
  float a1[4] = {0.f, 0.f, 0.f, 0.f}, a2[4] = {0.f, 0.f, 0.f, 0.f};
  for (int k = 0; k < K; ++k) {
    const float w1 = W1[k * HH + c];
    const float w2 = W2[k * HH + c];
#pragma unroll
    for (int ni = 0; ni < 4; ++ni) {
      const float av = sX[g * 4 + ni][k];
      a1[ni] = fmaf(av, w1, a1[ni]);
      a2[ni] = fmaf(av, w2, a2[ni]);
    }
  }
#pragma unroll
  for (int ni = 0; ni < 4; ++ni) {
    o2[((size_t)kb * 32 + g * 4 + ni) * HH + c] = a2[ni];
    sT[c][g * 4 + ni] = f2bf(a1[ni]);
  }
  __syncthreads();
  if (tid < 128) {
    const int row = tid >> 2, seg = tid & 3;
    u16x8 v;
#pragma unroll
    for (int j = 0; j < 8; ++j) v[j] = sT[row][seg * 8 + j];
    *reinterpret_cast<u16x8*>(&mB[((size_t)kb * 32 + row) * 32 + seg * 8]) = v;
  }
}

// ---------------- row-normalize x -> xn ----------------
__global__ __launch_bounds__(256) void k_xn(const float* __restrict__ x, float* __restrict__ xn) {
  const int lane = threadIdx.x & 63;
  const int row = blockIdx.x * 4 + (threadIdx.x >> 6);
  float v0 = x[(size_t)row * FF + lane];
  float v1 = x[(size_t)row * FF + 64 + lane];
  float ss = wave_sum(v0 * v0 + v1 * v1);
  float n = fmaxf(sqrtf(ss), 1e-8f);
  xn[(size_t)row * FF + lane] = v0 / n;
  xn[(size_t)row * FF + 64 + lane] = v1 / n;
}

// ---------------- xn -> xnB bf16 tiled [kb][GP][32] ----------------
__global__ __launch_bounds__(256) void k_xnB(const float* __restrict__ xn,
                                             unsigned short* __restrict__ xnB) {
  __shared__ unsigned short sT[FF][34];
  const int tid = threadIdx.x;
  const int kb = blockIdx.x;
  for (int p = tid; p < 1024; p += 256) {
    const int node = p >> 5, c4 = p & 31;
    const float4 v = *reinterpret_cast<const float4*>(&xn[((size_t)(kb * 32 + node)) * FF + c4 * 4]);
    sT[c4 * 4 + 0][node] = f2bf(v.x);
    sT[c4 * 4 + 1][node] = f2bf(v.y);
    sT[c4 * 4 + 2][node] = f2bf(v.z);
    sT[c4 * 4 + 3][node] = f2bf(v.w);
  }
  __syncthreads();
  const int row = tid >> 1, seg = (tid & 1) * 16;
  if (row < FF) {
    u16x8 a, b;
#pragma unroll
    for (int j = 0; j < 8; ++j) { a[j] = sT[row][seg + j]; b[j] = sT[row][seg + 8 + j]; }
    *reinterpret_cast<u16x8*>(&xnB[((size_t)kb * GP + row) * 32 + seg]) = a;
    *reinterpret_cast<u16x8*>(&xnB[((size_t)kb * GP + row) * 32 + seg + 8]) = b;
  }
}

// ---------------- FUSED conv1: fp32 adj -> bf16 tiled adj_t + sum(adj^2) + MFMA ----------------
__global__ __launch_bounds__(256) void k_conv1f(const float* __restrict__ adj,
                                                unsigned short* __restrict__ adj_t,
                                                const unsigned short* __restrict__ mB,
                                                float* __restrict__ part,
                                                float* __restrict__ scalars) {
  __shared__ unsigned short sA[64][264];
  __shared__ float red[4];
  const int tid = threadIdx.x;
  const int rbase_blk = blockIdx.x * 64;
  const int kbase = blockIdx.y * 256;
  const int rb0 = blockIdx.x * 4;
  const int kb0 = blockIdx.y * 8;
  float adjsq = 0.f;
#pragma unroll
  for (int i = 0; i < 16; ++i) {
    const int fi = i * 256 + tid;
    const int r = fi >> 6;
    const int c4 = fi & 63;
    const size_t goff = (size_t)(rbase_blk + r) * NN + kbase + c4 * 4;
    const float4 v = *reinterpret_cast<const float4*>(&adj[goff]);
    adjsq += v.x * v.x + v.y * v.y + v.z * v.z + v.w * v.w;
    ushort4 h;
    h.x = f2bf(v.x); h.y = f2bf(v.y); h.z = f2bf(v.z); h.w = f2bf(v.w);
    const size_t toff = ((size_t)(rb0 + (r >> 4)) * (NN / 32) + kb0 + (c4 >> 3)) * 512 +
                        (r & 15) * 32 + (c4 & 7) * 4;
    *reinterpret_cast<ushort4*>(&adj_t[toff]) = h;
    *reinterpret_cast<ushort4*>(&sA[r][c4 * 4]) = h;
  }
  __syncthreads();
  const int lane = tid & 63;
  const int w = tid >> 6;
  const int l15 = lane & 15;
  const int kgrp = (lane >> 4) * 8;
  const int rloc = w * 16 + l15;
  f32x4 acc0 = {0.f, 0.f, 0.f, 0.f}, acc1 = {0.f, 0.f, 0.f, 0.f};
#pragma unroll
  for (int k0 = 0; k0 < 256; k0 += 32) {
    const size_t boff = ((size_t)(kb0 + (k0 >> 5)) * 32) * 32;
    const bf16x8 a = *reinterpret_cast<const bf16x8*>(&sA[rloc][k0 + kgrp]);
    const bf16x8 b0 = *reinterpret_cast<const bf16x8*>(&mB[boff + (size_t)l15 * 32 + kgrp]);
    const bf16x8 b1 = *reinterpret_cast<const bf16x8*>(&mB[boff + (size_t)(16 + l15) * 32 + kgrp]);
    acc0 = __builtin_amdgcn_mfma_f32_16x16x32_bf16(a, b0, acc0, 0, 0, 0);
    acc1 = __builtin_amdgcn_mfma_f32_16x16x32_bf16(a, b1, acc1, 0, 0, 0);
  }
  float* pp = part + (size_t)blockIdx.y * (NN * HH);
  const int rout = rbase_blk + w * 16 + (lane >> 4) * 4;
#pragma unroll
  for (int r = 0; r < 4; ++r) {
    pp[(size_t)(rout + r) * HH + l15] = acc0[r];
    pp[(size_t)(rout + r) * HH + 16 + l15] = acc1[r];
  }
  adjsq = wave_sum(adjsq);
  if (lane == 0) red[w] = adjsq;
  __syncthreads();
  if (tid == 0) atomicAdd(&scalars[SC(1)], red[0] + red[1] + red[2] + red[3]);
}

// ---------------- MFMA adj pass (tiled A, tiled B [kb][32][32]) ----------------
__global__ __launch_bounds__(256) void k_adjmm(const unsigned short* __restrict__ adj_t,
                                               const unsigned short* __restrict__ mB,
                                               float* __restrict__ part) {
  const int tid = threadIdx.x;
  const int lane = tid & 63;
  const int w = tid >> 6;
  const int rb = blockIdx.x * 4 + w;
  const int kb0 = blockIdx.y * 8;
  const int l15 = lane & 15;
  const int kgrp = (lane >> 4) * 8;
  f32x4 acc0 = {0.f, 0.f, 0.f, 0.f}, acc1 = {0.f, 0.f, 0.f, 0.f};
#pragma unroll
  for (int kt = 0; kt < 8; ++kt) {
    const size_t aoff = ((size_t)rb * (NN / 32) + kb0 + kt) * 512;
    const size_t boff = ((size_t)(kb0 + kt) * 32) * 32;
    const bf16x8 a = *reinterpret_cast<const bf16x8*>(&adj_t[aoff + l15 * 32 + kgrp]);
    const bf16x8 b0 = *reinterpret_cast<const bf16x8*>(&mB[boff + (size_t)l15 * 32 + kgrp]);
    const bf16x8 b1 = *reinterpret_cast<const bf16x8*>(&mB[boff + (size_t)(16 + l15) * 32 + kgrp]);
    acc0 = __builtin_amdgcn_mfma_f32_16x16x32_bf16(a, b0, acc0, 0, 0, 0);
    acc1 = __builtin_amdgcn_mfma_f32_16x16x32_bf16(a, b1, acc1, 0, 0, 0);
  }
  float* pp = part + (size_t)blockIdx.y * (NN * HH);
  const int rout = rb * 16 + (lane >> 4) * 4;
#pragma unroll
  for (int r = 0; r < 4; ++r) {
    pp[(size_t)(rout + r) * HH + l15] = acc0[r];
    pp[(size_t)(rout + r) * HH + 16 + l15] = acc1[r];
  }
}

// ---------------- MFMA norm pass (tiled A, tiled s1B [kb][GP][32]) ----------------
__global__ __launch_bounds__(256) void k_normmfma(const unsigned short* __restrict__ adj_t,
                                                  const unsigned short* __restrict__ s1B,
                                                  const float* __restrict__ s1,
                                                  float* __restrict__ scalars) {
  __shared__ float red[4];
  const int tid = threadIdx.x;
  const int lane = tid & 63;
  const int w = tid >> 6;
  const int rb = blockIdx.x * 4 + w;
  const int kb0 = blockIdx.y * 8;
  const int l15 = lane & 15;
  const int kgrp = (lane >> 4) * 8;
  f32x4 acc[13];
#pragma unroll
  for (int ct = 0; ct < 13; ++ct) acc[ct] = (f32x4){0.f, 0.f, 0.f, 0.f};
#pragma unroll 2
  for (int kt = 0; kt < 8; ++kt) {
    const size_t aoff = ((size_t)rb * (NN / 32) + kb0 + kt) * 512;
    const bf16x8 a = *reinterpret_cast<const bf16x8*>(&adj_t[aoff + l15 * 32 + kgrp]);
    const size_t bbase = ((size_t)(kb0 + kt) * GP) * 32 + (size_t)l15 * 32 + kgrp;
#pragma unroll
    for (int ct = 0; ct < 13; ++ct) {
      const bf16x8 b = *reinterpret_cast<const bf16x8*>(&s1B[bbase + (size_t)ct * 512]);
      acc[ct] = __builtin_amdgcn_mfma_f32_16x16x32_bf16(a, b, acc[ct], 0, 0, 0);
    }
  }
  const int rout = rb * 16 + (lane >> 4) * 4;
  float sc = 0.f;
#pragma unroll
  for (int ct = 0; ct < 13; ++ct) {
    const int col = ct * 16 + l15;
    if (col < CC) {
#pragma unroll
      for (int r = 0; r < 4; ++r)
        sc = fmaf(acc[ct][r], s1[(size_t)(rout + r) * CC + col], sc);
    }
  }
  sc = wave_sum(sc);
  if (lane == 0) red[w] = sc;
  __syncthreads();
  if (tid == 0) atomicAdd(&scalars[SC(0)], red[0] + red[1] + red[2] + red[3]);
}

// ---------------- conv epilogue (32-wide) ----------------
__global__ __launch_bounds__(256) void k_epi32(const float* __restrict__ part,
                                               const float* __restrict__ bias,
                                               const float* __restrict__ root,
                                               float* __restrict__ t,
                                               float* __restrict__ colsum,
                                               float* __restrict__ colsq) {
  __shared__ float ls[HH], lq[HH];
  const int tid = threadIdx.x;
  const int idx = blockIdx.x * 256 + tid;
  const int c = idx & (HH - 1);
  if (tid < HH) { ls[tid] = 0.f; lq[tid] = 0.f; }
  __syncthreads();
  float s = bias[c] + root[idx];
#pragma unroll
  for (int sp = 0; sp < KS; ++sp) s += part[(size_t)sp * (NN * HH) + idx];
  s = fmaxf(s, 0.f);
  t[idx] = s;
  atomicAdd(&ls[c], s);
  atomicAdd(&lq[c], s * s);
  __syncthreads();
  if (tid < HH) {
    atomicAdd(&colsum[tid * 16], ls[tid]);
    atomicAdd(&colsq[tid * 16], lq[tid]);
  }
}

// ---------------- BN finalize ----------------
__global__ void k_bnfinal(float* __restrict__ colsum, float* __restrict__ colsq,
                          const float* __restrict__ g, const float* __restrict__ be,
                          float* __restrict__ A, float* __restrict__ B, int Ccols) {
  const int c = threadIdx.x;
  float cs = 0.f, cq = 0.f;
  if (c < Ccols) { cs = colsum[c * 16]; cq = colsq[c * 16]; }
  __syncthreads();
  for (int i = threadIdx.x; i < 4096; i += 256) { colsum[i] = 0.f; colsq[i] = 0.f; }
  if (c >= Ccols) return;
  const float m = cs * (1.f / NN);
  const float var = fmaxf(cq * (1.f / NN) - m * m, 0.f);
  const float a = g[c] / sqrtf(var + 1e-5f);
  A[c] = a;
  B[c] = be[c] - m * a;
}

// ---------------- bn apply (32-wide) + optional bf16 tiled copy ----------------
__global__ __launch_bounds__(256) void k_bnapply32(const float* __restrict__ t,
                                                   const float* __restrict__ A,
                                                   const float* __restrict__ B,
                                                   float* __restrict__ xo,
                                                   float* __restrict__ emb, int embOff,
                                                   unsigned short* __restrict__ xB) {
  __shared__ unsigned short sT[32][34];
  const int tid = threadIdx.x;
  const int kb = blockIdx.x;
  const int c = tid & 31, g = tid >> 5;
  const float Ac = A[c], Bc = B[c];
#pragma unroll
  for (int ni = 0; ni < 4; ++ni) {
    const int n = kb * 32 + g * 4 + ni;
    const float v = fmaf(Ac, t[(size_t)n * HH + c], Bc);
    xo[(size_t)n * HH + c] = v;
    emb[(size_t)n * DD + embOff + c] = v;
    if (xB) sT[c][g * 4 + ni] = f2bf(v);
  }
  if (xB) {
    __syncthreads();
    if (tid < 128) {
      const int row = tid >> 2, seg = tid & 3;
      u16x8 o;
#pragma unroll
      for (int j = 0; j < 8; ++j) o[j] = sT[row][seg * 8 + j];
      *reinterpret_cast<u16x8*>(&xB[((size_t)kb * 32 + row) * 32 + seg * 8]) = o;
    }
  }
}

// ---------------- conv3 epilogue ----------------
__global__ __launch_bounds__(256) void k_epi3(const float* __restrict__ part,
                                              const float* __restrict__ W3r,
                                              const float* __restrict__ b3,
                                              const float* __restrict__ x2,
                                              const float* __restrict__ W3root,
                                              float* __restrict__ t3,
                                              float* __restrict__ colsum,
                                              float* __restrict__ colsq) {
  __shared__ float z[16][33];
  __shared__ float xr[16][33];
  const int row0 = blockIdx.x * 16;
  for (int s = threadIdx.x; s < 16 * 32; s += 256) {
    const int r = s >> 5, k = s & 31;
    float a = 0.f;
#pragma unroll
    for (int sp = 0; sp < KS; ++sp)
      a += part[(size_t)sp * (NN * HH) + (size_t)(row0 + r) * HH + k];
    z[r][k] = a;
    xr[r][k] = x2[(size_t)(row0 + r) * HH + k];
  }
  __syncthreads();
  const int c = threadIdx.x;
  if (c >= CC) return;
  float acc[16];
  const float bb = b3[c];
#pragma unroll
  for (int r = 0; r < 16; ++r) acc[r] = bb;
  for (int k = 0; k < 32; ++k) {
    const float w1 = W3r[k * CC + c];
    const float w2 = W3root[k * CC + c];
#pragma unroll
    for (int r = 0; r < 16; ++r) acc[r] += z[r][k] * w1 + xr[r][k] * w2;
  }
  float lsm = 0.f, lqm = 0.f;
#pragma unroll
  for (int r = 0; r < 16; ++r) {
    const float v = fmaxf(acc[r], 0.f);
    t3[(size_t)(row0 + r) * CC + c] = v;
    lsm += v;
    lqm += v * v;
  }
  atomicAdd(&colsum[c * 16], lsm);
  atomicAdd(&colsq[c * 16], lqm);
}

__global__ void k_bnapply205(const float* __restrict__ t3, const float* __restrict__ A,
                             const float* __restrict__ B, float* __restrict__ x3,
                             float* __restrict__ emb) {
  const int row = blockIdx.x;
  const int c = threadIdx.x;
  if (c >= CC) return;
  const float v = fmaf(A[c], t3[(size_t)row * CC + c], B[c]);
  x3[(size_t)row * CC + c] = v;
  emb[(size_t)row * DD + 2 * HH + c] = v;
}

// ---------------- logits via MFMA: logits[N][GP] = embB @ Wl1T^T ----------------
// grid NN/16; block = 16 rows, 4 waves; wave w covers col-tiles {w, w+4, w+8, w+12<13}
__global__ __launch_bounds__(256) void k_logits(const unsigned short* __restrict__ embB,
                                                const unsigned short* __restrict__ Wl1T,
                                                float* __restrict__ logits) {
  __shared__ unsigned short sA[16][296];
  const int tid = threadIdx.x;
  const int row0 = blockIdx.x * 16;
  for (int p = tid; p < 576; p += 256) {  // 16 rows x 36 chunks of 8 ushorts
    const int r = p / 36, ch = p - r * 36;
    const u16x8 v = *reinterpret_cast<const u16x8*>(&embB[(size_t)(row0 + r) * DP + ch * 8]);
    *reinterpret_cast<u16x8*>(&sA[r][ch * 8]) = v;
  }
  __syncthreads();
  const int lane = tid & 63;
  const int w = tid >> 6;
  const int l15 = lane & 15;
  const int kgrp = (lane >> 4) * 8;
  f32x4 acc[4];
#pragma unroll
  for (int i = 0; i < 4; ++i) acc[i] = (f32x4){0.f, 0.f, 0.f, 0.f};
#pragma unroll
  for (int i = 0; i < 4; ++i) {
    const int ct = w + i * 4;
    if (ct < 13) {
      const size_t brow = (size_t)(ct * 16 + l15) * DP;
#pragma unroll
      for (int k0 = 0; k0 < DP; k0 += 32) {
        const bf16x8 a = *reinterpret_cast<const bf16x8*>(&sA[l15][k0 + kgrp]);
        const bf16x8 b = *reinterpret_cast<const bf16x8*>(&Wl1T[brow + k0 + kgrp]);
        acc[i] = __builtin_amdgcn_mfma_f32_16x16x32_bf16(a, b, acc[i], 0, 0, 0);
      }
    }
  }
  const int rout = row0 + (lane >> 4) * 4;
#pragma unroll
  for (int i = 0; i < 4; ++i) {
    const int ct = w + i * 4;
    if (ct < 13) {
#pragma unroll
      for (int r = 0; r < 4; ++r)
        logits[(size_t)(rout + r) * GP + ct * 16 + l15] = acc[i][r];
    }
  }
}

// ---------------- softmax head: logits -> s1, sn, s1B/snB tiles, entropy ----------------
// grid NN/8; 4 waves/block; wave owns 2 rows; lane owns cols {4*lane..4*lane+3}
__global__ __launch_bounds__(256) void k_softmax(const float* __restrict__ logits,
                                                 const float* __restrict__ bl1,
                                                 float* __restrict__ s1,
                                                 float* __restrict__ sn,
                                                 unsigned short* __restrict__ s1B,
                                                 unsigned short* __restrict__ snB,
                                                 float* __restrict__ scalars) {
  __shared__ unsigned short sTa[8][212];
  __shared__ unsigned short sTb[8][212];
  __shared__ float redE[4];
  const int row0 = blockIdx.x * 8;
  const int tid = threadIdx.x;
  const int w = tid >> 6;
  const int lane = tid & 63;
  const int r0 = w * 2;
  const int c0 = lane * 4;
  const bool active = (c0 < GP);
  float bl[4];
#pragma unroll
  for (int j = 0; j < 4; ++j) bl[j] = (c0 + j < CC) ? bl1[c0 + j] : 0.f;
  float ent_acc = 0.f;
#pragma unroll
  for (int r = 0; r < 2; ++r) {
    const int row = row0 + r0 + r;
    float4 lg = {0.f, 0.f, 0.f, 0.f};
    if (active) lg = *reinterpret_cast<const float4*>(&logits[(size_t)row * GP + c0]);
    const float lgv[4] = {lg.x, lg.y, lg.z, lg.w};
    float v[4];
    float ml = -1e30f;
#pragma unroll
    for (int j = 0; j < 4; ++j) {
      const int c = c0 + j;
      v[j] = (c < CC) ? fmaxf(lgv[j] + bl[j], 0.f) : -1e30f;
      ml = fmaxf(ml, v[j]);
    }
    const float m = wave_max(ml);
    float e[4];
    float sl = 0.f;
#pragma unroll
    for (int j = 0; j < 4; ++j) {
      const int c = c0 + j;
      e[j] = (c < CC) ? __expf(v[j] - m) : 0.f;
      sl += e[j];
    }
    const float S = wave_sum(sl);
    const float invS = 1.f / S;
    float p[4];
    float ql = 0.f;
#pragma unroll
    for (int j = 0; j < 4; ++j) {
      p[j] = e[j] * invS;
      ql += p[j] * p[j];
    }
    const float q = wave_sum(ql);
    const float inv = 1.f / fmaxf(sqrtf(q), 1e-8f);
    float m2l = -1e30f;
#pragma unroll
    for (int j = 0; j < 4; ++j) {
      const int c = c0 + j;
      if (c < CC) {
        s1[(size_t)row * CC + c] = p[j];
        sn[(size_t)row * CC + c] = p[j] * inv;
        m2l = fmaxf(m2l, p[j]);
      }
    }
    if (active) {
#pragma unroll
      for (int j = 0; j < 4; ++j) {
        const int c = c0 + j;
        const bool ok = (c < CC);
        sTa[r0 + r][c] = ok ? f2bf(p[j]) : (unsigned short)0;
        sTb[r0 + r][c] = ok ? f2bf(p[j] * inv) : (unsigned short)0;
      }
    }
    const float m2 = wave_max(m2l);
    float e2[4];
    float s2l = 0.f;
#pragma unroll
    for (int j = 0; j < 4; ++j) {
      const int c = c0 + j;
      e2[j] = (c < CC) ? __expf(p[j] - m2) : 0.f;
      s2l += e2[j];
    }
    const float S2 = wave_sum(s2l);
    const float invS2 = 1.f / S2;
    float tl = 0.f;
#pragma unroll
    for (int j = 0; j < 4; ++j) {
      const int c = c0 + j;
      if (c < CC) {
        const float sp = e2[j] * invS2;
        tl -= sp * logf(sp + 1e-15f);
      }
    }
    ent_acc += tl;
  }
  ent_acc = wave_sum(ent_acc);
  if (lane == 0) redE[w] = ent_acc;
  __syncthreads();
  if (tid == 0) atomicAdd(&scalars[SC(2)], redE[0] + redE[1] + redE[2] + redE[3]);
  if (tid < GP) {
    const int kb = row0 >> 5, no = row0 & 31;
    u16x8 oa, ob;
#pragma unroll
    for (int r = 0; r < 8; ++r) { oa[r] = sTa[r][tid]; ob[r] = sTb[r][tid]; }
    *reinterpret_cast<u16x8*>(&s1B[((size_t)kb * GP + tid) * 32 + no]) = oa;
    *reinterpret_cast<u16x8*>(&snB[((size_t)kb * GP + tid) * 32 + no]) = ob;
  }
}

// ---------------- MFMA Gram: Cp = P^T Q from tiled [kb][GP][32] operands ----------------
__global__ __launch_bounds__(256) void k_gramm(const unsigned short* __restrict__ xnB,
                                               const unsigned short* __restrict__ snB,
                                               const unsigned short* __restrict__ s1B,
                                               float* __restrict__ G, float* __restrict__ Gxs,
                                               float* __restrict__ Gs, float* __restrict__ Gs0) {
  const int gid = blockIdx.z;
  const int tp = blockIdx.x * 16;
  const int tq = blockIdx.y * 16;
  const unsigned short *PT, *QT;
  float* Cp;
  if (gid == 0)      { PT = xnB; QT = xnB; Cp = G;   if (tp >= FF || tq >= FF) return; }
  else if (gid == 1) { PT = xnB; QT = snB; Cp = Gxs; if (tp >= FF) return; }
  else if (gid == 2) { PT = snB; QT = snB; Cp = Gs; }
  else               { PT = s1B; QT = s1B; Cp = Gs0; }
  const int tid = threadIdx.x;
  const int lane = tid & 63;
  const int w = tid >> 6;
  const int l15 = lane & 15;
  const int kgrp = (lane >> 4) * 8;
  f32x4 acc = {0.f, 0.f, 0.f, 0.f};
#pragma unroll 8
  for (int kt = 0; kt < 32; ++kt) {
    const int kb = w * 32 + kt;
    const bf16x8 a = *reinterpret_cast<const bf16x8*>(&PT[((size_t)kb * GP + tp + l15) * 32 + kgrp]);
    const bf16x8 b = *reinterpret_cast<const bf16x8*>(&QT[((size_t)kb * GP + tq + l15) * 32 + kgrp]);
    acc = __builtin_amdgcn_mfma_f32_16x16x32_bf16(a, b, acc, 0, 0, 0);
  }
  __shared__ float red[4][16][17];
  const int crow = (lane >> 4) * 4;
#pragma unroll
  for (int r = 0; r < 4; ++r) red[w][crow + r][l15] = acc[r];
  __syncthreads();
  const int rr = tid >> 4, cc = tid & 15;
  const float v = red[0][rr][cc] + red[1][rr][cc] + red[2][rr][cc] + red[3][rr][cc];
  Cp[(size_t)(tp + rr) * GP + (tq + cc)] = v;
}

// ---------------- thin GEMMs (3 in one launch); B has stride GP ----------------
__global__ __launch_bounds__(256) void k_rowmm3(const float* __restrict__ xn,
                                                const float* __restrict__ sn,
                                                const float* __restrict__ G,
                                                const float* __restrict__ Gxs,
                                                const float* __restrict__ Gs,
                                                float* __restrict__ H1,
                                                float* __restrict__ Uu,
                                                float* __restrict__ H2) {
  const float *A, *B;
  float* Cm;
  int K, Nc;
  if (blockIdx.y == 0)      { A = xn; B = G;   Cm = H1; K = FF; Nc = FF; }
  else if (blockIdx.y == 1) { A = xn; B = Gxs; Cm = Uu; K = FF; Nc = CC; }
  else                      { A = sn; B = Gs;  Cm = H2; K = CC; Nc = CC; }
  __shared__ float sA[16][208];
  const int row0 = blockIdx.x * 16;
  for (int s = threadIdx.x; s < 16 * K; s += 256) {
    const int r = s / K, k = s - r * K;
    sA[r][k] = A[(size_t)(row0 + r) * K + k];
  }
  __syncthreads();
  const int c = threadIdx.x;
  if (c >= Nc) return;
  float acc[16];
#pragma unroll
  for (int r = 0; r < 16; ++r) acc[r] = 0.f;
  for (int k = 0; k < K; ++k) {
    const float w = B[(size_t)k * GP + c];
#pragma unroll
    for (int r = 0; r < 16; ++r) acc[r] = fmaf(sA[r][k], w, acc[r]);
  }
#pragma unroll
  for (int r = 0; r < 16; ++r) Cm[(size_t)(row0 + r) * Nc + c] = acc[r];
}

// ---------------- per-row sim + team embedding loss ----------------
__global__ __launch_bounds__(256) void k_losses(const float* __restrict__ H1,
                                                const float* __restrict__ Uu,
                                                const float* __restrict__ H2,
                                                const float* __restrict__ xn,
                                                const float* __restrict__ sn,
                                                const float* __restrict__ emb,
                                                const int* __restrict__ teams,
                                                const int* __restrict__ reps,
                                                float* __restrict__ scalars) {
  __shared__ float red[4];
  const int tid = threadIdx.x;
  const int lane = tid & 63;
  const int w = tid >> 6;
  if (blockIdx.x < NN / 4) {
    const int row = blockIdx.x * 4 + w;
    float suu = 0.f, suv = 0.f, svv = 0.f;
#pragma unroll
    for (int c0 = 0; c0 < FF; c0 += 64) {
      const float xv = xn[(size_t)row * FF + c0 + lane];
      suu = fmaf(H1[(size_t)row * FF + c0 + lane], xv, suu);
    }
    for (int cb = lane; cb < CC; cb += 64) {
      const float sv = sn[(size_t)row * CC + cb];
      suv = fmaf(Uu[(size_t)row * CC + cb], sv, suv);
      svv = fmaf(H2[(size_t)row * CC + cb], sv, svv);
    }
    suu = wave_sum(suu);
    suv = wave_sum(suv);
    svv = wave_sum(svv);
    if (lane == 0) red[w] = suv / sqrtf(suu * svv);
    __syncthreads();
    if (tid == 0) atomicAdd(&scalars[SC(3)], red[0] + red[1] + red[2] + red[3]);
  } else {
    const int team = blockIdx.x - NN / 4;
    float part = 0.f;
    for (int d = tid; d < DD; d += 256) {
      float a = 0.f, b = 0.f;
#pragma unroll
      for (int m = 0; m < RR; ++m) a += emb[(size_t)reps[team * RR + m] * DD + d];
#pragma unroll
      for (int m = RR; m < TT; ++m) b += emb[(size_t)teams[team * TT + m] * DD + d];
      part += fabsf(a * (1.f / RR) - b * (1.f / (TT - RR)));
    }
    part = wave_sum(part);
    if (lane == 0) red[w] = part;
    __syncthreads();
    if (tid == 0) atomicAdd(&scalars[SC(4)], red[0] + red[1] + red[2] + red[3]);
  }
}

// ---------------- finalize ----------------
__global__ void k_final(const float* __restrict__ Gs0, const float* __restrict__ scalars,
                        float* __restrict__ outsc) {
  __shared__ float red[4];
  float p = 0.f;
  for (int i = threadIdx.x; i < GP * GP; i += 256) {
    const float v = Gs0[i];
    p = fmaf(v, v, p);
  }
  p = wave_sum(p);
  if ((threadIdx.x & 63) == 0) red[threadIdx.x >> 6] = p;
  __syncthreads();
  if (threadIdx.x == 0) {
    const float sumP2 = red[0] + red[1] + red[2] + red[3];
    const float normsq = fmaxf(sumP2 - 2.f * scalars[SC(0)] + scalars[SC(1)], 0.f);
    const float norm = sqrtf(normsq);
    const float e1 = scalars[SC(2)] * (1.f / NN);
    const float sim = -scalars[SC(3)] * (1.f / NN);
    const float embl = scalars[SC(4)] * (1.f / LL);
    outsc[0] = norm;
    outsc[1] = e1;
    outsc[2] = sim;
    outsc[3] = 100.f * norm + 10.f * e1 + 100.f * sim + embl;
    outsc[4] = embl;
  }
}

// ================= launch =================
extern "C" void kernel_launch(void* const* d_in, const int* in_sizes, int n_in,
                              void* d_out, int out_size, void* d_ws, size_t ws_size,
                              hipStream_t stream) {
  const float* x      = (const float*)d_in[0];
  const float* adj    = (const float*)d_in[1];
  const int*   teams  = (const int*)d_in[2];
  const int*   reps   = (const int*)d_in[3];
  const float* W1r    = (const float*)d_in[4];
  const float* b1     = (const float*)d_in[5];
  const float* W1root = (const float*)d_in[6];
  const float* g1     = (const float*)d_in[7];
  const float* be1    = (const float*)d_in[8];
  const float* W2r    = (const float*)d_in[9];
  const float* b2     = (const float*)d_in[10];
  const float* W2root = (const float*)d_in[11];
  const float* g2     = (const float*)d_in[12];
  const float* be2    = (const float*)d_in[13];
  const float* W3r    = (const float*)d_in[14];
  const float* b3     = (const float*)d_in[15];
  const float* W3root = (const float*)d_in[16];
  const float* g3     = (const float*)d_in[17];
  const float* be3    = (const float*)d_in[18];
  const float* Wl1    = (const float*)d_in[19];
  const float* bl1    = (const float*)d_in[20];

  char* wp = (char*)d_ws;
  auto alloc = [&](size_t bytes) { char* p = wp; wp += (bytes + 255) & ~(size_t)255; return p; };
  unsigned short* adj_t = (unsigned short*)alloc((size_t)NN * NN * 2);
  unsigned short* mB    = (unsigned short*)alloc((size_t)HH * NN * 2);
  unsigned short* x2B   = (unsigned short*)alloc((size_t)HH * NN * 2);
  unsigned short* s1B   = (unsigned short*)alloc((size_t)GP * NN * 2);
  unsigned short* snB   = (unsigned short*)alloc((size_t)GP * NN * 2);
  unsigned short* xnB   = (unsigned short*)alloc((size_t)GP * NN * 2);
  unsigned short* embB  = (unsigned short*)alloc((size_t)NN * DP * 2);
  unsigned short* Wl1T  = (unsigned short*)alloc((size_t)GP * DP * 2);
  float* logits = (float*)alloc((size_t)NN * GP * 4);
  float* rootb  = (float*)alloc((size_t)NN * HH * 4);
  float* t      = (float*)alloc((size_t)NN * HH * 4);
  float* x1     = (float*)alloc((size_t)NN * HH * 4);
  float* x2     = (float*)alloc((size_t)NN * HH * 4);
  float* part   = (float*)alloc((size_t)KS * NN * HH * 4);
  float* t3     = (float*)alloc((size_t)NN * CC * 4);
  float* x3     = (float*)alloc((size_t)NN * CC * 4);
  float* sn     = (float*)alloc((size_t)NN * CC * 4);
  float* xn     = (float*)alloc((size_t)NN * FF * 4);
  float* H1     = (float*)alloc((size_t)NN * FF * 4);
  float* Uu     = (float*)alloc((size_t)NN * CC * 4);
  float* H2     = (float*)alloc((size_t)NN * CC * 4);
  float* G      = (float*)alloc((size_t)GP * GP * 4);
  float* Gxs    = (float*)alloc((size_t)GP * GP * 4);
  float* Gs     = (float*)alloc((size_t)GP * GP * 4);
  float* Gs0    = (float*)alloc((size_t)GP * GP * 4);
  float* scalars = (float*)alloc(160 * 4);
  float* colsum = (float*)alloc(4096 * 4);
  float* colsq  = (float*)alloc(4096 * 4);
  float* bnA    = (float*)alloc(1024);
  float* bnB    = (float*)alloc(1024);
  (void)ws_size; (void)in_sizes; (void)n_in; (void)out_size;

  float* out   = (float*)d_out;
  float* s1    = out;                          // N*C
  float* outsc = out + (size_t)NN * CC;        // 5 scalars
  float* emb   = out + (size_t)NN * CC + 5;    // N*D

  // zero scalar accumulators + padded BN stats + xnB pad rows
  hipMemsetAsync(scalars, 0, 160 * 4, stream);
  hipMemsetAsync(colsum, 0, 2 * 4096 * 4, stream);
  hipMemsetAsync(xnB, 0, (size_t)GP * NN * 2, stream);

  k_padWT<<<(GP * DP + 255) / 256, 256, 0, stream>>>(Wl1, Wl1T);
  k_xn<<<NN / 4, 256, 0, stream>>>(x, xn);
  k_xnB<<<NN / 32, 256, 0, stream>>>(xn, xnB);

  // conv1 (fused: adj cvt->tiled + adj^2 + MFMA)
  k_proj_t<<<NN / 32, 256, 0, stream>>>(x, W1r, W1root, mB, rootb, FF);
  k_conv1f<<<dim3(NN / 64, KS), 256, 0, stream>>>(adj, adj_t, mB, part, scalars);
  k_epi32<<<NN * HH / 256, 256, 0, stream>>>(part, b1, rootb, t, colsum, colsq);
  k_bnfinal<<<1, 256, 0, stream>>>(colsum, colsq, g1, be1, bnA, bnB, HH);
  k_bnapply32<<<NN / 32, 256, 0, stream>>>(t, bnA, bnB, x1, emb, 0, (unsigned short*)nullptr);

  // conv2
  k_proj_t<<<NN / 32, 256, 0, stream>>>(x1, W2r, W2root, mB, rootb, HH);
  k_adjmm<<<dim3(NN / 64, KS), 256, 0, stream>>>(adj_t, mB, part);
  k_epi32<<<NN * HH / 256, 256, 0, stream>>>(part, b2, rootb, t, colsum, colsq);
  k_bnfinal<<<1, 256, 0, stream>>>(colsum, colsq, g2, be2, bnA, bnB, HH);
  k_bnapply32<<<NN / 32, 256, 0, stream>>>(t, bnA, bnB, x2, emb, HH, x2B);

  // conv3
  k_adjmm<<<dim3(NN / 64, KS), 256, 0, stream>>>(adj_t, x2B, part);
  k_epi3<<<NN / 16, 256, 0, stream>>>(part, W3r, b3, x2, W3root, t3, colsum, colsq);
  k_bnfinal<<<1, 256, 0, stream>>>(colsum, colsq, g3, be3, bnA, bnB, CC);
  k_bnapply205<<<NN, 256, 0, stream>>>(t3, bnA, bnB, x3, emb);

  // head: emb -> bf16, MFMA logits, streaming softmax (fills s1B/snB tiles incl pad)
  k_embB<<<NN * DP / 256, 256, 0, stream>>>(emb, embB);
  k_logits<<<NN / 16, 256, 0, stream>>>(embB, Wl1T, logits);
  k_softmax<<<NN / 8, 256, 0, stream>>>(logits, bl1, s1, sn, s1B, snB, scalars);

  // tr(S' A S) via MFMA
  k_normmfma<<<dim3(NN / 64, KS), 256, 0, stream>>>(adj_t, s1B, s1, scalars);

  // Grams + bilinear forms + losses + finalize
  k_gramm<<<dim3(13, 13, 4), 256, 0, stream>>>(xnB, snB, s1B, G, Gxs, Gs, Gs0);
  k_rowmm3<<<dim3(NN / 16, 3), 256, 0, stream>>>(xn, sn, G, Gxs, Gs, H1, Uu, H2);
  k_losses<<<NN / 4 + LL, 256, 0, stream>>>(H1, Uu, H2, xn, sn, emb, teams, reps, scalars);
  k_final<<<1, 256, 0, stream>>>(Gs0, scalars, outsc);
}

// Round 9
// 304.408 us; speedup vs baseline: 3.0388x; 1.0983x over previous
//
#include <hip/hip_runtime.h>
#include <math.h>

#define NN 4096
#define FF 128
#define HH 32
#define CC 205
#define DD 269
#define LL 512
#define TT 12
#define RR 4
#define KS 16    // k-split for all adj MFMA passes
#define GP 208   // padded gram dim
#define DP 288   // padded D (k) dim for logits MFMA
#define BST 40   // padded LDS row stride (ushorts) for B tiles

// padded scalar slots: 0=trSAS 1=adjsq 2=entropy 3=sim 4=embloss
#define SC(i) ((i) * 32)

typedef __attribute__((ext_vector_type(8))) short bf16x8;
typedef __attribute__((ext_vector_type(4))) float f32x4;
typedef __attribute__((ext_vector_type(8))) unsigned short u16x8;

// ---------------- helpers ----------------
__device__ __forceinline__ float wave_sum(float v) {
#pragma unroll
  for (int o = 32; o > 0; o >>= 1) v += __shfl_xor(v, o, 64);
  return v;
}
__device__ __forceinline__ float wave_max(float v) {
#pragma unroll
  for (int o = 32; o > 0; o >>= 1) v = fmaxf(v, __shfl_xor(v, o, 64));
  return v;
}
__device__ __forceinline__ unsigned short f2bf(float x) {  // RNE
  union { float f; unsigned u; } v; v.f = x;
  unsigned r = v.u + 0x7FFFu + ((v.u >> 16) & 1u);
  return (unsigned short)(r >> 16);
}

// ---------------- Wl1 -> Wl1T bf16 [GP][DP] (transposed, zero-padded) ----------------
__global__ __launch_bounds__(256) void k_padWT(const float* __restrict__ Wl1,
                                               unsigned short* __restrict__ Wl1T) {
  const int idx = blockIdx.x * 256 + threadIdx.x;
  if (idx >= GP * DP) return;
  const int c = idx / DP, k = idx - c * DP;
  Wl1T[idx] = (c < CC && k < DD) ? f2bf(Wl1[(size_t)k * CC + c]) : (unsigned short)0;
}

// ---------------- emb fp32 [N][DD] -> embB bf16 [N][DP] (zero-padded) ----------------
__global__ __launch_bounds__(256) void k_embB(const float* __restrict__ emb,
                                              unsigned short* __restrict__ embB) {
  const int idx = blockIdx.x * 256 + threadIdx.x;  // NN*DP
  const int n = idx / DP, d = idx - n * DP;
  embB[idx] = (d < DD) ? f2bf(emb[(size_t)n * DD + d]) : (unsigned short)0;
}

// ---------------- dual projection: mB (bf16 tiled [kb][32][32]) = (A@W1)^T tiles, o2 = A@W2 ----------------
__global__ __launch_bounds__(256) void k_proj_t(const float* __restrict__ A,
                                                const float* __restrict__ W1,
                                                const float* __restrict__ W2,
                                                unsigned short* __restrict__ mB,
                                                float* __restrict__ o2, int K) {
  __shared__ float sX[32][132];
  __shared__ unsigned short sT[32][34];
  const int tid = threadIdx.x;
  const int kb = blockIdx.x;
  const int nf4 = K >> 2;
  const int tot4 = 32 * nf4;
  for (int p = tid; p < tot4; p += 256) {
    const int node = p / nf4, c4 = p - node * nf4;
    const float4 v = *reinterpret_cast<const float4*>(&A[((size_t)(kb * 32 + node)) * K + c4 * 4]);
    sX[node][c4 * 4 + 0] = v.x; sX[node][c4 * 4 + 1] = v.y;
    sX[node][c4 * 4 + 2] = v.z; sX[node][c4 * 4 + 3] = v.w;
  }
  __syncthreads();
  const int c = tid & 31, g = tid >> 5;
  float a1[4] = {0.f, 0.f, 0.f, 0.f}, a2[4] = {0.f, 0.f, 0.f, 0.f};
  for (int k = 0; k < K; ++k) {
    const float w1 = W1[k * HH + c];
    const float w2 = W2[k * HH + c];
#pragma unroll
    for (int ni = 0; ni < 4; ++ni) {
      const float av = sX[g * 4 + ni][k];
      a1[ni] = fmaf(av, w1, a1[ni]);
      a2[ni] = fmaf(av, w2, a2[ni]);
    }
  }
#pragma unroll
  for (int ni = 0; ni < 4; ++ni) {
    o2[((size_t)kb * 32 + g * 4 + ni) * HH + c] = a2[ni];
    sT[c][g * 4 + ni] = f2bf(a1[ni]);
  }
  __syncthreads();
  if (tid < 128) {
    const int row = tid >> 2, seg = tid & 3;
    u16x8 v;
#pragma unroll
    for (int j = 0; j < 8; ++j) v[j] = sT[row][seg * 8 + j];
    *reinterpret_cast<u16x8*>(&mB[((size_t)kb * 32 + row) * 32 + seg * 8]) = v;
  }
}

// ---------------- row-normalize x -> xn ----------------
__global__ __launch_bounds__(256) void k_xn(const float* __restrict__ x, float* __restrict__ xn) {
  const int lane = threadIdx.x & 63;
  const int row = blockIdx.x * 4 + (threadIdx.x >> 6);
  float v0 = x[(size_t)row * FF + lane];
  float v1 = x[(size_t)row * FF + 64 + lane];
  float ss = wave_sum(v0 * v0 + v1 * v1);
  float n = fmaxf(sqrtf(ss), 1e-8f);
  xn[(size_t)row * FF + lane] = v0 / n;
  xn[(size_t)row * FF + 64 + lane] = v1 / n;
}

// ---------------- xn -> xnB bf16 tiled [kb][GP][32] ----------------
__global__ __launch_bounds__(256) void k_xnB(const float* __restrict__ xn,
                                             unsigned short* __restrict__ xnB) {
  __shared__ unsigned short sT[FF][34];
  const int tid = threadIdx.x;
  const int kb = blockIdx.x;
  for (int p = tid; p < 1024; p += 256) {
    const int node = p >> 5, c4 = p & 31;
    const float4 v = *reinterpret_cast<const float4*>(&xn[((size_t)(kb * 32 + node)) * FF + c4 * 4]);
    sT[c4 * 4 + 0][node] = f2bf(v.x);
    sT[c4 * 4 + 1][node] = f2bf(v.y);
    sT[c4 * 4 + 2][node] = f2bf(v.z);
    sT[c4 * 4 + 3][node] = f2bf(v.w);
  }
  __syncthreads();
  const int row = tid >> 1, seg = (tid & 1) * 16;
  if (row < FF) {
    u16x8 a, b;
#pragma unroll
    for (int j = 0; j < 8; ++j) { a[j] = sT[row][seg + j]; b[j] = sT[row][seg + 8 + j]; }
    *reinterpret_cast<u16x8*>(&xnB[((size_t)kb * GP + row) * 32 + seg]) = a;
    *reinterpret_cast<u16x8*>(&xnB[((size_t)kb * GP + row) * 32 + seg + 8]) = b;
  }
}

// ---------------- FUSED conv1: fp32 adj -> bf16 tiled adj_t + sum(adj^2) + MFMA ----------------
__global__ __launch_bounds__(256) void k_conv1f(const float* __restrict__ adj,
                                                unsigned short* __restrict__ adj_t,
                                                const unsigned short* __restrict__ mB,
                                                float* __restrict__ part,
                                                float* __restrict__ scalars) {
  __shared__ unsigned short sA[64][264];
  __shared__ float red[4];
  const int tid = threadIdx.x;
  const int rbase_blk = blockIdx.x * 64;
  const int kbase = blockIdx.y * 256;
  const int rb0 = blockIdx.x * 4;
  const int kb0 = blockIdx.y * 8;
  const int lane = tid & 63;
  const int w = tid >> 6;
  const int l15 = lane & 15;
  const int kgrp = (lane >> 4) * 8;
  // hoist B-frag loads (overlap with the big fp32 sweep below)
  bf16x8 bb0[8], bb1[8];
#pragma unroll
  for (int kt = 0; kt < 8; ++kt) {
    const size_t boff = ((size_t)(kb0 + kt) * 32) * 32;
    bb0[kt] = *reinterpret_cast<const bf16x8*>(&mB[boff + (size_t)l15 * 32 + kgrp]);
    bb1[kt] = *reinterpret_cast<const bf16x8*>(&mB[boff + (size_t)(16 + l15) * 32 + kgrp]);
  }
  float adjsq = 0.f;
#pragma unroll
  for (int i = 0; i < 16; ++i) {
    const int fi = i * 256 + tid;
    const int r = fi >> 6;
    const int c4 = fi & 63;
    const size_t goff = (size_t)(rbase_blk + r) * NN + kbase + c4 * 4;
    const float4 v = *reinterpret_cast<const float4*>(&adj[goff]);
    adjsq += v.x * v.x + v.y * v.y + v.z * v.z + v.w * v.w;
    ushort4 h;
    h.x = f2bf(v.x); h.y = f2bf(v.y); h.z = f2bf(v.z); h.w = f2bf(v.w);
    const size_t toff = ((size_t)(rb0 + (r >> 4)) * (NN / 32) + kb0 + (c4 >> 3)) * 512 +
                        (r & 15) * 32 + (c4 & 7) * 4;
    *reinterpret_cast<ushort4*>(&adj_t[toff]) = h;
    *reinterpret_cast<ushort4*>(&sA[r][c4 * 4]) = h;
  }
  __syncthreads();
  const int rloc = w * 16 + l15;
  f32x4 acc0 = {0.f, 0.f, 0.f, 0.f}, acc1 = {0.f, 0.f, 0.f, 0.f};
#pragma unroll
  for (int k0 = 0; k0 < 256; k0 += 32) {
    const bf16x8 a = *reinterpret_cast<const bf16x8*>(&sA[rloc][k0 + kgrp]);
    acc0 = __builtin_amdgcn_mfma_f32_16x16x32_bf16(a, bb0[k0 >> 5], acc0, 0, 0, 0);
    acc1 = __builtin_amdgcn_mfma_f32_16x16x32_bf16(a, bb1[k0 >> 5], acc1, 0, 0, 0);
  }
  float* pp = part + (size_t)blockIdx.y * (NN * HH);
  const int rout = rbase_blk + w * 16 + (lane >> 4) * 4;
#pragma unroll
  for (int r = 0; r < 4; ++r) {
    pp[(size_t)(rout + r) * HH + l15] = acc0[r];
    pp[(size_t)(rout + r) * HH + 16 + l15] = acc1[r];
  }
  adjsq = wave_sum(adjsq);
  if (lane == 0) red[w] = adjsq;
  __syncthreads();
  if (tid == 0) atomicAdd(&scalars[SC(1)], red[0] + red[1] + red[2] + red[3]);
}

// ---------------- MFMA adj pass (register-hoisted: 24 independent loads, then 16 MFMAs) ----------------
__global__ __launch_bounds__(256) void k_adjmm(const unsigned short* __restrict__ adj_t,
                                               const unsigned short* __restrict__ mB,
                                               float* __restrict__ part) {
  const int tid = threadIdx.x;
  const int lane = tid & 63;
  const int w = tid >> 6;
  const int rb = blockIdx.x * 4 + w;
  const int kb0 = blockIdx.y * 8;
  const int l15 = lane & 15;
  const int kgrp = (lane >> 4) * 8;
  bf16x8 a[8], b0[8], b1[8];
#pragma unroll
  for (int kt = 0; kt < 8; ++kt) {
    const size_t aoff = ((size_t)rb * (NN / 32) + kb0 + kt) * 512;
    const size_t boff = ((size_t)(kb0 + kt) * 32) * 32;
    a[kt] = *reinterpret_cast<const bf16x8*>(&adj_t[aoff + l15 * 32 + kgrp]);
    b0[kt] = *reinterpret_cast<const bf16x8*>(&mB[boff + (size_t)l15 * 32 + kgrp]);
    b1[kt] = *reinterpret_cast<const bf16x8*>(&mB[boff + (size_t)(16 + l15) * 32 + kgrp]);
  }
  f32x4 acc0 = {0.f, 0.f, 0.f, 0.f}, acc1 = {0.f, 0.f, 0.f, 0.f};
#pragma unroll
  for (int kt = 0; kt < 8; ++kt) {
    acc0 = __builtin_amdgcn_mfma_f32_16x16x32_bf16(a[kt], b0[kt], acc0, 0, 0, 0);
    acc1 = __builtin_amdgcn_mfma_f32_16x16x32_bf16(a[kt], b1[kt], acc1, 0, 0, 0);
  }
  float* pp = part + (size_t)blockIdx.y * (NN * HH);
  const int rout = rb * 16 + (lane >> 4) * 4;
#pragma unroll
  for (int r = 0; r < 4; ++r) {
    pp[(size_t)(rout + r) * HH + l15] = acc0[r];
    pp[(size_t)(rout + r) * HH + 16 + l15] = acc1[r];
  }
}

// ---------------- MFMA norm pass v2: LDS-staged B (double-buffered), 8 waves x 1 row-tile ----------------
// grid (NN/128, KS), 512 threads. B-slice per kt = 13 tiles x 16 x 32 staged once per block.
__global__ __launch_bounds__(512) void k_normmfma(const unsigned short* __restrict__ adj_t,
                                                  const unsigned short* __restrict__ s1B,
                                                  const float* __restrict__ s1,
                                                  float* __restrict__ scalars) {
  __shared__ unsigned short sB[2][13][16][BST];
  __shared__ float red[8];
  const int tid = threadIdx.x;
  const int lane = tid & 63;
  const int w = tid >> 6;
  const int rb = blockIdx.x * 8 + w;
  const int kb0 = blockIdx.y * 8;
  const int l15 = lane & 15;
  const int g = lane >> 4;
  const int kgrp = g * 8;
  // staging decomposition: 832 chunks of 8 ushorts (13 ct x 16 rows x 4 segs)
  const int p0 = tid;
  const int ct0 = p0 >> 6, rr0 = (p0 >> 2) & 15, sg0 = (p0 & 3) * 8;
  const int p1 = tid + 512;
  const bool v1 = (p1 < 832);
  const int ct1 = p1 >> 6, rr1 = (p1 >> 2) & 15, sg1 = (p1 & 3) * 8;

  f32x4 acc[13];
#pragma unroll
  for (int ct = 0; ct < 13; ++ct) acc[ct] = (f32x4){0.f, 0.f, 0.f, 0.f};

  // prologue: stage kt=0 into buffer 0
  u16x8 st0, st1;
  st0 = *reinterpret_cast<const u16x8*>(&s1B[((size_t)kb0 * GP + ct0 * 16 + rr0) * 32 + sg0]);
  if (v1) st1 = *reinterpret_cast<const u16x8*>(&s1B[((size_t)kb0 * GP + ct1 * 16 + rr1) * 32 + sg1]);
  *reinterpret_cast<u16x8*>(&sB[0][ct0][rr0][sg0]) = st0;
  if (v1) *reinterpret_cast<u16x8*>(&sB[0][ct1][rr1][sg1]) = st1;
  __syncthreads();

  bf16x8 a = *reinterpret_cast<const bf16x8*>(
      &adj_t[((size_t)rb * (NN / 32) + kb0) * 512 + l15 * 32 + kgrp]);

  for (int kt = 0; kt < 8; ++kt) {
    const int cur = kt & 1;
    // issue next-slice global loads early (async-STAGE split)
    if (kt < 7) {
      const size_t kb = kb0 + kt + 1;
      st0 = *reinterpret_cast<const u16x8*>(&s1B[(kb * GP + ct0 * 16 + rr0) * 32 + sg0]);
      if (v1) st1 = *reinterpret_cast<const u16x8*>(&s1B[(kb * GP + ct1 * 16 + rr1) * 32 + sg1]);
    }
    bf16x8 a_next = a;
    if (kt < 7)
      a_next = *reinterpret_cast<const bf16x8*>(
          &adj_t[((size_t)rb * (NN / 32) + kb0 + kt + 1) * 512 + l15 * 32 + kgrp]);
    // compute current kt from LDS
#pragma unroll
    for (int ct = 0; ct < 13; ++ct) {
      const bf16x8 b = *reinterpret_cast<const bf16x8*>(&sB[cur][ct][l15][kgrp]);
      acc[ct] = __builtin_amdgcn_mfma_f32_16x16x32_bf16(a, b, acc[ct], 0, 0, 0);
    }
    // write next slice into the other buffer, then sync
    if (kt < 7) {
      *reinterpret_cast<u16x8*>(&sB[cur ^ 1][ct0][rr0][sg0]) = st0;
      if (v1) *reinterpret_cast<u16x8*>(&sB[cur ^ 1][ct1][rr1][sg1]) = st1;
    }
    __syncthreads();
    a = a_next;
  }
  const int rout = rb * 16 + g * 4;
  float sc = 0.f;
#pragma unroll
  for (int ct = 0; ct < 13; ++ct) {
    const int col = ct * 16 + l15;
    if (col < CC) {
#pragma unroll
      for (int r = 0; r < 4; ++r)
        sc = fmaf(acc[ct][r], s1[(size_t)(rout + r) * CC + col], sc);
    }
  }
  sc = wave_sum(sc);
  if (lane == 0) red[w] = sc;
  __syncthreads();
  if (tid == 0) {
    float s = 0.f;
#pragma unroll
    for (int i = 0; i < 8; ++i) s += red[i];
    atomicAdd(&scalars[SC(0)], s);
  }
}

// ---------------- conv epilogue (32-wide) ----------------
__global__ __launch_bounds__(256) void k_epi32(const float* __restrict__ part,
                                               const float* __restrict__ bias,
                                               const float* __restrict__ root,
                                               float* __restrict__ t,
                                               float* __restrict__ colsum,
                                               float* __restrict__ colsq) {
  __shared__ float ls[HH], lq[HH];
  const int tid = threadIdx.x;
  const int idx = blockIdx.x * 256 + tid;
  const int c = idx & (HH - 1);
  if (tid < HH) { ls[tid] = 0.f; lq[tid] = 0.f; }
  __syncthreads();
  float s = bias[c] + root[idx];
#pragma unroll
  for (int sp = 0; sp < KS; ++sp) s += part[(size_t)sp * (NN * HH) + idx];
  s = fmaxf(s, 0.f);
  t[idx] = s;
  atomicAdd(&ls[c], s);
  atomicAdd(&lq[c], s * s);
  __syncthreads();
  if (tid < HH) {
    atomicAdd(&colsum[tid * 16], ls[tid]);
    atomicAdd(&colsq[tid * 16], lq[tid]);
  }
}

// ---------------- BN finalize ----------------
__global__ void k_bnfinal(float* __restrict__ colsum, float* __restrict__ colsq,
                          const float* __restrict__ g, const float* __restrict__ be,
                          float* __restrict__ A, float* __restrict__ B, int Ccols) {
  const int c = threadIdx.x;
  float cs = 0.f, cq = 0.f;
  if (c < Ccols) { cs = colsum[c * 16]; cq = colsq[c * 16]; }
  __syncthreads();
  for (int i = threadIdx.x; i < 4096; i += 256) { colsum[i] = 0.f; colsq[i] = 0.f; }
  if (c >= Ccols) return;
  const float m = cs * (1.f / NN);
  const float var = fmaxf(cq * (1.f / NN) - m * m, 0.f);
  const float a = g[c] / sqrtf(var + 1e-5f);
  A[c] = a;
  B[c] = be[c] - m * a;
}

// ---------------- bn apply (32-wide) + optional bf16 tiled copy ----------------
__global__ __launch_bounds__(256) void k_bnapply32(const float* __restrict__ t,
                                                   const float* __restrict__ A,
                                                   const float* __restrict__ B,
                                                   float* __restrict__ xo,
                                                   float* __restrict__ emb, int embOff,
                                                   unsigned short* __restrict__ xB) {
  __shared__ unsigned short sT[32][34];
  const int tid = threadIdx.x;
  const int kb = blockIdx.x;
  const int c = tid & 31, g = tid >> 5;
  const float Ac = A[c], Bc = B[c];
#pragma unroll
  for (int ni = 0; ni < 4; ++ni) {
    const int n = kb * 32 + g * 4 + ni;
    const float v = fmaf(Ac, t[(size_t)n * HH + c], Bc);
    xo[(size_t)n * HH + c] = v;
    emb[(size_t)n * DD + embOff + c] = v;
    if (xB) sT[c][g * 4 + ni] = f2bf(v);
  }
  if (xB) {
    __syncthreads();
    if (tid < 128) {
      const int row = tid >> 2, seg = tid & 3;
      u16x8 o;
#pragma unroll
      for (int j = 0; j < 8; ++j) o[j] = sT[row][seg * 8 + j];
      *reinterpret_cast<u16x8*>(&xB[((size_t)kb * 32 + row) * 32 + seg * 8]) = o;
    }
  }
}

// ---------------- conv3 epilogue ----------------
__global__ __launch_bounds__(256) void k_epi3(const float* __restrict__ part,
                                              const float* __restrict__ W3r,
                                              const float* __restrict__ b3,
                                              const float* __restrict__ x2,
                                              const float* __restrict__ W3root,
                                              float* __restrict__ t3,
                                              float* __restrict__ colsum,
                                              float* __restrict__ colsq) {
  __shared__ float z[16][33];
  __shared__ float xr[16][33];
  const int row0 = blockIdx.x * 16;
  for (int s = threadIdx.x; s < 16 * 32; s += 256) {
    const int r = s >> 5, k = s & 31;
    float a = 0.f;
#pragma unroll
    for (int sp = 0; sp < KS; ++sp)
      a += part[(size_t)sp * (NN * HH) + (size_t)(row0 + r) * HH + k];
    z[r][k] = a;
    xr[r][k] = x2[(size_t)(row0 + r) * HH + k];
  }
  __syncthreads();
  const int c = threadIdx.x;
  if (c >= CC) return;
  float acc[16];
  const float bb = b3[c];
#pragma unroll
  for (int r = 0; r < 16; ++r) acc[r] = bb;
  for (int k = 0; k < 32; ++k) {
    const float w1 = W3r[k * CC + c];
    const float w2 = W3root[k * CC + c];
#pragma unroll
    for (int r = 0; r < 16; ++r) acc[r] += z[r][k] * w1 + xr[r][k] * w2;
  }
  float lsm = 0.f, lqm = 0.f;
#pragma unroll
  for (int r = 0; r < 16; ++r) {
    const float v = fmaxf(acc[r], 0.f);
    t3[(size_t)(row0 + r) * CC + c] = v;
    lsm += v;
    lqm += v * v;
  }
  atomicAdd(&colsum[c * 16], lsm);
  atomicAdd(&colsq[c * 16], lqm);
}

__global__ void k_bnapply205(const float* __restrict__ t3, const float* __restrict__ A,
                             const float* __restrict__ B, float* __restrict__ x3,
                             float* __restrict__ emb) {
  const int row = blockIdx.x;
  const int c = threadIdx.x;
  if (c >= CC) return;
  const float v = fmaf(A[c], t3[(size_t)row * CC + c], B[c]);
  x3[(size_t)row * CC + c] = v;
  emb[(size_t)row * DD + 2 * HH + c] = v;
}

// ---------------- logits via MFMA: logits[N][GP] = embB @ Wl1T^T ----------------
__global__ __launch_bounds__(256) void k_logits(const unsigned short* __restrict__ embB,
                                                const unsigned short* __restrict__ Wl1T,
                                                float* __restrict__ logits) {
  __shared__ unsigned short sA[16][296];
  const int tid = threadIdx.x;
  const int row0 = blockIdx.x * 16;
  for (int p = tid; p < 576; p += 256) {
    const int r = p / 36, ch = p - r * 36;
    const u16x8 v = *reinterpret_cast<const u16x8*>(&embB[(size_t)(row0 + r) * DP + ch * 8]);
    *reinterpret_cast<u16x8*>(&sA[r][ch * 8]) = v;
  }
  __syncthreads();
  const int lane = tid & 63;
  const int w = tid >> 6;
  const int l15 = lane & 15;
  const int kgrp = (lane >> 4) * 8;
  f32x4 acc[4];
#pragma unroll
  for (int i = 0; i < 4; ++i) acc[i] = (f32x4){0.f, 0.f, 0.f, 0.f};
#pragma unroll
  for (int i = 0; i < 4; ++i) {
    const int ct = w + i * 4;
    if (ct < 13) {
      const size_t brow = (size_t)(ct * 16 + l15) * DP;
#pragma unroll
      for (int k0 = 0; k0 < DP; k0 += 32) {
        const bf16x8 a = *reinterpret_cast<const bf16x8*>(&sA[l15][k0 + kgrp]);
        const bf16x8 b = *reinterpret_cast<const bf16x8*>(&Wl1T[brow + k0 + kgrp]);
        acc[i] = __builtin_amdgcn_mfma_f32_16x16x32_bf16(a, b, acc[i], 0, 0, 0);
      }
    }
  }
  const int rout = row0 + (lane >> 4) * 4;
#pragma unroll
  for (int i = 0; i < 4; ++i) {
    const int ct = w + i * 4;
    if (ct < 13) {
#pragma unroll
      for (int r = 0; r < 4; ++r)
        logits[(size_t)(rout + r) * GP + ct * 16 + l15] = acc[i][r];
    }
  }
}

// ---------------- softmax head: logits -> s1, sn, s1B/snB tiles, entropy ----------------
__global__ __launch_bounds__(256) void k_softmax(const float* __restrict__ logits,
                                                 const float* __restrict__ bl1,
                                                 float* __restrict__ s1,
                                                 float* __restrict__ sn,
                                                 unsigned short* __restrict__ s1B,
                                                 unsigned short* __restrict__ snB,
                                                 float* __restrict__ scalars) {
  __shared__ unsigned short sTa[8][212];
  __shared__ unsigned short sTb[8][212];
  __shared__ float redE[4];
  const int row0 = blockIdx.x * 8;
  const int tid = threadIdx.x;
  const int w = tid >> 6;
  const int lane = tid & 63;
  const int r0 = w * 2;
  const int c0 = lane * 4;
  const bool active = (c0 < GP);
  float bl[4];
#pragma unroll
  for (int j = 0; j < 4; ++j) bl[j] = (c0 + j < CC) ? bl1[c0 + j] : 0.f;
  float ent_acc = 0.f;
#pragma unroll
  for (int r = 0; r < 2; ++r) {
    const int row = row0 + r0 + r;
    float4 lg = {0.f, 0.f, 0.f, 0.f};
    if (active) lg = *reinterpret_cast<const float4*>(&logits[(size_t)row * GP + c0]);
    const float lgv[4] = {lg.x, lg.y, lg.z, lg.w};
    float v[4];
    float ml = -1e30f;
#pragma unroll
    for (int j = 0; j < 4; ++j) {
      const int c = c0 + j;
      v[j] = (c < CC) ? fmaxf(lgv[j] + bl[j], 0.f) : -1e30f;
      ml = fmaxf(ml, v[j]);
    }
    const float m = wave_max(ml);
    float e[4];
    float sl = 0.f;
#pragma unroll
    for (int j = 0; j < 4; ++j) {
      const int c = c0 + j;
      e[j] = (c < CC) ? __expf(v[j] - m) : 0.f;
      sl += e[j];
    }
    const float S = wave_sum(sl);
    const float invS = 1.f / S;
    float p[4];
    float ql = 0.f;
#pragma unroll
    for (int j = 0; j < 4; ++j) {
      p[j] = e[j] * invS;
      ql += p[j] * p[j];
    }
    const float q = wave_sum(ql);
    const float inv = 1.f / fmaxf(sqrtf(q), 1e-8f);
    float m2l = -1e30f;
#pragma unroll
    for (int j = 0; j < 4; ++j) {
      const int c = c0 + j;
      if (c < CC) {
        s1[(size_t)row * CC + c] = p[j];
        sn[(size_t)row * CC + c] = p[j] * inv;
        m2l = fmaxf(m2l, p[j]);
      }
    }
    if (active) {
#pragma unroll
      for (int j = 0; j < 4; ++j) {
        const int c = c0 + j;
        const bool ok = (c < CC);
        sTa[r0 + r][c] = ok ? f2bf(p[j]) : (unsigned short)0;
        sTb[r0 + r][c] = ok ? f2bf(p[j] * inv) : (unsigned short)0;
      }
    }
    const float m2 = wave_max(m2l);
    float e2[4];
    float s2l = 0.f;
#pragma unroll
    for (int j = 0; j < 4; ++j) {
      const int c = c0 + j;
      e2[j] = (c < CC) ? __expf(p[j] - m2) : 0.f;
      s2l += e2[j];
    }
    const float S2 = wave_sum(s2l);
    const float invS2 = 1.f / S2;
    float tl = 0.f;
#pragma unroll
    for (int j = 0; j < 4; ++j) {
      const int c = c0 + j;
      if (c < CC) {
        const float sp = e2[j] * invS2;
        tl -= sp * logf(sp + 1e-15f);
      }
    }
    ent_acc += tl;
  }
  ent_acc = wave_sum(ent_acc);
  if (lane == 0) redE[w] = ent_acc;
  __syncthreads();
  if (tid == 0) atomicAdd(&scalars[SC(2)], redE[0] + redE[1] + redE[2] + redE[3]);
  if (tid < GP) {
    const int kb = row0 >> 5, no = row0 & 31;
    u16x8 oa, ob;
#pragma unroll
    for (int r = 0; r < 8; ++r) { oa[r] = sTa[r][tid]; ob[r] = sTb[r][tid]; }
    *reinterpret_cast<u16x8*>(&s1B[((size_t)kb * GP + tid) * 32 + no]) = oa;
    *reinterpret_cast<u16x8*>(&snB[((size_t)kb * GP + tid) * 32 + no]) = ob;
  }
}

// ---------------- MFMA Gram: Cp = P^T Q from tiled [kb][GP][32] operands ----------------
__global__ __launch_bounds__(256) void k_gramm(const unsigned short* __restrict__ xnB,
                                               const unsigned short* __restrict__ snB,
                                               const unsigned short* __restrict__ s1B,
                                               float* __restrict__ G, float* __restrict__ Gxs,
                                               float* __restrict__ Gs, float* __restrict__ Gs0) {
  const int gid = blockIdx.z;
  const int tp = blockIdx.x * 16;
  const int tq = blockIdx.y * 16;
  const unsigned short *PT, *QT;
  float* Cp;
  if (gid == 0)      { PT = xnB; QT = xnB; Cp = G;   if (tp >= FF || tq >= FF) return; }
  else if (gid == 1) { PT = xnB; QT = snB; Cp = Gxs; if (tp >= FF) return; }
  else if (gid == 2) { PT = snB; QT = snB; Cp = Gs; }
  else               { PT = s1B; QT = s1B; Cp = Gs0; }
  const int tid = threadIdx.x;
  const int lane = tid & 63;
  const int w = tid >> 6;
  const int l15 = lane & 15;
  const int kgrp = (lane >> 4) * 8;
  f32x4 acc = {0.f, 0.f, 0.f, 0.f};
#pragma unroll 8
  for (int kt = 0; kt < 32; ++kt) {
    const int kb = w * 32 + kt;
    const bf16x8 a = *reinterpret_cast<const bf16x8*>(&PT[((size_t)kb * GP + tp + l15) * 32 + kgrp]);
    const bf16x8 b = *reinterpret_cast<const bf16x8*>(&QT[((size_t)kb * GP + tq + l15) * 32 + kgrp]);
    acc = __builtin_amdgcn_mfma_f32_16x16x32_bf16(a, b, acc, 0, 0, 0);
  }
  __shared__ float red[4][16][17];
  const int crow = (lane >> 4) * 4;
#pragma unroll
  for (int r = 0; r < 4; ++r) red[w][crow + r][l15] = acc[r];
  __syncthreads();
  const int rr = tid >> 4, cc = tid & 15;
  const float v = red[0][rr][cc] + red[1][rr][cc] + red[2][rr][cc] + red[3][rr][cc];
  Cp[(size_t)(tp + rr) * GP + (tq + cc)] = v;
}

// ---------------- thin GEMMs (3 in one launch); B has stride GP ----------------
__global__ __launch_bounds__(256) void k_rowmm3(const float* __restrict__ xn,
                                                const float* __restrict__ sn,
                                                const float* __restrict__ G,
                                                const float* __restrict__ Gxs,
                                                const float* __restrict__ Gs,
                                                float* __restrict__ H1,
                                                float* __restrict__ Uu,
                                                float* __restrict__ H2) {
  const float *A, *B;
  float* Cm;
  int K, Nc;
  if (blockIdx.y == 0)      { A = xn; B = G;   Cm = H1; K = FF; Nc = FF; }
  else if (blockIdx.y == 1) { A = xn; B = Gxs; Cm = Uu; K = FF; Nc = CC; }
  else                      { A = sn; B = Gs;  Cm = H2; K = CC; Nc = CC; }
  __shared__ float sA[16][208];
  const int row0 = blockIdx.x * 16;
  for (int s = threadIdx.x; s < 16 * K; s += 256) {
    const int r = s / K, k = s - r * K;
    sA[r][k] = A[(size_t)(row0 + r) * K + k];
  }
  __syncthreads();
  const int c = threadIdx.x;
  if (c >= Nc) return;
  float acc[16];
#pragma unroll
  for (int r = 0; r < 16; ++r) acc[r] = 0.f;
  for (int k = 0; k < K; ++k) {
    const float w = B[(size_t)k * GP + c];
#pragma unroll
    for (int r = 0; r < 16; ++r) acc[r] = fmaf(sA[r][k], w, acc[r]);
  }
#pragma unroll
  for (int r = 0; r < 16; ++r) Cm[(size_t)(row0 + r) * Nc + c] = acc[r];
}

// ---------------- per-row sim + team embedding loss ----------------
__global__ __launch_bounds__(256) void k_losses(const float* __restrict__ H1,
                                                const float* __restrict__ Uu,
                                                const float* __restrict__ H2,
                                                const float* __restrict__ xn,
                                                const float* __restrict__ sn,
                                                const float* __restrict__ emb,
                                                const int* __restrict__ teams,
                                                const int* __restrict__ reps,
                                                float* __restrict__ scalars) {
  __shared__ float red[4];
  const int tid = threadIdx.x;
  const int lane = tid & 63;
  const int w = tid >> 6;
  if (blockIdx.x < NN / 4) {
    const int row = blockIdx.x * 4 + w;
    float suu = 0.f, suv = 0.f, svv = 0.f;
#pragma unroll
    for (int c0 = 0; c0 < FF; c0 += 64) {
      const float xv = xn[(size_t)row * FF + c0 + lane];
      suu = fmaf(H1[(size_t)row * FF + c0 + lane], xv, suu);
    }
    for (int cb = lane; cb < CC; cb += 64) {
      const float sv = sn[(size_t)row * CC + cb];
      suv = fmaf(Uu[(size_t)row * CC + cb], sv, suv);
      svv = fmaf(H2[(size_t)row * CC + cb], sv, svv);
    }
    suu = wave_sum(suu);
    suv = wave_sum(suv);
    svv = wave_sum(svv);
    if (lane == 0) red[w] = suv / sqrtf(suu * svv);
    __syncthreads();
    if (tid == 0) atomicAdd(&scalars[SC(3)], red[0] + red[1] + red[2] + red[3]);
  } else {
    const int team = blockIdx.x - NN / 4;
    float part = 0.f;
    for (int d = tid; d < DD; d += 256) {
      float a = 0.f, b = 0.f;
#pragma unroll
      for (int m = 0; m < RR; ++m) a += emb[(size_t)reps[team * RR + m] * DD + d];
#pragma unroll
      for (int m = RR; m < TT; ++m) b += emb[(size_t)teams[team * TT + m] * DD + d];
      part += fabsf(a * (1.f / RR) - b * (1.f / (TT - RR)));
    }
    part = wave_sum(part);
    if (lane == 0) red[w] = part;
    __syncthreads();
    if (tid == 0) atomicAdd(&scalars[SC(4)], red[0] + red[1] + red[2] + red[3]);
  }
}

// ---------------- finalize ----------------
__global__ void k_final(const float* __restrict__ Gs0, const float* __restrict__ scalars,
                        float* __restrict__ outsc) {
  __shared__ float red[4];
  float p = 0.f;
  for (int i = threadIdx.x; i < GP * GP; i += 256) {
    const float v = Gs0[i];
    p = fmaf(v, v, p);
  }
  p = wave_sum(p);
  if ((threadIdx.x & 63) == 0) red[threadIdx.x >> 6] = p;
  __syncthreads();
  if (threadIdx.x == 0) {
    const float sumP2 = red[0] + red[1] + red[2] + red[3];
    const float normsq = fmaxf(sumP2 - 2.f * scalars[SC(0)] + scalars[SC(1)], 0.f);
    const float norm = sqrtf(normsq);
    const float e1 = scalars[SC(2)] * (1.f / NN);
    const float sim = -scalars[SC(3)] * (1.f / NN);
    const float embl = scalars[SC(4)] * (1.f / LL);
    outsc[0] = norm;
    outsc[1] = e1;
    outsc[2] = sim;
    outsc[3] = 100.f * norm + 10.f * e1 + 100.f * sim + embl;
    outsc[4] = embl;
  }
}

// ================= launch =================
extern "C" void kernel_launch(void* const* d_in, const int* in_sizes, int n_in,
                              void* d_out, int out_size, void* d_ws, size_t ws_size,
                              hipStream_t stream) {
  const float* x      = (const float*)d_in[0];
  const float* adj    = (const float*)d_in[1];
  const int*   teams  = (const int*)d_in[2];
  const int*   reps   = (const int*)d_in[3];
  const float* W1r    = (const float*)d_in[4];
  const float* b1     = (const float*)d_in[5];
  const float* W1root = (const float*)d_in[6];
  const float* g1     = (const float*)d_in[7];
  const float* be1    = (const float*)d_in[8];
  const float* W2r    = (const float*)d_in[9];
  const float* b2     = (const float*)d_in[10];
  const float* W2root = (const float*)d_in[11];
  const float* g2     = (const float*)d_in[12];
  const float* be2    = (const float*)d_in[13];
  const float* W3r    = (const float*)d_in[14];
  const float* b3     = (const float*)d_in[15];
  const float* W3root = (const float*)d_in[16];
  const float* g3     = (const float*)d_in[17];
  const float* be3    = (const float*)d_in[18];
  const float* Wl1    = (const float*)d_in[19];
  const float* bl1    = (const float*)d_in[20];

  char* wp = (char*)d_ws;
  auto alloc = [&](size_t bytes) { char* p = wp; wp += (bytes + 255) & ~(size_t)255; return p; };
  unsigned short* adj_t = (unsigned short*)alloc((size_t)NN * NN * 2);
  unsigned short* mB    = (unsigned short*)alloc((size_t)HH * NN * 2);
  unsigned short* x2B   = (unsigned short*)alloc((size_t)HH * NN * 2);
  unsigned short* s1B   = (unsigned short*)alloc((size_t)GP * NN * 2);
  unsigned short* snB   = (unsigned short*)alloc((size_t)GP * NN * 2);
  unsigned short* xnB   = (unsigned short*)alloc((size_t)GP * NN * 2);
  unsigned short* embB  = (unsigned short*)alloc((size_t)NN * DP * 2);
  unsigned short* Wl1T  = (unsigned short*)alloc((size_t)GP * DP * 2);
  float* logits = (float*)alloc((size_t)NN * GP * 4);
  float* rootb  = (float*)alloc((size_t)NN * HH * 4);
  float* t      = (float*)alloc((size_t)NN * HH * 4);
  float* x1     = (float*)alloc((size_t)NN * HH * 4);
  float* x2     = (float*)alloc((size_t)NN * HH * 4);
  float* part   = (float*)alloc((size_t)KS * NN * HH * 4);
  float* t3     = (float*)alloc((size_t)NN * CC * 4);
  float* x3     = (float*)alloc((size_t)NN * CC * 4);
  float* sn     = (float*)alloc((size_t)NN * CC * 4);
  float* xn     = (float*)alloc((size_t)NN * FF * 4);
  float* H1     = (float*)alloc((size_t)NN * FF * 4);
  float* Uu     = (float*)alloc((size_t)NN * CC * 4);
  float* H2     = (float*)alloc((size_t)NN * CC * 4);
  float* G      = (float*)alloc((size_t)GP * GP * 4);
  float* Gxs    = (float*)alloc((size_t)GP * GP * 4);
  float* Gs     = (float*)alloc((size_t)GP * GP * 4);
  float* Gs0    = (float*)alloc((size_t)GP * GP * 4);
  float* scalars = (float*)alloc(160 * 4);
  float* colsum = (float*)alloc(4096 * 4);
  float* colsq  = (float*)alloc(4096 * 4);
  float* bnA    = (float*)alloc(1024);
  float* bnB    = (float*)alloc(1024);
  (void)ws_size; (void)in_sizes; (void)n_in; (void)out_size;

  float* out   = (float*)d_out;
  float* s1    = out;                          // N*C
  float* outsc = out + (size_t)NN * CC;        // 5 scalars
  float* emb   = out + (size_t)NN * CC + 5;    // N*D

  // zero scalar accumulators + padded BN stats + xnB pad rows
  hipMemsetAsync(scalars, 0, 160 * 4, stream);
  hipMemsetAsync(colsum, 0, 2 * 4096 * 4, stream);
  hipMemsetAsync(xnB, 0, (size_t)GP * NN * 2, stream);

  k_padWT<<<(GP * DP + 255) / 256, 256, 0, stream>>>(Wl1, Wl1T);
  k_xn<<<NN / 4, 256, 0, stream>>>(x, xn);
  k_xnB<<<NN / 32, 256, 0, stream>>>(xn, xnB);

  // conv1 (fused: adj cvt->tiled + adj^2 + MFMA)
  k_proj_t<<<NN / 32, 256, 0, stream>>>(x, W1r, W1root, mB, rootb, FF);
  k_conv1f<<<dim3(NN / 64, KS), 256, 0, stream>>>(adj, adj_t, mB, part, scalars);
  k_epi32<<<NN * HH / 256, 256, 0, stream>>>(part, b1, rootb, t, colsum, colsq);
  k_bnfinal<<<1, 256, 0, stream>>>(colsum, colsq, g1, be1, bnA, bnB, HH);
  k_bnapply32<<<NN / 32, 256, 0, stream>>>(t, bnA, bnB, x1, emb, 0, (unsigned short*)nullptr);

  // conv2
  k_proj_t<<<NN / 32, 256, 0, stream>>>(x1, W2r, W2root, mB, rootb, HH);
  k_adjmm<<<dim3(NN / 64, KS), 256, 0, stream>>>(adj_t, mB, part);
  k_epi32<<<NN * HH / 256, 256, 0, stream>>>(part, b2, rootb, t, colsum, colsq);
  k_bnfinal<<<1, 256, 0, stream>>>(colsum, colsq, g2, be2, bnA, bnB, HH);
  k_bnapply32<<<NN / 32, 256, 0, stream>>>(t, bnA, bnB, x2, emb, HH, x2B);

  // conv3
  k_adjmm<<<dim3(NN / 64, KS), 256, 0, stream>>>(adj_t, x2B, part);
  k_epi3<<<NN / 16, 256, 0, stream>>>(part, W3r, b3, x2, W3root, t3, colsum, colsq);
  k_bnfinal<<<1, 256, 0, stream>>>(colsum, colsq, g3, be3, bnA, bnB, CC);
  k_bnapply205<<<NN, 256, 0, stream>>>(t3, bnA, bnB, x3, emb);

  // head: emb -> bf16, MFMA logits, streaming softmax (fills s1B/snB tiles incl pad)
  k_embB<<<NN * DP / 256, 256, 0, stream>>>(emb, embB);
  k_logits<<<NN / 16, 256, 0, stream>>>(embB, Wl1T, logits);
  k_softmax<<<NN / 8, 256, 0, stream>>>(logits, bl1, s1, sn, s1B, snB, scalars);

  // tr(S' A S) via MFMA (LDS-staged B, double-buffered)
  k_normmfma<<<dim3(NN / 128, KS), 512, 0, stream>>>(adj_t, s1B, s1, scalars);

  // Grams + bilinear forms + losses + finalize
  k_gramm<<<dim3(13, 13, 4), 256, 0, stream>>>(xnB, snB, s1B, G, Gxs, Gs, Gs0);
  k_rowmm3<<<dim3(NN / 16, 3), 256, 0, stream>>>(xn, sn, G, Gxs, Gs, H1, Uu, H2);
  k_losses<<<NN / 4 + LL, 256, 0, stream>>>(H1, Uu, H2, xn, sn, emb, teams, reps, scalars);
  k_final<<<1, 256, 0, stream>>>(Gs0, scalars, outsc);
}

// Round 10
// 278.646 us; speedup vs baseline: 3.3197x; 1.0925x over previous
//
#include <hip/hip_runtime.h>
#include <math.h>

#define NN 4096
#define FF 128
#define HH 32
#define CC 205
#define DD 269
#define LL 512
#define TT 12
#define RR 4
#define KS 16    // k-split for all adj MFMA passes
#define GP 208   // padded gram dim
#define DP 288   // padded D (k) dim for logits MFMA
#define BST 40   // padded LDS row stride (ushorts) for B tiles
#define GTS 224  // transposed-gram row stride / padded K
#define HS 208   // H1/Uu/H2 row stride (floats)

// padded scalar slots: 0=trSAS 1=adjsq 2=entropy 3=sim 4=embloss
#define SC(i) ((i) * 32)

typedef __attribute__((ext_vector_type(8))) short bf16x8;
typedef __attribute__((ext_vector_type(4))) float f32x4;
typedef __attribute__((ext_vector_type(8))) unsigned short u16x8;

// ---------------- helpers ----------------
__device__ __forceinline__ float wave_sum(float v) {
#pragma unroll
  for (int o = 32; o > 0; o >>= 1) v += __shfl_xor(v, o, 64);
  return v;
}
__device__ __forceinline__ float wave_max(float v) {
#pragma unroll
  for (int o = 32; o > 0; o >>= 1) v = fmaxf(v, __shfl_xor(v, o, 64));
  return v;
}
__device__ __forceinline__ unsigned short f2bf(float x) {  // RNE
  union { float f; unsigned u; } v; v.f = x;
  unsigned r = v.u + 0x7FFFu + ((v.u >> 16) & 1u);
  return (unsigned short)(r >> 16);
}

// ---------------- Wl1 -> Wl1T bf16 [GP][DP] (transposed, zero-padded) ----------------
__global__ __launch_bounds__(256) void k_padWT(const float* __restrict__ Wl1,
                                               unsigned short* __restrict__ Wl1T) {
  const int idx = blockIdx.x * 256 + threadIdx.x;
  if (idx >= GP * DP) return;
  const int c = idx / DP, k = idx - c * DP;
  Wl1T[idx] = (c < CC && k < DD) ? f2bf(Wl1[(size_t)k * CC + c]) : (unsigned short)0;
}

// ---------------- emb fp32 [N][DD] -> embB bf16 [N][DP] (zero-padded) ----------------
__global__ __launch_bounds__(256) void k_embB(const float* __restrict__ emb,
                                              unsigned short* __restrict__ embB) {
  const int idx = blockIdx.x * 256 + threadIdx.x;  // NN*DP
  const int n = idx / DP, d = idx - n * DP;
  embB[idx] = (d < DD) ? f2bf(emb[(size_t)n * DD + d]) : (unsigned short)0;
}

// ---------------- dual projection: mB (bf16 tiled [kb][32][32]) = (A@W1)^T tiles, o2 = A@W2 ----------------
__global__ __launch_bounds__(256) void k_proj_t(const float* __restrict__ A,
                                                const float* __restrict__ W1,
                                                const float* __restrict__ W2,
                                                unsigned short* __restrict__ mB,
                                                float* __restrict__ o2, int K) {
  __shared__ float sX[32][132];
  __shared__ unsigned short sT[32][34];
  const int tid = threadIdx.x;
  const int kb = blockIdx.x;
  const int nf4 = K >> 2;
  const int tot4 = 32 * nf4;
  for (int p = tid; p < tot4; p += 256) {
    const int node = p / nf4, c4 = p - node * nf4;
    const float4 v = *reinterpret_cast<const float4*>(&A[((size_t)(kb * 32 + node)) * K + c4 * 4]);
    sX[node][c4 * 4 + 0] = v.x; sX[node][c4 * 4 + 1] = v.y;
    sX[node][c4 * 4 + 2] = v.z; sX[node][c4 * 4 + 3] = v.w;
  }
  __syncthreads();
  const int c = tid & 31, g = tid >> 5;
  float a1[4] = {0.f, 0.f, 0.f, 0.f}, a2[4] = {0.f, 0.f, 0.f, 0.f};
  for (int k = 0; k < K; ++k) {
    const float w1 = W1[k * HH + c];
    const float w2 = W2[k * HH + c];
#pragma unroll
    for (int ni = 0; ni < 4; ++ni) {
      const float av = sX[g * 4 + ni][k];
      a1[ni] = fmaf(av, w1, a1[ni]);
      a2[ni] = fmaf(av, w2, a2[ni]);
    }
  }
#pragma unroll
  for (int ni = 0; ni < 4; ++ni) {
    o2[((size_t)kb * 32 + g * 4 + ni) * HH + c] = a2[ni];
    sT[c][g * 4 + ni] = f2bf(a1[ni]);
  }
  __syncthreads();
  if (tid < 128) {
    const int row = tid >> 2, seg = tid & 3;
    u16x8 v;
#pragma unroll
    for (int j = 0; j < 8; ++j) v[j] = sT[row][seg * 8 + j];
    *reinterpret_cast<u16x8*>(&mB[((size_t)kb * 32 + row) * 32 + seg * 8]) = v;
  }
}

// ---------------- row-normalize x -> xn (+ row bf16 xnR) ----------------
__global__ __launch_bounds__(256) void k_xn(const float* __restrict__ x, float* __restrict__ xn,
                                            unsigned short* __restrict__ xnR) {
  const int lane = threadIdx.x & 63;
  const int row = blockIdx.x * 4 + (threadIdx.x >> 6);
  float v0 = x[(size_t)row * FF + lane];
  float v1 = x[(size_t)row * FF + 64 + lane];
  float ss = wave_sum(v0 * v0 + v1 * v1);
  float n = fmaxf(sqrtf(ss), 1e-8f);
  const float a = v0 / n, b = v1 / n;
  xn[(size_t)row * FF + lane] = a;
  xn[(size_t)row * FF + 64 + lane] = b;
  xnR[(size_t)row * FF + lane] = f2bf(a);
  xnR[(size_t)row * FF + 64 + lane] = f2bf(b);
}

// ---------------- xn -> xnB bf16 tiled [kb][GP][32] ----------------
__global__ __launch_bounds__(256) void k_xnB(const float* __restrict__ xn,
                                             unsigned short* __restrict__ xnB) {
  __shared__ unsigned short sT[FF][34];
  const int tid = threadIdx.x;
  const int kb = blockIdx.x;
  for (int p = tid; p < 1024; p += 256) {
    const int node = p >> 5, c4 = p & 31;
    const float4 v = *reinterpret_cast<const float4*>(&xn[((size_t)(kb * 32 + node)) * FF + c4 * 4]);
    sT[c4 * 4 + 0][node] = f2bf(v.x);
    sT[c4 * 4 + 1][node] = f2bf(v.y);
    sT[c4 * 4 + 2][node] = f2bf(v.z);
    sT[c4 * 4 + 3][node] = f2bf(v.w);
  }
  __syncthreads();
  const int row = tid >> 1, seg = (tid & 1) * 16;
  if (row < FF) {
    u16x8 a, b;
#pragma unroll
    for (int j = 0; j < 8; ++j) { a[j] = sT[row][seg + j]; b[j] = sT[row][seg + 8 + j]; }
    *reinterpret_cast<u16x8*>(&xnB[((size_t)kb * GP + row) * 32 + seg]) = a;
    *reinterpret_cast<u16x8*>(&xnB[((size_t)kb * GP + row) * 32 + seg + 8]) = b;
  }
}

// ---------------- FUSED conv1: fp32 adj -> bf16 tiled adj_t + sum(adj^2) + MFMA ----------------
__global__ __launch_bounds__(256) void k_conv1f(const float* __restrict__ adj,
                                                unsigned short* __restrict__ adj_t,
                                                const unsigned short* __restrict__ mB,
                                                float* __restrict__ part,
                                                float* __restrict__ scalars) {
  __shared__ unsigned short sA[64][264];
  __shared__ float red[4];
  const int tid = threadIdx.x;
  const int rbase_blk = blockIdx.x * 64;
  const int kbase = blockIdx.y * 256;
  const int rb0 = blockIdx.x * 4;
  const int kb0 = blockIdx.y * 8;
  const int lane = tid & 63;
  const int w = tid >> 6;
  const int l15 = lane & 15;
  const int kgrp = (lane >> 4) * 8;
  bf16x8 bb0[8], bb1[8];
#pragma unroll
  for (int kt = 0; kt < 8; ++kt) {
    const size_t boff = ((size_t)(kb0 + kt) * 32) * 32;
    bb0[kt] = *reinterpret_cast<const bf16x8*>(&mB[boff + (size_t)l15 * 32 + kgrp]);
    bb1[kt] = *reinterpret_cast<const bf16x8*>(&mB[boff + (size_t)(16 + l15) * 32 + kgrp]);
  }
  float adjsq = 0.f;
#pragma unroll
  for (int i = 0; i < 16; ++i) {
    const int fi = i * 256 + tid;
    const int r = fi >> 6;
    const int c4 = fi & 63;
    const size_t goff = (size_t)(rbase_blk + r) * NN + kbase + c4 * 4;
    const float4 v = *reinterpret_cast<const float4*>(&adj[goff]);
    adjsq += v.x * v.x + v.y * v.y + v.z * v.z + v.w * v.w;
    ushort4 h;
    h.x = f2bf(v.x); h.y = f2bf(v.y); h.z = f2bf(v.z); h.w = f2bf(v.w);
    const size_t toff = ((size_t)(rb0 + (r >> 4)) * (NN / 32) + kb0 + (c4 >> 3)) * 512 +
                        (r & 15) * 32 + (c4 & 7) * 4;
    *reinterpret_cast<ushort4*>(&adj_t[toff]) = h;
    *reinterpret_cast<ushort4*>(&sA[r][c4 * 4]) = h;
  }
  __syncthreads();
  const int rloc = w * 16 + l15;
  f32x4 acc0 = {0.f, 0.f, 0.f, 0.f}, acc1 = {0.f, 0.f, 0.f, 0.f};
#pragma unroll
  for (int k0 = 0; k0 < 256; k0 += 32) {
    const bf16x8 a = *reinterpret_cast<const bf16x8*>(&sA[rloc][k0 + kgrp]);
    acc0 = __builtin_amdgcn_mfma_f32_16x16x32_bf16(a, bb0[k0 >> 5], acc0, 0, 0, 0);
    acc1 = __builtin_amdgcn_mfma_f32_16x16x32_bf16(a, bb1[k0 >> 5], acc1, 0, 0, 0);
  }
  float* pp = part + (size_t)blockIdx.y * (NN * HH);
  const int rout = rbase_blk + w * 16 + (lane >> 4) * 4;
#pragma unroll
  for (int r = 0; r < 4; ++r) {
    pp[(size_t)(rout + r) * HH + l15] = acc0[r];
    pp[(size_t)(rout + r) * HH + 16 + l15] = acc1[r];
  }
  adjsq = wave_sum(adjsq);
  if (lane == 0) red[w] = adjsq;
  __syncthreads();
  if (tid == 0) atomicAdd(&scalars[SC(1)], red[0] + red[1] + red[2] + red[3]);
}

// ---------------- MFMA adj pass (register-hoisted) ----------------
__global__ __launch_bounds__(256) void k_adjmm(const unsigned short* __restrict__ adj_t,
                                               const unsigned short* __restrict__ mB,
                                               float* __restrict__ part) {
  const int tid = threadIdx.x;
  const int lane = tid & 63;
  const int w = tid >> 6;
  const int rb = blockIdx.x * 4 + w;
  const int kb0 = blockIdx.y * 8;
  const int l15 = lane & 15;
  const int kgrp = (lane >> 4) * 8;
  bf16x8 a[8], b0[8], b1[8];
#pragma unroll
  for (int kt = 0; kt < 8; ++kt) {
    const size_t aoff = ((size_t)rb * (NN / 32) + kb0 + kt) * 512;
    const size_t boff = ((size_t)(kb0 + kt) * 32) * 32;
    a[kt] = *reinterpret_cast<const bf16x8*>(&adj_t[aoff + l15 * 32 + kgrp]);
    b0[kt] = *reinterpret_cast<const bf16x8*>(&mB[boff + (size_t)l15 * 32 + kgrp]);
    b1[kt] = *reinterpret_cast<const bf16x8*>(&mB[boff + (size_t)(16 + l15) * 32 + kgrp]);
  }
  f32x4 acc0 = {0.f, 0.f, 0.f, 0.f}, acc1 = {0.f, 0.f, 0.f, 0.f};
#pragma unroll
  for (int kt = 0; kt < 8; ++kt) {
    acc0 = __builtin_amdgcn_mfma_f32_16x16x32_bf16(a[kt], b0[kt], acc0, 0, 0, 0);
    acc1 = __builtin_amdgcn_mfma_f32_16x16x32_bf16(a[kt], b1[kt], acc1, 0, 0, 0);
  }
  float* pp = part + (size_t)blockIdx.y * (NN * HH);
  const int rout = rb * 16 + (lane >> 4) * 4;
#pragma unroll
  for (int r = 0; r < 4; ++r) {
    pp[(size_t)(rout + r) * HH + l15] = acc0[r];
    pp[(size_t)(rout + r) * HH + 16 + l15] = acc1[r];
  }
}

// ---------------- MFMA norm pass v2: LDS-staged B (double-buffered) ----------------
__global__ __launch_bounds__(512) void k_normmfma(const unsigned short* __restrict__ adj_t,
                                                  const unsigned short* __restrict__ s1B,
                                                  const float* __restrict__ s1,
                                                  float* __restrict__ scalars) {
  __shared__ unsigned short sB[2][13][16][BST];
  __shared__ float red[8];
  const int tid = threadIdx.x;
  const int lane = tid & 63;
  const int w = tid >> 6;
  const int rb = blockIdx.x * 8 + w;
  const int kb0 = blockIdx.y * 8;
  const int l15 = lane & 15;
  const int g = lane >> 4;
  const int kgrp = g * 8;
  const int p0 = tid;
  const int ct0 = p0 >> 6, rr0 = (p0 >> 2) & 15, sg0 = (p0 & 3) * 8;
  const int p1 = tid + 512;
  const bool v1 = (p1 < 832);
  const int ct1 = p1 >> 6, rr1 = (p1 >> 2) & 15, sg1 = (p1 & 3) * 8;

  f32x4 acc[13];
#pragma unroll
  for (int ct = 0; ct < 13; ++ct) acc[ct] = (f32x4){0.f, 0.f, 0.f, 0.f};

  u16x8 st0, st1;
  st0 = *reinterpret_cast<const u16x8*>(&s1B[((size_t)kb0 * GP + ct0 * 16 + rr0) * 32 + sg0]);
  if (v1) st1 = *reinterpret_cast<const u16x8*>(&s1B[((size_t)kb0 * GP + ct1 * 16 + rr1) * 32 + sg1]);
  *reinterpret_cast<u16x8*>(&sB[0][ct0][rr0][sg0]) = st0;
  if (v1) *reinterpret_cast<u16x8*>(&sB[0][ct1][rr1][sg1]) = st1;
  __syncthreads();

  bf16x8 a = *reinterpret_cast<const bf16x8*>(
      &adj_t[((size_t)rb * (NN / 32) + kb0) * 512 + l15 * 32 + kgrp]);

  for (int kt = 0; kt < 8; ++kt) {
    const int cur = kt & 1;
    if (kt < 7) {
      const size_t kb = kb0 + kt + 1;
      st0 = *reinterpret_cast<const u16x8*>(&s1B[(kb * GP + ct0 * 16 + rr0) * 32 + sg0]);
      if (v1) st1 = *reinterpret_cast<const u16x8*>(&s1B[(kb * GP + ct1 * 16 + rr1) * 32 + sg1]);
    }
    bf16x8 a_next = a;
    if (kt < 7)
      a_next = *reinterpret_cast<const bf16x8*>(
          &adj_t[((size_t)rb * (NN / 32) + kb0 + kt + 1) * 512 + l15 * 32 + kgrp]);
#pragma unroll
    for (int ct = 0; ct < 13; ++ct) {
      const bf16x8 b = *reinterpret_cast<const bf16x8*>(&sB[cur][ct][l15][kgrp]);
      acc[ct] = __builtin_amdgcn_mfma_f32_16x16x32_bf16(a, b, acc[ct], 0, 0, 0);
    }
    if (kt < 7) {
      *reinterpret_cast<u16x8*>(&sB[cur ^ 1][ct0][rr0][sg0]) = st0;
      if (v1) *reinterpret_cast<u16x8*>(&sB[cur ^ 1][ct1][rr1][sg1]) = st1;
    }
    __syncthreads();
    a = a_next;
  }
  const int rout = rb * 16 + g * 4;
  float sc = 0.f;
#pragma unroll
  for (int ct = 0; ct < 13; ++ct) {
    const int col = ct * 16 + l15;
    if (col < CC) {
#pragma unroll
      for (int r = 0; r < 4; ++r)
        sc = fmaf(acc[ct][r], s1[(size_t)(rout + r) * CC + col], sc);
    }
  }
  sc = wave_sum(sc);
  if (lane == 0) red[w] = sc;
  __syncthreads();
  if (tid == 0) {
    float s = 0.f;
#pragma unroll
    for (int i = 0; i < 8; ++i) s += red[i];
    atomicAdd(&scalars[SC(0)], s);
  }
}

// ---------------- conv epilogue (32-wide) ----------------
__global__ __launch_bounds__(256) void k_epi32(const float* __restrict__ part,
                                               const float* __restrict__ bias,
                                               const float* __restrict__ root,
                                               float* __restrict__ t,
                                               float* __restrict__ colsum,
                                               float* __restrict__ colsq) {
  __shared__ float ls[HH], lq[HH];
  const int tid = threadIdx.x;
  const int idx = blockIdx.x * 256 + tid;
  const int c = idx & (HH - 1);
  if (tid < HH) { ls[tid] = 0.f; lq[tid] = 0.f; }
  __syncthreads();
  float s = bias[c] + root[idx];
#pragma unroll
  for (int sp = 0; sp < KS; ++sp) s += part[(size_t)sp * (NN * HH) + idx];
  s = fmaxf(s, 0.f);
  t[idx] = s;
  atomicAdd(&ls[c], s);
  atomicAdd(&lq[c], s * s);
  __syncthreads();
  if (tid < HH) {
    atomicAdd(&colsum[tid * 16], ls[tid]);
    atomicAdd(&colsq[tid * 16], lq[tid]);
  }
}

// ---------------- BN finalize ----------------
__global__ void k_bnfinal(float* __restrict__ colsum, float* __restrict__ colsq,
                          const float* __restrict__ g, const float* __restrict__ be,
                          float* __restrict__ A, float* __restrict__ B, int Ccols) {
  const int c = threadIdx.x;
  float cs = 0.f, cq = 0.f;
  if (c < Ccols) { cs = colsum[c * 16]; cq = colsq[c * 16]; }
  __syncthreads();
  for (int i = threadIdx.x; i < 4096; i += 256) { colsum[i] = 0.f; colsq[i] = 0.f; }
  if (c >= Ccols) return;
  const float m = cs * (1.f / NN);
  const float var = fmaxf(cq * (1.f / NN) - m * m, 0.f);
  const float a = g[c] / sqrtf(var + 1e-5f);
  A[c] = a;
  B[c] = be[c] - m * a;
}

// ---------------- bn apply (32-wide) + optional bf16 tiled copy ----------------
__global__ __launch_bounds__(256) void k_bnapply32(const float* __restrict__ t,
                                                   const float* __restrict__ A,
                                                   const float* __restrict__ B,
                                                   float* __restrict__ xo,
                                                   float* __restrict__ emb, int embOff,
                                                   unsigned short* __restrict__ xB) {
  __shared__ unsigned short sT[32][34];
  const int tid = threadIdx.x;
  const int kb = blockIdx.x;
  const int c = tid & 31, g = tid >> 5;
  const float Ac = A[c], Bc = B[c];
#pragma unroll
  for (int ni = 0; ni < 4; ++ni) {
    const int n = kb * 32 + g * 4 + ni;
    const float v = fmaf(Ac, t[(size_t)n * HH + c], Bc);
    xo[(size_t)n * HH + c] = v;
    emb[(size_t)n * DD + embOff + c] = v;
    if (xB) sT[c][g * 4 + ni] = f2bf(v);
  }
  if (xB) {
    __syncthreads();
    if (tid < 128) {
      const int row = tid >> 2, seg = tid & 3;
      u16x8 o;
#pragma unroll
      for (int j = 0; j < 8; ++j) o[j] = sT[row][seg * 8 + j];
      *reinterpret_cast<u16x8*>(&xB[((size_t)kb * 32 + row) * 32 + seg * 8]) = o;
    }
  }
}

// ---------------- conv3 epilogue ----------------
__global__ __launch_bounds__(256) void k_epi3(const float* __restrict__ part,
                                              const float* __restrict__ W3r,
                                              const float* __restrict__ b3,
                                              const float* __restrict__ x2,
                                              const float* __restrict__ W3root,
                                              float* __restrict__ t3,
                                              float* __restrict__ colsum,
                                              float* __restrict__ colsq) {
  __shared__ float z[16][33];
  __shared__ float xr[16][33];
  const int row0 = blockIdx.x * 16;
  for (int s = threadIdx.x; s < 16 * 32; s += 256) {
    const int r = s >> 5, k = s & 31;
    float a = 0.f;
#pragma unroll
    for (int sp = 0; sp < KS; ++sp)
      a += part[(size_t)sp * (NN * HH) + (size_t)(row0 + r) * HH + k];
    z[r][k] = a;
    xr[r][k] = x2[(size_t)(row0 + r) * HH + k];
  }
  __syncthreads();
  const int c = threadIdx.x;
  if (c >= CC) return;
  float acc[16];
  const float bb = b3[c];
#pragma unroll
  for (int r = 0; r < 16; ++r) acc[r] = bb;
  for (int k = 0; k < 32; ++k) {
    const float w1 = W3r[k * CC + c];
    const float w2 = W3root[k * CC + c];
#pragma unroll
    for (int r = 0; r < 16; ++r) acc[r] += z[r][k] * w1 + xr[r][k] * w2;
  }
  float lsm = 0.f, lqm = 0.f;
#pragma unroll
  for (int r = 0; r < 16; ++r) {
    const float v = fmaxf(acc[r], 0.f);
    t3[(size_t)(row0 + r) * CC + c] = v;
    lsm += v;
    lqm += v * v;
  }
  atomicAdd(&colsum[c * 16], lsm);
  atomicAdd(&colsq[c * 16], lqm);
}

__global__ void k_bnapply205(const float* __restrict__ t3, const float* __restrict__ A,
                             const float* __restrict__ B, float* __restrict__ x3,
                             float* __restrict__ emb) {
  const int row = blockIdx.x;
  const int c = threadIdx.x;
  if (c >= CC) return;
  const float v = fmaf(A[c], t3[(size_t)row * CC + c], B[c]);
  x3[(size_t)row * CC + c] = v;
  emb[(size_t)row * DD + 2 * HH + c] = v;
}

// ---------------- logits via MFMA ----------------
__global__ __launch_bounds__(256) void k_logits(const unsigned short* __restrict__ embB,
                                                const unsigned short* __restrict__ Wl1T,
                                                float* __restrict__ logits) {
  __shared__ unsigned short sA[16][296];
  const int tid = threadIdx.x;
  const int row0 = blockIdx.x * 16;
  for (int p = tid; p < 576; p += 256) {
    const int r = p / 36, ch = p - r * 36;
    const u16x8 v = *reinterpret_cast<const u16x8*>(&embB[(size_t)(row0 + r) * DP + ch * 8]);
    *reinterpret_cast<u16x8*>(&sA[r][ch * 8]) = v;
  }
  __syncthreads();
  const int lane = tid & 63;
  const int w = tid >> 6;
  const int l15 = lane & 15;
  const int kgrp = (lane >> 4) * 8;
  f32x4 acc[4];
#pragma unroll
  for (int i = 0; i < 4; ++i) acc[i] = (f32x4){0.f, 0.f, 0.f, 0.f};
#pragma unroll
  for (int i = 0; i < 4; ++i) {
    const int ct = w + i * 4;
    if (ct < 13) {
      const size_t brow = (size_t)(ct * 16 + l15) * DP;
#pragma unroll
      for (int k0 = 0; k0 < DP; k0 += 32) {
        const bf16x8 a = *reinterpret_cast<const bf16x8*>(&sA[l15][k0 + kgrp]);
        const bf16x8 b = *reinterpret_cast<const bf16x8*>(&Wl1T[brow + k0 + kgrp]);
        acc[i] = __builtin_amdgcn_mfma_f32_16x16x32_bf16(a, b, acc[i], 0, 0, 0);
      }
    }
  }
  const int rout = row0 + (lane >> 4) * 4;
#pragma unroll
  for (int i = 0; i < 4; ++i) {
    const int ct = w + i * 4;
    if (ct < 13) {
#pragma unroll
      for (int r = 0; r < 4; ++r)
        logits[(size_t)(rout + r) * GP + ct * 16 + l15] = acc[i][r];
    }
  }
}

// ---------------- softmax head: logits -> s1, sn, s1B/snB tiles, snR rows, entropy ----------------
__global__ __launch_bounds__(256) void k_softmax(const float* __restrict__ logits,
                                                 const float* __restrict__ bl1,
                                                 float* __restrict__ s1,
                                                 float* __restrict__ sn,
                                                 unsigned short* __restrict__ s1B,
                                                 unsigned short* __restrict__ snB,
                                                 unsigned short* __restrict__ snR,
                                                 float* __restrict__ scalars) {
  __shared__ unsigned short sTa[8][212];
  __shared__ unsigned short sTb[8][212];
  __shared__ float redE[4];
  const int row0 = blockIdx.x * 8;
  const int tid = threadIdx.x;
  const int w = tid >> 6;
  const int lane = tid & 63;
  const int r0 = w * 2;
  const int c0 = lane * 4;
  const bool active = (c0 < GP);
  float bl[4];
#pragma unroll
  for (int j = 0; j < 4; ++j) bl[j] = (c0 + j < CC) ? bl1[c0 + j] : 0.f;
  float ent_acc = 0.f;
#pragma unroll
  for (int r = 0; r < 2; ++r) {
    const int row = row0 + r0 + r;
    float4 lg = {0.f, 0.f, 0.f, 0.f};
    if (active) lg = *reinterpret_cast<const float4*>(&logits[(size_t)row * GP + c0]);
    const float lgv[4] = {lg.x, lg.y, lg.z, lg.w};
    float v[4];
    float ml = -1e30f;
#pragma unroll
    for (int j = 0; j < 4; ++j) {
      const int c = c0 + j;
      v[j] = (c < CC) ? fmaxf(lgv[j] + bl[j], 0.f) : -1e30f;
      ml = fmaxf(ml, v[j]);
    }
    const float m = wave_max(ml);
    float e[4];
    float sl = 0.f;
#pragma unroll
    for (int j = 0; j < 4; ++j) {
      const int c = c0 + j;
      e[j] = (c < CC) ? __expf(v[j] - m) : 0.f;
      sl += e[j];
    }
    const float S = wave_sum(sl);
    const float invS = 1.f / S;
    float p[4];
    float ql = 0.f;
#pragma unroll
    for (int j = 0; j < 4; ++j) {
      p[j] = e[j] * invS;
      ql += p[j] * p[j];
    }
    const float q = wave_sum(ql);
    const float inv = 1.f / fmaxf(sqrtf(q), 1e-8f);
    float m2l = -1e30f;
#pragma unroll
    for (int j = 0; j < 4; ++j) {
      const int c = c0 + j;
      if (c < CC) {
        s1[(size_t)row * CC + c] = p[j];
        sn[(size_t)row * CC + c] = p[j] * inv;
        m2l = fmaxf(m2l, p[j]);
      }
    }
    if (active) {
#pragma unroll
      for (int j = 0; j < 4; ++j) {
        const int c = c0 + j;
        const bool ok = (c < CC);
        sTa[r0 + r][c] = ok ? f2bf(p[j]) : (unsigned short)0;
        sTb[r0 + r][c] = ok ? f2bf(p[j] * inv) : (unsigned short)0;
      }
    }
    if (c0 < GTS) {
      ushort4 o;
      o.x = (c0 + 0 < CC) ? f2bf(p[0] * inv) : (unsigned short)0;
      o.y = (c0 + 1 < CC) ? f2bf(p[1] * inv) : (unsigned short)0;
      o.z = (c0 + 2 < CC) ? f2bf(p[2] * inv) : (unsigned short)0;
      o.w = (c0 + 3 < CC) ? f2bf(p[3] * inv) : (unsigned short)0;
      *reinterpret_cast<ushort4*>(&snR[(size_t)row * GTS + c0]) = o;
    }
    const float m2 = wave_max(m2l);
    float e2[4];
    float s2l = 0.f;
#pragma unroll
    for (int j = 0; j < 4; ++j) {
      const int c = c0 + j;
      e2[j] = (c < CC) ? __expf(p[j] - m2) : 0.f;
      s2l += e2[j];
    }
    const float S2 = wave_sum(s2l);
    const float invS2 = 1.f / S2;
    float tl = 0.f;
#pragma unroll
    for (int j = 0; j < 4; ++j) {
      const int c = c0 + j;
      if (c < CC) {
        const float sp = e2[j] * invS2;
        tl -= sp * logf(sp + 1e-15f);
      }
    }
    ent_acc += tl;
  }
  ent_acc = wave_sum(ent_acc);
  if (lane == 0) redE[w] = ent_acc;
  __syncthreads();
  if (tid == 0) atomicAdd(&scalars[SC(2)], redE[0] + redE[1] + redE[2] + redE[3]);
  if (tid < GP) {
    const int kb = row0 >> 5, no = row0 & 31;
    u16x8 oa, ob;
#pragma unroll
    for (int r = 0; r < 8; ++r) { oa[r] = sTa[r][tid]; ob[r] = sTb[r][tid]; }
    *reinterpret_cast<u16x8*>(&s1B[((size_t)kb * GP + tid) * 32 + no]) = oa;
    *reinterpret_cast<u16x8*>(&snB[((size_t)kb * GP + tid) * 32 + no]) = ob;
  }
}

// ---------------- MFMA Gram: bf16 transposed GT[col][k] outputs (+ fp32 Gs0 for gid 3) ----------------
__global__ __launch_bounds__(256) void k_gramm(const unsigned short* __restrict__ xnB,
                                               const unsigned short* __restrict__ snB,
                                               const unsigned short* __restrict__ s1B,
                                               unsigned short* __restrict__ GT0,
                                               unsigned short* __restrict__ GxsT,
                                               unsigned short* __restrict__ GsT,
                                               float* __restrict__ Gs0) {
  const int gid = blockIdx.z;
  const int tp = blockIdx.x * 16;
  const int tq = blockIdx.y * 16;
  const unsigned short *PT, *QT;
  unsigned short* GTout = nullptr;
  if (gid == 0)      { PT = xnB; QT = xnB; GTout = GT0;  if (tp >= FF || tq >= FF) return; }
  else if (gid == 1) { PT = xnB; QT = snB; GTout = GxsT; if (tp >= FF) return; }
  else if (gid == 2) { PT = snB; QT = snB; GTout = GsT; }
  else               { PT = s1B; QT = s1B; }
  const int tid = threadIdx.x;
  const int lane = tid & 63;
  const int w = tid >> 6;
  const int l15 = lane & 15;
  const int kgrp = (lane >> 4) * 8;
  f32x4 acc = {0.f, 0.f, 0.f, 0.f};
#pragma unroll 8
  for (int kt = 0; kt < 32; ++kt) {
    const int kb = w * 32 + kt;
    const bf16x8 a = *reinterpret_cast<const bf16x8*>(&PT[((size_t)kb * GP + tp + l15) * 32 + kgrp]);
    const bf16x8 b = *reinterpret_cast<const bf16x8*>(&QT[((size_t)kb * GP + tq + l15) * 32 + kgrp]);
    acc = __builtin_amdgcn_mfma_f32_16x16x32_bf16(a, b, acc, 0, 0, 0);
  }
  __shared__ float red[4][16][17];
  const int crow = (lane >> 4) * 4;
#pragma unroll
  for (int r = 0; r < 4; ++r) red[w][crow + r][l15] = acc[r];
  __syncthreads();
  const int rr = tid >> 4, cc = tid & 15;
  if (gid == 3) {
    const float v = red[0][rr][cc] + red[1][rr][cc] + red[2][rr][cc] + red[3][rr][cc];
    Gs0[(size_t)(tp + rr) * GP + (tq + cc)] = v;
  } else {
    // transposed bf16: GT[(tq+rr)][tp+cc] = Cp[tp+cc][tq+rr]
    const float vt = red[0][cc][rr] + red[1][cc][rr] + red[2][cc][rr] + red[3][cc][rr];
    GTout[(size_t)(tq + rr) * GTS + (tp + cc)] = f2bf(vt);
  }
}

// ---------------- MFMA thin GEMMs: H = A @ Gram via GT[col][k] ----------------
// grid (NN/16, 3); 4 waves; logits-style
__global__ __launch_bounds__(256) void k_rowmm3m(const unsigned short* __restrict__ xnR,
                                                 const unsigned short* __restrict__ snR,
                                                 const unsigned short* __restrict__ GT0,
                                                 const unsigned short* __restrict__ GxsT,
                                                 const unsigned short* __restrict__ GsT,
                                                 float* __restrict__ H1,
                                                 float* __restrict__ Uu,
                                                 float* __restrict__ H2) {
  const int gid = blockIdx.y;
  const unsigned short *A, *B;
  float* C;
  int K, As, NCT;
  if (gid == 0)      { A = xnR; B = GT0;  C = H1; K = FF;  As = FF;  NCT = 8; }
  else if (gid == 1) { A = xnR; B = GxsT; C = Uu; K = FF;  As = FF;  NCT = 13; }
  else               { A = snR; B = GsT;  C = H2; K = GTS; As = GTS; NCT = 13; }
  __shared__ unsigned short sA[16][232];
  const int tid = threadIdx.x;
  const int row0 = blockIdx.x * 16;
  const int nch = K >> 3;
  for (int p = tid; p < 16 * nch; p += 256) {
    const int r = p / nch, ch = p - r * nch;
    const u16x8 v = *reinterpret_cast<const u16x8*>(&A[(size_t)(row0 + r) * As + ch * 8]);
    *reinterpret_cast<u16x8*>(&sA[r][ch * 8]) = v;
  }
  __syncthreads();
  const int lane = tid & 63;
  const int w = tid >> 6;
  const int l15 = lane & 15;
  const int kgrp = (lane >> 4) * 8;
  f32x4 acc[4];
#pragma unroll
  for (int i = 0; i < 4; ++i) acc[i] = (f32x4){0.f, 0.f, 0.f, 0.f};
#pragma unroll
  for (int i = 0; i < 4; ++i) {
    const int ct = w + i * 4;
    if (ct < NCT) {
      const size_t brow = (size_t)(ct * 16 + l15) * GTS;
      for (int k0 = 0; k0 < K; k0 += 32) {
        const bf16x8 a = *reinterpret_cast<const bf16x8*>(&sA[l15][k0 + kgrp]);
        const bf16x8 b = *reinterpret_cast<const bf16x8*>(&B[brow + k0 + kgrp]);
        acc[i] = __builtin_amdgcn_mfma_f32_16x16x32_bf16(a, b, acc[i], 0, 0, 0);
      }
    }
  }
  const int rout = row0 + (lane >> 4) * 4;
#pragma unroll
  for (int i = 0; i < 4; ++i) {
    const int ct = w + i * 4;
    if (ct < NCT) {
#pragma unroll
      for (int r = 0; r < 4; ++r)
        C[(size_t)(rout + r) * HS + ct * 16 + l15] = acc[i][r];
    }
  }
}

// ---------------- per-row sim + team embedding loss (H arrays stride HS) ----------------
__global__ __launch_bounds__(256) void k_losses(const float* __restrict__ H1,
                                                const float* __restrict__ Uu,
                                                const float* __restrict__ H2,
                                                const float* __restrict__ xn,
                                                const float* __restrict__ sn,
                                                const float* __restrict__ emb,
                                                const int* __restrict__ teams,
                                                const int* __restrict__ reps,
                                                float* __restrict__ scalars) {
  __shared__ float red[4];
  const int tid = threadIdx.x;
  const int lane = tid & 63;
  const int w = tid >> 6;
  if (blockIdx.x < NN / 4) {
    const int row = blockIdx.x * 4 + w;
    float suu = 0.f, suv = 0.f, svv = 0.f;
#pragma unroll
    for (int c0 = 0; c0 < FF; c0 += 64) {
      const float xv = xn[(size_t)row * FF + c0 + lane];
      suu = fmaf(H1[(size_t)row * HS + c0 + lane], xv, suu);
    }
    for (int cb = lane; cb < CC; cb += 64) {
      const float sv = sn[(size_t)row * CC + cb];
      suv = fmaf(Uu[(size_t)row * HS + cb], sv, suv);
      svv = fmaf(H2[(size_t)row * HS + cb], sv, svv);
    }
    suu = wave_sum(suu);
    suv = wave_sum(suv);
    svv = wave_sum(svv);
    if (lane == 0) red[w] = suv / sqrtf(suu * svv);
    __syncthreads();
    if (tid == 0) atomicAdd(&scalars[SC(3)], red[0] + red[1] + red[2] + red[3]);
  } else {
    const int team = blockIdx.x - NN / 4;
    float part = 0.f;
    for (int d = tid; d < DD; d += 256) {
      float a = 0.f, b = 0.f;
#pragma unroll
      for (int m = 0; m < RR; ++m) a += emb[(size_t)reps[team * RR + m] * DD + d];
#pragma unroll
      for (int m = RR; m < TT; ++m) b += emb[(size_t)teams[team * TT + m] * DD + d];
      part += fabsf(a * (1.f / RR) - b * (1.f / (TT - RR)));
    }
    part = wave_sum(part);
    if (lane == 0) red[w] = part;
    __syncthreads();
    if (tid == 0) atomicAdd(&scalars[SC(4)], red[0] + red[1] + red[2] + red[3]);
  }
}

// ---------------- finalize ----------------
__global__ void k_final(const float* __restrict__ Gs0, const float* __restrict__ scalars,
                        float* __restrict__ outsc) {
  __shared__ float red[4];
  float p = 0.f;
  for (int i = threadIdx.x; i < GP * GP; i += 256) {
    const float v = Gs0[i];
    p = fmaf(v, v, p);
  }
  p = wave_sum(p);
  if ((threadIdx.x & 63) == 0) red[threadIdx.x >> 6] = p;
  __syncthreads();
  if (threadIdx.x == 0) {
    const float sumP2 = red[0] + red[1] + red[2] + red[3];
    const float normsq = fmaxf(sumP2 - 2.f * scalars[SC(0)] + scalars[SC(1)], 0.f);
    const float norm = sqrtf(normsq);
    const float e1 = scalars[SC(2)] * (1.f / NN);
    const float sim = -scalars[SC(3)] * (1.f / NN);
    const float embl = scalars[SC(4)] * (1.f / LL);
    outsc[0] = norm;
    outsc[1] = e1;
    outsc[2] = sim;
    outsc[3] = 100.f * norm + 10.f * e1 + 100.f * sim + embl;
    outsc[4] = embl;
  }
}

// ================= launch =================
extern "C" void kernel_launch(void* const* d_in, const int* in_sizes, int n_in,
                              void* d_out, int out_size, void* d_ws, size_t ws_size,
                              hipStream_t stream) {
  const float* x      = (const float*)d_in[0];
  const float* adj    = (const float*)d_in[1];
  const int*   teams  = (const int*)d_in[2];
  const int*   reps   = (const int*)d_in[3];
  const float* W1r    = (const float*)d_in[4];
  const float* b1     = (const float*)d_in[5];
  const float* W1root = (const float*)d_in[6];
  const float* g1     = (const float*)d_in[7];
  const float* be1    = (const float*)d_in[8];
  const float* W2r    = (const float*)d_in[9];
  const float* b2     = (const float*)d_in[10];
  const float* W2root = (const float*)d_in[11];
  const float* g2     = (const float*)d_in[12];
  const float* be2    = (const float*)d_in[13];
  const float* W3r    = (const float*)d_in[14];
  const float* b3     = (const float*)d_in[15];
  const float* W3root = (const float*)d_in[16];
  const float* g3     = (const float*)d_in[17];
  const float* be3    = (const float*)d_in[18];
  const float* Wl1    = (const float*)d_in[19];
  const float* bl1    = (const float*)d_in[20];

  char* wp = (char*)d_ws;
  auto alloc = [&](size_t bytes) { char* p = wp; wp += (bytes + 255) & ~(size_t)255; return p; };
  unsigned short* adj_t = (unsigned short*)alloc((size_t)NN * NN * 2);
  unsigned short* mB    = (unsigned short*)alloc((size_t)HH * NN * 2);
  unsigned short* x2B   = (unsigned short*)alloc((size_t)HH * NN * 2);
  unsigned short* s1B   = (unsigned short*)alloc((size_t)GP * NN * 2);
  unsigned short* snB   = (unsigned short*)alloc((size_t)GP * NN * 2);
  unsigned short* xnB   = (unsigned short*)alloc((size_t)GP * NN * 2);
  unsigned short* embB  = (unsigned short*)alloc((size_t)NN * DP * 2);
  unsigned short* Wl1T  = (unsigned short*)alloc((size_t)GP * DP * 2);
  unsigned short* xnR   = (unsigned short*)alloc((size_t)NN * FF * 2);
  unsigned short* snR   = (unsigned short*)alloc((size_t)NN * GTS * 2);
  unsigned short* GTall = (unsigned short*)alloc((size_t)3 * GP * GTS * 2);
  unsigned short* GT0   = GTall;
  unsigned short* GxsT  = GTall + (size_t)GP * GTS;
  unsigned short* GsT   = GTall + (size_t)2 * GP * GTS;
  float* logits = (float*)alloc((size_t)NN * GP * 4);
  float* rootb  = (float*)alloc((size_t)NN * HH * 4);
  float* t      = (float*)alloc((size_t)NN * HH * 4);
  float* x1     = (float*)alloc((size_t)NN * HH * 4);
  float* x2     = (float*)alloc((size_t)NN * HH * 4);
  float* part   = (float*)alloc((size_t)KS * NN * HH * 4);
  float* t3     = (float*)alloc((size_t)NN * CC * 4);
  float* x3     = (float*)alloc((size_t)NN * CC * 4);
  float* sn     = (float*)alloc((size_t)NN * CC * 4);
  float* xn     = (float*)alloc((size_t)NN * FF * 4);
  float* H1     = (float*)alloc((size_t)NN * HS * 4);
  float* Uu     = (float*)alloc((size_t)NN * HS * 4);
  float* H2     = (float*)alloc((size_t)NN * HS * 4);
  float* Gs0    = (float*)alloc((size_t)GP * GP * 4);
  float* scalars = (float*)alloc(160 * 4);
  float* colsum = (float*)alloc(4096 * 4);
  float* colsq  = (float*)alloc(4096 * 4);
  float* bnA    = (float*)alloc(1024);
  float* bnB    = (float*)alloc(1024);
  (void)ws_size; (void)in_sizes; (void)n_in; (void)out_size;

  float* out   = (float*)d_out;
  float* s1    = out;                          // N*C
  float* outsc = out + (size_t)NN * CC;        // 5 scalars
  float* emb   = out + (size_t)NN * CC + 5;    // N*D

  // zero scalar accumulators + padded BN stats + xnB pad rows + GT buffers (pad zones)
  hipMemsetAsync(scalars, 0, 160 * 4, stream);
  hipMemsetAsync(colsum, 0, 2 * 4096 * 4, stream);
  hipMemsetAsync(xnB, 0, (size_t)GP * NN * 2, stream);
  hipMemsetAsync(GTall, 0, (size_t)3 * GP * GTS * 2, stream);

  k_padWT<<<(GP * DP + 255) / 256, 256, 0, stream>>>(Wl1, Wl1T);
  k_xn<<<NN / 4, 256, 0, stream>>>(x, xn, xnR);
  k_xnB<<<NN / 32, 256, 0, stream>>>(xn, xnB);

  // conv1 (fused: adj cvt->tiled + adj^2 + MFMA)
  k_proj_t<<<NN / 32, 256, 0, stream>>>(x, W1r, W1root, mB, rootb, FF);
  k_conv1f<<<dim3(NN / 64, KS), 256, 0, stream>>>(adj, adj_t, mB, part, scalars);
  k_epi32<<<NN * HH / 256, 256, 0, stream>>>(part, b1, rootb, t, colsum, colsq);
  k_bnfinal<<<1, 256, 0, stream>>>(colsum, colsq, g1, be1, bnA, bnB, HH);
  k_bnapply32<<<NN / 32, 256, 0, stream>>>(t, bnA, bnB, x1, emb, 0, (unsigned short*)nullptr);

  // conv2
  k_proj_t<<<NN / 32, 256, 0, stream>>>(x1, W2r, W2root, mB, rootb, HH);
  k_adjmm<<<dim3(NN / 64, KS), 256, 0, stream>>>(adj_t, mB, part);
  k_epi32<<<NN * HH / 256, 256, 0, stream>>>(part, b2, rootb, t, colsum, colsq);
  k_bnfinal<<<1, 256, 0, stream>>>(colsum, colsq, g2, be2, bnA, bnB, HH);
  k_bnapply32<<<NN / 32, 256, 0, stream>>>(t, bnA, bnB, x2, emb, HH, x2B);

  // conv3
  k_adjmm<<<dim3(NN / 64, KS), 256, 0, stream>>>(adj_t, x2B, part);
  k_epi3<<<NN / 16, 256, 0, stream>>>(part, W3r, b3, x2, W3root, t3, colsum, colsq);
  k_bnfinal<<<1, 256, 0, stream>>>(colsum, colsq, g3, be3, bnA, bnB, CC);
  k_bnapply205<<<NN, 256, 0, stream>>>(t3, bnA, bnB, x3, emb);

  // head: emb -> bf16, MFMA logits, streaming softmax
  k_embB<<<NN * DP / 256, 256, 0, stream>>>(emb, embB);
  k_logits<<<NN / 16, 256, 0, stream>>>(embB, Wl1T, logits);
  k_softmax<<<NN / 8, 256, 0, stream>>>(logits, bl1, s1, sn, s1B, snB, snR, scalars);

  // tr(S' A S) via MFMA (LDS-staged B, double-buffered)
  k_normmfma<<<dim3(NN / 128, KS), 512, 0, stream>>>(adj_t, s1B, s1, scalars);

  // Grams (bf16 transposed outputs) + MFMA bilinear forms + losses + finalize
  k_gramm<<<dim3(13, 13, 4), 256, 0, stream>>>(xnB, snB, s1B, GT0, GxsT, GsT, Gs0);
  k_rowmm3m<<<dim3(NN / 16, 3), 256, 0, stream>>>(xnR, snR, GT0, GxsT, GsT, H1, Uu, H2);
  k_losses<<<NN / 4 + LL, 256, 0, stream>>>(H1, Uu, H2, xn, sn, emb, teams, reps, scalars);
  k_final<<<1, 256, 0, stream>>>(Gs0, scalars, outsc);
}

// Round 11
// 240.267 us; speedup vs baseline: 3.8500x; 1.1597x over previous
//
#include <hip/hip_runtime.h>
#include <math.h>

#define NN 4096
#define FF 128
#define HH 32
#define CC 205
#define DD 269
#define LL 512
#define TT 12
#define RR 4
#define KS 16    // k-split for all adj MFMA passes
#define GP 208   // padded gram dim
#define DP 288   // padded D (k) dim for logits MFMA
#define BST 40   // padded LDS row stride (ushorts) for B tiles
#define GTS 224  // transposed-gram row stride / padded K
#define HS 208   // H1/Uu/H2 row stride (floats)

// padded scalar slots: 0=trSAS 1=adjsq 2=entropy 3=sim 4=embloss 5=sumP2
#define SC(i) ((i) * 32)

typedef __attribute__((ext_vector_type(8))) short bf16x8;
typedef __attribute__((ext_vector_type(4))) float f32x4;
typedef __attribute__((ext_vector_type(8))) unsigned short u16x8;

// ---------------- helpers ----------------
__device__ __forceinline__ float wave_sum(float v) {
#pragma unroll
  for (int o = 32; o > 0; o >>= 1) v += __shfl_xor(v, o, 64);
  return v;
}
__device__ __forceinline__ float wave_max(float v) {
#pragma unroll
  for (int o = 32; o > 0; o >>= 1) v = fmaxf(v, __shfl_xor(v, o, 64));
  return v;
}
__device__ __forceinline__ unsigned short f2bf(float x) {  // RNE
  union { float f; unsigned u; } v; v.f = x;
  unsigned r = v.u + 0x7FFFu + ((v.u >> 16) & 1u);
  return (unsigned short)(r >> 16);
}

// ---------------- Wl1 -> Wl1T bf16 [GP][DP] (transposed, zero-padded) ----------------
__global__ __launch_bounds__(256) void k_padWT(const float* __restrict__ Wl1,
                                               unsigned short* __restrict__ Wl1T) {
  const int idx = blockIdx.x * 256 + threadIdx.x;
  if (idx >= GP * DP) return;
  const int c = idx / DP, k = idx - c * DP;
  Wl1T[idx] = (c < CC && k < DD) ? f2bf(Wl1[(size_t)k * CC + c]) : (unsigned short)0;
}

// ---------------- emb fp32 [N][DD] -> embB bf16 [N][DP] (zero-padded) ----------------
__global__ __launch_bounds__(256) void k_embB(const float* __restrict__ emb,
                                              unsigned short* __restrict__ embB) {
  const int idx = blockIdx.x * 256 + threadIdx.x;  // NN*DP
  const int n = idx / DP, d = idx - n * DP;
  embB[idx] = (d < DD) ? f2bf(emb[(size_t)n * DD + d]) : (unsigned short)0;
}

// ---------------- dual projection: mB (bf16 tiled [kb][32][32]) = (A@W1)^T tiles, o2 = A@W2 ----------------
__global__ __launch_bounds__(256) void k_proj_t(const float* __restrict__ A,
                                                const float* __restrict__ W1,
                                                const float* __restrict__ W2,
                                                unsigned short* __restrict__ mB,
                                                float* __restrict__ o2, int K) {
  __shared__ float sX[32][132];
  __shared__ unsigned short sT[32][34];
  const int tid = threadIdx.x;
  const int kb = blockIdx.x;
  const int nf4 = K >> 2;
  const int tot4 = 32 * nf4;
  for (int p = tid; p < tot4; p += 256) {
    const int node = p / nf4, c4 = p - node * nf4;
    const float4 v = *reinterpret_cast<const float4*>(&A[((size_t)(kb * 32 + node)) * K + c4 * 4]);
    sX[node][c4 * 4 + 0] = v.x; sX[node][c4 * 4 + 1] = v.y;
    sX[node][c4 * 4 + 2] = v.z; sX[node][c4 * 4 + 3] = v.w;
  }
  __syncthreads();
  const int c = tid & 31, g = tid >> 5;
  float a1[4] = {0.f, 0.f, 0.f, 0.f}, a2[4] = {0.f, 0.f, 0.f, 0.f};
  for (int k = 0; k < K; ++k) {
    const float w1 = W1[k * HH + c];
    const float w2 = W2[k * HH + c];
#pragma unroll
    for (int ni = 0; ni < 4; ++ni) {
      const float av = sX[g * 4 + ni][k];
      a1[ni] = fmaf(av, w1, a1[ni]);
      a2[ni] = fmaf(av, w2, a2[ni]);
    }
  }
#pragma unroll
  for (int ni = 0; ni < 4; ++ni) {
    o2[((size_t)kb * 32 + g * 4 + ni) * HH + c] = a2[ni];
    sT[c][g * 4 + ni] = f2bf(a1[ni]);
  }
  __syncthreads();
  if (tid < 128) {
    const int row = tid >> 2, seg = tid & 3;
    u16x8 v;
#pragma unroll
    for (int j = 0; j < 8; ++j) v[j] = sT[row][seg * 8 + j];
    *reinterpret_cast<u16x8*>(&mB[((size_t)kb * 32 + row) * 32 + seg * 8]) = v;
  }
}

// ---------------- row-normalize x -> xn (+ row bf16 xnR) ----------------
__global__ __launch_bounds__(256) void k_xn(const float* __restrict__ x, float* __restrict__ xn,
                                            unsigned short* __restrict__ xnR) {
  const int lane = threadIdx.x & 63;
  const int row = blockIdx.x * 4 + (threadIdx.x >> 6);
  float v0 = x[(size_t)row * FF + lane];
  float v1 = x[(size_t)row * FF + 64 + lane];
  float ss = wave_sum(v0 * v0 + v1 * v1);
  float n = fmaxf(sqrtf(ss), 1e-8f);
  const float a = v0 / n, b = v1 / n;
  xn[(size_t)row * FF + lane] = a;
  xn[(size_t)row * FF + 64 + lane] = b;
  xnR[(size_t)row * FF + lane] = f2bf(a);
  xnR[(size_t)row * FF + 64 + lane] = f2bf(b);
}

// ---------------- xn -> xnB bf16 tiled [kb][GP][32] ----------------
__global__ __launch_bounds__(256) void k_xnB(const float* __restrict__ xn,
                                             unsigned short* __restrict__ xnB) {
  __shared__ unsigned short sT[FF][34];
  const int tid = threadIdx.x;
  const int kb = blockIdx.x;
  for (int p = tid; p < 1024; p += 256) {
    const int node = p >> 5, c4 = p & 31;
    const float4 v = *reinterpret_cast<const float4*>(&xn[((size_t)(kb * 32 + node)) * FF + c4 * 4]);
    sT[c4 * 4 + 0][node] = f2bf(v.x);
    sT[c4 * 4 + 1][node] = f2bf(v.y);
    sT[c4 * 4 + 2][node] = f2bf(v.z);
    sT[c4 * 4 + 3][node] = f2bf(v.w);
  }
  __syncthreads();
  const int row = tid >> 1, seg = (tid & 1) * 16;
  if (row < FF) {
    u16x8 a, b;
#pragma unroll
    for (int j = 0; j < 8; ++j) { a[j] = sT[row][seg + j]; b[j] = sT[row][seg + 8 + j]; }
    *reinterpret_cast<u16x8*>(&xnB[((size_t)kb * GP + row) * 32 + seg]) = a;
    *reinterpret_cast<u16x8*>(&xnB[((size_t)kb * GP + row) * 32 + seg + 8]) = b;
  }
}

// ---------------- FUSED conv1: fp32 adj -> bf16 tiled adj_t + sum(adj^2) + MFMA ----------------
__global__ __launch_bounds__(256) void k_conv1f(const float* __restrict__ adj,
                                                unsigned short* __restrict__ adj_t,
                                                const unsigned short* __restrict__ mB,
                                                float* __restrict__ part,
                                                float* __restrict__ scalars) {
  __shared__ unsigned short sA[64][264];
  __shared__ float red[4];
  const int tid = threadIdx.x;
  const int rbase_blk = blockIdx.x * 64;
  const int kbase = blockIdx.y * 256;
  const int rb0 = blockIdx.x * 4;
  const int kb0 = blockIdx.y * 8;
  const int lane = tid & 63;
  const int w = tid >> 6;
  const int l15 = lane & 15;
  const int kgrp = (lane >> 4) * 8;
  bf16x8 bb0[8], bb1[8];
#pragma unroll
  for (int kt = 0; kt < 8; ++kt) {
    const size_t boff = ((size_t)(kb0 + kt) * 32) * 32;
    bb0[kt] = *reinterpret_cast<const bf16x8*>(&mB[boff + (size_t)l15 * 32 + kgrp]);
    bb1[kt] = *reinterpret_cast<const bf16x8*>(&mB[boff + (size_t)(16 + l15) * 32 + kgrp]);
  }
  float adjsq = 0.f;
#pragma unroll
  for (int i = 0; i < 16; ++i) {
    const int fi = i * 256 + tid;
    const int r = fi >> 6;
    const int c4 = fi & 63;
    const size_t goff = (size_t)(rbase_blk + r) * NN + kbase + c4 * 4;
    const float4 v = *reinterpret_cast<const float4*>(&adj[goff]);
    adjsq += v.x * v.x + v.y * v.y + v.z * v.z + v.w * v.w;
    ushort4 h;
    h.x = f2bf(v.x); h.y = f2bf(v.y); h.z = f2bf(v.z); h.w = f2bf(v.w);
    const size_t toff = ((size_t)(rb0 + (r >> 4)) * (NN / 32) + kb0 + (c4 >> 3)) * 512 +
                        (r & 15) * 32 + (c4 & 7) * 4;
    *reinterpret_cast<ushort4*>(&adj_t[toff]) = h;
    *reinterpret_cast<ushort4*>(&sA[r][c4 * 4]) = h;
  }
  __syncthreads();
  const int rloc = w * 16 + l15;
  f32x4 acc0 = {0.f, 0.f, 0.f, 0.f}, acc1 = {0.f, 0.f, 0.f, 0.f};
#pragma unroll
  for (int k0 = 0; k0 < 256; k0 += 32) {
    const bf16x8 a = *reinterpret_cast<const bf16x8*>(&sA[rloc][k0 + kgrp]);
    acc0 = __builtin_amdgcn_mfma_f32_16x16x32_bf16(a, bb0[k0 >> 5], acc0, 0, 0, 0);
    acc1 = __builtin_amdgcn_mfma_f32_16x16x32_bf16(a, bb1[k0 >> 5], acc1, 0, 0, 0);
  }
  float* pp = part + (size_t)blockIdx.y * (NN * HH);
  const int rout = rbase_blk + w * 16 + (lane >> 4) * 4;
#pragma unroll
  for (int r = 0; r < 4; ++r) {
    pp[(size_t)(rout + r) * HH + l15] = acc0[r];
    pp[(size_t)(rout + r) * HH + 16 + l15] = acc1[r];
  }
  adjsq = wave_sum(adjsq);
  if (lane == 0) red[w] = adjsq;
  __syncthreads();
  if (tid == 0) atomicAdd(&scalars[SC(1)], red[0] + red[1] + red[2] + red[3]);
}

// ---------------- MFMA adj pass (register-hoisted) ----------------
__global__ __launch_bounds__(256) void k_adjmm(const unsigned short* __restrict__ adj_t,
                                               const unsigned short* __restrict__ mB,
                                               float* __restrict__ part) {
  const int tid = threadIdx.x;
  const int lane = tid & 63;
  const int w = tid >> 6;
  const int rb = blockIdx.x * 4 + w;
  const int kb0 = blockIdx.y * 8;
  const int l15 = lane & 15;
  const int kgrp = (lane >> 4) * 8;
  bf16x8 a[8], b0[8], b1[8];
#pragma unroll
  for (int kt = 0; kt < 8; ++kt) {
    const size_t aoff = ((size_t)rb * (NN / 32) + kb0 + kt) * 512;
    const size_t boff = ((size_t)(kb0 + kt) * 32) * 32;
    a[kt] = *reinterpret_cast<const bf16x8*>(&adj_t[aoff + l15 * 32 + kgrp]);
    b0[kt] = *reinterpret_cast<const bf16x8*>(&mB[boff + (size_t)l15 * 32 + kgrp]);
    b1[kt] = *reinterpret_cast<const bf16x8*>(&mB[boff + (size_t)(16 + l15) * 32 + kgrp]);
  }
  f32x4 acc0 = {0.f, 0.f, 0.f, 0.f}, acc1 = {0.f, 0.f, 0.f, 0.f};
#pragma unroll
  for (int kt = 0; kt < 8; ++kt) {
    acc0 = __builtin_amdgcn_mfma_f32_16x16x32_bf16(a[kt], b0[kt], acc0, 0, 0, 0);
    acc1 = __builtin_amdgcn_mfma_f32_16x16x32_bf16(a[kt], b1[kt], acc1, 0, 0, 0);
  }
  float* pp = part + (size_t)blockIdx.y * (NN * HH);
  const int rout = rb * 16 + (lane >> 4) * 4;
#pragma unroll
  for (int r = 0; r < 4; ++r) {
    pp[(size_t)(rout + r) * HH + l15] = acc0[r];
    pp[(size_t)(rout + r) * HH + 16 + l15] = acc1[r];
  }
}

// ---------------- MFMA norm pass v2: LDS-staged B (double-buffered) ----------------
__global__ __launch_bounds__(512) void k_normmfma(const unsigned short* __restrict__ adj_t,
                                                  const unsigned short* __restrict__ s1B,
                                                  const float* __restrict__ s1,
                                                  float* __restrict__ scalars) {
  __shared__ unsigned short sB[2][13][16][BST];
  __shared__ float red[8];
  const int tid = threadIdx.x;
  const int lane = tid & 63;
  const int w = tid >> 6;
  const int rb = blockIdx.x * 8 + w;
  const int kb0 = blockIdx.y * 8;
  const int l15 = lane & 15;
  const int g = lane >> 4;
  const int kgrp = g * 8;
  const int p0 = tid;
  const int ct0 = p0 >> 6, rr0 = (p0 >> 2) & 15, sg0 = (p0 & 3) * 8;
  const int p1 = tid + 512;
  const bool v1 = (p1 < 832);
  const int ct1 = p1 >> 6, rr1 = (p1 >> 2) & 15, sg1 = (p1 & 3) * 8;

  f32x4 acc[13];
#pragma unroll
  for (int ct = 0; ct < 13; ++ct) acc[ct] = (f32x4){0.f, 0.f, 0.f, 0.f};

  u16x8 st0, st1;
  st0 = *reinterpret_cast<const u16x8*>(&s1B[((size_t)kb0 * GP + ct0 * 16 + rr0) * 32 + sg0]);
  if (v1) st1 = *reinterpret_cast<const u16x8*>(&s1B[((size_t)kb0 * GP + ct1 * 16 + rr1) * 32 + sg1]);
  *reinterpret_cast<u16x8*>(&sB[0][ct0][rr0][sg0]) = st0;
  if (v1) *reinterpret_cast<u16x8*>(&sB[0][ct1][rr1][sg1]) = st1;
  __syncthreads();

  bf16x8 a = *reinterpret_cast<const bf16x8*>(
      &adj_t[((size_t)rb * (NN / 32) + kb0) * 512 + l15 * 32 + kgrp]);

  for (int kt = 0; kt < 8; ++kt) {
    const int cur = kt & 1;
    if (kt < 7) {
      const size_t kb = kb0 + kt + 1;
      st0 = *reinterpret_cast<const u16x8*>(&s1B[(kb * GP + ct0 * 16 + rr0) * 32 + sg0]);
      if (v1) st1 = *reinterpret_cast<const u16x8*>(&s1B[(kb * GP + ct1 * 16 + rr1) * 32 + sg1]);
    }
    bf16x8 a_next = a;
    if (kt < 7)
      a_next = *reinterpret_cast<const bf16x8*>(
          &adj_t[((size_t)rb * (NN / 32) + kb0 + kt + 1) * 512 + l15 * 32 + kgrp]);
#pragma unroll
    for (int ct = 0; ct < 13; ++ct) {
      const bf16x8 b = *reinterpret_cast<const bf16x8*>(&sB[cur][ct][l15][kgrp]);
      acc[ct] = __builtin_amdgcn_mfma_f32_16x16x32_bf16(a, b, acc[ct], 0, 0, 0);
    }
    if (kt < 7) {
      *reinterpret_cast<u16x8*>(&sB[cur ^ 1][ct0][rr0][sg0]) = st0;
      if (v1) *reinterpret_cast<u16x8*>(&sB[cur ^ 1][ct1][rr1][sg1]) = st1;
    }
    __syncthreads();
    a = a_next;
  }
  const int rout = rb * 16 + g * 4;
  float sc = 0.f;
#pragma unroll
  for (int ct = 0; ct < 13; ++ct) {
    const int col = ct * 16 + l15;
    if (col < CC) {
#pragma unroll
      for (int r = 0; r < 4; ++r)
        sc = fmaf(acc[ct][r], s1[(size_t)(rout + r) * CC + col], sc);
    }
  }
  sc = wave_sum(sc);
  if (lane == 0) red[w] = sc;
  __syncthreads();
  if (tid == 0) {
    float s = 0.f;
#pragma unroll
    for (int i = 0; i < 8; ++i) s += red[i];
    atomicAdd(&scalars[SC(0)], s);
  }
}

// ---------------- conv epilogue (32-wide) ----------------
__global__ __launch_bounds__(256) void k_epi32(const float* __restrict__ part,
                                               const float* __restrict__ bias,
                                               const float* __restrict__ root,
                                               float* __restrict__ t,
                                               float* __restrict__ colsum,
                                               float* __restrict__ colsq) {
  __shared__ float ls[HH], lq[HH];
  const int tid = threadIdx.x;
  const int idx = blockIdx.x * 256 + tid;
  const int c = idx & (HH - 1);
  if (tid < HH) { ls[tid] = 0.f; lq[tid] = 0.f; }
  __syncthreads();
  float s = bias[c] + root[idx];
#pragma unroll
  for (int sp = 0; sp < KS; ++sp) s += part[(size_t)sp * (NN * HH) + idx];
  s = fmaxf(s, 0.f);
  t[idx] = s;
  atomicAdd(&ls[c], s);
  atomicAdd(&lq[c], s * s);
  __syncthreads();
  if (tid < HH) {
    atomicAdd(&colsum[tid * 16], ls[tid]);
    atomicAdd(&colsq[tid * 16], lq[tid]);
  }
}

// ---------------- BN finalize ----------------
__global__ void k_bnfinal(float* __restrict__ colsum, float* __restrict__ colsq,
                          const float* __restrict__ g, const float* __restrict__ be,
                          float* __restrict__ A, float* __restrict__ B, int Ccols) {
  const int c = threadIdx.x;
  float cs = 0.f, cq = 0.f;
  if (c < Ccols) { cs = colsum[c * 16]; cq = colsq[c * 16]; }
  __syncthreads();
  for (int i = threadIdx.x; i < 4096; i += 256) { colsum[i] = 0.f; colsq[i] = 0.f; }
  if (c >= Ccols) return;
  const float m = cs * (1.f / NN);
  const float var = fmaxf(cq * (1.f / NN) - m * m, 0.f);
  const float a = g[c] / sqrtf(var + 1e-5f);
  A[c] = a;
  B[c] = be[c] - m * a;
}

// ---------------- bn apply (32-wide) + optional bf16 tiled copy ----------------
__global__ __launch_bounds__(256) void k_bnapply32(const float* __restrict__ t,
                                                   const float* __restrict__ A,
                                                   const float* __restrict__ B,
                                                   float* __restrict__ xo,
                                                   float* __restrict__ emb, int embOff,
                                                   unsigned short* __restrict__ xB) {
  __shared__ unsigned short sT[32][34];
  const int tid = threadIdx.x;
  const int kb = blockIdx.x;
  const int c = tid & 31, g = tid >> 5;
  const float Ac = A[c], Bc = B[c];
#pragma unroll
  for (int ni = 0; ni < 4; ++ni) {
    const int n = kb * 32 + g * 4 + ni;
    const float v = fmaf(Ac, t[(size_t)n * HH + c], Bc);
    xo[(size_t)n * HH + c] = v;
    emb[(size_t)n * DD + embOff + c] = v;
    if (xB) sT[c][g * 4 + ni] = f2bf(v);
  }
  if (xB) {
    __syncthreads();
    if (tid < 128) {
      const int row = tid >> 2, seg = tid & 3;
      u16x8 o;
#pragma unroll
      for (int j = 0; j < 8; ++j) o[j] = sT[row][seg * 8 + j];
      *reinterpret_cast<u16x8*>(&xB[((size_t)kb * 32 + row) * 32 + seg * 8]) = o;
    }
  }
}

// ---------------- conv3 epilogue ----------------
__global__ __launch_bounds__(256) void k_epi3(const float* __restrict__ part,
                                              const float* __restrict__ W3r,
                                              const float* __restrict__ b3,
                                              const float* __restrict__ x2,
                                              const float* __restrict__ W3root,
                                              float* __restrict__ t3,
                                              float* __restrict__ colsum,
                                              float* __restrict__ colsq) {
  __shared__ float z[16][33];
  __shared__ float xr[16][33];
  const int row0 = blockIdx.x * 16;
  for (int s = threadIdx.x; s < 16 * 32; s += 256) {
    const int r = s >> 5, k = s & 31;
    float a = 0.f;
#pragma unroll
    for (int sp = 0; sp < KS; ++sp)
      a += part[(size_t)sp * (NN * HH) + (size_t)(row0 + r) * HH + k];
    z[r][k] = a;
    xr[r][k] = x2[(size_t)(row0 + r) * HH + k];
  }
  __syncthreads();
  const int c = threadIdx.x;
  if (c >= CC) return;
  float acc[16];
  const float bb = b3[c];
#pragma unroll
  for (int r = 0; r < 16; ++r) acc[r] = bb;
  for (int k = 0; k < 32; ++k) {
    const float w1 = W3r[k * CC + c];
    const float w2 = W3root[k * CC + c];
#pragma unroll
    for (int r = 0; r < 16; ++r) acc[r] += z[r][k] * w1 + xr[r][k] * w2;
  }
  float lsm = 0.f, lqm = 0.f;
#pragma unroll
  for (int r = 0; r < 16; ++r) {
    const float v = fmaxf(acc[r], 0.f);
    t3[(size_t)(row0 + r) * CC + c] = v;
    lsm += v;
    lqm += v * v;
  }
  atomicAdd(&colsum[c * 16], lsm);
  atomicAdd(&colsq[c * 16], lqm);
}

__global__ void k_bnapply205(const float* __restrict__ t3, const float* __restrict__ A,
                             const float* __restrict__ B, float* __restrict__ x3,
                             float* __restrict__ emb) {
  const int row = blockIdx.x;
  const int c = threadIdx.x;
  if (c >= CC) return;
  const float v = fmaf(A[c], t3[(size_t)row * CC + c], B[c]);
  x3[(size_t)row * CC + c] = v;
  emb[(size_t)row * DD + 2 * HH + c] = v;
}

// ---------------- logits via MFMA ----------------
__global__ __launch_bounds__(256) void k_logits(const unsigned short* __restrict__ embB,
                                                const unsigned short* __restrict__ Wl1T,
                                                float* __restrict__ logits) {
  __shared__ unsigned short sA[16][296];
  const int tid = threadIdx.x;
  const int row0 = blockIdx.x * 16;
  for (int p = tid; p < 576; p += 256) {
    const int r = p / 36, ch = p - r * 36;
    const u16x8 v = *reinterpret_cast<const u16x8*>(&embB[(size_t)(row0 + r) * DP + ch * 8]);
    *reinterpret_cast<u16x8*>(&sA[r][ch * 8]) = v;
  }
  __syncthreads();
  const int lane = tid & 63;
  const int w = tid >> 6;
  const int l15 = lane & 15;
  const int kgrp = (lane >> 4) * 8;
  f32x4 acc[4];
#pragma unroll
  for (int i = 0; i < 4; ++i) acc[i] = (f32x4){0.f, 0.f, 0.f, 0.f};
#pragma unroll
  for (int i = 0; i < 4; ++i) {
    const int ct = w + i * 4;
    if (ct < 13) {
      const size_t brow = (size_t)(ct * 16 + l15) * DP;
#pragma unroll
      for (int k0 = 0; k0 < DP; k0 += 32) {
        const bf16x8 a = *reinterpret_cast<const bf16x8*>(&sA[l15][k0 + kgrp]);
        const bf16x8 b = *reinterpret_cast<const bf16x8*>(&Wl1T[brow + k0 + kgrp]);
        acc[i] = __builtin_amdgcn_mfma_f32_16x16x32_bf16(a, b, acc[i], 0, 0, 0);
      }
    }
  }
  const int rout = row0 + (lane >> 4) * 4;
#pragma unroll
  for (int i = 0; i < 4; ++i) {
    const int ct = w + i * 4;
    if (ct < 13) {
#pragma unroll
      for (int r = 0; r < 4; ++r)
        logits[(size_t)(rout + r) * GP + ct * 16 + l15] = acc[i][r];
    }
  }
}

// ---------------- softmax head: logits -> s1, sn, s1B/snB tiles, snR rows, entropy ----------------
__global__ __launch_bounds__(256) void k_softmax(const float* __restrict__ logits,
                                                 const float* __restrict__ bl1,
                                                 float* __restrict__ s1,
                                                 float* __restrict__ sn,
                                                 unsigned short* __restrict__ s1B,
                                                 unsigned short* __restrict__ snB,
                                                 unsigned short* __restrict__ snR,
                                                 float* __restrict__ scalars) {
  __shared__ unsigned short sTa[8][212];
  __shared__ unsigned short sTb[8][212];
  __shared__ float redE[4];
  const int row0 = blockIdx.x * 8;
  const int tid = threadIdx.x;
  const int w = tid >> 6;
  const int lane = tid & 63;
  const int r0 = w * 2;
  const int c0 = lane * 4;
  const bool active = (c0 < GP);
  float bl[4];
#pragma unroll
  for (int j = 0; j < 4; ++j) bl[j] = (c0 + j < CC) ? bl1[c0 + j] : 0.f;
  float ent_acc = 0.f;
#pragma unroll
  for (int r = 0; r < 2; ++r) {
    const int row = row0 + r0 + r;
    float4 lg = {0.f, 0.f, 0.f, 0.f};
    if (active) lg = *reinterpret_cast<const float4*>(&logits[(size_t)row * GP + c0]);
    const float lgv[4] = {lg.x, lg.y, lg.z, lg.w};
    float v[4];
    float ml = -1e30f;
#pragma unroll
    for (int j = 0; j < 4; ++j) {
      const int c = c0 + j;
      v[j] = (c < CC) ? fmaxf(lgv[j] + bl[j], 0.f) : -1e30f;
      ml = fmaxf(ml, v[j]);
    }
    const float m = wave_max(ml);
    float e[4];
    float sl = 0.f;
#pragma unroll
    for (int j = 0; j < 4; ++j) {
      const int c = c0 + j;
      e[j] = (c < CC) ? __expf(v[j] - m) : 0.f;
      sl += e[j];
    }
    const float S = wave_sum(sl);
    const float invS = 1.f / S;
    float p[4];
    float ql = 0.f;
#pragma unroll
    for (int j = 0; j < 4; ++j) {
      p[j] = e[j] * invS;
      ql += p[j] * p[j];
    }
    const float q = wave_sum(ql);
    const float inv = 1.f / fmaxf(sqrtf(q), 1e-8f);
    float m2l = -1e30f;
#pragma unroll
    for (int j = 0; j < 4; ++j) {
      const int c = c0 + j;
      if (c < CC) {
        s1[(size_t)row * CC + c] = p[j];
        sn[(size_t)row * CC + c] = p[j] * inv;
        m2l = fmaxf(m2l, p[j]);
      }
    }
    if (active) {
#pragma unroll
      for (int j = 0; j < 4; ++j) {
        const int c = c0 + j;
        const bool ok = (c < CC);
        sTa[r0 + r][c] = ok ? f2bf(p[j]) : (unsigned short)0;
        sTb[r0 + r][c] = ok ? f2bf(p[j] * inv) : (unsigned short)0;
      }
    }
    if (c0 < GTS) {
      ushort4 o;
      o.x = (c0 + 0 < CC) ? f2bf(p[0] * inv) : (unsigned short)0;
      o.y = (c0 + 1 < CC) ? f2bf(p[1] * inv) : (unsigned short)0;
      o.z = (c0 + 2 < CC) ? f2bf(p[2] * inv) : (unsigned short)0;
      o.w = (c0 + 3 < CC) ? f2bf(p[3] * inv) : (unsigned short)0;
      *reinterpret_cast<ushort4*>(&snR[(size_t)row * GTS + c0]) = o;
    }
    const float m2 = wave_max(m2l);
    float e2[4];
    float s2l = 0.f;
#pragma unroll
    for (int j = 0; j < 4; ++j) {
      const int c = c0 + j;
      e2[j] = (c < CC) ? __expf(p[j] - m2) : 0.f;
      s2l += e2[j];
    }
    const float S2 = wave_sum(s2l);
    const float invS2 = 1.f / S2;
    float tl = 0.f;
#pragma unroll
    for (int j = 0; j < 4; ++j) {
      const int c = c0 + j;
      if (c < CC) {
        const float sp = e2[j] * invS2;
        tl -= sp * logf(sp + 1e-15f);
      }
    }
    ent_acc += tl;
  }
  ent_acc = wave_sum(ent_acc);
  if (lane == 0) redE[w] = ent_acc;
  __syncthreads();
  if (tid == 0) atomicAdd(&scalars[SC(2)], redE[0] + redE[1] + redE[2] + redE[3]);
  if (tid < GP) {
    const int kb = row0 >> 5, no = row0 & 31;
    u16x8 oa, ob;
#pragma unroll
    for (int r = 0; r < 8; ++r) { oa[r] = sTa[r][tid]; ob[r] = sTb[r][tid]; }
    *reinterpret_cast<u16x8*>(&s1B[((size_t)kb * GP + tid) * 32 + no]) = oa;
    *reinterpret_cast<u16x8*>(&snB[((size_t)kb * GP + tid) * 32 + no]) = ob;
  }
}

// ---------------- MFMA Gram: bf16 transposed GT outputs; gid==3 reduces sum(Gs0^2) in-kernel ----------------
__global__ __launch_bounds__(256) void k_gramm(const unsigned short* __restrict__ xnB,
                                               const unsigned short* __restrict__ snB,
                                               const unsigned short* __restrict__ s1B,
                                               unsigned short* __restrict__ GT0,
                                               unsigned short* __restrict__ GxsT,
                                               unsigned short* __restrict__ GsT,
                                               float* __restrict__ scalars) {
  const int gid = blockIdx.z;
  const int tp = blockIdx.x * 16;
  const int tq = blockIdx.y * 16;
  const unsigned short *PT, *QT;
  unsigned short* GTout = nullptr;
  if (gid == 0)      { PT = xnB; QT = xnB; GTout = GT0;  if (tp >= FF || tq >= FF) return; }
  else if (gid == 1) { PT = xnB; QT = snB; GTout = GxsT; if (tp >= FF) return; }
  else if (gid == 2) { PT = snB; QT = snB; GTout = GsT; }
  else               { PT = s1B; QT = s1B; }
  const int tid = threadIdx.x;
  const int lane = tid & 63;
  const int w = tid >> 6;
  const int l15 = lane & 15;
  const int kgrp = (lane >> 4) * 8;
  f32x4 acc = {0.f, 0.f, 0.f, 0.f};
#pragma unroll 8
  for (int kt = 0; kt < 32; ++kt) {
    const int kb = w * 32 + kt;
    const bf16x8 a = *reinterpret_cast<const bf16x8*>(&PT[((size_t)kb * GP + tp + l15) * 32 + kgrp]);
    const bf16x8 b = *reinterpret_cast<const bf16x8*>(&QT[((size_t)kb * GP + tq + l15) * 32 + kgrp]);
    acc = __builtin_amdgcn_mfma_f32_16x16x32_bf16(a, b, acc, 0, 0, 0);
  }
  __shared__ float red[4][16][17];
  const int crow = (lane >> 4) * 4;
#pragma unroll
  for (int r = 0; r < 4; ++r) red[w][crow + r][l15] = acc[r];
  __syncthreads();
  const int rr = tid >> 4, cc = tid & 15;
  if (gid == 3) {
    // reduce sum of squares of this Gs0 tile directly (no global tile write)
    const float v = red[0][rr][cc] + red[1][rr][cc] + red[2][rr][cc] + red[3][rr][cc];
    __shared__ float redq[4];
    float q = wave_sum(v * v);
    if (lane == 0) redq[w] = q;
    __syncthreads();
    if (tid == 0) atomicAdd(&scalars[SC(5)], redq[0] + redq[1] + redq[2] + redq[3]);
  } else {
    // transposed bf16: GT[(tq+rr)][tp+cc] = Cp[tp+cc][tq+rr]
    const float vt = red[0][cc][rr] + red[1][cc][rr] + red[2][cc][rr] + red[3][cc][rr];
    GTout[(size_t)(tq + rr) * GTS + (tp + cc)] = f2bf(vt);
  }
}

// ---------------- MFMA thin GEMMs: H = A @ Gram via GT[col][k] ----------------
__global__ __launch_bounds__(256) void k_rowmm3m(const unsigned short* __restrict__ xnR,
                                                 const unsigned short* __restrict__ snR,
                                                 const unsigned short* __restrict__ GT0,
                                                 const unsigned short* __restrict__ GxsT,
                                                 const unsigned short* __restrict__ GsT,
                                                 float* __restrict__ H1,
                                                 float* __restrict__ Uu,
                                                 float* __restrict__ H2) {
  const int gid = blockIdx.y;
  const unsigned short *A, *B;
  float* C;
  int K, As, NCT;
  if (gid == 0)      { A = xnR; B = GT0;  C = H1; K = FF;  As = FF;  NCT = 8; }
  else if (gid == 1) { A = xnR; B = GxsT; C = Uu; K = FF;  As = FF;  NCT = 13; }
  else               { A = snR; B = GsT;  C = H2; K = GTS; As = GTS; NCT = 13; }
  __shared__ unsigned short sA[16][232];
  const int tid = threadIdx.x;
  const int row0 = blockIdx.x * 16;
  const int nch = K >> 3;
  for (int p = tid; p < 16 * nch; p += 256) {
    const int r = p / nch, ch = p - r * nch;
    const u16x8 v = *reinterpret_cast<const u16x8*>(&A[(size_t)(row0 + r) * As + ch * 8]);
    *reinterpret_cast<u16x8*>(&sA[r][ch * 8]) = v;
  }
  __syncthreads();
  const int lane = tid & 63;
  const int w = tid >> 6;
  const int l15 = lane & 15;
  const int kgrp = (lane >> 4) * 8;
  f32x4 acc[4];
#pragma unroll
  for (int i = 0; i < 4; ++i) acc[i] = (f32x4){0.f, 0.f, 0.f, 0.f};
#pragma unroll
  for (int i = 0; i < 4; ++i) {
    const int ct = w + i * 4;
    if (ct < NCT) {
      const size_t brow = (size_t)(ct * 16 + l15) * GTS;
      for (int k0 = 0; k0 < K; k0 += 32) {
        const bf16x8 a = *reinterpret_cast<const bf16x8*>(&sA[l15][k0 + kgrp]);
        const bf16x8 b = *reinterpret_cast<const bf16x8*>(&B[brow + k0 + kgrp]);
        acc[i] = __builtin_amdgcn_mfma_f32_16x16x32_bf16(a, b, acc[i], 0, 0, 0);
      }
    }
  }
  const int rout = row0 + (lane >> 4) * 4;
#pragma unroll
  for (int i = 0; i < 4; ++i) {
    const int ct = w + i * 4;
    if (ct < NCT) {
#pragma unroll
      for (int r = 0; r < 4; ++r)
        C[(size_t)(rout + r) * HS + ct * 16 + l15] = acc[i][r];
    }
  }
}

// ---------------- per-row sim + team embedding loss (H arrays stride HS) ----------------
__global__ __launch_bounds__(256) void k_losses(const float* __restrict__ H1,
                                                const float* __restrict__ Uu,
                                                const float* __restrict__ H2,
                                                const float* __restrict__ xn,
                                                const float* __restrict__ sn,
                                                const float* __restrict__ emb,
                                                const int* __restrict__ teams,
                                                const int* __restrict__ reps,
                                                float* __restrict__ scalars) {
  __shared__ float red[4];
  const int tid = threadIdx.x;
  const int lane = tid & 63;
  const int w = tid >> 6;
  if (blockIdx.x < NN / 4) {
    const int row = blockIdx.x * 4 + w;
    float suu = 0.f, suv = 0.f, svv = 0.f;
#pragma unroll
    for (int c0 = 0; c0 < FF; c0 += 64) {
      const float xv = xn[(size_t)row * FF + c0 + lane];
      suu = fmaf(H1[(size_t)row * HS + c0 + lane], xv, suu);
    }
    for (int cb = lane; cb < CC; cb += 64) {
      const float sv = sn[(size_t)row * CC + cb];
      suv = fmaf(Uu[(size_t)row * HS + cb], sv, suv);
      svv = fmaf(H2[(size_t)row * HS + cb], sv, svv);
    }
    suu = wave_sum(suu);
    suv = wave_sum(suv);
    svv = wave_sum(svv);
    if (lane == 0) red[w] = suv / sqrtf(suu * svv);
    __syncthreads();
    if (tid == 0) atomicAdd(&scalars[SC(3)], red[0] + red[1] + red[2] + red[3]);
  } else {
    const int team = blockIdx.x - NN / 4;
    float part = 0.f;
    for (int d = tid; d < DD; d += 256) {
      float a = 0.f, b = 0.f;
#pragma unroll
      for (int m = 0; m < RR; ++m) a += emb[(size_t)reps[team * RR + m] * DD + d];
#pragma unroll
      for (int m = RR; m < TT; ++m) b += emb[(size_t)teams[team * TT + m] * DD + d];
      part += fabsf(a * (1.f / RR) - b * (1.f / (TT - RR)));
    }
    part = wave_sum(part);
    if (lane == 0) red[w] = part;
    __syncthreads();
    if (tid == 0) atomicAdd(&scalars[SC(4)], red[0] + red[1] + red[2] + red[3]);
  }
}

// ---------------- finalize (scalars only) ----------------
__global__ void k_final(const float* __restrict__ scalars, float* __restrict__ outsc) {
  if (threadIdx.x != 0) return;
  const float sumP2 = scalars[SC(5)];
  const float normsq = fmaxf(sumP2 - 2.f * scalars[SC(0)] + scalars[SC(1)], 0.f);
  const float norm = sqrtf(normsq);
  const float e1 = scalars[SC(2)] * (1.f / NN);
  const float sim = -scalars[SC(3)] * (1.f / NN);
  const float embl = scalars[SC(4)] * (1.f / LL);
  outsc[0] = norm;
  outsc[1] = e1;
  outsc[2] = sim;
  outsc[3] = 100.f * norm + 10.f * e1 + 100.f * sim + embl;
  outsc[4] = embl;
}

// ================= launch =================
extern "C" void kernel_launch(void* const* d_in, const int* in_sizes, int n_in,
                              void* d_out, int out_size, void* d_ws, size_t ws_size,
                              hipStream_t stream) {
  const float* x      = (const float*)d_in[0];
  const float* adj    = (const float*)d_in[1];
  const int*   teams  = (const int*)d_in[2];
  const int*   reps   = (const int*)d_in[3];
  const float* W1r    = (const float*)d_in[4];
  const float* b1     = (const float*)d_in[5];
  const float* W1root = (const float*)d_in[6];
  const float* g1     = (const float*)d_in[7];
  const float* be1    = (const float*)d_in[8];
  const float* W2r    = (const float*)d_in[9];
  const float* b2     = (const float*)d_in[10];
  const float* W2root = (const float*)d_in[11];
  const float* g2     = (const float*)d_in[12];
  const float* be2    = (const float*)d_in[13];
  const float* W3r    = (const float*)d_in[14];
  const float* b3     = (const float*)d_in[15];
  const float* W3root = (const float*)d_in[16];
  const float* g3     = (const float*)d_in[17];
  const float* be3    = (const float*)d_in[18];
  const float* Wl1    = (const float*)d_in[19];
  const float* bl1    = (const float*)d_in[20];

  char* wp = (char*)d_ws;
  auto alloc = [&](size_t bytes) { char* p = wp; wp += (bytes + 255) & ~(size_t)255; return p; };
  unsigned short* adj_t = (unsigned short*)alloc((size_t)NN * NN * 2);
  unsigned short* mB    = (unsigned short*)alloc((size_t)HH * NN * 2);
  unsigned short* x2B   = (unsigned short*)alloc((size_t)HH * NN * 2);
  unsigned short* s1B   = (unsigned short*)alloc((size_t)GP * NN * 2);
  unsigned short* snB   = (unsigned short*)alloc((size_t)GP * NN * 2);
  unsigned short* xnB   = (unsigned short*)alloc((size_t)GP * NN * 2);
  unsigned short* embB  = (unsigned short*)alloc((size_t)NN * DP * 2);
  unsigned short* Wl1T  = (unsigned short*)alloc((size_t)GP * DP * 2);
  unsigned short* xnR   = (unsigned short*)alloc((size_t)NN * FF * 2);
  unsigned short* snR   = (unsigned short*)alloc((size_t)NN * GTS * 2);
  unsigned short* GTall = (unsigned short*)alloc((size_t)3 * GP * GTS * 2);
  unsigned short* GT0   = GTall;
  unsigned short* GxsT  = GTall + (size_t)GP * GTS;
  unsigned short* GsT   = GTall + (size_t)2 * GP * GTS;
  float* logits = (float*)alloc((size_t)NN * GP * 4);
  float* rootb  = (float*)alloc((size_t)NN * HH * 4);
  float* t      = (float*)alloc((size_t)NN * HH * 4);
  float* x1     = (float*)alloc((size_t)NN * HH * 4);
  float* x2     = (float*)alloc((size_t)NN * HH * 4);
  float* part   = (float*)alloc((size_t)KS * NN * HH * 4);
  float* t3     = (float*)alloc((size_t)NN * CC * 4);
  float* x3     = (float*)alloc((size_t)NN * CC * 4);
  float* sn     = (float*)alloc((size_t)NN * CC * 4);
  float* xn     = (float*)alloc((size_t)NN * FF * 4);
  float* H1     = (float*)alloc((size_t)NN * HS * 4);
  float* Uu     = (float*)alloc((size_t)NN * HS * 4);
  float* H2     = (float*)alloc((size_t)NN * HS * 4);
  float* scalars = (float*)alloc(256 * 4);
  float* colsum = (float*)alloc(4096 * 4);
  float* colsq  = (float*)alloc(4096 * 4);
  float* bnA    = (float*)alloc(1024);
  float* bnB    = (float*)alloc(1024);
  (void)ws_size; (void)in_sizes; (void)n_in; (void)out_size;

  float* out   = (float*)d_out;
  float* s1    = out;                          // N*C
  float* outsc = out + (size_t)NN * CC;        // 5 scalars
  float* emb   = out + (size_t)NN * CC + 5;    // N*D

  // zero scalar accumulators + padded BN stats + xnB pad rows + GT buffers (pad zones)
  hipMemsetAsync(scalars, 0, 256 * 4, stream);
  hipMemsetAsync(colsum, 0, 2 * 4096 * 4, stream);
  hipMemsetAsync(xnB, 0, (size_t)GP * NN * 2, stream);
  hipMemsetAsync(GTall, 0, (size_t)3 * GP * GTS * 2, stream);

  k_padWT<<<(GP * DP + 255) / 256, 256, 0, stream>>>(Wl1, Wl1T);
  k_xn<<<NN / 4, 256, 0, stream>>>(x, xn, xnR);
  k_xnB<<<NN / 32, 256, 0, stream>>>(xn, xnB);

  // conv1 (fused: adj cvt->tiled + adj^2 + MFMA)
  k_proj_t<<<NN / 32, 256, 0, stream>>>(x, W1r, W1root, mB, rootb, FF);
  k_conv1f<<<dim3(NN / 64, KS), 256, 0, stream>>>(adj, adj_t, mB, part, scalars);
  k_epi32<<<NN * HH / 256, 256, 0, stream>>>(part, b1, rootb, t, colsum, colsq);
  k_bnfinal<<<1, 256, 0, stream>>>(colsum, colsq, g1, be1, bnA, bnB, HH);
  k_bnapply32<<<NN / 32, 256, 0, stream>>>(t, bnA, bnB, x1, emb, 0, (unsigned short*)nullptr);

  // conv2
  k_proj_t<<<NN / 32, 256, 0, stream>>>(x1, W2r, W2root, mB, rootb, HH);
  k_adjmm<<<dim3(NN / 64, KS), 256, 0, stream>>>(adj_t, mB, part);
  k_epi32<<<NN * HH / 256, 256, 0, stream>>>(part, b2, rootb, t, colsum, colsq);
  k_bnfinal<<<1, 256, 0, stream>>>(colsum, colsq, g2, be2, bnA, bnB, HH);
  k_bnapply32<<<NN / 32, 256, 0, stream>>>(t, bnA, bnB, x2, emb, HH, x2B);

  // conv3
  k_adjmm<<<dim3(NN / 64, KS), 256, 0, stream>>>(adj_t, x2B, part);
  k_epi3<<<NN / 16, 256, 0, stream>>>(part, W3r, b3, x2, W3root, t3, colsum, colsq);
  k_bnfinal<<<1, 256, 0, stream>>>(colsum, colsq, g3, be3, bnA, bnB, CC);
  k_bnapply205<<<NN, 256, 0, stream>>>(t3, bnA, bnB, x3, emb);

  // head: emb -> bf16, MFMA logits, streaming softmax
  k_embB<<<NN * DP / 256, 256, 0, stream>>>(emb, embB);
  k_logits<<<NN / 16, 256, 0, stream>>>(embB, Wl1T, logits);
  k_softmax<<<NN / 8, 256, 0, stream>>>(logits, bl1, s1, sn, s1B, snB, snR, scalars);

  // tr(S' A S) via MFMA (LDS-staged B, double-buffered)
  k_normmfma<<<dim3(NN / 128, KS), 512, 0, stream>>>(adj_t, s1B, s1, scalars);

  // Grams (bf16 transposed outputs; Gs0^2 reduced in-kernel) + MFMA bilinear forms + losses
  k_gramm<<<dim3(13, 13, 4), 256, 0, stream>>>(xnB, snB, s1B, GT0, GxsT, GsT, scalars);
  k_rowmm3m<<<dim3(NN / 16, 3), 256, 0, stream>>>(xnR, snR, GT0, GxsT, GsT, H1, Uu, H2);
  k_losses<<<NN / 4 + LL, 256, 0, stream>>>(H1, Uu, H2, xn, sn, emb, teams, reps, scalars);
  k_final<<<1, 64, 0, stream>>>(scalars, outsc);
}

// Round 12
// 231.707 us; speedup vs baseline: 3.9922x; 1.0369x over previous
//
#include <hip/hip_runtime.h>
#include <math.h>

#define NN 4096
#define FF 128
#define HH 32
#define CC 205
#define DD 269
#define LL 512
#define TT 12
#define RR 4
#define KS 16    // k-split for all adj MFMA passes
#define GP 208   // padded gram dim
#define DP 288   // padded D (k) dim for logits MFMA
#define BST 40   // padded LDS row stride (ushorts) for B tiles
#define GTS 224  // transposed-gram row stride / padded K
#define HS 208   // H1/Uu/H2 row stride (floats)
#define NLOSS (NN / 4 + LL)

// padded scalar slots: 0=trSAS 1=adjsq 2=entropy 3=sim 4=embloss 5=sumP2 6=ticket
#define SC(i) ((i) * 32)

typedef __attribute__((ext_vector_type(8))) short bf16x8;
typedef __attribute__((ext_vector_type(4))) float f32x4;
typedef __attribute__((ext_vector_type(8))) unsigned short u16x8;

// ---------------- helpers ----------------
__device__ __forceinline__ float wave_sum(float v) {
#pragma unroll
  for (int o = 32; o > 0; o >>= 1) v += __shfl_xor(v, o, 64);
  return v;
}
__device__ __forceinline__ float wave_max(float v) {
#pragma unroll
  for (int o = 32; o > 0; o >>= 1) v = fmaxf(v, __shfl_xor(v, o, 64));
  return v;
}
__device__ __forceinline__ unsigned short f2bf(float x) {  // RNE
  union { float f; unsigned u; } v; v.f = x;
  unsigned r = v.u + 0x7FFFu + ((v.u >> 16) & 1u);
  return (unsigned short)(r >> 16);
}

// ---------------- fused prep: [blocks 0..127] conv1 dual projection; [128..255] xn/xnR/xnB; all: Wl1T fill ----------------
__global__ __launch_bounds__(256) void k_prep(const float* __restrict__ x,
                                              const float* __restrict__ W1r,
                                              const float* __restrict__ W1root,
                                              const float* __restrict__ Wl1,
                                              unsigned short* __restrict__ mB,
                                              float* __restrict__ rootb,
                                              float* __restrict__ xn,
                                              unsigned short* __restrict__ xnR,
                                              unsigned short* __restrict__ xnB,
                                              unsigned short* __restrict__ Wl1T) {
  __shared__ float sX[32][132];
  __shared__ unsigned short sT[32][34];
  __shared__ unsigned short sT2[FF][34];
  const int tid = threadIdx.x;
  // Wl1T fill (grid-strided once; 59904 < 65536)
  {
    const int i = blockIdx.x * 256 + tid;
    if (i < GP * DP) {
      const int c = i / DP, k = i - c * DP;
      Wl1T[i] = (c < CC && k < DD) ? f2bf(Wl1[(size_t)k * CC + c]) : (unsigned short)0;
    }
  }
  if (blockIdx.x < 128) {
    // dual projection: mB tiles = (x@W1r)^T bf16, rootb = x@W1root
    const int kb = blockIdx.x;
    for (int p = tid; p < 1024; p += 256) {
      const int node = p >> 5, c4 = p & 31;
      const float4 v = *reinterpret_cast<const float4*>(&x[((size_t)(kb * 32 + node)) * FF + c4 * 4]);
      sX[node][c4 * 4 + 0] = v.x; sX[node][c4 * 4 + 1] = v.y;
      sX[node][c4 * 4 + 2] = v.z; sX[node][c4 * 4 + 3] = v.w;
    }
    __syncthreads();
    const int c = tid & 31, g = tid >> 5;
    float a1[4] = {0.f, 0.f, 0.f, 0.f}, a2[4] = {0.f, 0.f, 0.f, 0.f};
    for (int k = 0; k < FF; ++k) {
      const float w1 = W1r[k * HH + c];
      const float w2 = W1root[k * HH + c];
#pragma unroll
      for (int ni = 0; ni < 4; ++ni) {
        const float av = sX[g * 4 + ni][k];
        a1[ni] = fmaf(av, w1, a1[ni]);
        a2[ni] = fmaf(av, w2, a2[ni]);
      }
    }
#pragma unroll
    for (int ni = 0; ni < 4; ++ni) {
      rootb[((size_t)kb * 32 + g * 4 + ni) * HH + c] = a2[ni];
      sT[c][g * 4 + ni] = f2bf(a1[ni]);
    }
    __syncthreads();
    if (tid < 128) {
      const int row = tid >> 2, seg = tid & 3;
      u16x8 v;
#pragma unroll
      for (int j = 0; j < 8; ++j) v[j] = sT[row][seg * 8 + j];
      *reinterpret_cast<u16x8*>(&mB[((size_t)kb * 32 + row) * 32 + seg * 8]) = v;
    }
  } else {
    // row-normalize 32 rows + bf16 row copy + tiled xnB
    const int kb = blockIdx.x - 128;
    const int lane = tid & 63;
    const int w = tid >> 6;
#pragma unroll
    for (int i = 0; i < 8; ++i) {
      const int node = w * 8 + i;
      const int row = kb * 32 + node;
      const float v0 = x[(size_t)row * FF + lane];
      const float v1 = x[(size_t)row * FF + 64 + lane];
      const float ss = wave_sum(v0 * v0 + v1 * v1);
      const float n = fmaxf(sqrtf(ss), 1e-8f);
      const float a = v0 / n, b = v1 / n;
      xn[(size_t)row * FF + lane] = a;
      xn[(size_t)row * FF + 64 + lane] = b;
      xnR[(size_t)row * FF + lane] = f2bf(a);
      xnR[(size_t)row * FF + 64 + lane] = f2bf(b);
      sT2[lane][node] = f2bf(a);
      sT2[64 + lane][node] = f2bf(b);
    }
    __syncthreads();
    const int rowc = tid >> 1, seg = (tid & 1) * 16;
    if (rowc < FF) {
      u16x8 a, b;
#pragma unroll
      for (int j = 0; j < 8; ++j) { a[j] = sT2[rowc][seg + j]; b[j] = sT2[rowc][seg + 8 + j]; }
      *reinterpret_cast<u16x8*>(&xnB[((size_t)kb * GP + rowc) * 32 + seg]) = a;
      *reinterpret_cast<u16x8*>(&xnB[((size_t)kb * GP + rowc) * 32 + seg + 8]) = b;
    }
  }
}

// ---------------- dual projection (conv2): mB tiles = (A@W1)^T, o2 = A@W2 ----------------
__global__ __launch_bounds__(256) void k_proj_t(const float* __restrict__ A,
                                                const float* __restrict__ W1,
                                                const float* __restrict__ W2,
                                                unsigned short* __restrict__ mB,
                                                float* __restrict__ o2, int K) {
  __shared__ float sX[32][132];
  __shared__ unsigned short sT[32][34];
  const int tid = threadIdx.x;
  const int kb = blockIdx.x;
  const int nf4 = K >> 2;
  const int tot4 = 32 * nf4;
  for (int p = tid; p < tot4; p += 256) {
    const int node = p / nf4, c4 = p - node * nf4;
    const float4 v = *reinterpret_cast<const float4*>(&A[((size_t)(kb * 32 + node)) * K + c4 * 4]);
    sX[node][c4 * 4 + 0] = v.x; sX[node][c4 * 4 + 1] = v.y;
    sX[node][c4 * 4 + 2] = v.z; sX[node][c4 * 4 + 3] = v.w;
  }
  __syncthreads();
  const int c = tid & 31, g = tid >> 5;
  float a1[4] = {0.f, 0.f, 0.f, 0.f}, a2[4] = {0.f, 0.f, 0.f, 0.f};
  for (int k = 0; k < K; ++k) {
    const float w1 = W1[k * HH + c];
    const float w2 = W2[k * HH + c];
#pragma unroll
    for (int ni = 0; ni < 4; ++ni) {
      const float av = sX[g * 4 + ni][k];
      a1[ni] = fmaf(av, w1, a1[ni]);
      a2[ni] = fmaf(av, w2, a2[ni]);
    }
  }
#pragma unroll
  for (int ni = 0; ni < 4; ++ni) {
    o2[((size_t)kb * 32 + g * 4 + ni) * HH + c] = a2[ni];
    sT[c][g * 4 + ni] = f2bf(a1[ni]);
  }
  __syncthreads();
  if (tid < 128) {
    const int row = tid >> 2, seg = tid & 3;
    u16x8 v;
#pragma unroll
    for (int j = 0; j < 8; ++j) v[j] = sT[row][seg * 8 + j];
    *reinterpret_cast<u16x8*>(&mB[((size_t)kb * 32 + row) * 32 + seg * 8]) = v;
  }
}

// ---------------- FUSED conv1: fp32 adj -> bf16 tiled adj_t + sum(adj^2) + MFMA ----------------
__global__ __launch_bounds__(256) void k_conv1f(const float* __restrict__ adj,
                                                unsigned short* __restrict__ adj_t,
                                                const unsigned short* __restrict__ mB,
                                                float* __restrict__ part,
                                                float* __restrict__ scalars) {
  __shared__ unsigned short sA[64][264];
  __shared__ float red[4];
  const int tid = threadIdx.x;
  const int rbase_blk = blockIdx.x * 64;
  const int kbase = blockIdx.y * 256;
  const int rb0 = blockIdx.x * 4;
  const int kb0 = blockIdx.y * 8;
  const int lane = tid & 63;
  const int w = tid >> 6;
  const int l15 = lane & 15;
  const int kgrp = (lane >> 4) * 8;
  bf16x8 bb0[8], bb1[8];
#pragma unroll
  for (int kt = 0; kt < 8; ++kt) {
    const size_t boff = ((size_t)(kb0 + kt) * 32) * 32;
    bb0[kt] = *reinterpret_cast<const bf16x8*>(&mB[boff + (size_t)l15 * 32 + kgrp]);
    bb1[kt] = *reinterpret_cast<const bf16x8*>(&mB[boff + (size_t)(16 + l15) * 32 + kgrp]);
  }
  float adjsq = 0.f;
#pragma unroll
  for (int i = 0; i < 16; ++i) {
    const int fi = i * 256 + tid;
    const int r = fi >> 6;
    const int c4 = fi & 63;
    const size_t goff = (size_t)(rbase_blk + r) * NN + kbase + c4 * 4;
    const float4 v = *reinterpret_cast<const float4*>(&adj[goff]);
    adjsq += v.x * v.x + v.y * v.y + v.z * v.z + v.w * v.w;
    ushort4 h;
    h.x = f2bf(v.x); h.y = f2bf(v.y); h.z = f2bf(v.z); h.w = f2bf(v.w);
    const size_t toff = ((size_t)(rb0 + (r >> 4)) * (NN / 32) + kb0 + (c4 >> 3)) * 512 +
                        (r & 15) * 32 + (c4 & 7) * 4;
    *reinterpret_cast<ushort4*>(&adj_t[toff]) = h;
    *reinterpret_cast<ushort4*>(&sA[r][c4 * 4]) = h;
  }
  __syncthreads();
  const int rloc = w * 16 + l15;
  f32x4 acc0 = {0.f, 0.f, 0.f, 0.f}, acc1 = {0.f, 0.f, 0.f, 0.f};
#pragma unroll
  for (int k0 = 0; k0 < 256; k0 += 32) {
    const bf16x8 a = *reinterpret_cast<const bf16x8*>(&sA[rloc][k0 + kgrp]);
    acc0 = __builtin_amdgcn_mfma_f32_16x16x32_bf16(a, bb0[k0 >> 5], acc0, 0, 0, 0);
    acc1 = __builtin_amdgcn_mfma_f32_16x16x32_bf16(a, bb1[k0 >> 5], acc1, 0, 0, 0);
  }
  float* pp = part + (size_t)blockIdx.y * (NN * HH);
  const int rout = rbase_blk + w * 16 + (lane >> 4) * 4;
#pragma unroll
  for (int r = 0; r < 4; ++r) {
    pp[(size_t)(rout + r) * HH + l15] = acc0[r];
    pp[(size_t)(rout + r) * HH + 16 + l15] = acc1[r];
  }
  adjsq = wave_sum(adjsq);
  if (lane == 0) red[w] = adjsq;
  __syncthreads();
  if (tid == 0) atomicAdd(&scalars[SC(1)], red[0] + red[1] + red[2] + red[3]);
}

// ---------------- MFMA adj pass (register-hoisted) ----------------
__global__ __launch_bounds__(256) void k_adjmm(const unsigned short* __restrict__ adj_t,
                                               const unsigned short* __restrict__ mB,
                                               float* __restrict__ part) {
  const int tid = threadIdx.x;
  const int lane = tid & 63;
  const int w = tid >> 6;
  const int rb = blockIdx.x * 4 + w;
  const int kb0 = blockIdx.y * 8;
  const int l15 = lane & 15;
  const int kgrp = (lane >> 4) * 8;
  bf16x8 a[8], b0[8], b1[8];
#pragma unroll
  for (int kt = 0; kt < 8; ++kt) {
    const size_t aoff = ((size_t)rb * (NN / 32) + kb0 + kt) * 512;
    const size_t boff = ((size_t)(kb0 + kt) * 32) * 32;
    a[kt] = *reinterpret_cast<const bf16x8*>(&adj_t[aoff + l15 * 32 + kgrp]);
    b0[kt] = *reinterpret_cast<const bf16x8*>(&mB[boff + (size_t)l15 * 32 + kgrp]);
    b1[kt] = *reinterpret_cast<const bf16x8*>(&mB[boff + (size_t)(16 + l15) * 32 + kgrp]);
  }
  f32x4 acc0 = {0.f, 0.f, 0.f, 0.f}, acc1 = {0.f, 0.f, 0.f, 0.f};
#pragma unroll
  for (int kt = 0; kt < 8; ++kt) {
    acc0 = __builtin_amdgcn_mfma_f32_16x16x32_bf16(a[kt], b0[kt], acc0, 0, 0, 0);
    acc1 = __builtin_amdgcn_mfma_f32_16x16x32_bf16(a[kt], b1[kt], acc1, 0, 0, 0);
  }
  float* pp = part + (size_t)blockIdx.y * (NN * HH);
  const int rout = rb * 16 + (lane >> 4) * 4;
#pragma unroll
  for (int r = 0; r < 4; ++r) {
    pp[(size_t)(rout + r) * HH + l15] = acc0[r];
    pp[(size_t)(rout + r) * HH + 16 + l15] = acc1[r];
  }
}

// ---------------- MFMA norm pass: LDS-staged B (double-buffered) ----------------
__global__ __launch_bounds__(512) void k_normmfma(const unsigned short* __restrict__ adj_t,
                                                  const unsigned short* __restrict__ s1B,
                                                  const float* __restrict__ s1,
                                                  float* __restrict__ scalars) {
  __shared__ unsigned short sB[2][13][16][BST];
  __shared__ float red[8];
  const int tid = threadIdx.x;
  const int lane = tid & 63;
  const int w = tid >> 6;
  const int rb = blockIdx.x * 8 + w;
  const int kb0 = blockIdx.y * 8;
  const int l15 = lane & 15;
  const int g = lane >> 4;
  const int kgrp = g * 8;
  const int p0 = tid;
  const int ct0 = p0 >> 6, rr0 = (p0 >> 2) & 15, sg0 = (p0 & 3) * 8;
  const int p1 = tid + 512;
  const bool v1 = (p1 < 832);
  const int ct1 = p1 >> 6, rr1 = (p1 >> 2) & 15, sg1 = (p1 & 3) * 8;

  f32x4 acc[13];
#pragma unroll
  for (int ct = 0; ct < 13; ++ct) acc[ct] = (f32x4){0.f, 0.f, 0.f, 0.f};

  u16x8 st0, st1;
  st0 = *reinterpret_cast<const u16x8*>(&s1B[((size_t)kb0 * GP + ct0 * 16 + rr0) * 32 + sg0]);
  if (v1) st1 = *reinterpret_cast<const u16x8*>(&s1B[((size_t)kb0 * GP + ct1 * 16 + rr1) * 32 + sg1]);
  *reinterpret_cast<u16x8*>(&sB[0][ct0][rr0][sg0]) = st0;
  if (v1) *reinterpret_cast<u16x8*>(&sB[0][ct1][rr1][sg1]) = st1;
  __syncthreads();

  bf16x8 a = *reinterpret_cast<const bf16x8*>(
      &adj_t[((size_t)rb * (NN / 32) + kb0) * 512 + l15 * 32 + kgrp]);

  for (int kt = 0; kt < 8; ++kt) {
    const int cur = kt & 1;
    if (kt < 7) {
      const size_t kb = kb0 + kt + 1;
      st0 = *reinterpret_cast<const u16x8*>(&s1B[(kb * GP + ct0 * 16 + rr0) * 32 + sg0]);
      if (v1) st1 = *reinterpret_cast<const u16x8*>(&s1B[(kb * GP + ct1 * 16 + rr1) * 32 + sg1]);
    }
    bf16x8 a_next = a;
    if (kt < 7)
      a_next = *reinterpret_cast<const bf16x8*>(
          &adj_t[((size_t)rb * (NN / 32) + kb0 + kt + 1) * 512 + l15 * 32 + kgrp]);
#pragma unroll
    for (int ct = 0; ct < 13; ++ct) {
      const bf16x8 b = *reinterpret_cast<const bf16x8*>(&sB[cur][ct][l15][kgrp]);
      acc[ct] = __builtin_amdgcn_mfma_f32_16x16x32_bf16(a, b, acc[ct], 0, 0, 0);
    }
    if (kt < 7) {
      *reinterpret_cast<u16x8*>(&sB[cur ^ 1][ct0][rr0][sg0]) = st0;
      if (v1) *reinterpret_cast<u16x8*>(&sB[cur ^ 1][ct1][rr1][sg1]) = st1;
    }
    __syncthreads();
    a = a_next;
  }
  const int rout = rb * 16 + g * 4;
  float sc = 0.f;
#pragma unroll
  for (int ct = 0; ct < 13; ++ct) {
    const int col = ct * 16 + l15;
    if (col < CC) {
#pragma unroll
      for (int r = 0; r < 4; ++r)
        sc = fmaf(acc[ct][r], s1[(size_t)(rout + r) * CC + col], sc);
    }
  }
  sc = wave_sum(sc);
  if (lane == 0) red[w] = sc;
  __syncthreads();
  if (tid == 0) {
    float s = 0.f;
#pragma unroll
    for (int i = 0; i < 8; ++i) s += red[i];
    atomicAdd(&scalars[SC(0)], s);
  }
}

// ---------------- conv epilogue (32-wide) ----------------
__global__ __launch_bounds__(256) void k_epi32(const float* __restrict__ part,
                                               const float* __restrict__ bias,
                                               const float* __restrict__ root,
                                               float* __restrict__ t,
                                               float* __restrict__ colsum,
                                               float* __restrict__ colsq) {
  __shared__ float ls[HH], lq[HH];
  const int tid = threadIdx.x;
  const int idx = blockIdx.x * 256 + tid;
  const int c = idx & (HH - 1);
  if (tid < HH) { ls[tid] = 0.f; lq[tid] = 0.f; }
  __syncthreads();
  float s = bias[c] + root[idx];
#pragma unroll
  for (int sp = 0; sp < KS; ++sp) s += part[(size_t)sp * (NN * HH) + idx];
  s = fmaxf(s, 0.f);
  t[idx] = s;
  atomicAdd(&ls[c], s);
  atomicAdd(&lq[c], s * s);
  __syncthreads();
  if (tid < HH) {
    atomicAdd(&colsum[tid * 16], ls[tid]);
    atomicAdd(&colsq[tid * 16], lq[tid]);
  }
}

// ---------------- bn apply (32-wide), inline A/B + optional bf16 tiled copy ----------------
__global__ __launch_bounds__(256) void k_bnapply32(const float* __restrict__ t,
                                                   const float* __restrict__ colsum,
                                                   const float* __restrict__ colsq,
                                                   const float* __restrict__ g,
                                                   const float* __restrict__ be,
                                                   float* __restrict__ xo,
                                                   float* __restrict__ emb, int embOff,
                                                   unsigned short* __restrict__ xB) {
  __shared__ unsigned short sT[32][34];
  const int tid = threadIdx.x;
  const int kb = blockIdx.x;
  const int c = tid & 31, gq = tid >> 5;
  const float m = colsum[c * 16] * (1.f / NN);
  const float var = fmaxf(colsq[c * 16] * (1.f / NN) - m * m, 0.f);
  const float Ac = g[c] / sqrtf(var + 1e-5f);
  const float Bc = be[c] - m * Ac;
#pragma unroll
  for (int ni = 0; ni < 4; ++ni) {
    const int n = kb * 32 + gq * 4 + ni;
    const float v = fmaf(Ac, t[(size_t)n * HH + c], Bc);
    xo[(size_t)n * HH + c] = v;
    emb[(size_t)n * DD + embOff + c] = v;
    if (xB) sT[c][gq * 4 + ni] = f2bf(v);
  }
  if (xB) {
    __syncthreads();
    if (tid < 128) {
      const int row = tid >> 2, seg = tid & 3;
      u16x8 o;
#pragma unroll
      for (int j = 0; j < 8; ++j) o[j] = sT[row][seg * 8 + j];
      *reinterpret_cast<u16x8*>(&xB[((size_t)kb * 32 + row) * 32 + seg * 8]) = o;
    }
  }
}

// ---------------- conv3 epilogue ----------------
__global__ __launch_bounds__(256) void k_epi3(const float* __restrict__ part,
                                              const float* __restrict__ W3r,
                                              const float* __restrict__ b3,
                                              const float* __restrict__ x2,
                                              const float* __restrict__ W3root,
                                              float* __restrict__ t3,
                                              float* __restrict__ colsum,
                                              float* __restrict__ colsq) {
  __shared__ float z[16][33];
  __shared__ float xr[16][33];
  const int row0 = blockIdx.x * 16;
  for (int s = threadIdx.x; s < 16 * 32; s += 256) {
    const int r = s >> 5, k = s & 31;
    float a = 0.f;
#pragma unroll
    for (int sp = 0; sp < KS; ++sp)
      a += part[(size_t)sp * (NN * HH) + (size_t)(row0 + r) * HH + k];
    z[r][k] = a;
    xr[r][k] = x2[(size_t)(row0 + r) * HH + k];
  }
  __syncthreads();
  const int c = threadIdx.x;
  if (c >= CC) return;
  float acc[16];
  const float bb = b3[c];
#pragma unroll
  for (int r = 0; r < 16; ++r) acc[r] = bb;
  for (int k = 0; k < 32; ++k) {
    const float w1 = W3r[k * CC + c];
    const float w2 = W3root[k * CC + c];
#pragma unroll
    for (int r = 0; r < 16; ++r) acc[r] += z[r][k] * w1 + xr[r][k] * w2;
  }
  float lsm = 0.f, lqm = 0.f;
#pragma unroll
  for (int r = 0; r < 16; ++r) {
    const float v = fmaxf(acc[r], 0.f);
    t3[(size_t)(row0 + r) * CC + c] = v;
    lsm += v;
    lqm += v * v;
  }
  atomicAdd(&colsum[c * 16], lsm);
  atomicAdd(&colsq[c * 16], lqm);
}

// ---------------- bn apply 205 (inline A/B; writes emb only) ----------------
__global__ void k_bnapply205(const float* __restrict__ t3,
                             const float* __restrict__ colsum,
                             const float* __restrict__ colsq,
                             const float* __restrict__ g, const float* __restrict__ be,
                             float* __restrict__ emb) {
  const int row = blockIdx.x;
  const int c = threadIdx.x;
  if (c >= CC) return;
  const float m = colsum[c * 16] * (1.f / NN);
  const float var = fmaxf(colsq[c * 16] * (1.f / NN) - m * m, 0.f);
  const float Ac = g[c] / sqrtf(var + 1e-5f);
  const float Bc = be[c] - m * Ac;
  emb[(size_t)row * DD + 2 * HH + c] = fmaf(Ac, t3[(size_t)row * CC + c], Bc);
}

// ---------------- fused head: emb->bf16 LDS, MFMA logits->LDS, softmax -> s1/sn/tiles/snR/entropy ----------------
// grid NN/16; 16 rows per block; 4 waves
__global__ __launch_bounds__(256) void k_head(const float* __restrict__ emb,
                                              const unsigned short* __restrict__ Wl1T,
                                              const float* __restrict__ bl1,
                                              float* __restrict__ s1,
                                              float* __restrict__ sn,
                                              unsigned short* __restrict__ s1B,
                                              unsigned short* __restrict__ snB,
                                              unsigned short* __restrict__ snR,
                                              float* __restrict__ scalars) {
  __shared__ unsigned short sA[16][296];
  __shared__ float lg[16][212];
  __shared__ unsigned short sTa[16][212];
  __shared__ unsigned short sTb[16][212];
  __shared__ float redE[4];
  const int tid = threadIdx.x;
  const int row0 = blockIdx.x * 16;
  // stage emb fp32 -> bf16 LDS (pad 269..287 zero)
  for (int p = tid; p < 16 * 36; p += 256) {
    const int r = p / 36, ch = p - r * 36;
#pragma unroll
    for (int j = 0; j < 8; ++j) {
      const int d = ch * 8 + j;
      const float v = (d < DD) ? emb[(size_t)(row0 + r) * DD + d] : 0.f;
      sA[r][d] = f2bf(v);
    }
  }
  __syncthreads();
  const int lane = tid & 63;
  const int w = tid >> 6;
  const int l15 = lane & 15;
  const int kgrp = (lane >> 4) * 8;
  // MFMA logits into LDS
  {
    f32x4 acc[4];
#pragma unroll
    for (int i = 0; i < 4; ++i) acc[i] = (f32x4){0.f, 0.f, 0.f, 0.f};
#pragma unroll
    for (int i = 0; i < 4; ++i) {
      const int ct = w + i * 4;
      if (ct < 13) {
        const size_t brow = (size_t)(ct * 16 + l15) * DP;
#pragma unroll
        for (int k0 = 0; k0 < DP; k0 += 32) {
          const bf16x8 a = *reinterpret_cast<const bf16x8*>(&sA[l15][k0 + kgrp]);
          const bf16x8 b = *reinterpret_cast<const bf16x8*>(&Wl1T[brow + k0 + kgrp]);
          acc[i] = __builtin_amdgcn_mfma_f32_16x16x32_bf16(a, b, acc[i], 0, 0, 0);
        }
      }
    }
    const int lrow = (lane >> 4) * 4;
#pragma unroll
    for (int i = 0; i < 4; ++i) {
      const int ct = w + i * 4;
      if (ct < 13) {
#pragma unroll
        for (int r = 0; r < 4; ++r) lg[lrow + r][ct * 16 + l15] = acc[i][r];
      }
    }
  }
  __syncthreads();
  // wave-parallel softmax: wave owns 4 rows; lane owns cols {4*lane..4*lane+3}
  const int r0 = w * 4;
  const int c0 = lane * 4;
  const bool active = (c0 < GP);
  float bl[4];
#pragma unroll
  for (int j = 0; j < 4; ++j) bl[j] = (c0 + j < CC) ? bl1[c0 + j] : 0.f;
  float ent_acc = 0.f;
#pragma unroll
  for (int r = 0; r < 4; ++r) {
    const int lr = r0 + r;
    const int row = row0 + lr;
    float lgv[4] = {0.f, 0.f, 0.f, 0.f};
    if (active) {
#pragma unroll
      for (int j = 0; j < 4; ++j) lgv[j] = lg[lr][c0 + j];
    }
    float v[4];
    float ml = -1e30f;
#pragma unroll
    for (int j = 0; j < 4; ++j) {
      const int c = c0 + j;
      v[j] = (c < CC) ? fmaxf(lgv[j] + bl[j], 0.f) : -1e30f;
      ml = fmaxf(ml, v[j]);
    }
    const float m = wave_max(ml);
    float e[4];
    float sl = 0.f;
#pragma unroll
    for (int j = 0; j < 4; ++j) {
      const int c = c0 + j;
      e[j] = (c < CC) ? __expf(v[j] - m) : 0.f;
      sl += e[j];
    }
    const float S = wave_sum(sl);
    const float invS = 1.f / S;
    float p[4];
    float ql = 0.f;
#pragma unroll
    for (int j = 0; j < 4; ++j) {
      p[j] = e[j] * invS;
      ql += p[j] * p[j];
    }
    const float q = wave_sum(ql);
    const float inv = 1.f / fmaxf(sqrtf(q), 1e-8f);
    float m2l = -1e30f;
#pragma unroll
    for (int j = 0; j < 4; ++j) {
      const int c = c0 + j;
      if (c < CC) {
        s1[(size_t)row * CC + c] = p[j];
        sn[(size_t)row * CC + c] = p[j] * inv;
        m2l = fmaxf(m2l, p[j]);
      }
    }
    if (active) {
#pragma unroll
      for (int j = 0; j < 4; ++j) {
        const int c = c0 + j;
        const bool ok = (c < CC);
        sTa[lr][c] = ok ? f2bf(p[j]) : (unsigned short)0;
        sTb[lr][c] = ok ? f2bf(p[j] * inv) : (unsigned short)0;
      }
    }
    if (c0 < GTS) {
      ushort4 o;
      o.x = (c0 + 0 < CC) ? f2bf(p[0] * inv) : (unsigned short)0;
      o.y = (c0 + 1 < CC) ? f2bf(p[1] * inv) : (unsigned short)0;
      o.z = (c0 + 2 < CC) ? f2bf(p[2] * inv) : (unsigned short)0;
      o.w = (c0 + 3 < CC) ? f2bf(p[3] * inv) : (unsigned short)0;
      *reinterpret_cast<ushort4*>(&snR[(size_t)row * GTS + c0]) = o;
    }
    const float m2 = wave_max(m2l);
    float e2[4];
    float s2l = 0.f;
#pragma unroll
    for (int j = 0; j < 4; ++j) {
      const int c = c0 + j;
      e2[j] = (c < CC) ? __expf(p[j] - m2) : 0.f;
      s2l += e2[j];
    }
    const float S2 = wave_sum(s2l);
    const float invS2 = 1.f / S2;
    float tl = 0.f;
#pragma unroll
    for (int j = 0; j < 4; ++j) {
      const int c = c0 + j;
      if (c < CC) {
        const float sp = e2[j] * invS2;
        tl -= sp * logf(sp + 1e-15f);
      }
    }
    ent_acc += tl;
  }
  ent_acc = wave_sum(ent_acc);
  if (lane == 0) redE[w] = ent_acc;
  __syncthreads();
  if (tid == 0) atomicAdd(&scalars[SC(2)], redE[0] + redE[1] + redE[2] + redE[3]);
  // tiled write-out: 16 nodes -> two u16x8 per array
  if (tid < GP) {
    const int kb = row0 >> 5, no = row0 & 31;
    u16x8 oa0, ob0, oa1, ob1;
#pragma unroll
    for (int r = 0; r < 8; ++r) {
      oa0[r] = sTa[r][tid]; ob0[r] = sTb[r][tid];
      oa1[r] = sTa[8 + r][tid]; ob1[r] = sTb[8 + r][tid];
    }
    *reinterpret_cast<u16x8*>(&s1B[((size_t)kb * GP + tid) * 32 + no]) = oa0;
    *reinterpret_cast<u16x8*>(&s1B[((size_t)kb * GP + tid) * 32 + no + 8]) = oa1;
    *reinterpret_cast<u16x8*>(&snB[((size_t)kb * GP + tid) * 32 + no]) = ob0;
    *reinterpret_cast<u16x8*>(&snB[((size_t)kb * GP + tid) * 32 + no + 8]) = ob1;
  }
}

// ---------------- MFMA Gram: bf16 transposed GT outputs; gid==3 reduces sum(Gs0^2) in-kernel ----------------
__global__ __launch_bounds__(256) void k_gramm(const unsigned short* __restrict__ xnB,
                                               const unsigned short* __restrict__ snB,
                                               const unsigned short* __restrict__ s1B,
                                               unsigned short* __restrict__ GT0,
                                               unsigned short* __restrict__ GxsT,
                                               unsigned short* __restrict__ GsT,
                                               float* __restrict__ scalars) {
  const int gid = blockIdx.z;
  const int tp = blockIdx.x * 16;
  const int tq = blockIdx.y * 16;
  const unsigned short *PT, *QT;
  unsigned short* GTout = nullptr;
  if (gid == 0)      { PT = xnB; QT = xnB; GTout = GT0;  if (tp >= FF || tq >= FF) return; }
  else if (gid == 1) { PT = xnB; QT = snB; GTout = GxsT; if (tp >= FF) return; }
  else if (gid == 2) { PT = snB; QT = snB; GTout = GsT; }
  else               { PT = s1B; QT = s1B; }
  const int tid = threadIdx.x;
  const int lane = tid & 63;
  const int w = tid >> 6;
  const int l15 = lane & 15;
  const int kgrp = (lane >> 4) * 8;
  f32x4 acc = {0.f, 0.f, 0.f, 0.f};
#pragma unroll 8
  for (int kt = 0; kt < 32; ++kt) {
    const int kb = w * 32 + kt;
    const bf16x8 a = *reinterpret_cast<const bf16x8*>(&PT[((size_t)kb * GP + tp + l15) * 32 + kgrp]);
    const bf16x8 b = *reinterpret_cast<const bf16x8*>(&QT[((size_t)kb * GP + tq + l15) * 32 + kgrp]);
    acc = __builtin_amdgcn_mfma_f32_16x16x32_bf16(a, b, acc, 0, 0, 0);
  }
  __shared__ float red[4][16][17];
  const int crow = (lane >> 4) * 4;
#pragma unroll
  for (int r = 0; r < 4; ++r) red[w][crow + r][l15] = acc[r];
  __syncthreads();
  const int rr = tid >> 4, cc = tid & 15;
  if (gid == 3) {
    const float v = red[0][rr][cc] + red[1][rr][cc] + red[2][rr][cc] + red[3][rr][cc];
    __shared__ float redq[4];
    float q = wave_sum(v * v);
    if (lane == 0) redq[w] = q;
    __syncthreads();
    if (tid == 0) atomicAdd(&scalars[SC(5)], redq[0] + redq[1] + redq[2] + redq[3]);
  } else {
    const float vt = red[0][cc][rr] + red[1][cc][rr] + red[2][cc][rr] + red[3][cc][rr];
    GTout[(size_t)(tq + rr) * GTS + (tp + cc)] = f2bf(vt);
  }
}

// ---------------- MFMA thin GEMMs: H = A @ Gram via GT[col][k] ----------------
__global__ __launch_bounds__(256) void k_rowmm3m(const unsigned short* __restrict__ xnR,
                                                 const unsigned short* __restrict__ snR,
                                                 const unsigned short* __restrict__ GT0,
                                                 const unsigned short* __restrict__ GxsT,
                                                 const unsigned short* __restrict__ GsT,
                                                 float* __restrict__ H1,
                                                 float* __restrict__ Uu,
                                                 float* __restrict__ H2) {
  const int gid = blockIdx.y;
  const unsigned short *A, *B;
  float* C;
  int K, As, NCT;
  if (gid == 0)      { A = xnR; B = GT0;  C = H1; K = FF;  As = FF;  NCT = 8; }
  else if (gid == 1) { A = xnR; B = GxsT; C = Uu; K = FF;  As = FF;  NCT = 13; }
  else               { A = snR; B = GsT;  C = H2; K = GTS; As = GTS; NCT = 13; }
  __shared__ unsigned short sA[16][232];
  const int tid = threadIdx.x;
  const int row0 = blockIdx.x * 16;
  const int nch = K >> 3;
  for (int p = tid; p < 16 * nch; p += 256) {
    const int r = p / nch, ch = p - r * nch;
    const u16x8 v = *reinterpret_cast<const u16x8*>(&A[(size_t)(row0 + r) * As + ch * 8]);
    *reinterpret_cast<u16x8*>(&sA[r][ch * 8]) = v;
  }
  __syncthreads();
  const int lane = tid & 63;
  const int w = tid >> 6;
  const int l15 = lane & 15;
  const int kgrp = (lane >> 4) * 8;
  f32x4 acc[4];
#pragma unroll
  for (int i = 0; i < 4; ++i) acc[i] = (f32x4){0.f, 0.f, 0.f, 0.f};
#pragma unroll
  for (int i = 0; i < 4; ++i) {
    const int ct = w + i * 4;
    if (ct < NCT) {
      const size_t brow = (size_t)(ct * 16 + l15) * GTS;
      for (int k0 = 0; k0 < K; k0 += 32) {
        const bf16x8 a = *reinterpret_cast<const bf16x8*>(&sA[l15][k0 + kgrp]);
        const bf16x8 b = *reinterpret_cast<const bf16x8*>(&B[brow + k0 + kgrp]);
        acc[i] = __builtin_amdgcn_mfma_f32_16x16x32_bf16(a, b, acc[i], 0, 0, 0);
      }
    }
  }
  const int rout = row0 + (lane >> 4) * 4;
#pragma unroll
  for (int i = 0; i < 4; ++i) {
    const int ct = w + i * 4;
    if (ct < NCT) {
#pragma unroll
      for (int r = 0; r < 4; ++r)
        C[(size_t)(rout + r) * HS + ct * 16 + l15] = acc[i][r];
    }
  }
}

// ---------------- per-row sim + team embedding loss + ticket-based finalize ----------------
__global__ __launch_bounds__(256) void k_losses(const float* __restrict__ H1,
                                                const float* __restrict__ Uu,
                                                const float* __restrict__ H2,
                                                const float* __restrict__ xn,
                                                const float* __restrict__ sn,
                                                const float* __restrict__ emb,
                                                const int* __restrict__ teams,
                                                const int* __restrict__ reps,
                                                float* __restrict__ scalars,
                                                unsigned int* __restrict__ ticket,
                                                float* __restrict__ outsc) {
  __shared__ float red[4];
  const int tid = threadIdx.x;
  const int lane = tid & 63;
  const int w = tid >> 6;
  if (blockIdx.x < NN / 4) {
    const int row = blockIdx.x * 4 + w;
    float suu = 0.f, suv = 0.f, svv = 0.f;
#pragma unroll
    for (int c0 = 0; c0 < FF; c0 += 64) {
      const float xv = xn[(size_t)row * FF + c0 + lane];
      suu = fmaf(H1[(size_t)row * HS + c0 + lane], xv, suu);
    }
    for (int cb = lane; cb < CC; cb += 64) {
      const float sv = sn[(size_t)row * CC + cb];
      suv = fmaf(Uu[(size_t)row * HS + cb], sv, suv);
      svv = fmaf(H2[(size_t)row * HS + cb], sv, svv);
    }
    suu = wave_sum(suu);
    suv = wave_sum(suv);
    svv = wave_sum(svv);
    if (lane == 0) red[w] = suv / sqrtf(suu * svv);
    __syncthreads();
    if (tid == 0) atomicAdd(&scalars[SC(3)], red[0] + red[1] + red[2] + red[3]);
  } else {
    const int team = blockIdx.x - NN / 4;
    float part = 0.f;
    for (int d = tid; d < DD; d += 256) {
      float a = 0.f, b = 0.f;
#pragma unroll
      for (int m = 0; m < RR; ++m) a += emb[(size_t)reps[team * RR + m] * DD + d];
#pragma unroll
      for (int m = RR; m < TT; ++m) b += emb[(size_t)teams[team * TT + m] * DD + d];
      part += fabsf(a * (1.f / RR) - b * (1.f / (TT - RR)));
    }
    part = wave_sum(part);
    if (lane == 0) red[w] = part;
    __syncthreads();
    if (tid == 0) atomicAdd(&scalars[SC(4)], red[0] + red[1] + red[2] + red[3]);
  }
  // ticket finalize (last block computes scalars)
  if (tid == 0) {
    __threadfence();
    const unsigned int old = atomicAdd(ticket, 1u);
    if (old == (unsigned int)(NLOSS - 1)) {
      // device-scope reads of accumulated scalars
      const float trSAS = atomicAdd(&scalars[SC(0)], 0.f);
      const float adjsq = atomicAdd(&scalars[SC(1)], 0.f);
      const float ent   = atomicAdd(&scalars[SC(2)], 0.f);
      const float simS  = atomicAdd(&scalars[SC(3)], 0.f);
      const float embS  = atomicAdd(&scalars[SC(4)], 0.f);
      const float sumP2 = atomicAdd(&scalars[SC(5)], 0.f);
      const float normsq = fmaxf(sumP2 - 2.f * trSAS + adjsq, 0.f);
      const float norm = sqrtf(normsq);
      const float e1 = ent * (1.f / NN);
      const float sim = -simS * (1.f / NN);
      const float embl = embS * (1.f / LL);
      outsc[0] = norm;
      outsc[1] = e1;
      outsc[2] = sim;
      outsc[3] = 100.f * norm + 10.f * e1 + 100.f * sim + embl;
      outsc[4] = embl;
    }
  }
}

// ================= launch =================
extern "C" void kernel_launch(void* const* d_in, const int* in_sizes, int n_in,
                              void* d_out, int out_size, void* d_ws, size_t ws_size,
                              hipStream_t stream) {
  const float* x      = (const float*)d_in[0];
  const float* adj    = (const float*)d_in[1];
  const int*   teams  = (const int*)d_in[2];
  const int*   reps   = (const int*)d_in[3];
  const float* W1r    = (const float*)d_in[4];
  const float* b1     = (const float*)d_in[5];
  const float* W1root = (const float*)d_in[6];
  const float* g1     = (const float*)d_in[7];
  const float* be1    = (const float*)d_in[8];
  const float* W2r    = (const float*)d_in[9];
  const float* b2     = (const float*)d_in[10];
  const float* W2root = (const float*)d_in[11];
  const float* g2     = (const float*)d_in[12];
  const float* be2    = (const float*)d_in[13];
  const float* W3r    = (const float*)d_in[14];
  const float* b3     = (const float*)d_in[15];
  const float* W3root = (const float*)d_in[16];
  const float* g3     = (const float*)d_in[17];
  const float* be3    = (const float*)d_in[18];
  const float* Wl1    = (const float*)d_in[19];
  const float* bl1    = (const float*)d_in[20];

  char* wp = (char*)d_ws;
  auto alloc = [&](size_t bytes) { char* p = wp; wp += (bytes + 255) & ~(size_t)255; return p; };
  unsigned short* adj_t = (unsigned short*)alloc((size_t)NN * NN * 2);
  unsigned short* mB    = (unsigned short*)alloc((size_t)HH * NN * 2);
  unsigned short* x2B   = (unsigned short*)alloc((size_t)HH * NN * 2);
  unsigned short* s1B   = (unsigned short*)alloc((size_t)GP * NN * 2);
  unsigned short* snB   = (unsigned short*)alloc((size_t)GP * NN * 2);
  unsigned short* Wl1T  = (unsigned short*)alloc((size_t)GP * DP * 2);
  unsigned short* xnR   = (unsigned short*)alloc((size_t)NN * FF * 2);
  unsigned short* snR   = (unsigned short*)alloc((size_t)NN * GTS * 2);
  float* rootb  = (float*)alloc((size_t)NN * HH * 4);
  float* t      = (float*)alloc((size_t)NN * HH * 4);
  float* x1     = (float*)alloc((size_t)NN * HH * 4);
  float* x2     = (float*)alloc((size_t)NN * HH * 4);
  float* part   = (float*)alloc((size_t)KS * NN * HH * 4);
  float* t3     = (float*)alloc((size_t)NN * CC * 4);
  float* sn     = (float*)alloc((size_t)NN * CC * 4);
  float* xn     = (float*)alloc((size_t)NN * FF * 4);
  float* H1     = (float*)alloc((size_t)NN * HS * 4);
  float* Uu     = (float*)alloc((size_t)NN * HS * 4);
  float* H2     = (float*)alloc((size_t)NN * HS * 4);
  // ---- contiguous zero-init region ----
  float* scalars = (float*)alloc(256 * 4);
  float* colsum1 = (float*)alloc(512 * 4);
  float* colsq1  = (float*)alloc(512 * 4);
  float* colsum2 = (float*)alloc(512 * 4);
  float* colsq2  = (float*)alloc(512 * 4);
  float* colsum3 = (float*)alloc(4096 * 4);
  float* colsq3  = (float*)alloc(4096 * 4);
  unsigned short* GTall = (unsigned short*)alloc((size_t)3 * GP * GTS * 2);
  unsigned short* xnB   = (unsigned short*)alloc((size_t)GP * NN * 2);
  char* zero_end = wp;
  unsigned short* GT0   = GTall;
  unsigned short* GxsT  = GTall + (size_t)GP * GTS;
  unsigned short* GsT   = GTall + (size_t)2 * GP * GTS;
  unsigned int* ticket = (unsigned int*)&scalars[SC(6)];
  (void)ws_size; (void)in_sizes; (void)n_in; (void)out_size;

  float* out   = (float*)d_out;
  float* s1    = out;                          // N*C
  float* outsc = out + (size_t)NN * CC;        // 5 scalars
  float* emb   = out + (size_t)NN * CC + 5;    // N*D

  // single zero-init (scalars + ticket + BN stats + GT pads + xnB pad rows)
  hipMemsetAsync(scalars, 0, (size_t)(zero_end - (char*)scalars), stream);

  // prep: conv1 projection + xn/xnR/xnB + Wl1T
  k_prep<<<256, 256, 0, stream>>>(x, W1r, W1root, Wl1, mB, rootb, xn, xnR, xnB, Wl1T);

  // conv1 (fused: adj cvt->tiled + adj^2 + MFMA)
  k_conv1f<<<dim3(NN / 64, KS), 256, 0, stream>>>(adj, adj_t, mB, part, scalars);
  k_epi32<<<NN * HH / 256, 256, 0, stream>>>(part, b1, rootb, t, colsum1, colsq1);
  k_bnapply32<<<NN / 32, 256, 0, stream>>>(t, colsum1, colsq1, g1, be1, x1, emb, 0,
                                           (unsigned short*)nullptr);

  // conv2
  k_proj_t<<<NN / 32, 256, 0, stream>>>(x1, W2r, W2root, mB, rootb, HH);
  k_adjmm<<<dim3(NN / 64, KS), 256, 0, stream>>>(adj_t, mB, part);
  k_epi32<<<NN * HH / 256, 256, 0, stream>>>(part, b2, rootb, t, colsum2, colsq2);
  k_bnapply32<<<NN / 32, 256, 0, stream>>>(t, colsum2, colsq2, g2, be2, x2, emb, HH, x2B);

  // conv3
  k_adjmm<<<dim3(NN / 64, KS), 256, 0, stream>>>(adj_t, x2B, part);
  k_epi3<<<NN / 16, 256, 0, stream>>>(part, W3r, b3, x2, W3root, t3, colsum3, colsq3);
  k_bnapply205<<<NN, 256, 0, stream>>>(t3, colsum3, colsq3, g3, be3, emb);

  // fused head (emb -> logits -> softmax -> s1/sn/tiles/snR/entropy)
  k_head<<<NN / 16, 256, 0, stream>>>(emb, Wl1T, bl1, s1, sn, s1B, snB, snR, scalars);

  // tr(S' A S) via MFMA
  k_normmfma<<<dim3(NN / 128, KS), 512, 0, stream>>>(adj_t, s1B, s1, scalars);

  // Grams + MFMA bilinear forms + losses (+ ticket finalize)
  k_gramm<<<dim3(13, 13, 4), 256, 0, stream>>>(xnB, snB, s1B, GT0, GxsT, GsT, scalars);
  k_rowmm3m<<<dim3(NN / 16, 3), 256, 0, stream>>>(xnR, snR, GT0, GxsT, GsT, H1, Uu, H2);
  k_losses<<<NLOSS, 256, 0, stream>>>(H1, Uu, H2, xn, sn, emb, teams, reps, scalars, ticket, outsc);
}